// Round 9
// baseline (5395.097 us; speedup 1.0000x reference)
//
#include <hip/hip_runtime.h>
#include <cstddef>
#include <cstdint>

// ============================================================================
// DevignModel round 9: GEMM K-loop -> 3-deep pipeline with COUNTED vmcnt
// (T4): stage t+2 in flight while computing t; s_waitcnt vmcnt(4) + raw
// s_barrier once per K-step (never vmcnt(0) in the loop); setprio around MFMA.
// ============================================================================

typedef unsigned short u16;
typedef __attribute__((ext_vector_type(8))) short bf16x8;
typedef __attribute__((ext_vector_type(4))) float f32x4;
typedef __attribute__((ext_vector_type(4))) unsigned short u16x4;

static __device__ __forceinline__ float bf2f(u16 u) {
  union { unsigned int i; float f; } v; v.i = ((unsigned int)u) << 16; return v.f;
}
static __device__ __forceinline__ u16 f2bf(float f) {
  union { float f; unsigned int i; } v; v.f = f;
  unsigned int r = v.i + 0x7FFFu + ((v.i >> 16) & 1u);
  return (u16)(r >> 16);
}
static __device__ __forceinline__ float sigm(float x) { return 1.f / (1.f + __expf(-x)); }

// async global->LDS 16B: dest = wave-uniform base + lane*16 (HW), src per-lane
static __device__ __forceinline__ void gload16(const u16* gp, u16* lp) {
  __builtin_amdgcn_global_load_lds(
      (const __attribute__((address_space(1))) void*)gp,
      (__attribute__((address_space(3))) void*)lp, 16, 0, 0);
}

__global__ void fail_k(float* out, float code) { out[0] = code; out[1] = code; }

// ah[n][448]: [a(200)+pad24 | h(200)+pad24]; h0 = [feat | 0]
__global__ void init_ah_k(const float* __restrict__ feat, u16* __restrict__ ah, int N) {
  int total = N * 448;
  for (int i = blockIdx.x * blockDim.x + threadIdx.x; i < total; i += blockDim.x * gridDim.x) {
    int n = i / 448, j = i - n * 448;
    u16 v = 0;
    if (j >= 224 && j < 324) v = f2bf(feat[(size_t)n * 100 + (j - 224)]);
    ah[i] = v;
  }
}

__global__ void count_deg_k(const int* __restrict__ dst, const int* __restrict__ et,
                            int* __restrict__ deg_et, int N, int E) {
  for (int e = blockIdx.x * blockDim.x + threadIdx.x; e < E; e += blockDim.x * gridDim.x)
    atomicAdd(&deg_et[et[e] * N + dst[e]], 1);
}

// ---- parallel exclusive scan (3 kernels) ----
__global__ __launch_bounds__(1024) void bsum_k(const int* __restrict__ cnt,
                                               int* __restrict__ bsum, int L) {
  __shared__ int buf[1024];
  int i = blockIdx.x * 1024 + threadIdx.x;
  buf[threadIdx.x] = (i < L) ? cnt[i] : 0;
  __syncthreads();
  for (int o = 512; o > 0; o >>= 1) {
    if (threadIdx.x < o) buf[threadIdx.x] += buf[threadIdx.x + o];
    __syncthreads();
  }
  if (threadIdx.x == 0) bsum[blockIdx.x] = buf[0];
}

__global__ __launch_bounds__(1024) void scanb_k(int* __restrict__ bsum, int nb) {
  __shared__ int buf[1024];
  int v = (threadIdx.x < nb) ? bsum[threadIdx.x] : 0;
  buf[threadIdx.x] = v;
  __syncthreads();
  for (int o = 1; o < 1024; o <<= 1) {
    int t = (threadIdx.x >= o) ? buf[threadIdx.x - o] : 0;
    __syncthreads();
    buf[threadIdx.x] += t;
    __syncthreads();
  }
  if (threadIdx.x < nb) bsum[threadIdx.x] = buf[threadIdx.x] - v;
}

__global__ __launch_bounds__(1024) void scan_fin_k(const int* __restrict__ cnt,
                                                   const int* __restrict__ bsum,
                                                   int* __restrict__ off, int L) {
  __shared__ int buf[1024];
  int i = blockIdx.x * 1024 + threadIdx.x;
  int v = (i < L) ? cnt[i] : 0;
  buf[threadIdx.x] = v;
  __syncthreads();
  for (int o = 1; o < 1024; o <<= 1) {
    int t = (threadIdx.x >= o) ? buf[threadIdx.x - o] : 0;
    __syncthreads();
    buf[threadIdx.x] += t;
    __syncthreads();
  }
  if (i < L) off[i] = buf[threadIdx.x] - v + bsum[blockIdx.x];
}

__global__ void copy_int_k(const int* __restrict__ a, int* __restrict__ b, int n) {
  for (int i = blockIdx.x * blockDim.x + threadIdx.x; i < n; i += blockDim.x * gridDim.x) b[i] = a[i];
}

__global__ void fill_src_k(const int* __restrict__ src, const int* __restrict__ dst,
                           const int* __restrict__ et, int* __restrict__ cursor,
                           int* __restrict__ esrc, int N, int E) {
  for (int e = blockIdx.x * blockDim.x + threadIdx.x; e < E; e += blockDim.x * gridDim.x) {
    int p = atomicAdd(&cursor[et[e] * N + dst[e]], 1);
    esrc[p] = src[e];
  }
}

// ---- weight packs ----

__global__ void pack_wcat_k(const float* __restrict__ W, const float* __restrict__ gb,
                            u16* __restrict__ dst) {
  int total = 200 * 832;
  for (int i = blockIdx.x * blockDim.x + threadIdx.x; i < total; i += blockDim.x * gridDim.x) {
    int o = i / 832, kp = i - o * 832;
    float v = 0.f;
    if (kp < 800) { int k = kp / 200, kk = kp - k * 200; v = W[((size_t)k * 200 + o) * 200 + kk]; }
    else if (kp < 804) v = gb[(kp - 800) * 200 + o];
    dst[i] = f2bf(v);
  }
}

// Wall[800][448]: rows 0-399 = [Wih_rz | 0 | Whh_rz | 0];
// rows 400-599 = [Wih_n | 0]; rows 600-799 = [0 | Whh_n]
__global__ void pack_wall_k(const float* __restrict__ Wih, const float* __restrict__ Whh,
                            u16* __restrict__ dst) {
  int total = 800 * 448;
  for (int i = blockIdx.x * blockDim.x + threadIdx.x; i < total; i += blockDim.x * gridDim.x) {
    int j = i / 448, kp = i - j * 448;
    float v = 0.f;
    if (j < 400) {
      if (kp < 200) v = Wih[(size_t)j * 200 + kp];
      else if (kp >= 224 && kp < 424) v = Whh[(size_t)j * 200 + (kp - 224)];
    } else if (j < 600) {
      if (kp < 200) v = Wih[(size_t)j * 200 + kp];
    } else {
      if (kp >= 224 && kp < 424) v = Whh[(size_t)(j - 200) * 200 + (kp - 224)];
    }
    dst[i] = f2bf(v);
  }
}

__global__ void ball_k(const float* __restrict__ bih, const float* __restrict__ bhh,
                       float* __restrict__ ball) {
  int j = blockIdx.x * blockDim.x + threadIdx.x;
  if (j < 800) ball[j] = (j < 400) ? bih[j] + bhh[j] : (j < 600 ? bih[j] : bhh[j - 200]);
}

__global__ void pack_lin_b(const float* __restrict__ src, u16* __restrict__ dst,
                           int Nn, int K, int Kp) {
  int total = Nn * Kp;
  for (int i = blockIdx.x * blockDim.x + threadIdx.x; i < total; i += blockDim.x * gridDim.x) {
    int o = i / Kp, kp = i - o * Kp;
    dst[i] = (kp < K) ? f2bf(src[(size_t)o * K + kp]) : (u16)0;
  }
}

__global__ void pack_w1c_k(const float* __restrict__ src, u16* __restrict__ dst) {
  int total = 200 * 1056;
  for (int i = blockIdx.x * blockDim.x + threadIdx.x; i < total; i += blockDim.x * gridDim.x) {
    int o = i / 1056, r = i - o * 1056;
    int t = r / 352, kp = r - t * 352;
    dst[i] = (kp < 200) ? f2bf(src[((size_t)o * 200 + kp) * 3 + t]) : (u16)0;
  }
}

__global__ void pack_wc1_b(const float* __restrict__ src, u16* __restrict__ dst) {
  int total = 300 * 1056;
  for (int i = blockIdx.x * blockDim.x + threadIdx.x; i < total; i += blockDim.x * gridDim.x) {
    int o = i / 1056, r = i - o * 1056;
    int t = r / 352, kp = r - t * 352;
    int ci = (kp < 224) ? (kp < 200 ? kp : -1) : ((kp - 224) < 100 ? 200 + (kp - 224) : -1);
    dst[i] = (ci >= 0) ? f2bf(src[((size_t)o * 300 + ci) * 3 + t]) : (u16)0;
  }
}

// aggregation: wave per (node, etype); scat[n-n0][832] = [s0|s1|s2|s3|deg0..3|0...]
__global__ void agg_k(const int* __restrict__ off_et, const int* __restrict__ deg_et,
                      const int* __restrict__ esrc, const u16* __restrict__ ah,
                      u16* __restrict__ scat, int n0, int Nc, int N) {
  int gtid = blockIdx.x * blockDim.x + threadIdx.x;
  int wid = gtid >> 6, lane = threadIdx.x & 63;
  int nw = (blockDim.x * gridDim.x) >> 6;
  int total = Nc * 4;
  for (int u = wid; u < total; u += nw) {
    int n = n0 + (u >> 2), k = u & 3;
    u16* srow = scat + (size_t)(u >> 2) * 832;
    if (lane < 50) {
      int rs = off_et[(size_t)k * N + n], d = deg_et[(size_t)k * N + n];
      float a0 = 0.f, a1 = 0.f, a2 = 0.f, a3 = 0.f;
      for (int i = 0; i < d; ++i) {
        const u16* hr = ah + (size_t)esrc[rs + i] * 448 + 224 + lane * 4;
        u16x4 v = *reinterpret_cast<const u16x4*>(hr);
        a0 += bf2f(v[0]); a1 += bf2f(v[1]); a2 += bf2f(v[2]); a3 += bf2f(v[3]);
      }
      u16x4 r;
#pragma unroll
      for (int kk = 0; kk < 4; ++kk) { }
      r[0] = f2bf(a0); r[1] = f2bf(a1); r[2] = f2bf(a2); r[3] = f2bf(a3);
      *reinterpret_cast<u16x4*>(srow + k * 200 + lane * 4) = r;
    } else if (k == 0 && lane == 50) {
      u16x4 r;
#pragma unroll
      for (int kk = 0; kk < 4; ++kk) r[kk] = f2bf((float)deg_et[(size_t)kk * N + n]);
      *reinterpret_cast<u16x4*>(srow + 800) = r;
    } else if (k == 1 && lane >= 51 && lane <= 57) {
      u16x4 z; z[0] = z[1] = z[2] = z[3] = 0;
      *reinterpret_cast<u16x4*>(srow + 804 + (lane - 51) * 4) = z;
    }
  }
}

// ---------------- bf16 MFMA GEMM, 128x128 tile, 3-deep counted-vmcnt pipeline ------
// LDS tile (per buffer): 16B slot s = r*4 + (g ^ ((r>>1)&3)) holds row r, k-chunk g.
__global__ __launch_bounds__(256) void gemm_mfma(
    const u16* __restrict__ A, int lda,
    const u16* __restrict__ B, int ldb,
    u16* __restrict__ Cb, int ldcb, int npad,
    int M, int Nn, int K, const float* __restrict__ bias, int gyr) {
  const int gx = gridDim.x;
  int lin = blockIdx.y * gx + blockIdx.x;
  int k8 = lin & 7, j = lin >> 3;
  int band = gridDim.y >> 3;
  int yy = j / gx, xx = j - yy * gx;
  int by = k8 * band + yy;
  if (by >= gyr) return;
  const int m0 = by * 128, n0 = xx * 128;

  __shared__ __align__(16) u16 As[3 * 128 * 32];
  __shared__ __align__(16) u16 Bs[3 * 128 * 32];
  const int tid = threadIdx.x;
  const int lane = tid & 63;
  const int w = tid >> 6;
  const int wr = w >> 1, wc = w & 1;
  const int fr = lane & 15;
  const int g = lane >> 4;

  // staging geometry (per buffer): wave w writes slots [w*64, w*64+64) and +256
  const int gg = (lane & 3) ^ ((lane >> 3) & 3);  // swizzled k-chunk for this lane
  const int r0 = tid >> 2;
  const int r1 = r0 + 64;
  int ra0 = m0 + r0; if (ra0 >= M) ra0 = M - 1;
  int ra1 = m0 + r1; if (ra1 >= M) ra1 = M - 1;
  int rb0 = n0 + r0; if (rb0 >= Nn) rb0 = Nn - 1;
  int rb1 = n0 + r1; if (rb1 >= Nn) rb1 = Nn - 1;
  const u16* pa0 = A + (size_t)ra0 * lda + gg * 8;
  const u16* pa1 = A + (size_t)ra1 * lda + gg * 8;
  const u16* pb0 = B + (size_t)rb0 * ldb + gg * 8;
  const u16* pb1 = B + (size_t)rb1 * ldb + gg * 8;
  const int sl0 = (w * 64) * 8;
  const int sl1 = (256 + w * 64) * 8;

  // fragment read swizzle (matches store): slot = row*4 + (g ^ ((row>>1)&3))
  const int gxr = g ^ ((fr >> 1) & 3);

  f32x4 acc[4][4] = {};
  const int nt = K >> 5;
  const int BUF = 4096;  // u16 per buffer (128 rows x 32 k)

  // prologue: stage tiles 0 and 1 (4 loads each; up to 8 in flight)
  gload16(pa0, &As[sl0]); gload16(pa1, &As[sl1]);
  gload16(pb0, &Bs[sl0]); gload16(pb1, &Bs[sl1]);
  pa0 += 32; pa1 += 32; pb0 += 32; pb1 += 32;
  if (nt > 1) {
    gload16(pa0, &As[BUF + sl0]); gload16(pa1, &As[BUF + sl1]);
    gload16(pb0, &Bs[BUF + sl0]); gload16(pb1, &Bs[BUF + sl1]);
    pa0 += 32; pa1 += 32; pb0 += 32; pb1 += 32;
  }

  for (int t = 0; t < nt; ++t) {
    // wait ONLY the oldest tile's 4 loads; tile t+1 stays in flight
    if (t + 1 < nt) asm volatile("s_waitcnt vmcnt(4)" ::: "memory");
    else            asm volatile("s_waitcnt vmcnt(0)" ::: "memory");
    __builtin_amdgcn_s_barrier();
    if (t + 2 < nt) {
      int nb = ((t + 2) % 3) * BUF;
      gload16(pa0, &As[nb + sl0]); gload16(pa1, &As[nb + sl1]);
      gload16(pb0, &Bs[nb + sl0]); gload16(pb1, &Bs[nb + sl1]);
      pa0 += 32; pa1 += 32; pb0 += 32; pb1 += 32;
    }
    int cb = (t % 3) * BUF;
    bf16x8 af[4], bfv[4];
#pragma unroll
    for (int i = 0; i < 4; ++i) {
      int row = wr * 64 + i * 16 + fr;
      af[i] = *reinterpret_cast<const bf16x8*>(&As[cb + (row * 4 + gxr) * 8]);
    }
#pragma unroll
    for (int jj = 0; jj < 4; ++jj) {
      int row = wc * 64 + jj * 16 + fr;
      bfv[jj] = *reinterpret_cast<const bf16x8*>(&Bs[cb + (row * 4 + gxr) * 8]);
    }
    __builtin_amdgcn_s_setprio(1);
#pragma unroll
    for (int i = 0; i < 4; ++i)
#pragma unroll
      for (int jj = 0; jj < 4; ++jj)
        acc[i][jj] = __builtin_amdgcn_mfma_f32_16x16x32_bf16(af[i], bfv[jj], acc[i][jj], 0, 0, 0);
    __builtin_amdgcn_s_setprio(0);
  }

  const int er = (lane >> 4) * 4;
  const int ec = lane & 15;
#pragma unroll
  for (int i = 0; i < 4; ++i) {
#pragma unroll
    for (int jj = 0; jj < 4; ++jj) {
      int n = n0 + wc * 64 + jj * 16 + ec;
#pragma unroll
      for (int r = 0; r < 4; ++r) {
        int m = m0 + wr * 64 + i * 16 + er + r;
        if (m >= M) continue;
        if (n < Nn) {
          float v = acc[i][jj][r];
          if (bias) v += bias[n];
          Cb[(size_t)m * ldcb + n] = f2bf(v);
        } else if (n < npad) {
          Cb[(size_t)m * ldcb + n] = (u16)0;
        }
      }
    }
  }
}

// GRU finisher: gates[n][832] = [r|z|inn|hn]; h := (1-z)*tanh(inn + r*hn) + z*h
__global__ void gru_fin_k(const u16* __restrict__ g, u16* __restrict__ ah, int c0, int Nc) {
  int total = Nc * 200;
  for (int i = blockIdx.x * blockDim.x + threadIdx.x; i < total; i += blockDim.x * gridDim.x) {
    int n = i / 200, o = i - n * 200;
    const u16* gr = g + (size_t)n * 832;
    float r = sigm(bf2f(gr[o]));
    float z = sigm(bf2f(gr[200 + o]));
    float x = bf2f(gr[400 + o]) + r * bf2f(gr[600 + o]);
    float e2 = __expf(2.f * x);
    float nn = (e2 - 1.f) / (e2 + 1.f);
    size_t hi = (size_t)(c0 + n) * 448 + 224 + o;
    float hold = bf2f(ah[hi]);
    ah[hi] = f2bf((1.f - z) * nn + z * hold);
  }
}

// cmat[n][352] = [h(224 incl zero pads) | feat(100) | 0(28)]
__global__ void cmat_k(const u16* __restrict__ ah, const float* __restrict__ feat,
                       u16* __restrict__ c, int N) {
  int total = N * 352;
  for (int i = blockIdx.x * blockDim.x + threadIdx.x; i < total; i += blockDim.x * gridDim.x) {
    int n = i / 352, j = i - n * 352;
    u16 v;
    if (j < 224) v = ah[(size_t)n * 448 + 224 + j];
    else { int f = j - 224; v = (f < 100) ? f2bf(feat[(size_t)n * 100 + f]) : (u16)0; }
    c[i] = v;
  }
}

// per-channel stats: fixed channel per thread, coalesced
__global__ __launch_bounds__(1024) void bn_stats2_k(const u16* __restrict__ X, int L, int C,
                                                    float* __restrict__ stats) {
  const int Q = 1024 / C;
  const int T = Q * C;
  const int tid = threadIdx.x;
  float s = 0.f, q = 0.f;
  int c = 0;
  if (tid < T) {
    int qi = tid / C; c = tid - qi * C;
    for (size_t r = (size_t)blockIdx.x * Q + qi; r < (size_t)L; r += (size_t)gridDim.x * Q) {
      float v = bf2f(X[r * C + c]);
      s += v; q += v * v;
    }
  }
  __shared__ float sb[304], qb[304];
  for (int cc = tid; cc < C; cc += 1024) { sb[cc] = 0.f; qb[cc] = 0.f; }
  __syncthreads();
  if (tid < T) { atomicAdd(&sb[c], s); atomicAdd(&qb[c], q); }
  __syncthreads();
  for (int cc = tid; cc < C; cc += 1024) {
    atomicAdd(&stats[cc], sb[cc]);
    atomicAdd(&stats[C + cc], qb[cc]);
  }
}

__global__ void bn_fin_k(const float* __restrict__ stats, const float* __restrict__ g,
                         const float* __restrict__ b, int C, float Linv,
                         float* __restrict__ scsh) {
  int c = blockIdx.x * blockDim.x + threadIdx.x;
  if (c < C) {
    float mean = stats[c] * Linv;
    float var = stats[C + c] * Linv - mean * mean;
    float sc = g[c] * rsqrtf(var + 1e-5f);
    scsh[c] = sc;
    scsh[C + c] = b[c] - mean * sc;
  }
}

__global__ void pool_bf_k(const u16* __restrict__ X, int C, const float* __restrict__ scsh,
                          int kw, int stride, u16* __restrict__ Y, int Cpad, int Lout) {
  int total = Lout * Cpad;
  for (int i = blockIdx.x * blockDim.x + threadIdx.x; i < total; i += blockDim.x * gridDim.x) {
    int lp = i / Cpad, c = i - lp * Cpad;
    if (c >= C) { Y[i] = (u16)0; continue; }
    float sc = scsh[c], sh = scsh[C + c];
    int l0 = lp * stride;
    float m = 0.f;
    for (int wq = 0; wq < kw; ++wq)
      m = fmaxf(m, fmaf(bf2f(X[(size_t)(l0 + wq) * C + c]), sc, sh));
    Y[i] = f2bf(m);
  }
}

__global__ void pool_f32_k(const u16* __restrict__ X, int C, const float* __restrict__ scsh,
                           int kw, int stride, float* __restrict__ Y, int Lout) {
  int total = Lout * C;
  for (int i = blockIdx.x * blockDim.x + threadIdx.x; i < total; i += blockDim.x * gridDim.x) {
    int lp = i / C, c = i - lp * C;
    float sc = scsh[c], sh = scsh[C + c];
    int l0 = lp * stride;
    float m = 0.f;
    for (int wq = 0; wq < kw; ++wq)
      m = fmaxf(m, fmaf(bf2f(X[(size_t)(l0 + wq) * C + c]), sc, sh));
    Y[i] = m;
  }
}

__global__ __launch_bounds__(256) void final_dot_k(
    const float* __restrict__ Y2, const float* __restrict__ Z2,
    const float* __restrict__ wy, const float* __restrict__ by,
    const float* __restrict__ wz, const float* __restrict__ bz,
    float* __restrict__ acc, int L) {
  float s0 = 0.f, s1 = 0.f;
  for (int lp = blockIdx.x * blockDim.x + threadIdx.x; lp < L; lp += blockDim.x * gridDim.x) {
    const float* y = Y2 + (size_t)lp * 200;
    const float* z = Z2 + (size_t)lp * 300;
    float d0 = 0.f, d1 = 0.f;
    for (int k = 0; k < 200; ++k) { float v = y[k]; d0 += v * wy[k]; d1 += v * wy[200 + k]; }
    float e0 = 0.f, e1 = 0.f;
    for (int k = 0; k < 300; ++k) { float v = z[k]; e0 += v * wz[k]; e1 += v * wz[300 + k]; }
    s0 += (d0 + by[0]) * (e0 + bz[0]);
    s1 += (d1 + by[1]) * (e1 + bz[1]);
  }
  __shared__ float r0[256], r1[256];
  r0[threadIdx.x] = s0; r1[threadIdx.x] = s1;
  __syncthreads();
  for (int off = 128; off > 0; off >>= 1) {
    if (threadIdx.x < off) { r0[threadIdx.x] += r0[threadIdx.x + off]; r1[threadIdx.x] += r1[threadIdx.x + off]; }
    __syncthreads();
  }
  if (threadIdx.x == 0) { atomicAdd(&acc[0], r0[0]); atomicAdd(&acc[1], r1[0]); }
}

__global__ void final_out_k(const float* __restrict__ acc, float invL, float* __restrict__ out) {
  int j = threadIdx.x;
  if (j < 2) out[j] = 1.f / (1.f + expf(-acc[j] * invL));
}

// ---------------- host ----------------

static inline void gemmL(hipStream_t st, const u16* A, int lda, const u16* B, int ldb,
                         u16* Cb, int ldcb, int npad, int M, int Nn, int K, const float* bias) {
  int ncols = (npad > Nn) ? npad : Nn;
  int gx = (ncols + 127) / 128;
  int gy = (M + 127) / 128;
  int gyp = ((gy + 7) / 8) * 8;
  dim3 g(gx, gyp);
  gemm_mfma<<<g, 256, 0, st>>>(A, lda, B, ldb, Cb, ldcb, npad, M, Nn, K, bias, gy);
}

extern "C" void kernel_launch(void* const* d_in, const int* in_sizes, int n_in,
                              void* d_out, int out_size, void* d_ws, size_t ws_size,
                              hipStream_t stream) {
  (void)n_in; (void)out_size;
  const float* feat    = (const float*)d_in[0];
  const int*   eix     = (const int*)d_in[1];
  const int*   etyp    = (const int*)d_in[2];
  const float* ggnnW   = (const float*)d_in[3];
  const float* ggnnB   = (const float*)d_in[4];
  const float* Wih     = (const float*)d_in[5];
  const float* Whh     = (const float*)d_in[6];
  const float* bih     = (const float*)d_in[7];
  const float* bhh     = (const float*)d_in[8];
  const float* conv1w  = (const float*)d_in[9];
  const float* conv2w  = (const float*)d_in[11];
  const float* convc1w = (const float*)d_in[13];
  const float* convc2w = (const float*)d_in[15];
  const float* bnyg    = (const float*)d_in[17];
  const float* bnyb    = (const float*)d_in[18];
  const float* bncg    = (const float*)d_in[19];
  const float* bncb    = (const float*)d_in[20];
  const float* mlpyw   = (const float*)d_in[21];
  const float* mlpyb   = (const float*)d_in[22];
  const float* mlpzw   = (const float*)d_in[23];
  const float* mlpzb   = (const float*)d_in[24];

  const int N = in_sizes[0] / 100;
  const int E = in_sizes[2];
  const int* src = eix;
  const int* dst = eix + E;

  char* base = (char*)d_ws;
  const size_t AH_B = (size_t)N * 448 * 2;
  const int CH = (N + 1) / 2;
  const size_t SCR_B = (size_t)CH * 1664;   // scat / gates: CH x 832 u16

  u16* ah = (u16*)base;
  char* R1 = base + AH_B;
  char* WREG = R1 + SCR_B;

  u16* Wcat = (u16*)WREG;          // 200*832
  u16* Wall = Wcat + 166400;       // 800*448
  u16* w1c  = Wall + 358400;       // 200*1056
  u16* c2b  = w1c + 211200;        // 200*224
  u16* wc1  = c2b + 44800;         // 300*1056
  u16* wc2  = wc1 + 316800;        // 300*320
  float* ball  = (float*)(wc2 + 96000);  // 800
  float* stats = ball + 832;             // 600
  float* scsh  = stats + 600;            // 600
  float* acc2  = scsh + 600;             // 2 (+pad)
  int* deg_et = (int*)(acc2 + 8);
  int* off_et = deg_et + 4 * (size_t)N;
  int* cursor = off_et + 4 * (size_t)N;
  int* esrc   = cursor + 4 * (size_t)N;
  int* bsum   = esrc + E;
  const int L4 = 4 * N;
  const int NB = (L4 + 1023) / 1024;
  size_t need = (size_t)((char*)(bsum + NB) - base);

  if (ws_size < need) {
    fail_k<<<1, 64, 0, stream>>>((float*)d_out, -(float)(ws_size >> 20));
    return;
  }

  // ---- CSR build + packs ----
  hipMemsetAsync(deg_et, 0, sizeof(int) * 4 * (size_t)N, stream);
  init_ah_k<<<4096, 256, 0, stream>>>(feat, ah, N);
  count_deg_k<<<2048, 256, 0, stream>>>(dst, etyp, deg_et, N, E);
  bsum_k<<<NB, 1024, 0, stream>>>(deg_et, bsum, L4);
  scanb_k<<<1, 1024, 0, stream>>>(bsum, NB);
  scan_fin_k<<<NB, 1024, 0, stream>>>(deg_et, bsum, off_et, L4);
  copy_int_k<<<512, 256, 0, stream>>>(off_et, cursor, L4);
  fill_src_k<<<2048, 256, 0, stream>>>(src, dst, etyp, cursor, esrc, N, E);
  pack_wcat_k<<<651, 256, 0, stream>>>(ggnnW, ggnnB, Wcat);
  pack_wall_k<<<1400, 256, 0, stream>>>(Wih, Whh, Wall);
  ball_k<<<4, 256, 0, stream>>>(bih, bhh, ball);
  pack_w1c_k<<<825, 256, 0, stream>>>(conv1w, w1c);
  pack_lin_b<<<175, 256, 0, stream>>>(conv2w, c2b, 200, 200, 224);
  pack_wc1_b<<<1238, 256, 0, stream>>>(convc1w, wc1);
  pack_lin_b<<<375, 256, 0, stream>>>(convc2w, wc2, 300, 300, 320);

  // ---- GGNN 8 steps ----
  u16* scat = (u16*)R1;    // CH x 832 (aliases gates)

  for (int step = 0; step < 8; ++step) {
    for (int c0 = 0; c0 < N; c0 += CH) {
      int Nc = (c0 + CH <= N) ? CH : (N - c0);
      agg_k<<<4096, 256, 0, stream>>>(off_et, deg_et, esrc, ah, scat, c0, Nc, N);
      gemmL(stream, scat, 832, Wcat, 832, ah + (size_t)c0 * 448, 448, 224,
            Nc, 200, 832, nullptr);
    }
    for (int c0 = 0; c0 < N; c0 += CH) {
      int Nc = (c0 + CH <= N) ? CH : (N - c0);
      const u16* ahc = ah + (size_t)c0 * 448;
      gemmL(stream, ahc, 448, Wall, 448, scat, 832, 800, Nc, 800, 448, ball);
      gru_fin_k<<<2048, 256, 0, stream>>>(scat, ah, c0, Nc);
    }
  }

  // ---- conv paths ----
  const int L1 = N - 2;
  const int L2 = (L1 - 3) / 2 + 1;
  const int L3 = (L2 - 2) / 2 + 1;

  u16* cmat = (u16*)R1;                                              // N*352
  u16* out1 = (u16*)base;                                            // L1*200
  size_t y1_off = (((size_t)L1 * 400) + 255) & ~(size_t)255;
  u16* y1 = (u16*)(base + y1_off);                                   // L2*224
  size_t o2_off = y1_off + ((((size_t)L2 * 448) + 255) & ~(size_t)255);
  u16* out2 = (u16*)(base + o2_off);                                 // L2*200
  float* Y2f = (float*)base;                                         // L3*200 f32
  size_t oc1_off = (((size_t)L3 * 800) + 255) & ~(size_t)255;
  u16* outc1 = (u16*)(base + oc1_off);                               // L1*300
  u16* z1 = (u16*)R1;                                                // L2*320
  size_t oc2_off = (((size_t)L2 * 640) + 255) & ~(size_t)255;
  u16* outc2 = (u16*)(R1 + oc2_off);                                 // L2*300
  float* Z2f = (float*)(base + oc1_off);                             // L3*300 f32

  cmat_k<<<4096, 256, 0, stream>>>(ah, feat, cmat, N);

  // Y path
  gemmL(stream, cmat, 352, w1c, 1056, out1, 200, 200, L1, 200, 1056, nullptr);
  hipMemsetAsync(stats, 0, sizeof(float) * 400, stream);
  bn_stats2_k<<<512, 1024, 0, stream>>>(out1, L1, 200, stats);
  bn_fin_k<<<2, 256, 0, stream>>>(stats, bnyg, bnyb, 200, 1.f / (float)L1, scsh);
  pool_bf_k<<<2048, 256, 0, stream>>>(out1, 200, scsh, 3, 2, y1, 224, L2);

  gemmL(stream, y1, 224, c2b, 224, out2, 200, 200, L2, 200, 224, nullptr);
  hipMemsetAsync(stats, 0, sizeof(float) * 400, stream);
  bn_stats2_k<<<512, 1024, 0, stream>>>(out2, L2, 200, stats);
  bn_fin_k<<<2, 256, 0, stream>>>(stats, bnyg, bnyb, 200, 1.f / (float)L2, scsh);
  pool_f32_k<<<2048, 256, 0, stream>>>(out2, 200, scsh, 2, 2, Y2f, L3);

  // Z path
  gemmL(stream, cmat, 352, wc1, 1056, outc1, 300, 300, L1, 300, 1056, nullptr);
  hipMemsetAsync(stats, 0, sizeof(float) * 600, stream);
  bn_stats2_k<<<512, 1024, 0, stream>>>(outc1, L1, 300, stats);
  bn_fin_k<<<2, 256, 0, stream>>>(stats, bncg, bncb, 300, 1.f / (float)L1, scsh);
  pool_bf_k<<<2048, 256, 0, stream>>>(outc1, 300, scsh, 3, 2, z1, 320, L2);

  gemmL(stream, z1, 320, wc2, 320, outc2, 300, 300, L2, 300, 320, nullptr);
  hipMemsetAsync(stats, 0, sizeof(float) * 600, stream);
  bn_stats2_k<<<512, 1024, 0, stream>>>(outc2, L2, 300, stats);
  bn_fin_k<<<2, 256, 0, stream>>>(stats, bncg, bncb, 300, 1.f / (float)L2, scsh);
  pool_f32_k<<<2048, 256, 0, stream>>>(outc2, 300, scsh, 2, 2, Z2f, L3);

  // ---- final MLP product + mean + sigmoid ----
  hipMemsetAsync(acc2, 0, sizeof(float) * 2, stream);
  final_dot_k<<<256, 256, 0, stream>>>(Y2f, Z2f, mlpyw, mlpyb, mlpzw, mlpzb, acc2, L3);
  final_out_k<<<1, 64, 0, stream>>>(acc2, 1.f / (float)L3, (float*)d_out);
}

// Round 10
// 5006.901 us; speedup vs baseline: 1.0775x; 1.0775x over previous
//
#include <hip/hip_runtime.h>
#include <cstddef>
#include <cstdint>

// ============================================================================
// DevignModel round 10: testing the VMEM-request-throughput model.
//  - GEMM: BM=256,BN=128, 8 waves/512 thr -> flops per 16B-request 1024->1365
//    (3-deep counted-vmcnt pipeline and verified swizzle kept from r9)
//  - agg: u16x8 gathers (25 requests/edge instead of 50)
// ============================================================================

typedef unsigned short u16;
typedef __attribute__((ext_vector_type(8))) short bf16x8;
typedef __attribute__((ext_vector_type(4))) float f32x4;
typedef __attribute__((ext_vector_type(4))) unsigned short u16x4;
typedef __attribute__((ext_vector_type(8))) unsigned short u16x8;

static __device__ __forceinline__ float bf2f(u16 u) {
  union { unsigned int i; float f; } v; v.i = ((unsigned int)u) << 16; return v.f;
}
static __device__ __forceinline__ u16 f2bf(float f) {
  union { float f; unsigned int i; } v; v.f = f;
  unsigned int r = v.i + 0x7FFFu + ((v.i >> 16) & 1u);
  return (u16)(r >> 16);
}
static __device__ __forceinline__ float sigm(float x) { return 1.f / (1.f + __expf(-x)); }

static __device__ __forceinline__ void gload16(const u16* gp, u16* lp) {
  __builtin_amdgcn_global_load_lds(
      (const __attribute__((address_space(1))) void*)gp,
      (__attribute__((address_space(3))) void*)lp, 16, 0, 0);
}

__global__ void fail_k(float* out, float code) { out[0] = code; out[1] = code; }

// ah[n][448]: [a(200)+pad24 | h(200)+pad24]; h0 = [feat | 0]
__global__ void init_ah_k(const float* __restrict__ feat, u16* __restrict__ ah, int N) {
  int total = N * 448;
  for (int i = blockIdx.x * blockDim.x + threadIdx.x; i < total; i += blockDim.x * gridDim.x) {
    int n = i / 448, j = i - n * 448;
    u16 v = 0;
    if (j >= 224 && j < 324) v = f2bf(feat[(size_t)n * 100 + (j - 224)]);
    ah[i] = v;
  }
}

__global__ void count_deg_k(const int* __restrict__ dst, const int* __restrict__ et,
                            int* __restrict__ deg_et, int N, int E) {
  for (int e = blockIdx.x * blockDim.x + threadIdx.x; e < E; e += blockDim.x * gridDim.x)
    atomicAdd(&deg_et[et[e] * N + dst[e]], 1);
}

// ---- parallel exclusive scan (3 kernels) ----
__global__ __launch_bounds__(1024) void bsum_k(const int* __restrict__ cnt,
                                               int* __restrict__ bsum, int L) {
  __shared__ int buf[1024];
  int i = blockIdx.x * 1024 + threadIdx.x;
  buf[threadIdx.x] = (i < L) ? cnt[i] : 0;
  __syncthreads();
  for (int o = 512; o > 0; o >>= 1) {
    if (threadIdx.x < o) buf[threadIdx.x] += buf[threadIdx.x + o];
    __syncthreads();
  }
  if (threadIdx.x == 0) bsum[blockIdx.x] = buf[0];
}

__global__ __launch_bounds__(1024) void scanb_k(int* __restrict__ bsum, int nb) {
  __shared__ int buf[1024];
  int v = (threadIdx.x < nb) ? bsum[threadIdx.x] : 0;
  buf[threadIdx.x] = v;
  __syncthreads();
  for (int o = 1; o < 1024; o <<= 1) {
    int t = (threadIdx.x >= o) ? buf[threadIdx.x - o] : 0;
    __syncthreads();
    buf[threadIdx.x] += t;
    __syncthreads();
  }
  if (threadIdx.x < nb) bsum[threadIdx.x] = buf[threadIdx.x] - v;
}

__global__ __launch_bounds__(1024) void scan_fin_k(const int* __restrict__ cnt,
                                                   const int* __restrict__ bsum,
                                                   int* __restrict__ off, int L) {
  __shared__ int buf[1024];
  int i = blockIdx.x * 1024 + threadIdx.x;
  int v = (i < L) ? cnt[i] : 0;
  buf[threadIdx.x] = v;
  __syncthreads();
  for (int o = 1; o < 1024; o <<= 1) {
    int t = (threadIdx.x >= o) ? buf[threadIdx.x - o] : 0;
    __syncthreads();
    buf[threadIdx.x] += t;
    __syncthreads();
  }
  if (i < L) off[i] = buf[threadIdx.x] - v + bsum[blockIdx.x];
}

__global__ void copy_int_k(const int* __restrict__ a, int* __restrict__ b, int n) {
  for (int i = blockIdx.x * blockDim.x + threadIdx.x; i < n; i += blockDim.x * gridDim.x) b[i] = a[i];
}

__global__ void fill_src_k(const int* __restrict__ src, const int* __restrict__ dst,
                           const int* __restrict__ et, int* __restrict__ cursor,
                           int* __restrict__ esrc, int N, int E) {
  for (int e = blockIdx.x * blockDim.x + threadIdx.x; e < E; e += blockDim.x * gridDim.x) {
    int p = atomicAdd(&cursor[et[e] * N + dst[e]], 1);
    esrc[p] = src[e];
  }
}

// ---- weight packs ----

__global__ void pack_wcat_k(const float* __restrict__ W, const float* __restrict__ gb,
                            u16* __restrict__ dst) {
  int total = 200 * 832;
  for (int i = blockIdx.x * blockDim.x + threadIdx.x; i < total; i += blockDim.x * gridDim.x) {
    int o = i / 832, kp = i - o * 832;
    float v = 0.f;
    if (kp < 800) { int k = kp / 200, kk = kp - k * 200; v = W[((size_t)k * 200 + o) * 200 + kk]; }
    else if (kp < 804) v = gb[(kp - 800) * 200 + o];
    dst[i] = f2bf(v);
  }
}

// Wall[800][448]
__global__ void pack_wall_k(const float* __restrict__ Wih, const float* __restrict__ Whh,
                            u16* __restrict__ dst) {
  int total = 800 * 448;
  for (int i = blockIdx.x * blockDim.x + threadIdx.x; i < total; i += blockDim.x * gridDim.x) {
    int j = i / 448, kp = i - j * 448;
    float v = 0.f;
    if (j < 400) {
      if (kp < 200) v = Wih[(size_t)j * 200 + kp];
      else if (kp >= 224 && kp < 424) v = Whh[(size_t)j * 200 + (kp - 224)];
    } else if (j < 600) {
      if (kp < 200) v = Wih[(size_t)j * 200 + kp];
    } else {
      if (kp >= 224 && kp < 424) v = Whh[(size_t)(j - 200) * 200 + (kp - 224)];
    }
    dst[i] = f2bf(v);
  }
}

__global__ void ball_k(const float* __restrict__ bih, const float* __restrict__ bhh,
                       float* __restrict__ ball) {
  int j = blockIdx.x * blockDim.x + threadIdx.x;
  if (j < 800) ball[j] = (j < 400) ? bih[j] + bhh[j] : (j < 600 ? bih[j] : bhh[j - 200]);
}

__global__ void pack_lin_b(const float* __restrict__ src, u16* __restrict__ dst,
                           int Nn, int K, int Kp) {
  int total = Nn * Kp;
  for (int i = blockIdx.x * blockDim.x + threadIdx.x; i < total; i += blockDim.x * gridDim.x) {
    int o = i / Kp, kp = i - o * Kp;
    dst[i] = (kp < K) ? f2bf(src[(size_t)o * K + kp]) : (u16)0;
  }
}

__global__ void pack_w1c_k(const float* __restrict__ src, u16* __restrict__ dst) {
  int total = 200 * 1056;
  for (int i = blockIdx.x * blockDim.x + threadIdx.x; i < total; i += blockDim.x * gridDim.x) {
    int o = i / 1056, r = i - o * 1056;
    int t = r / 352, kp = r - t * 352;
    dst[i] = (kp < 200) ? f2bf(src[((size_t)o * 200 + kp) * 3 + t]) : (u16)0;
  }
}

__global__ void pack_wc1_b(const float* __restrict__ src, u16* __restrict__ dst) {
  int total = 300 * 1056;
  for (int i = blockIdx.x * blockDim.x + threadIdx.x; i < total; i += blockDim.x * gridDim.x) {
    int o = i / 1056, r = i - o * 1056;
    int t = r / 352, kp = r - t * 352;
    int ci = (kp < 224) ? (kp < 200 ? kp : -1) : ((kp - 224) < 100 ? 200 + (kp - 224) : -1);
    dst[i] = (ci >= 0) ? f2bf(src[((size_t)o * 300 + ci) * 3 + t]) : (u16)0;
  }
}

// aggregation: wave per (node, etype); 16B gathers (25 lane-requests/edge)
__global__ void agg_k(const int* __restrict__ off_et, const int* __restrict__ deg_et,
                      const int* __restrict__ esrc, const u16* __restrict__ ah,
                      u16* __restrict__ scat, int n0, int Nc, int N) {
  int gtid = blockIdx.x * blockDim.x + threadIdx.x;
  int wid = gtid >> 6, lane = threadIdx.x & 63;
  int nw = (blockDim.x * gridDim.x) >> 6;
  int total = Nc * 4;
  for (int u = wid; u < total; u += nw) {
    int n = n0 + (u >> 2), k = u & 3;
    u16* srow = scat + (size_t)(u >> 2) * 832;
    if (lane < 25) {
      int rs = off_et[(size_t)k * N + n], d = deg_et[(size_t)k * N + n];
      float a[8] = {};
      for (int i = 0; i < d; ++i) {
        const u16* hr = ah + (size_t)esrc[rs + i] * 448 + 224 + lane * 8;
        u16x8 v = *reinterpret_cast<const u16x8*>(hr);
#pragma unroll
        for (int jq = 0; jq < 8; ++jq) a[jq] += bf2f(v[jq]);
      }
      u16x8 r;
#pragma unroll
      for (int jq = 0; jq < 8; ++jq) r[jq] = f2bf(a[jq]);
      *reinterpret_cast<u16x8*>(srow + k * 200 + lane * 8) = r;
    } else if (k == 0 && lane == 25) {
      u16x4 r;
#pragma unroll
      for (int kk = 0; kk < 4; ++kk) r[kk] = f2bf((float)deg_et[(size_t)kk * N + n]);
      *reinterpret_cast<u16x4*>(srow + 800) = r;
    } else if (k == 1 && lane >= 26 && lane <= 31) {
      u16x4 z; z[0] = z[1] = z[2] = z[3] = 0;
      *reinterpret_cast<u16x4*>(srow + 804 + (lane - 26) * 4) = z;   // 804..828
    } else if (k == 2 && lane == 26) {
      u16x4 z; z[0] = z[1] = z[2] = z[3] = 0;
      *reinterpret_cast<u16x4*>(srow + 828) = z;
    }
  }
}

// ------- bf16 MFMA GEMM, 256x128 tile, 8 waves, 3-deep counted-vmcnt pipeline ------
// LDS per buffer: A 256x32, B 128x32; 16B slot s = r*4 + (g ^ ((r>>1)&3)).
__global__ __launch_bounds__(512, 4) void gemm_mfma(
    const u16* __restrict__ A, int lda,
    const u16* __restrict__ B, int ldb,
    u16* __restrict__ Cb, int ldcb, int npad,
    int M, int Nn, int K, const float* __restrict__ bias, int gyr) {
  const int gx = gridDim.x;
  int lin = blockIdx.y * gx + blockIdx.x;
  int k8 = lin & 7, j = lin >> 3;
  int band = gridDim.y >> 3;
  int yy = j / gx, xx = j - yy * gx;
  int by = k8 * band + yy;
  if (by >= gyr) return;
  const int m0 = by * 256, n0 = xx * 128;

  __shared__ __align__(16) u16 As[3 * 8192];   // 3 bufs x 256x32
  __shared__ __align__(16) u16 Bs[3 * 4096];   // 3 bufs x 128x32
  const int tid = threadIdx.x;
  const int lane = tid & 63;
  const int w = tid >> 6;          // 0..7
  const int wr = w >> 1, wc = w & 1;   // 4 x 2 wave grid; per-wave 64x64
  const int fr = lane & 15;
  const int g = lane >> 4;

  // staging: A slots sA0=w*64+lane, sA1=sA0+512 (1024 slots = 256 rows x 4 chunks);
  // B slot sB = w*64+lane (512 slots = 128 rows x 4).
  const int sA0 = w * 64 + lane, sA1 = sA0 + 512, sB = sA0;
  int rA0 = sA0 >> 2, cA0 = (sA0 & 3) ^ ((rA0 >> 1) & 3);
  int rA1 = sA1 >> 2, cA1 = (sA1 & 3) ^ ((rA1 >> 1) & 3);
  int rB  = sB  >> 2, cB  = (sB & 3) ^ ((rB >> 1) & 3);
  int ga0 = m0 + rA0; if (ga0 >= M) ga0 = M - 1;
  int ga1 = m0 + rA1; if (ga1 >= M) ga1 = M - 1;
  int gb  = n0 + rB;  if (gb >= Nn) gb = Nn - 1;
  const u16* pa0 = A + (size_t)ga0 * lda + cA0 * 8;
  const u16* pa1 = A + (size_t)ga1 * lda + cA1 * 8;
  const u16* pb  = B + (size_t)gb  * ldb + cB * 8;
  u16* lA0 = &As[(w * 64) * 8];
  u16* lA1 = &As[(512 + w * 64) * 8];
  u16* lB  = &Bs[(w * 64) * 8];

  const int gxr = g ^ ((fr >> 1) & 3);

  f32x4 acc[4][4] = {};
  const int nt = K >> 5;
  const int ABUF = 8192, BBUF = 4096;

  // prologue: stage tiles 0 and 1 (3 loads each per thread; 6 in flight)
  gload16(pa0, lA0); gload16(pa1, lA1); gload16(pb, lB);
  pa0 += 32; pa1 += 32; pb += 32;
  if (nt > 1) {
    gload16(pa0, lA0 + ABUF); gload16(pa1, lA1 + ABUF); gload16(pb, lB + BBUF);
    pa0 += 32; pa1 += 32; pb += 32;
  }

  for (int t = 0; t < nt; ++t) {
    if (t + 1 < nt) asm volatile("s_waitcnt vmcnt(3)" ::: "memory");
    else            asm volatile("s_waitcnt vmcnt(0)" ::: "memory");
    __builtin_amdgcn_s_barrier();
    if (t + 2 < nt) {
      int bi = (t + 2) % 3;
      gload16(pa0, lA0 + bi * ABUF); gload16(pa1, lA1 + bi * ABUF); gload16(pb, lB + bi * BBUF);
      pa0 += 32; pa1 += 32; pb += 32;
    }
    int ca = (t % 3) * ABUF, cbb = (t % 3) * BBUF;
    bf16x8 af[4], bfv[4];
#pragma unroll
    for (int i = 0; i < 4; ++i) {
      int row = wr * 64 + i * 16 + fr;
      af[i] = *reinterpret_cast<const bf16x8*>(&As[ca + (row * 4 + gxr) * 8]);
    }
#pragma unroll
    for (int jj = 0; jj < 4; ++jj) {
      int row = wc * 64 + jj * 16 + fr;
      bfv[jj] = *reinterpret_cast<const bf16x8*>(&Bs[cbb + (row * 4 + gxr) * 8]);
    }
    __builtin_amdgcn_s_setprio(1);
#pragma unroll
    for (int i = 0; i < 4; ++i)
#pragma unroll
      for (int jj = 0; jj < 4; ++jj)
        acc[i][jj] = __builtin_amdgcn_mfma_f32_16x16x32_bf16(af[i], bfv[jj], acc[i][jj], 0, 0, 0);
    __builtin_amdgcn_s_setprio(0);
  }

  const int er = (lane >> 4) * 4;
  const int ec = lane & 15;
#pragma unroll
  for (int i = 0; i < 4; ++i) {
#pragma unroll
    for (int jj = 0; jj < 4; ++jj) {
      int n = n0 + wc * 64 + jj * 16 + ec;
#pragma unroll
      for (int r = 0; r < 4; ++r) {
        int m = m0 + wr * 64 + i * 16 + er + r;
        if (m >= M) continue;
        if (n < Nn) {
          float v = acc[i][jj][r];
          if (bias) v += bias[n];
          Cb[(size_t)m * ldcb + n] = f2bf(v);
        } else if (n < npad) {
          Cb[(size_t)m * ldcb + n] = (u16)0;
        }
      }
    }
  }
}

// GRU finisher
__global__ void gru_fin_k(const u16* __restrict__ g, u16* __restrict__ ah, int c0, int Nc) {
  int total = Nc * 200;
  for (int i = blockIdx.x * blockDim.x + threadIdx.x; i < total; i += blockDim.x * gridDim.x) {
    int n = i / 200, o = i - n * 200;
    const u16* gr = g + (size_t)n * 832;
    float r = sigm(bf2f(gr[o]));
    float z = sigm(bf2f(gr[200 + o]));
    float x = bf2f(gr[400 + o]) + r * bf2f(gr[600 + o]);
    float e2 = __expf(2.f * x);
    float nn = (e2 - 1.f) / (e2 + 1.f);
    size_t hi = (size_t)(c0 + n) * 448 + 224 + o;
    float hold = bf2f(ah[hi]);
    ah[hi] = f2bf((1.f - z) * nn + z * hold);
  }
}

// cmat[n][352] = [h(224) | feat(100) | 0(28)]
__global__ void cmat_k(const u16* __restrict__ ah, const float* __restrict__ feat,
                       u16* __restrict__ c, int N) {
  int total = N * 352;
  for (int i = blockIdx.x * blockDim.x + threadIdx.x; i < total; i += blockDim.x * gridDim.x) {
    int n = i / 352, j = i - n * 352;
    u16 v;
    if (j < 224) v = ah[(size_t)n * 448 + 224 + j];
    else { int f = j - 224; v = (f < 100) ? f2bf(feat[(size_t)n * 100 + f]) : (u16)0; }
    c[i] = v;
  }
}

__global__ __launch_bounds__(1024) void bn_stats2_k(const u16* __restrict__ X, int L, int C,
                                                    float* __restrict__ stats) {
  const int Q = 1024 / C;
  const int T = Q * C;
  const int tid = threadIdx.x;
  float s = 0.f, q = 0.f;
  int c = 0;
  if (tid < T) {
    int qi = tid / C; c = tid - qi * C;
    for (size_t r = (size_t)blockIdx.x * Q + qi; r < (size_t)L; r += (size_t)gridDim.x * Q) {
      float v = bf2f(X[r * C + c]);
      s += v; q += v * v;
    }
  }
  __shared__ float sb[304], qb[304];
  for (int cc = tid; cc < C; cc += 1024) { sb[cc] = 0.f; qb[cc] = 0.f; }
  __syncthreads();
  if (tid < T) { atomicAdd(&sb[c], s); atomicAdd(&qb[c], q); }
  __syncthreads();
  for (int cc = tid; cc < C; cc += 1024) {
    atomicAdd(&stats[cc], sb[cc]);
    atomicAdd(&stats[C + cc], qb[cc]);
  }
}

__global__ void bn_fin_k(const float* __restrict__ stats, const float* __restrict__ g,
                         const float* __restrict__ b, int C, float Linv,
                         float* __restrict__ scsh) {
  int c = blockIdx.x * blockDim.x + threadIdx.x;
  if (c < C) {
    float mean = stats[c] * Linv;
    float var = stats[C + c] * Linv - mean * mean;
    float sc = g[c] * rsqrtf(var + 1e-5f);
    scsh[c] = sc;
    scsh[C + c] = b[c] - mean * sc;
  }
}

__global__ void pool_bf_k(const u16* __restrict__ X, int C, const float* __restrict__ scsh,
                          int kw, int stride, u16* __restrict__ Y, int Cpad, int Lout) {
  int total = Lout * Cpad;
  for (int i = blockIdx.x * blockDim.x + threadIdx.x; i < total; i += blockDim.x * gridDim.x) {
    int lp = i / Cpad, c = i - lp * Cpad;
    if (c >= C) { Y[i] = (u16)0; continue; }
    float sc = scsh[c], sh = scsh[C + c];
    int l0 = lp * stride;
    float m = 0.f;
    for (int wq = 0; wq < kw; ++wq)
      m = fmaxf(m, fmaf(bf2f(X[(size_t)(l0 + wq) * C + c]), sc, sh));
    Y[i] = f2bf(m);
  }
}

__global__ void pool_f32_k(const u16* __restrict__ X, int C, const float* __restrict__ scsh,
                           int kw, int stride, float* __restrict__ Y, int Lout) {
  int total = Lout * C;
  for (int i = blockIdx.x * blockDim.x + threadIdx.x; i < total; i += blockDim.x * gridDim.x) {
    int lp = i / C, c = i - lp * C;
    float sc = scsh[c], sh = scsh[C + c];
    int l0 = lp * stride;
    float m = 0.f;
    for (int wq = 0; wq < kw; ++wq)
      m = fmaxf(m, fmaf(bf2f(X[(size_t)(l0 + wq) * C + c]), sc, sh));
    Y[i] = m;
  }
}

__global__ __launch_bounds__(256) void final_dot_k(
    const float* __restrict__ Y2, const float* __restrict__ Z2,
    const float* __restrict__ wy, const float* __restrict__ by,
    const float* __restrict__ wz, const float* __restrict__ bz,
    float* __restrict__ acc, int L) {
  float s0 = 0.f, s1 = 0.f;
  for (int lp = blockIdx.x * blockDim.x + threadIdx.x; lp < L; lp += blockDim.x * gridDim.x) {
    const float* y = Y2 + (size_t)lp * 200;
    const float* z = Z2 + (size_t)lp * 300;
    float d0 = 0.f, d1 = 0.f;
    for (int k = 0; k < 200; ++k) { float v = y[k]; d0 += v * wy[k]; d1 += v * wy[200 + k]; }
    float e0 = 0.f, e1 = 0.f;
    for (int k = 0; k < 300; ++k) { float v = z[k]; e0 += v * wz[k]; e1 += v * wz[300 + k]; }
    s0 += (d0 + by[0]) * (e0 + bz[0]);
    s1 += (d1 + by[1]) * (e1 + bz[1]);
  }
  __shared__ float r0[256], r1[256];
  r0[threadIdx.x] = s0; r1[threadIdx.x] = s1;
  __syncthreads();
  for (int off = 128; off > 0; off >>= 1) {
    if (threadIdx.x < off) { r0[threadIdx.x] += r0[threadIdx.x + off]; r1[threadIdx.x] += r1[threadIdx.x + off]; }
    __syncthreads();
  }
  if (threadIdx.x == 0) { atomicAdd(&acc[0], r0[0]); atomicAdd(&acc[1], r1[0]); }
}

__global__ void final_out_k(const float* __restrict__ acc, float invL, float* __restrict__ out) {
  int j = threadIdx.x;
  if (j < 2) out[j] = 1.f / (1.f + expf(-acc[j] * invL));
}

// ---------------- host ----------------

static inline void gemmL(hipStream_t st, const u16* A, int lda, const u16* B, int ldb,
                         u16* Cb, int ldcb, int npad, int M, int Nn, int K, const float* bias) {
  int ncols = (npad > Nn) ? npad : Nn;
  int gx = (ncols + 127) / 128;
  int gy = (M + 255) / 256;
  int gyp = ((gy + 7) / 8) * 8;
  dim3 g(gx, gyp);
  gemm_mfma<<<g, 512, 0, st>>>(A, lda, B, ldb, Cb, ldcb, npad, M, Nn, K, bias, gy);
}

extern "C" void kernel_launch(void* const* d_in, const int* in_sizes, int n_in,
                              void* d_out, int out_size, void* d_ws, size_t ws_size,
                              hipStream_t stream) {
  (void)n_in; (void)out_size;
  const float* feat    = (const float*)d_in[0];
  const int*   eix     = (const int*)d_in[1];
  const int*   etyp    = (const int*)d_in[2];
  const float* ggnnW   = (const float*)d_in[3];
  const float* ggnnB   = (const float*)d_in[4];
  const float* Wih     = (const float*)d_in[5];
  const float* Whh     = (const float*)d_in[6];
  const float* bih     = (const float*)d_in[7];
  const float* bhh     = (const float*)d_in[8];
  const float* conv1w  = (const float*)d_in[9];
  const float* conv2w  = (const float*)d_in[11];
  const float* convc1w = (const float*)d_in[13];
  const float* convc2w = (const float*)d_in[15];
  const float* bnyg    = (const float*)d_in[17];
  const float* bnyb    = (const float*)d_in[18];
  const float* bncg    = (const float*)d_in[19];
  const float* bncb    = (const float*)d_in[20];
  const float* mlpyw   = (const float*)d_in[21];
  const float* mlpyb   = (const float*)d_in[22];
  const float* mlpzw   = (const float*)d_in[23];
  const float* mlpzb   = (const float*)d_in[24];

  const int N = in_sizes[0] / 100;
  const int E = in_sizes[2];
  const int* src = eix;
  const int* dst = eix + E;

  char* base = (char*)d_ws;
  const size_t AH_B = (size_t)N * 448 * 2;
  const int CH = (N + 1) / 2;
  const size_t SCR_B = (size_t)CH * 1664;   // scat / gates: CH x 832 u16

  u16* ah = (u16*)base;
  char* R1 = base + AH_B;
  char* WREG = R1 + SCR_B;

  u16* Wcat = (u16*)WREG;          // 200*832
  u16* Wall = Wcat + 166400;       // 800*448
  u16* w1c  = Wall + 358400;       // 200*1056
  u16* c2b  = w1c + 211200;        // 200*224
  u16* wc1  = c2b + 44800;         // 300*1056
  u16* wc2  = wc1 + 316800;        // 300*320
  float* ball  = (float*)(wc2 + 96000);  // 800
  float* stats = ball + 832;             // 600
  float* scsh  = stats + 600;            // 600
  float* acc2  = scsh + 600;             // 2 (+pad)
  int* deg_et = (int*)(acc2 + 8);
  int* off_et = deg_et + 4 * (size_t)N;
  int* cursor = off_et + 4 * (size_t)N;
  int* esrc   = cursor + 4 * (size_t)N;
  int* bsum   = esrc + E;
  const int L4 = 4 * N;
  const int NB = (L4 + 1023) / 1024;
  size_t need = (size_t)((char*)(bsum + NB) - base);

  if (ws_size < need) {
    fail_k<<<1, 64, 0, stream>>>((float*)d_out, -(float)(ws_size >> 20));
    return;
  }

  // ---- CSR build + packs ----
  hipMemsetAsync(deg_et, 0, sizeof(int) * 4 * (size_t)N, stream);
  init_ah_k<<<4096, 256, 0, stream>>>(feat, ah, N);
  count_deg_k<<<2048, 256, 0, stream>>>(dst, etyp, deg_et, N, E);
  bsum_k<<<NB, 1024, 0, stream>>>(deg_et, bsum, L4);
  scanb_k<<<1, 1024, 0, stream>>>(bsum, NB);
  scan_fin_k<<<NB, 1024, 0, stream>>>(deg_et, bsum, off_et, L4);
  copy_int_k<<<512, 256, 0, stream>>>(off_et, cursor, L4);
  fill_src_k<<<2048, 256, 0, stream>>>(src, dst, etyp, cursor, esrc, N, E);
  pack_wcat_k<<<651, 256, 0, stream>>>(ggnnW, ggnnB, Wcat);
  pack_wall_k<<<1400, 256, 0, stream>>>(Wih, Whh, Wall);
  ball_k<<<4, 256, 0, stream>>>(bih, bhh, ball);
  pack_w1c_k<<<825, 256, 0, stream>>>(conv1w, w1c);
  pack_lin_b<<<175, 256, 0, stream>>>(conv2w, c2b, 200, 200, 224);
  pack_wc1_b<<<1238, 256, 0, stream>>>(convc1w, wc1);
  pack_lin_b<<<375, 256, 0, stream>>>(convc2w, wc2, 300, 300, 320);

  // ---- GGNN 8 steps ----
  u16* scat = (u16*)R1;    // CH x 832 (aliases gates)

  for (int step = 0; step < 8; ++step) {
    for (int c0 = 0; c0 < N; c0 += CH) {
      int Nc = (c0 + CH <= N) ? CH : (N - c0);
      agg_k<<<4096, 256, 0, stream>>>(off_et, deg_et, esrc, ah, scat, c0, Nc, N);
      gemmL(stream, scat, 832, Wcat, 832, ah + (size_t)c0 * 448, 448, 224,
            Nc, 200, 832, nullptr);
    }
    for (int c0 = 0; c0 < N; c0 += CH) {
      int Nc = (c0 + CH <= N) ? CH : (N - c0);
      const u16* ahc = ah + (size_t)c0 * 448;
      gemmL(stream, ahc, 448, Wall, 448, scat, 832, 800, Nc, 800, 448, ball);
      gru_fin_k<<<2048, 256, 0, stream>>>(scat, ah, c0, Nc);
    }
  }

  // ---- conv paths ----
  const int L1 = N - 2;
  const int L2 = (L1 - 3) / 2 + 1;
  const int L3 = (L2 - 2) / 2 + 1;

  u16* cmat = (u16*)R1;                                              // N*352
  u16* out1 = (u16*)base;                                            // L1*200
  size_t y1_off = (((size_t)L1 * 400) + 255) & ~(size_t)255;
  u16* y1 = (u16*)(base + y1_off);                                   // L2*224
  size_t o2_off = y1_off + ((((size_t)L2 * 448) + 255) & ~(size_t)255);
  u16* out2 = (u16*)(base + o2_off);                                 // L2*200
  float* Y2f = (float*)base;                                         // L3*200 f32
  size_t oc1_off = (((size_t)L3 * 800) + 255) & ~(size_t)255;
  u16* outc1 = (u16*)(base + oc1_off);                               // L1*300
  u16* z1 = (u16*)R1;                                                // L2*320
  size_t oc2_off = (((size_t)L2 * 640) + 255) & ~(size_t)255;
  u16* outc2 = (u16*)(R1 + oc2_off);                                 // L2*300
  float* Z2f = (float*)(base + oc1_off);                             // L3*300 f32

  cmat_k<<<4096, 256, 0, stream>>>(ah, feat, cmat, N);

  // Y path
  gemmL(stream, cmat, 352, w1c, 1056, out1, 200, 200, L1, 200, 1056, nullptr);
  hipMemsetAsync(stats, 0, sizeof(float) * 400, stream);
  bn_stats2_k<<<512, 1024, 0, stream>>>(out1, L1, 200, stats);
  bn_fin_k<<<2, 256, 0, stream>>>(stats, bnyg, bnyb, 200, 1.f / (float)L1, scsh);
  pool_bf_k<<<2048, 256, 0, stream>>>(out1, 200, scsh, 3, 2, y1, 224, L2);

  gemmL(stream, y1, 224, c2b, 224, out2, 200, 200, L2, 200, 224, nullptr);
  hipMemsetAsync(stats, 0, sizeof(float) * 400, stream);
  bn_stats2_k<<<512, 1024, 0, stream>>>(out2, L2, 200, stats);
  bn_fin_k<<<2, 256, 0, stream>>>(stats, bnyg, bnyb, 200, 1.f / (float)L2, scsh);
  pool_f32_k<<<2048, 256, 0, stream>>>(out2, 200, scsh, 2, 2, Y2f, L3);

  // Z path
  gemmL(stream, cmat, 352, wc1, 1056, outc1, 300, 300, L1, 300, 1056, nullptr);
  hipMemsetAsync(stats, 0, sizeof(float) * 600, stream);
  bn_stats2_k<<<512, 1024, 0, stream>>>(outc1, L1, 300, stats);
  bn_fin_k<<<2, 256, 0, stream>>>(stats, bncg, bncb, 300, 1.f / (float)L1, scsh);
  pool_bf_k<<<2048, 256, 0, stream>>>(outc1, 300, scsh, 3, 2, z1, 320, L2);

  gemmL(stream, z1, 320, wc2, 320, outc2, 300, 300, L2, 300, 320, nullptr);
  hipMemsetAsync(stats, 0, sizeof(float) * 600, stream);
  bn_stats2_k<<<512, 1024, 0, stream>>>(outc2, L2, 300, stats);
  bn_fin_k<<<2, 256, 0, stream>>>(stats, bncg, bncb, 300, 1.f / (float)L2, scsh);
  pool_f32_k<<<2048, 256, 0, stream>>>(outc2, 300, scsh, 2, 2, Z2f, L3);

  // ---- final MLP product + mean + sigmoid ----
  hipMemsetAsync(acc2, 0, sizeof(float) * 2, stream);
  final_dot_k<<<256, 256, 0, stream>>>(Y2f, Z2f, mlpyw, mlpyb, mlpzw, mlpzb, acc2, L3);
  final_out_k<<<1, 64, 0, stream>>>(acc2, 1.f / (float)L3, (float*)d_out);
}

// Round 11
// 4466.095 us; speedup vs baseline: 1.2080x; 1.1211x over previous
//
#include <hip/hip_runtime.h>
#include <hip/hip_fp8.h>
#include <cstddef>
#include <cstdint>

// ============================================================================
// DevignModel round 11: fp8 gather table for GGNN aggregation.
//  - h8[N][224] fp8-e4m3 copy of h (22.4 MB, ~L2/L3-resident), updated by GRU
//  - agg: 13 lanes x 16B per edge, 4 edges/wave in flight + shfl_xor reduce
//  - everything else (GEMMs bf16, r10 256x128 pipeline) unchanged
// ============================================================================

typedef unsigned short u16;
typedef unsigned char u8;
typedef __attribute__((ext_vector_type(8))) short bf16x8;
typedef __attribute__((ext_vector_type(4))) float f32x4;
typedef __attribute__((ext_vector_type(2))) float f32x2;
typedef __attribute__((ext_vector_type(4))) unsigned short u16x4;
typedef __attribute__((ext_vector_type(8))) unsigned short u16x8;

static __device__ __forceinline__ float bf2f(u16 u) {
  union { unsigned int i; float f; } v; v.i = ((unsigned int)u) << 16; return v.f;
}
static __device__ __forceinline__ u16 f2bf(float f) {
  union { float f; unsigned int i; } v; v.f = f;
  unsigned int r = v.i + 0x7FFFu + ((v.i >> 16) & 1u);
  return (u16)(r >> 16);
}
static __device__ __forceinline__ float sigm(float x) { return 1.f / (1.f + __expf(-x)); }
static __device__ __forceinline__ u8 f2fp8(float x) {
  return (u8)__hip_cvt_float_to_fp8(x, __HIP_SATFINITE, __HIP_E4M3);
}

static __device__ __forceinline__ void gload16(const u16* gp, u16* lp) {
  __builtin_amdgcn_global_load_lds(
      (const __attribute__((address_space(1))) void*)gp,
      (__attribute__((address_space(3))) void*)lp, 16, 0, 0);
}

__global__ void fail_k(float* out, float code) { out[0] = code; out[1] = code; }

// ah[n][448]: [a(200)+pad24 | h(200)+pad24]; h0 = [feat | 0]
__global__ void init_ah_k(const float* __restrict__ feat, u16* __restrict__ ah, int N) {
  int total = N * 448;
  for (int i = blockIdx.x * blockDim.x + threadIdx.x; i < total; i += blockDim.x * gridDim.x) {
    int n = i / 448, j = i - n * 448;
    u16 v = 0;
    if (j >= 224 && j < 324) v = f2bf(feat[(size_t)n * 100 + (j - 224)]);
    ah[i] = v;
  }
}

// h8[n][224] fp8: [h(200) | 0(24)]
__global__ void init_h8_k(const float* __restrict__ feat, u8* __restrict__ h8, int N) {
  int total = N * 224;
  for (int i = blockIdx.x * blockDim.x + threadIdx.x; i < total; i += blockDim.x * gridDim.x) {
    int n = i / 224, c = i - n * 224;
    h8[i] = (c < 100) ? f2fp8(feat[(size_t)n * 100 + c]) : (u8)0;
  }
}

__global__ void count_deg_k(const int* __restrict__ dst, const int* __restrict__ et,
                            int* __restrict__ deg_et, int N, int E) {
  for (int e = blockIdx.x * blockDim.x + threadIdx.x; e < E; e += blockDim.x * gridDim.x)
    atomicAdd(&deg_et[et[e] * N + dst[e]], 1);
}

// ---- parallel exclusive scan (3 kernels) ----
__global__ __launch_bounds__(1024) void bsum_k(const int* __restrict__ cnt,
                                               int* __restrict__ bsum, int L) {
  __shared__ int buf[1024];
  int i = blockIdx.x * 1024 + threadIdx.x;
  buf[threadIdx.x] = (i < L) ? cnt[i] : 0;
  __syncthreads();
  for (int o = 512; o > 0; o >>= 1) {
    if (threadIdx.x < o) buf[threadIdx.x] += buf[threadIdx.x + o];
    __syncthreads();
  }
  if (threadIdx.x == 0) bsum[blockIdx.x] = buf[0];
}

__global__ __launch_bounds__(1024) void scanb_k(int* __restrict__ bsum, int nb) {
  __shared__ int buf[1024];
  int v = (threadIdx.x < nb) ? bsum[threadIdx.x] : 0;
  buf[threadIdx.x] = v;
  __syncthreads();
  for (int o = 1; o < 1024; o <<= 1) {
    int t = (threadIdx.x >= o) ? buf[threadIdx.x - o] : 0;
    __syncthreads();
    buf[threadIdx.x] += t;
    __syncthreads();
  }
  if (threadIdx.x < nb) bsum[threadIdx.x] = buf[threadIdx.x] - v;
}

__global__ __launch_bounds__(1024) void scan_fin_k(const int* __restrict__ cnt,
                                                   const int* __restrict__ bsum,
                                                   int* __restrict__ off, int L) {
  __shared__ int buf[1024];
  int i = blockIdx.x * 1024 + threadIdx.x;
  int v = (i < L) ? cnt[i] : 0;
  buf[threadIdx.x] = v;
  __syncthreads();
  for (int o = 1; o < 1024; o <<= 1) {
    int t = (threadIdx.x >= o) ? buf[threadIdx.x - o] : 0;
    __syncthreads();
    buf[threadIdx.x] += t;
    __syncthreads();
  }
  if (i < L) off[i] = buf[threadIdx.x] - v + bsum[blockIdx.x];
}

__global__ void copy_int_k(const int* __restrict__ a, int* __restrict__ b, int n) {
  for (int i = blockIdx.x * blockDim.x + threadIdx.x; i < n; i += blockDim.x * gridDim.x) b[i] = a[i];
}

__global__ void fill_src_k(const int* __restrict__ src, const int* __restrict__ dst,
                           const int* __restrict__ et, int* __restrict__ cursor,
                           int* __restrict__ esrc, int N, int E) {
  for (int e = blockIdx.x * blockDim.x + threadIdx.x; e < E; e += blockDim.x * gridDim.x) {
    int p = atomicAdd(&cursor[et[e] * N + dst[e]], 1);
    esrc[p] = src[e];
  }
}

// ---- weight packs ----

__global__ void pack_wcat_k(const float* __restrict__ W, const float* __restrict__ gb,
                            u16* __restrict__ dst) {
  int total = 200 * 832;
  for (int i = blockIdx.x * blockDim.x + threadIdx.x; i < total; i += blockDim.x * gridDim.x) {
    int o = i / 832, kp = i - o * 832;
    float v = 0.f;
    if (kp < 800) { int k = kp / 200, kk = kp - k * 200; v = W[((size_t)k * 200 + o) * 200 + kk]; }
    else if (kp < 804) v = gb[(kp - 800) * 200 + o];
    dst[i] = f2bf(v);
  }
}

// Wall[800][448]
__global__ void pack_wall_k(const float* __restrict__ Wih, const float* __restrict__ Whh,
                            u16* __restrict__ dst) {
  int total = 800 * 448;
  for (int i = blockIdx.x * blockDim.x + threadIdx.x; i < total; i += blockDim.x * gridDim.x) {
    int j = i / 448, kp = i - j * 448;
    float v = 0.f;
    if (j < 400) {
      if (kp < 200) v = Wih[(size_t)j * 200 + kp];
      else if (kp >= 224 && kp < 424) v = Whh[(size_t)j * 200 + (kp - 224)];
    } else if (j < 600) {
      if (kp < 200) v = Wih[(size_t)j * 200 + kp];
    } else {
      if (kp >= 224 && kp < 424) v = Whh[(size_t)(j - 200) * 200 + (kp - 224)];
    }
    dst[i] = f2bf(v);
  }
}

__global__ void ball_k(const float* __restrict__ bih, const float* __restrict__ bhh,
                       float* __restrict__ ball) {
  int j = blockIdx.x * blockDim.x + threadIdx.x;
  if (j < 800) ball[j] = (j < 400) ? bih[j] + bhh[j] : (j < 600 ? bih[j] : bhh[j - 200]);
}

__global__ void pack_lin_b(const float* __restrict__ src, u16* __restrict__ dst,
                           int Nn, int K, int Kp) {
  int total = Nn * Kp;
  for (int i = blockIdx.x * blockDim.x + threadIdx.x; i < total; i += blockDim.x * gridDim.x) {
    int o = i / Kp, kp = i - o * Kp;
    dst[i] = (kp < K) ? f2bf(src[(size_t)o * K + kp]) : (u16)0;
  }
}

__global__ void pack_w1c_k(const float* __restrict__ src, u16* __restrict__ dst) {
  int total = 200 * 1056;
  for (int i = blockIdx.x * blockDim.x + threadIdx.x; i < total; i += blockDim.x * gridDim.x) {
    int o = i / 1056, r = i - o * 1056;
    int t = r / 352, kp = r - t * 352;
    dst[i] = (kp < 200) ? f2bf(src[((size_t)o * 200 + kp) * 3 + t]) : (u16)0;
  }
}

__global__ void pack_wc1_b(const float* __restrict__ src, u16* __restrict__ dst) {
  int total = 300 * 1056;
  for (int i = blockIdx.x * blockDim.x + threadIdx.x; i < total; i += blockDim.x * gridDim.x) {
    int o = i / 1056, r = i - o * 1056;
    int t = r / 352, kp = r - t * 352;
    int ci = (kp < 224) ? (kp < 200 ? kp : -1) : ((kp - 224) < 100 ? 200 + (kp - 224) : -1);
    dst[i] = (ci >= 0) ? f2bf(src[((size_t)o * 300 + ci) * 3 + t]) : (u16)0;
  }
}

// aggregation from fp8 table: wave per (node, etype); 4 edges in flight via
// 16-lane sub-groups; 13 lanes x 16B per edge; shfl_xor reduce across groups.
__global__ void agg8_k(const int* __restrict__ off_et, const int* __restrict__ deg_et,
                       const int* __restrict__ esrc, const u8* __restrict__ h8,
                       u16* __restrict__ scat, int n0, int Nc, int N) {
  int gtid = blockIdx.x * blockDim.x + threadIdx.x;
  int wid = gtid >> 6, lane = threadIdx.x & 63;
  int nw = (blockDim.x * gridDim.x) >> 6;
  int sub = lane >> 4, l = lane & 15;
  int total = Nc * 4;
  for (int u = wid; u < total; u += nw) {
    int n = n0 + (u >> 2), k = u & 3;
    u16* srow = scat + (size_t)(u >> 2) * 832;
    int rs = off_et[(size_t)k * N + n], d = deg_et[(size_t)k * N + n];
    float a[16];
#pragma unroll
    for (int j = 0; j < 16; ++j) a[j] = 0.f;
    if (l < 13) {
      for (int i = sub; i < d; i += 4) {
        const u8* hr = h8 + (size_t)esrc[rs + i] * 224 + l * 16;
        uint4 v = *reinterpret_cast<const uint4*>(hr);
        f32x2 p;
        p = __builtin_amdgcn_cvt_pk_f32_fp8(v.x, 0); a[0] += p[0]; a[1] += p[1];
        p = __builtin_amdgcn_cvt_pk_f32_fp8(v.x, 1); a[2] += p[0]; a[3] += p[1];
        p = __builtin_amdgcn_cvt_pk_f32_fp8(v.y, 0); a[4] += p[0]; a[5] += p[1];
        p = __builtin_amdgcn_cvt_pk_f32_fp8(v.y, 1); a[6] += p[0]; a[7] += p[1];
        p = __builtin_amdgcn_cvt_pk_f32_fp8(v.z, 0); a[8] += p[0]; a[9] += p[1];
        p = __builtin_amdgcn_cvt_pk_f32_fp8(v.z, 1); a[10] += p[0]; a[11] += p[1];
        p = __builtin_amdgcn_cvt_pk_f32_fp8(v.w, 0); a[12] += p[0]; a[13] += p[1];
        p = __builtin_amdgcn_cvt_pk_f32_fp8(v.w, 1); a[14] += p[0]; a[15] += p[1];
      }
    }
#pragma unroll
    for (int j = 0; j < 16; ++j) {
      a[j] += __shfl_xor(a[j], 16);
      a[j] += __shfl_xor(a[j], 32);
    }
    if (sub == 0 && l < 13) {
      u16x8 r0;
#pragma unroll
      for (int j = 0; j < 8; ++j) r0[j] = f2bf(a[j]);
      *reinterpret_cast<u16x8*>(srow + k * 200 + l * 16) = r0;
      if (l < 12) {
        u16x8 r1;
#pragma unroll
        for (int j = 0; j < 8; ++j) r1[j] = f2bf(a[j + 8]);
        *reinterpret_cast<u16x8*>(srow + k * 200 + l * 16 + 8) = r1;
      }
    }
    if (k == 0 && lane == 13) {
      u16x4 r;
#pragma unroll
      for (int kk = 0; kk < 4; ++kk) r[kk] = f2bf((float)deg_et[(size_t)kk * N + n]);
      *reinterpret_cast<u16x4*>(srow + 800) = r;
    }
    if (k == 3 && lane >= 32 && lane < 60) srow[804 + (lane - 32)] = 0;
  }
}

// ------- bf16 MFMA GEMM, 256x128 tile, 8 waves, 3-deep counted-vmcnt pipeline ------
__global__ __launch_bounds__(512, 4) void gemm_mfma(
    const u16* __restrict__ A, int lda,
    const u16* __restrict__ B, int ldb,
    u16* __restrict__ Cb, int ldcb, int npad,
    int M, int Nn, int K, const float* __restrict__ bias, int gyr) {
  const int gx = gridDim.x;
  int lin = blockIdx.y * gx + blockIdx.x;
  int k8 = lin & 7, j = lin >> 3;
  int band = gridDim.y >> 3;
  int yy = j / gx, xx = j - yy * gx;
  int by = k8 * band + yy;
  if (by >= gyr) return;
  const int m0 = by * 256, n0 = xx * 128;

  __shared__ __align__(16) u16 As[3 * 8192];
  __shared__ __align__(16) u16 Bs[3 * 4096];
  const int tid = threadIdx.x;
  const int lane = tid & 63;
  const int w = tid >> 6;
  const int wr = w >> 1, wc = w & 1;
  const int fr = lane & 15;
  const int g = lane >> 4;

  const int sA0 = w * 64 + lane, sA1 = sA0 + 512, sB = sA0;
  int rA0 = sA0 >> 2, cA0 = (sA0 & 3) ^ ((rA0 >> 1) & 3);
  int rA1 = sA1 >> 2, cA1 = (sA1 & 3) ^ ((rA1 >> 1) & 3);
  int rB  = sB  >> 2, cB  = (sB & 3) ^ ((rB >> 1) & 3);
  int ga0 = m0 + rA0; if (ga0 >= M) ga0 = M - 1;
  int ga1 = m0 + rA1; if (ga1 >= M) ga1 = M - 1;
  int gb  = n0 + rB;  if (gb >= Nn) gb = Nn - 1;
  const u16* pa0 = A + (size_t)ga0 * lda + cA0 * 8;
  const u16* pa1 = A + (size_t)ga1 * lda + cA1 * 8;
  const u16* pb  = B + (size_t)gb  * ldb + cB * 8;
  u16* lA0 = &As[(w * 64) * 8];
  u16* lA1 = &As[(512 + w * 64) * 8];
  u16* lB  = &Bs[(w * 64) * 8];

  const int gxr = g ^ ((fr >> 1) & 3);

  f32x4 acc[4][4] = {};
  const int nt = K >> 5;
  const int ABUF = 8192, BBUF = 4096;

  gload16(pa0, lA0); gload16(pa1, lA1); gload16(pb, lB);
  pa0 += 32; pa1 += 32; pb += 32;
  if (nt > 1) {
    gload16(pa0, lA0 + ABUF); gload16(pa1, lA1 + ABUF); gload16(pb, lB + BBUF);
    pa0 += 32; pa1 += 32; pb += 32;
  }

  for (int t = 0; t < nt; ++t) {
    if (t + 1 < nt) asm volatile("s_waitcnt vmcnt(3)" ::: "memory");
    else            asm volatile("s_waitcnt vmcnt(0)" ::: "memory");
    __builtin_amdgcn_s_barrier();
    if (t + 2 < nt) {
      int bi = (t + 2) % 3;
      gload16(pa0, lA0 + bi * ABUF); gload16(pa1, lA1 + bi * ABUF); gload16(pb, lB + bi * BBUF);
      pa0 += 32; pa1 += 32; pb += 32;
    }
    int ca = (t % 3) * ABUF, cbb = (t % 3) * BBUF;
    bf16x8 af[4], bfv[4];
#pragma unroll
    for (int i = 0; i < 4; ++i) {
      int row = wr * 64 + i * 16 + fr;
      af[i] = *reinterpret_cast<const bf16x8*>(&As[ca + (row * 4 + gxr) * 8]);
    }
#pragma unroll
    for (int jj = 0; jj < 4; ++jj) {
      int row = wc * 64 + jj * 16 + fr;
      bfv[jj] = *reinterpret_cast<const bf16x8*>(&Bs[cbb + (row * 4 + gxr) * 8]);
    }
    __builtin_amdgcn_s_setprio(1);
#pragma unroll
    for (int i = 0; i < 4; ++i)
#pragma unroll
      for (int jj = 0; jj < 4; ++jj)
        acc[i][jj] = __builtin_amdgcn_mfma_f32_16x16x32_bf16(af[i], bfv[jj], acc[i][jj], 0, 0, 0);
    __builtin_amdgcn_s_setprio(0);
  }

  const int er = (lane >> 4) * 4;
  const int ec = lane & 15;
#pragma unroll
  for (int i = 0; i < 4; ++i) {
#pragma unroll
    for (int jj = 0; jj < 4; ++jj) {
      int n = n0 + wc * 64 + jj * 16 + ec;
#pragma unroll
      for (int r = 0; r < 4; ++r) {
        int m = m0 + wr * 64 + i * 16 + er + r;
        if (m >= M) continue;
        if (n < Nn) {
          float v = acc[i][jj][r];
          if (bias) v += bias[n];
          Cb[(size_t)m * ldcb + n] = f2bf(v);
        } else if (n < npad) {
          Cb[(size_t)m * ldcb + n] = (u16)0;
        }
      }
    }
  }
}

// GRU finisher: updates bf16 h in ah AND fp8 copy in h8
__global__ void gru_fin_k(const u16* __restrict__ g, u16* __restrict__ ah,
                          u8* __restrict__ h8, int c0, int Nc) {
  int total = Nc * 200;
  for (int i = blockIdx.x * blockDim.x + threadIdx.x; i < total; i += blockDim.x * gridDim.x) {
    int n = i / 200, o = i - n * 200;
    const u16* gr = g + (size_t)n * 832;
    float r = sigm(bf2f(gr[o]));
    float z = sigm(bf2f(gr[200 + o]));
    float x = bf2f(gr[400 + o]) + r * bf2f(gr[600 + o]);
    float e2 = __expf(2.f * x);
    float nn = (e2 - 1.f) / (e2 + 1.f);
    size_t hi = (size_t)(c0 + n) * 448 + 224 + o;
    float hold = bf2f(ah[hi]);
    float hnew = (1.f - z) * nn + z * hold;
    ah[hi] = f2bf(hnew);
    h8[(size_t)(c0 + n) * 224 + o] = f2fp8(hnew);
  }
}

// cmat[n][352] = [h(224) | feat(100) | 0(28)]
__global__ void cmat_k(const u16* __restrict__ ah, const float* __restrict__ feat,
                       u16* __restrict__ c, int N) {
  int total = N * 352;
  for (int i = blockIdx.x * blockDim.x + threadIdx.x; i < total; i += blockDim.x * gridDim.x) {
    int n = i / 352, j = i - n * 352;
    u16 v;
    if (j < 224) v = ah[(size_t)n * 448 + 224 + j];
    else { int f = j - 224; v = (f < 100) ? f2bf(feat[(size_t)n * 100 + f]) : (u16)0; }
    c[i] = v;
  }
}

__global__ __launch_bounds__(1024) void bn_stats2_k(const u16* __restrict__ X, int L, int C,
                                                    float* __restrict__ stats) {
  const int Q = 1024 / C;
  const int T = Q * C;
  const int tid = threadIdx.x;
  float s = 0.f, q = 0.f;
  int c = 0;
  if (tid < T) {
    int qi = tid / C; c = tid - qi * C;
    for (size_t r = (size_t)blockIdx.x * Q + qi; r < (size_t)L; r += (size_t)gridDim.x * Q) {
      float v = bf2f(X[r * C + c]);
      s += v; q += v * v;
    }
  }
  __shared__ float sb[304], qb[304];
  for (int cc = tid; cc < C; cc += 1024) { sb[cc] = 0.f; qb[cc] = 0.f; }
  __syncthreads();
  if (tid < T) { atomicAdd(&sb[c], s); atomicAdd(&qb[c], q); }
  __syncthreads();
  for (int cc = tid; cc < C; cc += 1024) {
    atomicAdd(&stats[cc], sb[cc]);
    atomicAdd(&stats[C + cc], qb[cc]);
  }
}

__global__ void bn_fin_k(const float* __restrict__ stats, const float* __restrict__ g,
                         const float* __restrict__ b, int C, float Linv,
                         float* __restrict__ scsh) {
  int c = blockIdx.x * blockDim.x + threadIdx.x;
  if (c < C) {
    float mean = stats[c] * Linv;
    float var = stats[C + c] * Linv - mean * mean;
    float sc = g[c] * rsqrtf(var + 1e-5f);
    scsh[c] = sc;
    scsh[C + c] = b[c] - mean * sc;
  }
}

__global__ void pool_bf_k(const u16* __restrict__ X, int C, const float* __restrict__ scsh,
                          int kw, int stride, u16* __restrict__ Y, int Cpad, int Lout) {
  int total = Lout * Cpad;
  for (int i = blockIdx.x * blockDim.x + threadIdx.x; i < total; i += blockDim.x * gridDim.x) {
    int lp = i / Cpad, c = i - lp * Cpad;
    if (c >= C) { Y[i] = (u16)0; continue; }
    float sc = scsh[c], sh = scsh[C + c];
    int l0 = lp * stride;
    float m = 0.f;
    for (int wq = 0; wq < kw; ++wq)
      m = fmaxf(m, fmaf(bf2f(X[(size_t)(l0 + wq) * C + c]), sc, sh));
    Y[i] = f2bf(m);
  }
}

__global__ void pool_f32_k(const u16* __restrict__ X, int C, const float* __restrict__ scsh,
                           int kw, int stride, float* __restrict__ Y, int Lout) {
  int total = Lout * C;
  for (int i = blockIdx.x * blockDim.x + threadIdx.x; i < total; i += blockDim.x * gridDim.x) {
    int lp = i / C, c = i - lp * C;
    float sc = scsh[c], sh = scsh[C + c];
    int l0 = lp * stride;
    float m = 0.f;
    for (int wq = 0; wq < kw; ++wq)
      m = fmaxf(m, fmaf(bf2f(X[(size_t)(l0 + wq) * C + c]), sc, sh));
    Y[i] = m;
  }
}

__global__ __launch_bounds__(256) void final_dot_k(
    const float* __restrict__ Y2, const float* __restrict__ Z2,
    const float* __restrict__ wy, const float* __restrict__ by,
    const float* __restrict__ wz, const float* __restrict__ bz,
    float* __restrict__ acc, int L) {
  float s0 = 0.f, s1 = 0.f;
  for (int lp = blockIdx.x * blockDim.x + threadIdx.x; lp < L; lp += blockDim.x * gridDim.x) {
    const float* y = Y2 + (size_t)lp * 200;
    const float* z = Z2 + (size_t)lp * 300;
    float d0 = 0.f, d1 = 0.f;
    for (int k = 0; k < 200; ++k) { float v = y[k]; d0 += v * wy[k]; d1 += v * wy[200 + k]; }
    float e0 = 0.f, e1 = 0.f;
    for (int k = 0; k < 300; ++k) { float v = z[k]; e0 += v * wz[k]; e1 += v * wz[300 + k]; }
    s0 += (d0 + by[0]) * (e0 + bz[0]);
    s1 += (d1 + by[1]) * (e1 + bz[1]);
  }
  __shared__ float r0[256], r1[256];
  r0[threadIdx.x] = s0; r1[threadIdx.x] = s1;
  __syncthreads();
  for (int off = 128; off > 0; off >>= 1) {
    if (threadIdx.x < off) { r0[threadIdx.x] += r0[threadIdx.x + off]; r1[threadIdx.x] += r1[threadIdx.x + off]; }
    __syncthreads();
  }
  if (threadIdx.x == 0) { atomicAdd(&acc[0], r0[0]); atomicAdd(&acc[1], r1[0]); }
}

__global__ void final_out_k(const float* __restrict__ acc, float invL, float* __restrict__ out) {
  int j = threadIdx.x;
  if (j < 2) out[j] = 1.f / (1.f + expf(-acc[j] * invL));
}

// ---------------- host ----------------

static inline void gemmL(hipStream_t st, const u16* A, int lda, const u16* B, int ldb,
                         u16* Cb, int ldcb, int npad, int M, int Nn, int K, const float* bias) {
  int ncols = (npad > Nn) ? npad : Nn;
  int gx = (ncols + 127) / 128;
  int gy = (M + 255) / 256;
  int gyp = ((gy + 7) / 8) * 8;
  dim3 g(gx, gyp);
  gemm_mfma<<<g, 512, 0, st>>>(A, lda, B, ldb, Cb, ldcb, npad, M, Nn, K, bias, gy);
}

extern "C" void kernel_launch(void* const* d_in, const int* in_sizes, int n_in,
                              void* d_out, int out_size, void* d_ws, size_t ws_size,
                              hipStream_t stream) {
  (void)n_in; (void)out_size;
  const float* feat    = (const float*)d_in[0];
  const int*   eix     = (const int*)d_in[1];
  const int*   etyp    = (const int*)d_in[2];
  const float* ggnnW   = (const float*)d_in[3];
  const float* ggnnB   = (const float*)d_in[4];
  const float* Wih     = (const float*)d_in[5];
  const float* Whh     = (const float*)d_in[6];
  const float* bih     = (const float*)d_in[7];
  const float* bhh     = (const float*)d_in[8];
  const float* conv1w  = (const float*)d_in[9];
  const float* conv2w  = (const float*)d_in[11];
  const float* convc1w = (const float*)d_in[13];
  const float* convc2w = (const float*)d_in[15];
  const float* bnyg    = (const float*)d_in[17];
  const float* bnyb    = (const float*)d_in[18];
  const float* bncg    = (const float*)d_in[19];
  const float* bncb    = (const float*)d_in[20];
  const float* mlpyw   = (const float*)d_in[21];
  const float* mlpyb   = (const float*)d_in[22];
  const float* mlpzw   = (const float*)d_in[23];
  const float* mlpzb   = (const float*)d_in[24];

  const int N = in_sizes[0] / 100;
  const int E = in_sizes[2];
  const int* src = eix;
  const int* dst = eix + E;

  char* base = (char*)d_ws;
  const size_t AH_B = (size_t)N * 448 * 2;
  const int CH = (N + 1) / 2;
  const size_t SCR_B = (size_t)CH * 1664;

  u16* ah = (u16*)base;
  char* R1 = base + AH_B;
  char* WREG = R1 + SCR_B;

  u16* Wcat = (u16*)WREG;          // 200*832
  u16* Wall = Wcat + 166400;       // 800*448
  u16* w1c  = Wall + 358400;       // 200*1056
  u16* c2b  = w1c + 211200;        // 200*224
  u16* wc1  = c2b + 44800;         // 300*1056
  u16* wc2  = wc1 + 316800;        // 300*320
  float* ball  = (float*)(wc2 + 96000);  // 800
  float* stats = ball + 832;             // 600
  float* scsh  = stats + 600;            // 600
  float* acc2  = scsh + 600;             // 2 (+pad)
  int* deg_et = (int*)(acc2 + 8);
  int* off_et = deg_et + 4 * (size_t)N;
  int* cursor = off_et + 4 * (size_t)N;
  int* esrc   = cursor + 4 * (size_t)N;
  int* bsum   = esrc + E;
  const int L4 = 4 * N;
  const int NB = (L4 + 1023) / 1024;
  u8* h8 = (u8*)(((uintptr_t)(bsum + NB) + 255) & ~(uintptr_t)255);
  size_t need = (size_t)((h8 + (size_t)N * 224) - (u8*)base);

  if (ws_size < need) {
    fail_k<<<1, 64, 0, stream>>>((float*)d_out, -(float)(ws_size >> 20));
    return;
  }

  // ---- CSR build + packs ----
  hipMemsetAsync(deg_et, 0, sizeof(int) * 4 * (size_t)N, stream);
  init_ah_k<<<4096, 256, 0, stream>>>(feat, ah, N);
  init_h8_k<<<2048, 256, 0, stream>>>(feat, h8, N);
  count_deg_k<<<2048, 256, 0, stream>>>(dst, etyp, deg_et, N, E);
  bsum_k<<<NB, 1024, 0, stream>>>(deg_et, bsum, L4);
  scanb_k<<<1, 1024, 0, stream>>>(bsum, NB);
  scan_fin_k<<<NB, 1024, 0, stream>>>(deg_et, bsum, off_et, L4);
  copy_int_k<<<512, 256, 0, stream>>>(off_et, cursor, L4);
  fill_src_k<<<2048, 256, 0, stream>>>(src, dst, etyp, cursor, esrc, N, E);
  pack_wcat_k<<<651, 256, 0, stream>>>(ggnnW, ggnnB, Wcat);
  pack_wall_k<<<1400, 256, 0, stream>>>(Wih, Whh, Wall);
  ball_k<<<4, 256, 0, stream>>>(bih, bhh, ball);
  pack_w1c_k<<<825, 256, 0, stream>>>(conv1w, w1c);
  pack_lin_b<<<175, 256, 0, stream>>>(conv2w, c2b, 200, 200, 224);
  pack_wc1_b<<<1238, 256, 0, stream>>>(convc1w, wc1);
  pack_lin_b<<<375, 256, 0, stream>>>(convc2w, wc2, 300, 300, 320);

  // ---- GGNN 8 steps ----
  u16* scat = (u16*)R1;    // CH x 832 (aliases gates)

  for (int step = 0; step < 8; ++step) {
    for (int c0 = 0; c0 < N; c0 += CH) {
      int Nc = (c0 + CH <= N) ? CH : (N - c0);
      agg8_k<<<4096, 256, 0, stream>>>(off_et, deg_et, esrc, h8, scat, c0, Nc, N);
      gemmL(stream, scat, 832, Wcat, 832, ah + (size_t)c0 * 448, 448, 224,
            Nc, 200, 832, nullptr);
    }
    for (int c0 = 0; c0 < N; c0 += CH) {
      int Nc = (c0 + CH <= N) ? CH : (N - c0);
      const u16* ahc = ah + (size_t)c0 * 448;
      gemmL(stream, ahc, 448, Wall, 448, scat, 832, 800, Nc, 800, 448, ball);
      gru_fin_k<<<2048, 256, 0, stream>>>(scat, ah, h8, c0, Nc);
    }
  }

  // ---- conv paths ----
  const int L1 = N - 2;
  const int L2 = (L1 - 3) / 2 + 1;
  const int L3 = (L2 - 2) / 2 + 1;

  u16* cmat = (u16*)R1;                                              // N*352
  u16* out1 = (u16*)base;                                            // L1*200
  size_t y1_off = (((size_t)L1 * 400) + 255) & ~(size_t)255;
  u16* y1 = (u16*)(base + y1_off);                                   // L2*224
  size_t o2_off = y1_off + ((((size_t)L2 * 448) + 255) & ~(size_t)255);
  u16* out2 = (u16*)(base + o2_off);                                 // L2*200
  float* Y2f = (float*)base;                                         // L3*200 f32
  size_t oc1_off = (((size_t)L3 * 800) + 255) & ~(size_t)255;
  u16* outc1 = (u16*)(base + oc1_off);                               // L1*300
  u16* z1 = (u16*)R1;                                                // L2*320
  size_t oc2_off = (((size_t)L2 * 640) + 255) & ~(size_t)255;
  u16* outc2 = (u16*)(R1 + oc2_off);                                 // L2*300
  float* Z2f = (float*)(base + oc1_off);                             // L3*300 f32

  cmat_k<<<4096, 256, 0, stream>>>(ah, feat, cmat, N);

  // Y path
  gemmL(stream, cmat, 352, w1c, 1056, out1, 200, 200, L1, 200, 1056, nullptr);
  hipMemsetAsync(stats, 0, sizeof(float) * 400, stream);
  bn_stats2_k<<<512, 1024, 0, stream>>>(out1, L1, 200, stats);
  bn_fin_k<<<2, 256, 0, stream>>>(stats, bnyg, bnyb, 200, 1.f / (float)L1, scsh);
  pool_bf_k<<<2048, 256, 0, stream>>>(out1, 200, scsh, 3, 2, y1, 224, L2);

  gemmL(stream, y1, 224, c2b, 224, out2, 200, 200, L2, 200, 224, nullptr);
  hipMemsetAsync(stats, 0, sizeof(float) * 400, stream);
  bn_stats2_k<<<512, 1024, 0, stream>>>(out2, L2, 200, stats);
  bn_fin_k<<<2, 256, 0, stream>>>(stats, bnyg, bnyb, 200, 1.f / (float)L2, scsh);
  pool_f32_k<<<2048, 256, 0, stream>>>(out2, 200, scsh, 2, 2, Y2f, L3);

  // Z path
  gemmL(stream, cmat, 352, wc1, 1056, outc1, 300, 300, L1, 300, 1056, nullptr);
  hipMemsetAsync(stats, 0, sizeof(float) * 600, stream);
  bn_stats2_k<<<512, 1024, 0, stream>>>(outc1, L1, 300, stats);
  bn_fin_k<<<2, 256, 0, stream>>>(stats, bncg, bncb, 300, 1.f / (float)L1, scsh);
  pool_bf_k<<<2048, 256, 0, stream>>>(outc1, 300, scsh, 3, 2, z1, 320, L2);

  gemmL(stream, z1, 320, wc2, 320, outc2, 300, 300, L2, 300, 320, nullptr);
  hipMemsetAsync(stats, 0, sizeof(float) * 600, stream);
  bn_stats2_k<<<512, 1024, 0, stream>>>(outc2, L2, 300, stats);
  bn_fin_k<<<2, 256, 0, stream>>>(stats, bncg, bncb, 300, 1.f / (float)L2, scsh);
  pool_f32_k<<<2048, 256, 0, stream>>>(outc2, 300, scsh, 2, 2, Z2f, L3);

  // ---- final MLP product + mean + sigmoid ----
  hipMemsetAsync(acc2, 0, sizeof(float) * 2, stream);
  final_dot_k<<<256, 256, 0, stream>>>(Y2f, Z2f, mlpyw, mlpyb, mlpzw, mlpzb, acc2, L3);
  final_out_k<<<1, 64, 0, stream>>>(acc2, 1.f / (float)L3, (float*)d_out);
}

// Round 12
// 3861.427 us; speedup vs baseline: 1.3972x; 1.1566x over previous
//
#include <hip/hip_runtime.h>
#include <hip/hip_fp8.h>
#include <cstddef>
#include <cstdint>

// ============================================================================
// DevignModel round 12: GRU fused into gates-GEMM epilogue.
//  - Wall packed gate-interleaved (row 4o+g) -> each 128-col block owns
//    complete o-groups; epilogue does sigmoid/tanh/blend via LDS transpose
//  - writes h8 (fp8) + hnew (bf16, scat scratch); hcopy merges into ah
//  - kills 16 gru_fin dispatches + 2.6 GB gates round-trip traffic
// ============================================================================

typedef unsigned short u16;
typedef unsigned char u8;
typedef __attribute__((ext_vector_type(8))) short bf16x8;
typedef __attribute__((ext_vector_type(4))) float f32x4;
typedef __attribute__((ext_vector_type(2))) float f32x2;
typedef __attribute__((ext_vector_type(4))) unsigned short u16x4;
typedef __attribute__((ext_vector_type(8))) unsigned short u16x8;

static __device__ __forceinline__ float bf2f(u16 u) {
  union { unsigned int i; float f; } v; v.i = ((unsigned int)u) << 16; return v.f;
}
static __device__ __forceinline__ u16 f2bf(float f) {
  union { float f; unsigned int i; } v; v.f = f;
  unsigned int r = v.i + 0x7FFFu + ((v.i >> 16) & 1u);
  return (u16)(r >> 16);
}
static __device__ __forceinline__ float sigm(float x) { return 1.f / (1.f + __expf(-x)); }
static __device__ __forceinline__ u8 f2fp8(float x) {
  return (u8)__hip_cvt_float_to_fp8(x, __HIP_SATFINITE, __HIP_E4M3);
}

static __device__ __forceinline__ void gload16(const u16* gp, u16* lp) {
  __builtin_amdgcn_global_load_lds(
      (const __attribute__((address_space(1))) void*)gp,
      (__attribute__((address_space(3))) void*)lp, 16, 0, 0);
}

__global__ void fail_k(float* out, float code) { out[0] = code; out[1] = code; }

// ah[n][448]: [a(200)+pad24 | h(200)+pad24]; h0 = [feat | 0]
__global__ void init_ah_k(const float* __restrict__ feat, u16* __restrict__ ah, int N) {
  int total = N * 448;
  for (int i = blockIdx.x * blockDim.x + threadIdx.x; i < total; i += blockDim.x * gridDim.x) {
    int n = i / 448, j = i - n * 448;
    u16 v = 0;
    if (j >= 224 && j < 324) v = f2bf(feat[(size_t)n * 100 + (j - 224)]);
    ah[i] = v;
  }
}

// h8[n][224] fp8: [h(200) | 0(24)]
__global__ void init_h8_k(const float* __restrict__ feat, u8* __restrict__ h8, int N) {
  int total = N * 224;
  for (int i = blockIdx.x * blockDim.x + threadIdx.x; i < total; i += blockDim.x * gridDim.x) {
    int n = i / 224, c = i - n * 224;
    h8[i] = (c < 100) ? f2fp8(feat[(size_t)n * 100 + c]) : (u8)0;
  }
}

__global__ void count_deg_k(const int* __restrict__ dst, const int* __restrict__ et,
                            int* __restrict__ deg_et, int N, int E) {
  for (int e = blockIdx.x * blockDim.x + threadIdx.x; e < E; e += blockDim.x * gridDim.x)
    atomicAdd(&deg_et[et[e] * N + dst[e]], 1);
}

// ---- parallel exclusive scan (3 kernels) ----
__global__ __launch_bounds__(1024) void bsum_k(const int* __restrict__ cnt,
                                               int* __restrict__ bsum, int L) {
  __shared__ int buf[1024];
  int i = blockIdx.x * 1024 + threadIdx.x;
  buf[threadIdx.x] = (i < L) ? cnt[i] : 0;
  __syncthreads();
  for (int o = 512; o > 0; o >>= 1) {
    if (threadIdx.x < o) buf[threadIdx.x] += buf[threadIdx.x + o];
    __syncthreads();
  }
  if (threadIdx.x == 0) bsum[blockIdx.x] = buf[0];
}

__global__ __launch_bounds__(1024) void scanb_k(int* __restrict__ bsum, int nb) {
  __shared__ int buf[1024];
  int v = (threadIdx.x < nb) ? bsum[threadIdx.x] : 0;
  buf[threadIdx.x] = v;
  __syncthreads();
  for (int o = 1; o < 1024; o <<= 1) {
    int t = (threadIdx.x >= o) ? buf[threadIdx.x - o] : 0;
    __syncthreads();
    buf[threadIdx.x] += t;
    __syncthreads();
  }
  if (threadIdx.x < nb) bsum[threadIdx.x] = buf[threadIdx.x] - v;
}

__global__ __launch_bounds__(1024) void scan_fin_k(const int* __restrict__ cnt,
                                                   const int* __restrict__ bsum,
                                                   int* __restrict__ off, int L) {
  __shared__ int buf[1024];
  int i = blockIdx.x * 1024 + threadIdx.x;
  int v = (i < L) ? cnt[i] : 0;
  buf[threadIdx.x] = v;
  __syncthreads();
  for (int o = 1; o < 1024; o <<= 1) {
    int t = (threadIdx.x >= o) ? buf[threadIdx.x - o] : 0;
    __syncthreads();
    buf[threadIdx.x] += t;
    __syncthreads();
  }
  if (i < L) off[i] = buf[threadIdx.x] - v + bsum[blockIdx.x];
}

__global__ void copy_int_k(const int* __restrict__ a, int* __restrict__ b, int n) {
  for (int i = blockIdx.x * blockDim.x + threadIdx.x; i < n; i += blockDim.x * gridDim.x) b[i] = a[i];
}

__global__ void fill_src_k(const int* __restrict__ src, const int* __restrict__ dst,
                           const int* __restrict__ et, int* __restrict__ cursor,
                           int* __restrict__ esrc, int N, int E) {
  for (int e = blockIdx.x * blockDim.x + threadIdx.x; e < E; e += blockDim.x * gridDim.x) {
    int p = atomicAdd(&cursor[et[e] * N + dst[e]], 1);
    esrc[p] = src[e];
  }
}

// ---- weight packs ----

__global__ void pack_wcat_k(const float* __restrict__ W, const float* __restrict__ gb,
                            u16* __restrict__ dst) {
  int total = 200 * 832;
  for (int i = blockIdx.x * blockDim.x + threadIdx.x; i < total; i += blockDim.x * gridDim.x) {
    int o = i / 832, kp = i - o * 832;
    float v = 0.f;
    if (kp < 800) { int k = kp / 200, kk = kp - k * 200; v = W[((size_t)k * 200 + o) * 200 + kk]; }
    else if (kp < 804) v = gb[(kp - 800) * 200 + o];
    dst[i] = f2bf(v);
  }
}

// Wall_i[800][448] gate-interleaved: row 4o+g;
// g=0(r): [Wih_o | 0 | Whh_o | 0]; g=1(z): rows 200+o; g=2(inn): Wih row 400+o;
// g=3(hn): Whh row 400+o in k 224..424.
__global__ void pack_wall_i_k(const float* __restrict__ Wih, const float* __restrict__ Whh,
                              u16* __restrict__ dst) {
  int total = 800 * 448;
  for (int i = blockIdx.x * blockDim.x + threadIdx.x; i < total; i += blockDim.x * gridDim.x) {
    int jp = i / 448, kp = i - jp * 448;
    int o = jp >> 2, g = jp & 3;
    float v = 0.f;
    if (g == 0) {
      if (kp < 200) v = Wih[(size_t)o * 200 + kp];
      else if (kp >= 224 && kp < 424) v = Whh[(size_t)o * 200 + (kp - 224)];
    } else if (g == 1) {
      if (kp < 200) v = Wih[(size_t)(200 + o) * 200 + kp];
      else if (kp >= 224 && kp < 424) v = Whh[(size_t)(200 + o) * 200 + (kp - 224)];
    } else if (g == 2) {
      if (kp < 200) v = Wih[(size_t)(400 + o) * 200 + kp];
    } else {
      if (kp >= 224 && kp < 424) v = Whh[(size_t)(400 + o) * 200 + (kp - 224)];
    }
    dst[i] = f2bf(v);
  }
}

__global__ void ball_i_k(const float* __restrict__ bih, const float* __restrict__ bhh,
                         float* __restrict__ ball) {
  int j = blockIdx.x * blockDim.x + threadIdx.x;
  if (j < 800) {
    int o = j >> 2, g = j & 3;
    float v;
    if (g == 0) v = bih[o] + bhh[o];
    else if (g == 1) v = bih[200 + o] + bhh[200 + o];
    else if (g == 2) v = bih[400 + o];
    else v = bhh[400 + o];
    ball[j] = v;
  }
}

__global__ void pack_lin_b(const float* __restrict__ src, u16* __restrict__ dst,
                           int Nn, int K, int Kp) {
  int total = Nn * Kp;
  for (int i = blockIdx.x * blockDim.x + threadIdx.x; i < total; i += blockDim.x * gridDim.x) {
    int o = i / Kp, kp = i - o * Kp;
    dst[i] = (kp < K) ? f2bf(src[(size_t)o * K + kp]) : (u16)0;
  }
}

__global__ void pack_w1c_k(const float* __restrict__ src, u16* __restrict__ dst) {
  int total = 200 * 1056;
  for (int i = blockIdx.x * blockDim.x + threadIdx.x; i < total; i += blockDim.x * gridDim.x) {
    int o = i / 1056, r = i - o * 1056;
    int t = r / 352, kp = r - t * 352;
    dst[i] = (kp < 200) ? f2bf(src[((size_t)o * 200 + kp) * 3 + t]) : (u16)0;
  }
}

__global__ void pack_wc1_b(const float* __restrict__ src, u16* __restrict__ dst) {
  int total = 300 * 1056;
  for (int i = blockIdx.x * blockDim.x + threadIdx.x; i < total; i += blockDim.x * gridDim.x) {
    int o = i / 1056, r = i - o * 1056;
    int t = r / 352, kp = r - t * 352;
    int ci = (kp < 224) ? (kp < 200 ? kp : -1) : ((kp - 224) < 100 ? 200 + (kp - 224) : -1);
    dst[i] = (ci >= 0) ? f2bf(src[((size_t)o * 300 + ci) * 3 + t]) : (u16)0;
  }
}

// aggregation from fp8 table (unchanged from r11)
__global__ void agg8_k(const int* __restrict__ off_et, const int* __restrict__ deg_et,
                       const int* __restrict__ esrc, const u8* __restrict__ h8,
                       u16* __restrict__ scat, int n0, int Nc, int N) {
  int gtid = blockIdx.x * blockDim.x + threadIdx.x;
  int wid = gtid >> 6, lane = threadIdx.x & 63;
  int nw = (blockDim.x * gridDim.x) >> 6;
  int sub = lane >> 4, l = lane & 15;
  int total = Nc * 4;
  for (int u = wid; u < total; u += nw) {
    int n = n0 + (u >> 2), k = u & 3;
    u16* srow = scat + (size_t)(u >> 2) * 832;
    int rs = off_et[(size_t)k * N + n], d = deg_et[(size_t)k * N + n];
    float a[16];
#pragma unroll
    for (int j = 0; j < 16; ++j) a[j] = 0.f;
    if (l < 13) {
      for (int i = sub; i < d; i += 4) {
        const u8* hr = h8 + (size_t)esrc[rs + i] * 224 + l * 16;
        uint4 v = *reinterpret_cast<const uint4*>(hr);
        f32x2 p;
        p = __builtin_amdgcn_cvt_pk_f32_fp8(v.x, 0); a[0] += p[0]; a[1] += p[1];
        p = __builtin_amdgcn_cvt_pk_f32_fp8(v.x, 1); a[2] += p[0]; a[3] += p[1];
        p = __builtin_amdgcn_cvt_pk_f32_fp8(v.y, 0); a[4] += p[0]; a[5] += p[1];
        p = __builtin_amdgcn_cvt_pk_f32_fp8(v.y, 1); a[6] += p[0]; a[7] += p[1];
        p = __builtin_amdgcn_cvt_pk_f32_fp8(v.z, 0); a[8] += p[0]; a[9] += p[1];
        p = __builtin_amdgcn_cvt_pk_f32_fp8(v.z, 1); a[10] += p[0]; a[11] += p[1];
        p = __builtin_amdgcn_cvt_pk_f32_fp8(v.w, 0); a[12] += p[0]; a[13] += p[1];
        p = __builtin_amdgcn_cvt_pk_f32_fp8(v.w, 1); a[14] += p[0]; a[15] += p[1];
      }
    }
#pragma unroll
    for (int j = 0; j < 16; ++j) {
      a[j] += __shfl_xor(a[j], 16);
      a[j] += __shfl_xor(a[j], 32);
    }
    if (sub == 0 && l < 13) {
      u16x8 r0;
#pragma unroll
      for (int j = 0; j < 8; ++j) r0[j] = f2bf(a[j]);
      *reinterpret_cast<u16x8*>(srow + k * 200 + l * 16) = r0;
      if (l < 12) {
        u16x8 r1;
#pragma unroll
        for (int j = 0; j < 8; ++j) r1[j] = f2bf(a[j + 8]);
        *reinterpret_cast<u16x8*>(srow + k * 200 + l * 16 + 8) = r1;
      }
    }
    if (k == 0 && lane == 13) {
      u16x4 r;
#pragma unroll
      for (int kk = 0; kk < 4; ++kk) r[kk] = f2bf((float)deg_et[(size_t)kk * N + n]);
      *reinterpret_cast<u16x4*>(srow + 800) = r;
    }
    if (k == 3 && lane >= 32 && lane < 60) srow[804 + (lane - 32)] = 0;
  }
}

// ------- generic bf16 MFMA GEMM, 256x128 tile (unchanged from r10/11) ------
__global__ __launch_bounds__(512, 4) void gemm_mfma(
    const u16* __restrict__ A, int lda,
    const u16* __restrict__ B, int ldb,
    u16* __restrict__ Cb, int ldcb, int npad,
    int M, int Nn, int K, const float* __restrict__ bias, int gyr) {
  const int gx = gridDim.x;
  int lin = blockIdx.y * gx + blockIdx.x;
  int k8 = lin & 7, j = lin >> 3;
  int band = gridDim.y >> 3;
  int yy = j / gx, xx = j - yy * gx;
  int by = k8 * band + yy;
  if (by >= gyr) return;
  const int m0 = by * 256, n0 = xx * 128;

  __shared__ __align__(16) u16 As[3 * 8192];
  __shared__ __align__(16) u16 Bs[3 * 4096];
  const int tid = threadIdx.x;
  const int lane = tid & 63;
  const int w = tid >> 6;
  const int wr = w >> 1, wc = w & 1;
  const int fr = lane & 15;
  const int g = lane >> 4;

  const int sA0 = w * 64 + lane, sA1 = sA0 + 512, sB = sA0;
  int rA0 = sA0 >> 2, cA0 = (sA0 & 3) ^ ((rA0 >> 1) & 3);
  int rA1 = sA1 >> 2, cA1 = (sA1 & 3) ^ ((rA1 >> 1) & 3);
  int rB  = sB  >> 2, cB  = (sB & 3) ^ ((rB >> 1) & 3);
  int ga0 = m0 + rA0; if (ga0 >= M) ga0 = M - 1;
  int ga1 = m0 + rA1; if (ga1 >= M) ga1 = M - 1;
  int gb  = n0 + rB;  if (gb >= Nn) gb = Nn - 1;
  const u16* pa0 = A + (size_t)ga0 * lda + cA0 * 8;
  const u16* pa1 = A + (size_t)ga1 * lda + cA1 * 8;
  const u16* pb  = B + (size_t)gb  * ldb + cB * 8;
  u16* lA0 = &As[(w * 64) * 8];
  u16* lA1 = &As[(512 + w * 64) * 8];
  u16* lB  = &Bs[(w * 64) * 8];

  const int gxr = g ^ ((fr >> 1) & 3);

  f32x4 acc[4][4] = {};
  const int nt = K >> 5;
  const int ABUF = 8192, BBUF = 4096;

  gload16(pa0, lA0); gload16(pa1, lA1); gload16(pb, lB);
  pa0 += 32; pa1 += 32; pb += 32;
  if (nt > 1) {
    gload16(pa0, lA0 + ABUF); gload16(pa1, lA1 + ABUF); gload16(pb, lB + BBUF);
    pa0 += 32; pa1 += 32; pb += 32;
  }

  for (int t = 0; t < nt; ++t) {
    if (t + 1 < nt) asm volatile("s_waitcnt vmcnt(3)" ::: "memory");
    else            asm volatile("s_waitcnt vmcnt(0)" ::: "memory");
    __builtin_amdgcn_s_barrier();
    if (t + 2 < nt) {
      int bi = (t + 2) % 3;
      gload16(pa0, lA0 + bi * ABUF); gload16(pa1, lA1 + bi * ABUF); gload16(pb, lB + bi * BBUF);
      pa0 += 32; pa1 += 32; pb += 32;
    }
    int ca = (t % 3) * ABUF, cbb = (t % 3) * BBUF;
    bf16x8 af[4], bfv[4];
#pragma unroll
    for (int i = 0; i < 4; ++i) {
      int row = wr * 64 + i * 16 + fr;
      af[i] = *reinterpret_cast<const bf16x8*>(&As[ca + (row * 4 + gxr) * 8]);
    }
#pragma unroll
    for (int jj = 0; jj < 4; ++jj) {
      int row = wc * 64 + jj * 16 + fr;
      bfv[jj] = *reinterpret_cast<const bf16x8*>(&Bs[cbb + (row * 4 + gxr) * 8]);
    }
    __builtin_amdgcn_s_setprio(1);
#pragma unroll
    for (int i = 0; i < 4; ++i)
#pragma unroll
      for (int jj = 0; jj < 4; ++jj)
        acc[i][jj] = __builtin_amdgcn_mfma_f32_16x16x32_bf16(af[i], bfv[jj], acc[i][jj], 0, 0, 0);
    __builtin_amdgcn_s_setprio(0);
  }

  const int er = (lane >> 4) * 4;
  const int ec = lane & 15;
#pragma unroll
  for (int i = 0; i < 4; ++i) {
#pragma unroll
    for (int jj = 0; jj < 4; ++jj) {
      int n = n0 + wc * 64 + jj * 16 + ec;
#pragma unroll
      for (int r = 0; r < 4; ++r) {
        int m = m0 + wr * 64 + i * 16 + er + r;
        if (m >= M) continue;
        if (n < Nn) {
          float v = acc[i][jj][r];
          if (bias) v += bias[n];
          Cb[(size_t)m * ldcb + n] = f2bf(v);
        } else if (n < npad) {
          Cb[(size_t)m * ldcb + n] = (u16)0;
        }
      }
    }
  }
}

// ------- gates GEMM with fused GRU epilogue (Nn=800 interleaved, gx=7) ------
// Writes hnew[m][224-stride] (bf16) + h8c[m][224] (fp8). No gate materialization.
__global__ __launch_bounds__(512, 4) void gemm_gru(
    const u16* __restrict__ A, int lda,
    const u16* __restrict__ B, int ldb,
    int M, int K, const float* __restrict__ bias,
    u16* __restrict__ hnew, u8* __restrict__ h8c, int gyr) {
  const int gx = gridDim.x;
  int lin = blockIdx.y * gx + blockIdx.x;
  int k8 = lin & 7, j = lin >> 3;
  int band = gridDim.y >> 3;
  int yy = j / gx, xx = j - yy * gx;
  int by = k8 * band + yy;
  if (by >= gyr) return;
  const int m0 = by * 256, n0 = xx * 128;
  const int Nn = 800;

  __shared__ __align__(16) u16 SM[3 * 8192 + 3 * 4096];
  u16* As = SM;
  u16* Bs = SM + 3 * 8192;
  const int tid = threadIdx.x;
  const int lane = tid & 63;
  const int w = tid >> 6;
  const int wr = w >> 1, wc = w & 1;
  const int fr = lane & 15;
  const int g = lane >> 4;

  const int sA0 = w * 64 + lane, sA1 = sA0 + 512, sB = sA0;
  int rA0 = sA0 >> 2, cA0 = (sA0 & 3) ^ ((rA0 >> 1) & 3);
  int rA1 = sA1 >> 2, cA1 = (sA1 & 3) ^ ((rA1 >> 1) & 3);
  int rB  = sB  >> 2, cB  = (sB & 3) ^ ((rB >> 1) & 3);
  int ga0 = m0 + rA0; if (ga0 >= M) ga0 = M - 1;
  int ga1 = m0 + rA1; if (ga1 >= M) ga1 = M - 1;
  int gb  = n0 + rB;  if (gb >= Nn) gb = Nn - 1;
  const u16* pa0 = A + (size_t)ga0 * lda + cA0 * 8;
  const u16* pa1 = A + (size_t)ga1 * lda + cA1 * 8;
  const u16* pb  = B + (size_t)gb  * ldb + cB * 8;
  u16* lA0 = &As[(w * 64) * 8];
  u16* lA1 = &As[(512 + w * 64) * 8];
  u16* lB  = &Bs[(w * 64) * 8];

  const int gxr = g ^ ((fr >> 1) & 3);

  f32x4 acc[4][4] = {};
  const int nt = K >> 5;
  const int ABUF = 8192, BBUF = 4096;

  gload16(pa0, lA0); gload16(pa1, lA1); gload16(pb, lB);
  pa0 += 32; pa1 += 32; pb += 32;
  if (nt > 1) {
    gload16(pa0, lA0 + ABUF); gload16(pa1, lA1 + ABUF); gload16(pb, lB + BBUF);
    pa0 += 32; pa1 += 32; pb += 32;
  }

  for (int t = 0; t < nt; ++t) {
    if (t + 1 < nt) asm volatile("s_waitcnt vmcnt(3)" ::: "memory");
    else            asm volatile("s_waitcnt vmcnt(0)" ::: "memory");
    __builtin_amdgcn_s_barrier();
    if (t + 2 < nt) {
      int bi = (t + 2) % 3;
      gload16(pa0, lA0 + bi * ABUF); gload16(pa1, lA1 + bi * ABUF); gload16(pb, lB + bi * BBUF);
      pa0 += 32; pa1 += 32; pb += 32;
    }
    int ca = (t % 3) * ABUF, cbb = (t % 3) * BBUF;
    bf16x8 af[4], bfv[4];
#pragma unroll
    for (int i = 0; i < 4; ++i) {
      int row = wr * 64 + i * 16 + fr;
      af[i] = *reinterpret_cast<const bf16x8*>(&As[ca + (row * 4 + gxr) * 8]);
    }
#pragma unroll
    for (int jj = 0; jj < 4; ++jj) {
      int row = wc * 64 + jj * 16 + fr;
      bfv[jj] = *reinterpret_cast<const bf16x8*>(&Bs[cbb + (row * 4 + gxr) * 8]);
    }
    __builtin_amdgcn_s_setprio(1);
#pragma unroll
    for (int i = 0; i < 4; ++i)
#pragma unroll
      for (int jj = 0; jj < 4; ++jj)
        acc[i][jj] = __builtin_amdgcn_mfma_f32_16x16x32_bf16(af[i], bfv[jj], acc[i][jj], 0, 0, 0);
    __builtin_amdgcn_s_setprio(0);
  }

  // ---- fused GRU epilogue ----
  const int er = (lane >> 4) * 4;
  const int ec = lane & 15;
  __syncthreads();                       // all LDS staging reads done
  float* ep = (float*)SM + (size_t)w * 2048;   // per-wave [64][32] f32

  for (int hh = 0; hh < 2; ++hh) {
    // write phase: my acc cols for this half, bias added
#pragma unroll
    for (int jj2 = 0; jj2 < 2; ++jj2) {
      int jj = hh * 2 + jj2;
      int n = n0 + wc * 64 + jj * 16 + ec;
      float bv = (n < 800) ? bias[n] : 0.f;
#pragma unroll
      for (int i = 0; i < 4; ++i)
#pragma unroll
        for (int r = 0; r < 4; ++r) {
          int row_loc = i * 16 + er + r;
          ep[row_loc * 32 + jj2 * 16 + ec] = acc[i][jj][r] + bv;
        }
    }
    __syncthreads();
    // read phase: 64 rows x 8 o-groups; gates are 4 consecutive f32
#pragma unroll
    for (int p = 0; p < 8; ++p) {
      int idx = p * 64 + lane;
      int row = idx >> 3, og = idx & 7;
      int n_base = n0 + wc * 64 + hh * 32 + og * 4;
      int m = m0 + wr * 64 + row;
      if (n_base < 800 && m < M) {
        f32x4 gv = *reinterpret_cast<f32x4*>(&ep[row * 32 + og * 4]);
        float rg = sigm(gv[0]);
        float zg = sigm(gv[1]);
        float x = gv[2] + rg * gv[3];
        float e2 = __expf(2.f * x);
        float nn = (e2 - 1.f) / (e2 + 1.f);
        int o = n_base >> 2;
        float hold = bf2f(A[(size_t)m * 448 + 224 + o]);
        float hv = (1.f - zg) * nn + zg * hold;
        hnew[(size_t)m * 224 + o] = f2bf(hv);
        h8c[(size_t)m * 224 + o] = f2fp8(hv);
      }
    }
    __syncthreads();
  }
}

// merge hnew (bf16, stride 224) into ah h-slice
__global__ void hcopy_k(const u16* __restrict__ hn_, u16* __restrict__ ahc, int Nc) {
  int total = Nc * 200;
  for (int i = blockIdx.x * blockDim.x + threadIdx.x; i < total; i += blockDim.x * gridDim.x) {
    int n = i / 200, o = i - n * 200;
    ahc[(size_t)n * 448 + 224 + o] = hn_[(size_t)n * 224 + o];
  }
}

// cmat[n][352] = [h(224) | feat(100) | 0(28)]
__global__ void cmat_k(const u16* __restrict__ ah, const float* __restrict__ feat,
                       u16* __restrict__ c, int N) {
  int total = N * 352;
  for (int i = blockIdx.x * blockDim.x + threadIdx.x; i < total; i += blockDim.x * gridDim.x) {
    int n = i / 352, j = i - n * 352;
    u16 v;
    if (j < 224) v = ah[(size_t)n * 448 + 224 + j];
    else { int f = j - 224; v = (f < 100) ? f2bf(feat[(size_t)n * 100 + f]) : (u16)0; }
    c[i] = v;
  }
}

__global__ __launch_bounds__(1024) void bn_stats2_k(const u16* __restrict__ X, int L, int C,
                                                    float* __restrict__ stats) {
  const int Q = 1024 / C;
  const int T = Q * C;
  const int tid = threadIdx.x;
  float s = 0.f, q = 0.f;
  int c = 0;
  if (tid < T) {
    int qi = tid / C; c = tid - qi * C;
    for (size_t r = (size_t)blockIdx.x * Q + qi; r < (size_t)L; r += (size_t)gridDim.x * Q) {
      float v = bf2f(X[r * C + c]);
      s += v; q += v * v;
    }
  }
  __shared__ float sb[304], qb[304];
  for (int cc = tid; cc < C; cc += 1024) { sb[cc] = 0.f; qb[cc] = 0.f; }
  __syncthreads();
  if (tid < T) { atomicAdd(&sb[c], s); atomicAdd(&qb[c], q); }
  __syncthreads();
  for (int cc = tid; cc < C; cc += 1024) {
    atomicAdd(&stats[cc], sb[cc]);
    atomicAdd(&stats[C + cc], qb[cc]);
  }
}

__global__ void bn_fin_k(const float* __restrict__ stats, const float* __restrict__ g,
                         const float* __restrict__ b, int C, float Linv,
                         float* __restrict__ scsh) {
  int c = blockIdx.x * blockDim.x + threadIdx.x;
  if (c < C) {
    float mean = stats[c] * Linv;
    float var = stats[C + c] * Linv - mean * mean;
    float sc = g[c] * rsqrtf(var + 1e-5f);
    scsh[c] = sc;
    scsh[C + c] = b[c] - mean * sc;
  }
}

__global__ void pool_bf_k(const u16* __restrict__ X, int C, const float* __restrict__ scsh,
                          int kw, int stride, u16* __restrict__ Y, int Cpad, int Lout) {
  int total = Lout * Cpad;
  for (int i = blockIdx.x * blockDim.x + threadIdx.x; i < total; i += blockDim.x * gridDim.x) {
    int lp = i / Cpad, c = i - lp * Cpad;
    if (c >= C) { Y[i] = (u16)0; continue; }
    float sc = scsh[c], sh = scsh[C + c];
    int l0 = lp * stride;
    float m = 0.f;
    for (int wq = 0; wq < kw; ++wq)
      m = fmaxf(m, fmaf(bf2f(X[(size_t)(l0 + wq) * C + c]), sc, sh));
    Y[i] = f2bf(m);
  }
}

__global__ void pool_f32_k(const u16* __restrict__ X, int C, const float* __restrict__ scsh,
                           int kw, int stride, float* __restrict__ Y, int Lout) {
  int total = Lout * C;
  for (int i = blockIdx.x * blockDim.x + threadIdx.x; i < total; i += blockDim.x * gridDim.x) {
    int lp = i / C, c = i - lp * C;
    float sc = scsh[c], sh = scsh[C + c];
    int l0 = lp * stride;
    float m = 0.f;
    for (int wq = 0; wq < kw; ++wq)
      m = fmaxf(m, fmaf(bf2f(X[(size_t)(l0 + wq) * C + c]), sc, sh));
    Y[i] = m;
  }
}

__global__ __launch_bounds__(256) void final_dot_k(
    const float* __restrict__ Y2, const float* __restrict__ Z2,
    const float* __restrict__ wy, const float* __restrict__ by,
    const float* __restrict__ wz, const float* __restrict__ bz,
    float* __restrict__ acc, int L) {
  float s0 = 0.f, s1 = 0.f;
  for (int lp = blockIdx.x * blockDim.x + threadIdx.x; lp < L; lp += blockDim.x * gridDim.x) {
    const float* y = Y2 + (size_t)lp * 200;
    const float* z = Z2 + (size_t)lp * 300;
    float d0 = 0.f, d1 = 0.f;
    for (int k = 0; k < 200; ++k) { float v = y[k]; d0 += v * wy[k]; d1 += v * wy[200 + k]; }
    float e0 = 0.f, e1 = 0.f;
    for (int k = 0; k < 300; ++k) { float v = z[k]; e0 += v * wz[k]; e1 += v * wz[300 + k]; }
    s0 += (d0 + by[0]) * (e0 + bz[0]);
    s1 += (d1 + by[1]) * (e1 + bz[1]);
  }
  __shared__ float r0[256], r1[256];
  r0[threadIdx.x] = s0; r1[threadIdx.x] = s1;
  __syncthreads();
  for (int off = 128; off > 0; off >>= 1) {
    if (threadIdx.x < off) { r0[threadIdx.x] += r0[threadIdx.x + off]; r1[threadIdx.x] += r1[threadIdx.x + off]; }
    __syncthreads();
  }
  if (threadIdx.x == 0) { atomicAdd(&acc[0], r0[0]); atomicAdd(&acc[1], r1[0]); }
}

__global__ void final_out_k(const float* __restrict__ acc, float invL, float* __restrict__ out) {
  int j = threadIdx.x;
  if (j < 2) out[j] = 1.f / (1.f + expf(-acc[j] * invL));
}

// ---------------- host ----------------

static inline void gemmL(hipStream_t st, const u16* A, int lda, const u16* B, int ldb,
                         u16* Cb, int ldcb, int npad, int M, int Nn, int K, const float* bias) {
  int ncols = (npad > Nn) ? npad : Nn;
  int gx = (ncols + 127) / 128;
  int gy = (M + 255) / 256;
  int gyp = ((gy + 7) / 8) * 8;
  dim3 g(gx, gyp);
  gemm_mfma<<<g, 512, 0, st>>>(A, lda, B, ldb, Cb, ldcb, npad, M, Nn, K, bias, gy);
}

extern "C" void kernel_launch(void* const* d_in, const int* in_sizes, int n_in,
                              void* d_out, int out_size, void* d_ws, size_t ws_size,
                              hipStream_t stream) {
  (void)n_in; (void)out_size;
  const float* feat    = (const float*)d_in[0];
  const int*   eix     = (const int*)d_in[1];
  const int*   etyp    = (const int*)d_in[2];
  const float* ggnnW   = (const float*)d_in[3];
  const float* ggnnB   = (const float*)d_in[4];
  const float* Wih     = (const float*)d_in[5];
  const float* Whh     = (const float*)d_in[6];
  const float* bih     = (const float*)d_in[7];
  const float* bhh     = (const float*)d_in[8];
  const float* conv1w  = (const float*)d_in[9];
  const float* conv2w  = (const float*)d_in[11];
  const float* convc1w = (const float*)d_in[13];
  const float* convc2w = (const float*)d_in[15];
  const float* bnyg    = (const float*)d_in[17];
  const float* bnyb    = (const float*)d_in[18];
  const float* bncg    = (const float*)d_in[19];
  const float* bncb    = (const float*)d_in[20];
  const float* mlpyw   = (const float*)d_in[21];
  const float* mlpyb   = (const float*)d_in[22];
  const float* mlpzw   = (const float*)d_in[23];
  const float* mlpzb   = (const float*)d_in[24];

  const int N = in_sizes[0] / 100;
  const int E = in_sizes[2];
  const int* src = eix;
  const int* dst = eix + E;

  char* base = (char*)d_ws;
  const size_t AH_B = (size_t)N * 448 * 2;
  const int CH = (N + 1) / 2;
  const size_t SCR_B = (size_t)CH * 1664;

  u16* ah = (u16*)base;
  char* R1 = base + AH_B;
  char* WREG = R1 + SCR_B;

  u16* Wcat = (u16*)WREG;          // 200*832
  u16* Wall = Wcat + 166400;       // 800*448 (interleaved)
  u16* w1c  = Wall + 358400;       // 200*1056
  u16* c2b  = w1c + 211200;        // 200*224
  u16* wc1  = c2b + 44800;         // 300*1056
  u16* wc2  = wc1 + 316800;        // 300*320
  float* ball  = (float*)(wc2 + 96000);  // 800
  float* stats = ball + 832;             // 600
  float* scsh  = stats + 600;            // 600
  float* acc2  = scsh + 600;             // 2 (+pad)
  int* deg_et = (int*)(acc2 + 8);
  int* off_et = deg_et + 4 * (size_t)N;
  int* cursor = off_et + 4 * (size_t)N;
  int* esrc   = cursor + 4 * (size_t)N;
  int* bsum   = esrc + E;
  const int L4 = 4 * N;
  const int NB = (L4 + 1023) / 1024;
  u8* h8 = (u8*)(((uintptr_t)(bsum + NB) + 255) & ~(uintptr_t)255);
  size_t need = (size_t)((h8 + (size_t)N * 224) - (u8*)base);

  if (ws_size < need) {
    fail_k<<<1, 64, 0, stream>>>((float*)d_out, -(float)(ws_size >> 20));
    return;
  }

  // ---- CSR build + packs ----
  hipMemsetAsync(deg_et, 0, sizeof(int) * 4 * (size_t)N, stream);
  init_ah_k<<<4096, 256, 0, stream>>>(feat, ah, N);
  init_h8_k<<<2048, 256, 0, stream>>>(feat, h8, N);
  count_deg_k<<<2048, 256, 0, stream>>>(dst, etyp, deg_et, N, E);
  bsum_k<<<NB, 1024, 0, stream>>>(deg_et, bsum, L4);
  scanb_k<<<1, 1024, 0, stream>>>(bsum, NB);
  scan_fin_k<<<NB, 1024, 0, stream>>>(deg_et, bsum, off_et, L4);
  copy_int_k<<<512, 256, 0, stream>>>(off_et, cursor, L4);
  fill_src_k<<<2048, 256, 0, stream>>>(src, dst, etyp, cursor, esrc, N, E);
  pack_wcat_k<<<651, 256, 0, stream>>>(ggnnW, ggnnB, Wcat);
  pack_wall_i_k<<<1400, 256, 0, stream>>>(Wih, Whh, Wall);
  ball_i_k<<<4, 256, 0, stream>>>(bih, bhh, ball);
  pack_w1c_k<<<825, 256, 0, stream>>>(conv1w, w1c);
  pack_lin_b<<<175, 256, 0, stream>>>(conv2w, c2b, 200, 200, 224);
  pack_wc1_b<<<1238, 256, 0, stream>>>(convc1w, wc1);
  pack_lin_b<<<375, 256, 0, stream>>>(convc2w, wc2, 300, 300, 320);

  // ---- GGNN 8 steps ----
  u16* scat = (u16*)R1;    // CH x 832 (agg out; also hnew scratch in phase B)

  for (int step = 0; step < 8; ++step) {
    for (int c0 = 0; c0 < N; c0 += CH) {
      int Nc = (c0 + CH <= N) ? CH : (N - c0);
      agg8_k<<<4096, 256, 0, stream>>>(off_et, deg_et, esrc, h8, scat, c0, Nc, N);
      gemmL(stream, scat, 832, Wcat, 832, ah + (size_t)c0 * 448, 448, 224,
            Nc, 200, 832, nullptr);
    }
    for (int c0 = 0; c0 < N; c0 += CH) {
      int Nc = (c0 + CH <= N) ? CH : (N - c0);
      u16* ahc = ah + (size_t)c0 * 448;
      int gy = (Nc + 255) / 256;
      int gyp = ((gy + 7) / 8) * 8;
      gemm_gru<<<dim3(7, gyp), 512, 0, stream>>>(ahc, 448, Wall, 448, Nc, 448, ball,
                                                 scat, h8 + (size_t)c0 * 224, gy);
      hcopy_k<<<2048, 256, 0, stream>>>(scat, ahc, Nc);
    }
  }

  // ---- conv paths ----
  const int L1 = N - 2;
  const int L2 = (L1 - 3) / 2 + 1;
  const int L3 = (L2 - 2) / 2 + 1;

  u16* cmat = (u16*)R1;                                              // N*352
  u16* out1 = (u16*)base;                                            // L1*200
  size_t y1_off = (((size_t)L1 * 400) + 255) & ~(size_t)255;
  u16* y1 = (u16*)(base + y1_off);                                   // L2*224
  size_t o2_off = y1_off + ((((size_t)L2 * 448) + 255) & ~(size_t)255);
  u16* out2 = (u16*)(base + o2_off);                                 // L2*200
  float* Y2f = (float*)base;                                         // L3*200 f32
  size_t oc1_off = (((size_t)L3 * 800) + 255) & ~(size_t)255;
  u16* outc1 = (u16*)(base + oc1_off);                               // L1*300
  u16* z1 = (u16*)R1;                                                // L2*320
  size_t oc2_off = (((size_t)L2 * 640) + 255) & ~(size_t)255;
  u16* outc2 = (u16*)(R1 + oc2_off);                                 // L2*300
  float* Z2f = (float*)(base + oc1_off);                             // L3*300 f32

  cmat_k<<<4096, 256, 0, stream>>>(ah, feat, cmat, N);

  // Y path
  gemmL(stream, cmat, 352, w1c, 1056, out1, 200, 200, L1, 200, 1056, nullptr);
  hipMemsetAsync(stats, 0, sizeof(float) * 400, stream);
  bn_stats2_k<<<512, 1024, 0, stream>>>(out1, L1, 200, stats);
  bn_fin_k<<<2, 256, 0, stream>>>(stats, bnyg, bnyb, 200, 1.f / (float)L1, scsh);
  pool_bf_k<<<2048, 256, 0, stream>>>(out1, 200, scsh, 3, 2, y1, 224, L2);

  gemmL(stream, y1, 224, c2b, 224, out2, 200, 200, L2, 200, 224, nullptr);
  hipMemsetAsync(stats, 0, sizeof(float) * 400, stream);
  bn_stats2_k<<<512, 1024, 0, stream>>>(out2, L2, 200, stats);
  bn_fin_k<<<2, 256, 0, stream>>>(stats, bnyg, bnyb, 200, 1.f / (float)L2, scsh);
  pool_f32_k<<<2048, 256, 0, stream>>>(out2, 200, scsh, 2, 2, Y2f, L3);

  // Z path
  gemmL(stream, cmat, 352, wc1, 1056, outc1, 300, 300, L1, 300, 1056, nullptr);
  hipMemsetAsync(stats, 0, sizeof(float) * 600, stream);
  bn_stats2_k<<<512, 1024, 0, stream>>>(outc1, L1, 300, stats);
  bn_fin_k<<<2, 256, 0, stream>>>(stats, bncg, bncb, 300, 1.f / (float)L1, scsh);
  pool_bf_k<<<2048, 256, 0, stream>>>(outc1, 300, scsh, 3, 2, z1, 320, L2);

  gemmL(stream, z1, 320, wc2, 320, outc2, 300, 300, L2, 300, 320, nullptr);
  hipMemsetAsync(stats, 0, sizeof(float) * 600, stream);
  bn_stats2_k<<<512, 1024, 0, stream>>>(outc2, L2, 300, stats);
  bn_fin_k<<<2, 256, 0, stream>>>(stats, bncg, bncb, 300, 1.f / (float)L2, scsh);
  pool_f32_k<<<2048, 256, 0, stream>>>(outc2, 300, scsh, 2, 2, Z2f, L3);

  // ---- final MLP product + mean + sigmoid ----
  hipMemsetAsync(acc2, 0, sizeof(float) * 2, stream);
  final_dot_k<<<256, 256, 0, stream>>>(Y2f, Z2f, mlpyw, mlpyb, mlpzw, mlpzb, acc2, L3);
  final_out_k<<<1, 64, 0, stream>>>(acc2, 1.f / (float)L3, (float*)d_out);
}

// Round 13
// 3738.246 us; speedup vs baseline: 1.4432x; 1.0330x over previous
//
#include <hip/hip_runtime.h>
#include <hip/hip_fp8.h>
#include <cstddef>
#include <cstdint>

// ============================================================================
// DevignModel round 13: fp8 scat + fp8 phase-A GEMM + de-chunked GGNN.
//  - agg writes full-N scat8 (fp8, 83 MB = same scratch budget as before)
//  - gemm_a8: 256x128 fp8x fp8 MFMA, 3-deep counted-vmcnt (2 loads/thread/step)
//  - one agg/gemmA/gemmGRU/hcopy per step (was 2 chunks each)
// ============================================================================

typedef unsigned short u16;
typedef unsigned char u8;
typedef unsigned long long u64;
typedef __attribute__((ext_vector_type(8))) short bf16x8;
typedef __attribute__((ext_vector_type(4))) float f32x4;
typedef __attribute__((ext_vector_type(2))) float f32x2;
typedef __attribute__((ext_vector_type(4))) unsigned short u16x4;
typedef __attribute__((ext_vector_type(8))) unsigned short u16x8;

static __device__ __forceinline__ float bf2f(u16 u) {
  union { unsigned int i; float f; } v; v.i = ((unsigned int)u) << 16; return v.f;
}
static __device__ __forceinline__ u16 f2bf(float f) {
  union { float f; unsigned int i; } v; v.f = f;
  unsigned int r = v.i + 0x7FFFu + ((v.i >> 16) & 1u);
  return (u16)(r >> 16);
}
static __device__ __forceinline__ float sigm(float x) { return 1.f / (1.f + __expf(-x)); }
static __device__ __forceinline__ u8 f2fp8(float x) {
  return (u8)__hip_cvt_float_to_fp8(x, __HIP_SATFINITE, __HIP_E4M3);
}

static __device__ __forceinline__ void gload16(const void* gp, void* lp) {
  __builtin_amdgcn_global_load_lds(
      (const __attribute__((address_space(1))) void*)gp,
      (__attribute__((address_space(3))) void*)lp, 16, 0, 0);
}

__global__ void fail_k(float* out, float code) { out[0] = code; out[1] = code; }

// ah[n][448]: [a(200)+pad24 | h(200)+pad24]; h0 = [feat | 0]
__global__ void init_ah_k(const float* __restrict__ feat, u16* __restrict__ ah, int N) {
  int total = N * 448;
  for (int i = blockIdx.x * blockDim.x + threadIdx.x; i < total; i += blockDim.x * gridDim.x) {
    int n = i / 448, j = i - n * 448;
    u16 v = 0;
    if (j >= 224 && j < 324) v = f2bf(feat[(size_t)n * 100 + (j - 224)]);
    ah[i] = v;
  }
}

// h8[n][224] fp8: [h(200) | 0(24)]
__global__ void init_h8_k(const float* __restrict__ feat, u8* __restrict__ h8, int N) {
  int total = N * 224;
  for (int i = blockIdx.x * blockDim.x + threadIdx.x; i < total; i += blockDim.x * gridDim.x) {
    int n = i / 224, c = i - n * 224;
    h8[i] = (c < 100) ? f2fp8(feat[(size_t)n * 100 + c]) : (u8)0;
  }
}

__global__ void count_deg_k(const int* __restrict__ dst, const int* __restrict__ et,
                            int* __restrict__ deg_et, int N, int E) {
  for (int e = blockIdx.x * blockDim.x + threadIdx.x; e < E; e += blockDim.x * gridDim.x)
    atomicAdd(&deg_et[et[e] * N + dst[e]], 1);
}

// ---- parallel exclusive scan (3 kernels) ----
__global__ __launch_bounds__(1024) void bsum_k(const int* __restrict__ cnt,
                                               int* __restrict__ bsum, int L) {
  __shared__ int buf[1024];
  int i = blockIdx.x * 1024 + threadIdx.x;
  buf[threadIdx.x] = (i < L) ? cnt[i] : 0;
  __syncthreads();
  for (int o = 512; o > 0; o >>= 1) {
    if (threadIdx.x < o) buf[threadIdx.x] += buf[threadIdx.x + o];
    __syncthreads();
  }
  if (threadIdx.x == 0) bsum[blockIdx.x] = buf[0];
}

__global__ __launch_bounds__(1024) void scanb_k(int* __restrict__ bsum, int nb) {
  __shared__ int buf[1024];
  int v = (threadIdx.x < nb) ? bsum[threadIdx.x] : 0;
  buf[threadIdx.x] = v;
  __syncthreads();
  for (int o = 1; o < 1024; o <<= 1) {
    int t = (threadIdx.x >= o) ? buf[threadIdx.x - o] : 0;
    __syncthreads();
    buf[threadIdx.x] += t;
    __syncthreads();
  }
  if (threadIdx.x < nb) bsum[threadIdx.x] = buf[threadIdx.x] - v;
}

__global__ __launch_bounds__(1024) void scan_fin_k(const int* __restrict__ cnt,
                                                   const int* __restrict__ bsum,
                                                   int* __restrict__ off, int L) {
  __shared__ int buf[1024];
  int i = blockIdx.x * 1024 + threadIdx.x;
  int v = (i < L) ? cnt[i] : 0;
  buf[threadIdx.x] = v;
  __syncthreads();
  for (int o = 1; o < 1024; o <<= 1) {
    int t = (threadIdx.x >= o) ? buf[threadIdx.x - o] : 0;
    __syncthreads();
    buf[threadIdx.x] += t;
    __syncthreads();
  }
  if (i < L) off[i] = buf[threadIdx.x] - v + bsum[blockIdx.x];
}

__global__ void copy_int_k(const int* __restrict__ a, int* __restrict__ b, int n) {
  for (int i = blockIdx.x * blockDim.x + threadIdx.x; i < n; i += blockDim.x * gridDim.x) b[i] = a[i];
}

__global__ void fill_src_k(const int* __restrict__ src, const int* __restrict__ dst,
                           const int* __restrict__ et, int* __restrict__ cursor,
                           int* __restrict__ esrc, int N, int E) {
  for (int e = blockIdx.x * blockDim.x + threadIdx.x; e < E; e += blockDim.x * gridDim.x) {
    int p = atomicAdd(&cursor[et[e] * N + dst[e]], 1);
    esrc[p] = src[e];
  }
}

// ---- weight packs ----

// Wcat8[200][832] fp8: [o][k*200+kk]=W[k][o][kk]; [o][800+k]=b[k][o]; else 0
__global__ void pack_wcat8_k(const float* __restrict__ W, const float* __restrict__ gb,
                             u8* __restrict__ dst) {
  int total = 200 * 832;
  for (int i = blockIdx.x * blockDim.x + threadIdx.x; i < total; i += blockDim.x * gridDim.x) {
    int o = i / 832, kp = i - o * 832;
    float v = 0.f;
    if (kp < 800) { int k = kp / 200, kk = kp - k * 200; v = W[((size_t)k * 200 + o) * 200 + kk]; }
    else if (kp < 804) v = gb[(kp - 800) * 200 + o];
    dst[i] = f2fp8(v);
  }
}

// Wall_i[800][448] gate-interleaved (row 4o+g)
__global__ void pack_wall_i_k(const float* __restrict__ Wih, const float* __restrict__ Whh,
                              u16* __restrict__ dst) {
  int total = 800 * 448;
  for (int i = blockIdx.x * blockDim.x + threadIdx.x; i < total; i += blockDim.x * gridDim.x) {
    int jp = i / 448, kp = i - jp * 448;
    int o = jp >> 2, g = jp & 3;
    float v = 0.f;
    if (g == 0) {
      if (kp < 200) v = Wih[(size_t)o * 200 + kp];
      else if (kp >= 224 && kp < 424) v = Whh[(size_t)o * 200 + (kp - 224)];
    } else if (g == 1) {
      if (kp < 200) v = Wih[(size_t)(200 + o) * 200 + kp];
      else if (kp >= 224 && kp < 424) v = Whh[(size_t)(200 + o) * 200 + (kp - 224)];
    } else if (g == 2) {
      if (kp < 200) v = Wih[(size_t)(400 + o) * 200 + kp];
    } else {
      if (kp >= 224 && kp < 424) v = Whh[(size_t)(400 + o) * 200 + (kp - 224)];
    }
    dst[i] = f2bf(v);
  }
}

__global__ void ball_i_k(const float* __restrict__ bih, const float* __restrict__ bhh,
                         float* __restrict__ ball) {
  int j = blockIdx.x * blockDim.x + threadIdx.x;
  if (j < 800) {
    int o = j >> 2, g = j & 3;
    float v;
    if (g == 0) v = bih[o] + bhh[o];
    else if (g == 1) v = bih[200 + o] + bhh[200 + o];
    else if (g == 2) v = bih[400 + o];
    else v = bhh[400 + o];
    ball[j] = v;
  }
}

__global__ void pack_lin_b(const float* __restrict__ src, u16* __restrict__ dst,
                           int Nn, int K, int Kp) {
  int total = Nn * Kp;
  for (int i = blockIdx.x * blockDim.x + threadIdx.x; i < total; i += blockDim.x * gridDim.x) {
    int o = i / Kp, kp = i - o * Kp;
    dst[i] = (kp < K) ? f2bf(src[(size_t)o * K + kp]) : (u16)0;
  }
}

__global__ void pack_w1c_k(const float* __restrict__ src, u16* __restrict__ dst) {
  int total = 200 * 1056;
  for (int i = blockIdx.x * blockDim.x + threadIdx.x; i < total; i += blockDim.x * gridDim.x) {
    int o = i / 1056, r = i - o * 1056;
    int t = r / 352, kp = r - t * 352;
    dst[i] = (kp < 200) ? f2bf(src[((size_t)o * 200 + kp) * 3 + t]) : (u16)0;
  }
}

__global__ void pack_wc1_b(const float* __restrict__ src, u16* __restrict__ dst) {
  int total = 300 * 1056;
  for (int i = blockIdx.x * blockDim.x + threadIdx.x; i < total; i += blockDim.x * gridDim.x) {
    int o = i / 1056, r = i - o * 1056;
    int t = r / 352, kp = r - t * 352;
    int ci = (kp < 224) ? (kp < 200 ? kp : -1) : ((kp - 224) < 100 ? 200 + (kp - 224) : -1);
    dst[i] = (ci >= 0) ? f2bf(src[((size_t)o * 300 + ci) * 3 + t]) : (u16)0;
  }
}

// aggregation from fp8 table -> fp8 scat (full N): wave per (node,etype);
// 4 edges in flight via 16-lane sub-groups; shfl_xor reduce.
__global__ void agg8_k(const int* __restrict__ off_et, const int* __restrict__ deg_et,
                       const int* __restrict__ esrc, const u8* __restrict__ h8,
                       u8* __restrict__ scat8, int N) {
  int gtid = blockIdx.x * blockDim.x + threadIdx.x;
  int wid = gtid >> 6, lane = threadIdx.x & 63;
  int nw = (blockDim.x * gridDim.x) >> 6;
  int sub = lane >> 4, l = lane & 15;
  int total = N * 4;
  for (int u = wid; u < total; u += nw) {
    int n = u >> 2, k = u & 3;
    u8* srow = scat8 + (size_t)n * 832;
    int rs = off_et[(size_t)k * N + n], d = deg_et[(size_t)k * N + n];
    float a[16];
#pragma unroll
    for (int j = 0; j < 16; ++j) a[j] = 0.f;
    if (l < 13) {
      for (int i = sub; i < d; i += 4) {
        const u8* hr = h8 + (size_t)esrc[rs + i] * 224 + l * 16;
        uint4 v = *reinterpret_cast<const uint4*>(hr);
        f32x2 p;
        p = __builtin_amdgcn_cvt_pk_f32_fp8(v.x, 0); a[0] += p[0]; a[1] += p[1];
        p = __builtin_amdgcn_cvt_pk_f32_fp8(v.x, 1); a[2] += p[0]; a[3] += p[1];
        p = __builtin_amdgcn_cvt_pk_f32_fp8(v.y, 0); a[4] += p[0]; a[5] += p[1];
        p = __builtin_amdgcn_cvt_pk_f32_fp8(v.y, 1); a[6] += p[0]; a[7] += p[1];
        p = __builtin_amdgcn_cvt_pk_f32_fp8(v.z, 0); a[8] += p[0]; a[9] += p[1];
        p = __builtin_amdgcn_cvt_pk_f32_fp8(v.z, 1); a[10] += p[0]; a[11] += p[1];
        p = __builtin_amdgcn_cvt_pk_f32_fp8(v.w, 0); a[12] += p[0]; a[13] += p[1];
        p = __builtin_amdgcn_cvt_pk_f32_fp8(v.w, 1); a[14] += p[0]; a[15] += p[1];
      }
    }
#pragma unroll
    for (int j = 0; j < 16; ++j) {
      a[j] += __shfl_xor(a[j], 16);
      a[j] += __shfl_xor(a[j], 32);
    }
    if (sub == 0 && l < 13) {
      u64 r0 = 0, r1 = 0;
#pragma unroll
      for (int j = 0; j < 8; ++j) r0 |= (u64)f2fp8(a[j]) << (8 * j);
#pragma unroll
      for (int j = 0; j < 8; ++j) r1 |= (u64)f2fp8(a[j + 8]) << (8 * j);
      *reinterpret_cast<u64*>(srow + k * 200 + l * 16) = r0;
      if (l < 12) *reinterpret_cast<u64*>(srow + k * 200 + l * 16 + 8) = r1;
    }
    if (k == 0 && lane == 13) {
      unsigned rr = 0;
#pragma unroll
      for (int kk = 0; kk < 4; ++kk)
        rr |= (unsigned)f2fp8((float)deg_et[(size_t)kk * N + n]) << (8 * kk);
      *reinterpret_cast<unsigned*>(srow + 800) = rr;
    }
    if (k == 3 && lane >= 32 && lane < 39)
      *reinterpret_cast<unsigned*>(srow + 804 + (lane - 32) * 4) = 0;
  }
}

// ------- fp8 MFMA GEMM (phase A): 256x128 tile, K-step 32 fp8, 3-deep pipeline ----
// LDS per buffer: A 256x32B, B 128x32B; 16B chunk swizzle: phys = c ^ (row&1).
__global__ __launch_bounds__(512, 4) void gemm_a8(
    const u8* __restrict__ A, int lda,
    const u8* __restrict__ B, int ldb,
    u16* __restrict__ Cb, int ldcb, int npad,
    int M, int Nn, int K, int gyr) {
  const int gx = gridDim.x;
  int lin = blockIdx.y * gx + blockIdx.x;
  int k8 = lin & 7, j = lin >> 3;
  int band = gridDim.y >> 3;
  int yy = j / gx, xx = j - yy * gx;
  int by = k8 * band + yy;
  if (by >= gyr) return;
  const int m0 = by * 256, n0 = xx * 128;

  __shared__ __align__(16) u8 As[3 * 8192];
  __shared__ __align__(16) u8 Bs[3 * 4096];
  const int tid = threadIdx.x;
  const int lane = tid & 63;
  const int w = tid >> 6;
  const int wr = w >> 1, wc = w & 1;
  const int fr = lane & 15;
  const int g = lane >> 4;

  // A staging: slot s=tid (512 = 256 rows x 2 chunks)
  const int rowA = tid >> 1;
  const int cA = (tid & 1) ^ (rowA & 1);
  int gaA = m0 + rowA; if (gaA >= M) gaA = M - 1;
  const u8* pa = A + (size_t)gaA * lda + cA * 16;
  u8* lA = &As[(size_t)(w * 64) * 16];
  // B staging: lanes <32, slot sB = w*32 + l (256 = 128 rows x 2 chunks)
  const int sB = w * 32 + (lane & 31);
  const int rowB = sB >> 1;
  const int cB = (sB & 1) ^ (rowB & 1);
  int gbB = n0 + rowB; if (gbB >= Nn) gbB = Nn - 1;
  const u8* pb = B + (size_t)gbB * ldb + cB * 16;
  u8* lB = &Bs[(size_t)(w * 32) * 16];
  const bool doB = (lane < 32);

  // fragment read: logical byte col g*8 -> chunk (g>>1)^(fr&1), off (g&1)*8
  const int rdoff = (((g >> 1) ^ (fr & 1)) << 4) + ((g & 1) << 3);

  f32x4 acc[4][4] = {};
  const int nt = K >> 5;
  const int ABUF = 8192, BBUF = 4096;

  gload16(pa, lA);
  if (doB) gload16(pb, lB);
  pa += 32; pb += 32;
  if (nt > 1) {
    gload16(pa, lA + ABUF);
    if (doB) gload16(pb, lB + BBUF);
    pa += 32; pb += 32;
  }

  for (int t = 0; t < nt; ++t) {
    if (t + 1 < nt) asm volatile("s_waitcnt vmcnt(2)" ::: "memory");
    else            asm volatile("s_waitcnt vmcnt(0)" ::: "memory");
    __builtin_amdgcn_s_barrier();
    if (t + 2 < nt) {
      int bi = (t + 2) % 3;
      gload16(pa, lA + bi * ABUF);
      if (doB) gload16(pb, lB + bi * BBUF);
      pa += 32; pb += 32;
    }
    int ca = (t % 3) * ABUF, cbb = (t % 3) * BBUF;
    long af[4], bfv[4];
#pragma unroll
    for (int i = 0; i < 4; ++i) {
      int row = wr * 64 + i * 16 + fr;
      af[i] = *reinterpret_cast<const long*>(&As[ca + row * 32 + rdoff]);
    }
#pragma unroll
    for (int jj = 0; jj < 4; ++jj) {
      int row = wc * 64 + jj * 16 + fr;
      bfv[jj] = *reinterpret_cast<const long*>(&Bs[cbb + row * 32 + rdoff]);
    }
    __builtin_amdgcn_s_setprio(1);
#pragma unroll
    for (int i = 0; i < 4; ++i)
#pragma unroll
      for (int jj = 0; jj < 4; ++jj)
        acc[i][jj] = __builtin_amdgcn_mfma_f32_16x16x32_fp8_fp8(af[i], bfv[jj], acc[i][jj], 0, 0, 0);
    __builtin_amdgcn_s_setprio(0);
  }

  const int er = (lane >> 4) * 4;
  const int ec = lane & 15;
#pragma unroll
  for (int i = 0; i < 4; ++i) {
#pragma unroll
    for (int jj = 0; jj < 4; ++jj) {
      int n = n0 + wc * 64 + jj * 16 + ec;
#pragma unroll
      for (int r = 0; r < 4; ++r) {
        int m = m0 + wr * 64 + i * 16 + er + r;
        if (m >= M) continue;
        if (n < Nn) Cb[(size_t)m * ldcb + n] = f2bf(acc[i][jj][r]);
        else if (n < npad) Cb[(size_t)m * ldcb + n] = (u16)0;
      }
    }
  }
}

// ------- generic bf16 MFMA GEMM, 256x128 tile (conv paths) ------
__global__ __launch_bounds__(512, 4) void gemm_mfma(
    const u16* __restrict__ A, int lda,
    const u16* __restrict__ B, int ldb,
    u16* __restrict__ Cb, int ldcb, int npad,
    int M, int Nn, int K, const float* __restrict__ bias, int gyr) {
  const int gx = gridDim.x;
  int lin = blockIdx.y * gx + blockIdx.x;
  int k8 = lin & 7, j = lin >> 3;
  int band = gridDim.y >> 3;
  int yy = j / gx, xx = j - yy * gx;
  int by = k8 * band + yy;
  if (by >= gyr) return;
  const int m0 = by * 256, n0 = xx * 128;

  __shared__ __align__(16) u16 As[3 * 8192];
  __shared__ __align__(16) u16 Bs[3 * 4096];
  const int tid = threadIdx.x;
  const int lane = tid & 63;
  const int w = tid >> 6;
  const int wr = w >> 1, wc = w & 1;
  const int fr = lane & 15;
  const int g = lane >> 4;

  const int sA0 = w * 64 + lane, sA1 = sA0 + 512, sB = sA0;
  int rA0 = sA0 >> 2, cA0 = (sA0 & 3) ^ ((rA0 >> 1) & 3);
  int rA1 = sA1 >> 2, cA1 = (sA1 & 3) ^ ((rA1 >> 1) & 3);
  int rB  = sB  >> 2, cB  = (sB & 3) ^ ((rB >> 1) & 3);
  int ga0 = m0 + rA0; if (ga0 >= M) ga0 = M - 1;
  int ga1 = m0 + rA1; if (ga1 >= M) ga1 = M - 1;
  int gb  = n0 + rB;  if (gb >= Nn) gb = Nn - 1;
  const u16* pa0 = A + (size_t)ga0 * lda + cA0 * 8;
  const u16* pa1 = A + (size_t)ga1 * lda + cA1 * 8;
  const u16* pb  = B + (size_t)gb  * ldb + cB * 8;
  u16* lA0 = &As[(w * 64) * 8];
  u16* lA1 = &As[(512 + w * 64) * 8];
  u16* lB  = &Bs[(w * 64) * 8];

  const int gxr = g ^ ((fr >> 1) & 3);

  f32x4 acc[4][4] = {};
  const int nt = K >> 5;
  const int ABUF = 8192, BBUF = 4096;

  gload16(pa0, lA0); gload16(pa1, lA1); gload16(pb, lB);
  pa0 += 32; pa1 += 32; pb += 32;
  if (nt > 1) {
    gload16(pa0, lA0 + ABUF); gload16(pa1, lA1 + ABUF); gload16(pb, lB + BBUF);
    pa0 += 32; pa1 += 32; pb += 32;
  }

  for (int t = 0; t < nt; ++t) {
    if (t + 1 < nt) asm volatile("s_waitcnt vmcnt(3)" ::: "memory");
    else            asm volatile("s_waitcnt vmcnt(0)" ::: "memory");
    __builtin_amdgcn_s_barrier();
    if (t + 2 < nt) {
      int bi = (t + 2) % 3;
      gload16(pa0, lA0 + bi * ABUF); gload16(pa1, lA1 + bi * ABUF); gload16(pb, lB + bi * BBUF);
      pa0 += 32; pa1 += 32; pb += 32;
    }
    int ca = (t % 3) * ABUF, cbb = (t % 3) * BBUF;
    bf16x8 af[4], bfv[4];
#pragma unroll
    for (int i = 0; i < 4; ++i) {
      int row = wr * 64 + i * 16 + fr;
      af[i] = *reinterpret_cast<const bf16x8*>(&As[ca + (row * 4 + gxr) * 8]);
    }
#pragma unroll
    for (int jj = 0; jj < 4; ++jj) {
      int row = wc * 64 + jj * 16 + fr;
      bfv[jj] = *reinterpret_cast<const bf16x8*>(&Bs[cbb + (row * 4 + gxr) * 8]);
    }
    __builtin_amdgcn_s_setprio(1);
#pragma unroll
    for (int i = 0; i < 4; ++i)
#pragma unroll
      for (int jj = 0; jj < 4; ++jj)
        acc[i][jj] = __builtin_amdgcn_mfma_f32_16x16x32_bf16(af[i], bfv[jj], acc[i][jj], 0, 0, 0);
    __builtin_amdgcn_s_setprio(0);
  }

  const int er = (lane >> 4) * 4;
  const int ec = lane & 15;
#pragma unroll
  for (int i = 0; i < 4; ++i) {
#pragma unroll
    for (int jj = 0; jj < 4; ++jj) {
      int n = n0 + wc * 64 + jj * 16 + ec;
#pragma unroll
      for (int r = 0; r < 4; ++r) {
        int m = m0 + wr * 64 + i * 16 + er + r;
        if (m >= M) continue;
        if (n < Nn) {
          float v = acc[i][jj][r];
          if (bias) v += bias[n];
          Cb[(size_t)m * ldcb + n] = f2bf(v);
        } else if (n < npad) {
          Cb[(size_t)m * ldcb + n] = (u16)0;
        }
      }
    }
  }
}

// ------- gates GEMM with fused GRU epilogue (Nn=800 interleaved, gx=7) ------
__global__ __launch_bounds__(512, 4) void gemm_gru(
    const u16* __restrict__ A, int lda,
    const u16* __restrict__ B, int ldb,
    int M, int K, const float* __restrict__ bias,
    u16* __restrict__ hnew, u8* __restrict__ h8c, int gyr) {
  const int gx = gridDim.x;
  int lin = blockIdx.y * gx + blockIdx.x;
  int k8 = lin & 7, j = lin >> 3;
  int band = gridDim.y >> 3;
  int yy = j / gx, xx = j - yy * gx;
  int by = k8 * band + yy;
  if (by >= gyr) return;
  const int m0 = by * 256, n0 = xx * 128;
  const int Nn = 800;

  __shared__ __align__(16) u16 SM[3 * 8192 + 3 * 4096];
  u16* As = SM;
  u16* Bs = SM + 3 * 8192;
  const int tid = threadIdx.x;
  const int lane = tid & 63;
  const int w = tid >> 6;
  const int wr = w >> 1, wc = w & 1;
  const int fr = lane & 15;
  const int g = lane >> 4;

  const int sA0 = w * 64 + lane, sA1 = sA0 + 512, sB = sA0;
  int rA0 = sA0 >> 2, cA0 = (sA0 & 3) ^ ((rA0 >> 1) & 3);
  int rA1 = sA1 >> 2, cA1 = (sA1 & 3) ^ ((rA1 >> 1) & 3);
  int rB  = sB  >> 2, cB  = (sB & 3) ^ ((rB >> 1) & 3);
  int ga0 = m0 + rA0; if (ga0 >= M) ga0 = M - 1;
  int ga1 = m0 + rA1; if (ga1 >= M) ga1 = M - 1;
  int gb  = n0 + rB;  if (gb >= Nn) gb = Nn - 1;
  const u16* pa0 = A + (size_t)ga0 * lda + cA0 * 8;
  const u16* pa1 = A + (size_t)ga1 * lda + cA1 * 8;
  const u16* pb  = B + (size_t)gb  * ldb + cB * 8;
  u16* lA0 = &As[(w * 64) * 8];
  u16* lA1 = &As[(512 + w * 64) * 8];
  u16* lB  = &Bs[(w * 64) * 8];

  const int gxr = g ^ ((fr >> 1) & 3);

  f32x4 acc[4][4] = {};
  const int nt = K >> 5;
  const int ABUF = 8192, BBUF = 4096;

  gload16(pa0, lA0); gload16(pa1, lA1); gload16(pb, lB);
  pa0 += 32; pa1 += 32; pb += 32;
  if (nt > 1) {
    gload16(pa0, lA0 + ABUF); gload16(pa1, lA1 + ABUF); gload16(pb, lB + BBUF);
    pa0 += 32; pa1 += 32; pb += 32;
  }

  for (int t = 0; t < nt; ++t) {
    if (t + 1 < nt) asm volatile("s_waitcnt vmcnt(3)" ::: "memory");
    else            asm volatile("s_waitcnt vmcnt(0)" ::: "memory");
    __builtin_amdgcn_s_barrier();
    if (t + 2 < nt) {
      int bi = (t + 2) % 3;
      gload16(pa0, lA0 + bi * ABUF); gload16(pa1, lA1 + bi * ABUF); gload16(pb, lB + bi * BBUF);
      pa0 += 32; pa1 += 32; pb += 32;
    }
    int ca = (t % 3) * ABUF, cbb = (t % 3) * BBUF;
    bf16x8 af[4], bfv[4];
#pragma unroll
    for (int i = 0; i < 4; ++i) {
      int row = wr * 64 + i * 16 + fr;
      af[i] = *reinterpret_cast<const bf16x8*>(&As[ca + (row * 4 + gxr) * 8]);
    }
#pragma unroll
    for (int jj = 0; jj < 4; ++jj) {
      int row = wc * 64 + jj * 16 + fr;
      bfv[jj] = *reinterpret_cast<const bf16x8*>(&Bs[cbb + (row * 4 + gxr) * 8]);
    }
    __builtin_amdgcn_s_setprio(1);
#pragma unroll
    for (int i = 0; i < 4; ++i)
#pragma unroll
      for (int jj = 0; jj < 4; ++jj)
        acc[i][jj] = __builtin_amdgcn_mfma_f32_16x16x32_bf16(af[i], bfv[jj], acc[i][jj], 0, 0, 0);
    __builtin_amdgcn_s_setprio(0);
  }

  // ---- fused GRU epilogue ----
  const int er = (lane >> 4) * 4;
  const int ec = lane & 15;
  __syncthreads();
  float* ep = (float*)SM + (size_t)w * 2048;   // per-wave [64][32] f32

  for (int hh = 0; hh < 2; ++hh) {
#pragma unroll
    for (int jj2 = 0; jj2 < 2; ++jj2) {
      int jj = hh * 2 + jj2;
      int n = n0 + wc * 64 + jj * 16 + ec;
      float bv = (n < 800) ? bias[n] : 0.f;
#pragma unroll
      for (int i = 0; i < 4; ++i)
#pragma unroll
        for (int r = 0; r < 4; ++r) {
          int row_loc = i * 16 + er + r;
          ep[row_loc * 32 + jj2 * 16 + ec] = acc[i][jj][r] + bv;
        }
    }
    __syncthreads();
#pragma unroll
    for (int p = 0; p < 8; ++p) {
      int idx = p * 64 + lane;
      int row = idx >> 3, og = idx & 7;
      int n_base = n0 + wc * 64 + hh * 32 + og * 4;
      int m = m0 + wr * 64 + row;
      if (n_base < 800 && m < M) {
        f32x4 gv = *reinterpret_cast<f32x4*>(&ep[row * 32 + og * 4]);
        float rg = sigm(gv[0]);
        float zg = sigm(gv[1]);
        float x = gv[2] + rg * gv[3];
        float e2 = __expf(2.f * x);
        float nn = (e2 - 1.f) / (e2 + 1.f);
        int o = n_base >> 2;
        float hold = bf2f(A[(size_t)m * 448 + 224 + o]);
        float hv = (1.f - zg) * nn + zg * hold;
        hnew[(size_t)m * 224 + o] = f2bf(hv);
        h8c[(size_t)m * 224 + o] = f2fp8(hv);
      }
    }
    __syncthreads();
  }
}

// merge hnew (bf16, stride 224) into ah h-slice
__global__ void hcopy_k(const u16* __restrict__ hn_, u16* __restrict__ ahc, int Nc) {
  int total = Nc * 200;
  for (int i = blockIdx.x * blockDim.x + threadIdx.x; i < total; i += blockDim.x * gridDim.x) {
    int n = i / 200, o = i - n * 200;
    ahc[(size_t)n * 448 + 224 + o] = hn_[(size_t)n * 224 + o];
  }
}

// cmat[n][352] = [h(224) | feat(100) | 0(28)]
__global__ void cmat_k(const u16* __restrict__ ah, const float* __restrict__ feat,
                       u16* __restrict__ c, int N) {
  int total = N * 352;
  for (int i = blockIdx.x * blockDim.x + threadIdx.x; i < total; i += blockDim.x * gridDim.x) {
    int n = i / 352, j = i - n * 352;
    u16 v;
    if (j < 224) v = ah[(size_t)n * 448 + 224 + j];
    else { int f = j - 224; v = (f < 100) ? f2bf(feat[(size_t)n * 100 + f]) : (u16)0; }
    c[i] = v;
  }
}

__global__ __launch_bounds__(1024) void bn_stats2_k(const u16* __restrict__ X, int L, int C,
                                                    float* __restrict__ stats) {
  const int Q = 1024 / C;
  const int T = Q * C;
  const int tid = threadIdx.x;
  float s = 0.f, q = 0.f;
  int c = 0;
  if (tid < T) {
    int qi = tid / C; c = tid - qi * C;
    for (size_t r = (size_t)blockIdx.x * Q + qi; r < (size_t)L; r += (size_t)gridDim.x * Q) {
      float v = bf2f(X[r * C + c]);
      s += v; q += v * v;
    }
  }
  __shared__ float sb[304], qb[304];
  for (int cc = tid; cc < C; cc += 1024) { sb[cc] = 0.f; qb[cc] = 0.f; }
  __syncthreads();
  if (tid < T) { atomicAdd(&sb[c], s); atomicAdd(&qb[c], q); }
  __syncthreads();
  for (int cc = tid; cc < C; cc += 1024) {
    atomicAdd(&stats[cc], sb[cc]);
    atomicAdd(&stats[C + cc], qb[cc]);
  }
}

__global__ void bn_fin_k(const float* __restrict__ stats, const float* __restrict__ g,
                         const float* __restrict__ b, int C, float Linv,
                         float* __restrict__ scsh) {
  int c = blockIdx.x * blockDim.x + threadIdx.x;
  if (c < C) {
    float mean = stats[c] * Linv;
    float var = stats[C + c] * Linv - mean * mean;
    float sc = g[c] * rsqrtf(var + 1e-5f);
    scsh[c] = sc;
    scsh[C + c] = b[c] - mean * sc;
  }
}

__global__ void pool_bf_k(const u16* __restrict__ X, int C, const float* __restrict__ scsh,
                          int kw, int stride, u16* __restrict__ Y, int Cpad, int Lout) {
  int total = Lout * Cpad;
  for (int i = blockIdx.x * blockDim.x + threadIdx.x; i < total; i += blockDim.x * gridDim.x) {
    int lp = i / Cpad, c = i - lp * Cpad;
    if (c >= C) { Y[i] = (u16)0; continue; }
    float sc = scsh[c], sh = scsh[C + c];
    int l0 = lp * stride;
    float m = 0.f;
    for (int wq = 0; wq < kw; ++wq)
      m = fmaxf(m, fmaf(bf2f(X[(size_t)(l0 + wq) * C + c]), sc, sh));
    Y[i] = f2bf(m);
  }
}

__global__ void pool_f32_k(const u16* __restrict__ X, int C, const float* __restrict__ scsh,
                           int kw, int stride, float* __restrict__ Y, int Lout) {
  int total = Lout * C;
  for (int i = blockIdx.x * blockDim.x + threadIdx.x; i < total; i += blockDim.x * gridDim.x) {
    int lp = i / C, c = i - lp * C;
    float sc = scsh[c], sh = scsh[C + c];
    int l0 = lp * stride;
    float m = 0.f;
    for (int wq = 0; wq < kw; ++wq)
      m = fmaxf(m, fmaf(bf2f(X[(size_t)(l0 + wq) * C + c]), sc, sh));
    Y[i] = m;
  }
}

__global__ __launch_bounds__(256) void final_dot_k(
    const float* __restrict__ Y2, const float* __restrict__ Z2,
    const float* __restrict__ wy, const float* __restrict__ by,
    const float* __restrict__ wz, const float* __restrict__ bz,
    float* __restrict__ acc, int L) {
  float s0 = 0.f, s1 = 0.f;
  for (int lp = blockIdx.x * blockDim.x + threadIdx.x; lp < L; lp += blockDim.x * gridDim.x) {
    const float* y = Y2 + (size_t)lp * 200;
    const float* z = Z2 + (size_t)lp * 300;
    float d0 = 0.f, d1 = 0.f;
    for (int k = 0; k < 200; ++k) { float v = y[k]; d0 += v * wy[k]; d1 += v * wy[200 + k]; }
    float e0 = 0.f, e1 = 0.f;
    for (int k = 0; k < 300; ++k) { float v = z[k]; e0 += v * wz[k]; e1 += v * wz[300 + k]; }
    s0 += (d0 + by[0]) * (e0 + bz[0]);
    s1 += (d1 + by[1]) * (e1 + bz[1]);
  }
  __shared__ float r0[256], r1[256];
  r0[threadIdx.x] = s0; r1[threadIdx.x] = s1;
  __syncthreads();
  for (int off = 128; off > 0; off >>= 1) {
    if (threadIdx.x < off) { r0[threadIdx.x] += r0[threadIdx.x + off]; r1[threadIdx.x] += r1[threadIdx.x + off]; }
    __syncthreads();
  }
  if (threadIdx.x == 0) { atomicAdd(&acc[0], r0[0]); atomicAdd(&acc[1], r1[0]); }
}

__global__ void final_out_k(const float* __restrict__ acc, float invL, float* __restrict__ out) {
  int j = threadIdx.x;
  if (j < 2) out[j] = 1.f / (1.f + expf(-acc[j] * invL));
}

// ---------------- host ----------------

static inline void gemmL(hipStream_t st, const u16* A, int lda, const u16* B, int ldb,
                         u16* Cb, int ldcb, int npad, int M, int Nn, int K, const float* bias) {
  int ncols = (npad > Nn) ? npad : Nn;
  int gx = (ncols + 127) / 128;
  int gy = (M + 255) / 256;
  int gyp = ((gy + 7) / 8) * 8;
  dim3 g(gx, gyp);
  gemm_mfma<<<g, 512, 0, st>>>(A, lda, B, ldb, Cb, ldcb, npad, M, Nn, K, bias, gy);
}

extern "C" void kernel_launch(void* const* d_in, const int* in_sizes, int n_in,
                              void* d_out, int out_size, void* d_ws, size_t ws_size,
                              hipStream_t stream) {
  (void)n_in; (void)out_size;
  const float* feat    = (const float*)d_in[0];
  const int*   eix     = (const int*)d_in[1];
  const int*   etyp    = (const int*)d_in[2];
  const float* ggnnW   = (const float*)d_in[3];
  const float* ggnnB   = (const float*)d_in[4];
  const float* Wih     = (const float*)d_in[5];
  const float* Whh     = (const float*)d_in[6];
  const float* bih     = (const float*)d_in[7];
  const float* bhh     = (const float*)d_in[8];
  const float* conv1w  = (const float*)d_in[9];
  const float* conv2w  = (const float*)d_in[11];
  const float* convc1w = (const float*)d_in[13];
  const float* convc2w = (const float*)d_in[15];
  const float* bnyg    = (const float*)d_in[17];
  const float* bnyb    = (const float*)d_in[18];
  const float* bncg    = (const float*)d_in[19];
  const float* bncb    = (const float*)d_in[20];
  const float* mlpyw   = (const float*)d_in[21];
  const float* mlpyb   = (const float*)d_in[22];
  const float* mlpzw   = (const float*)d_in[23];
  const float* mlpzb   = (const float*)d_in[24];

  const int N = in_sizes[0] / 100;
  const int E = in_sizes[2];
  const int* src = eix;
  const int* dst = eix + E;

  char* base = (char*)d_ws;
  const size_t AH_B = (size_t)N * 448 * 2;
  const int CH = (N + 1) / 2;
  const size_t SCR_B = (size_t)CH * 1664;   // >= N*832 (scat8) and N*352*2 (cmat)

  u16* ah = (u16*)base;
  char* R1 = base + AH_B;
  char* WREG = R1 + SCR_B;

  u8*  Wcat8 = (u8*)WREG;                  // 200*832 fp8
  u16* Wall = (u16*)(WREG + 166400);       // 800*448 (interleaved)
  u16* w1c  = Wall + 358400;               // 200*1056
  u16* c2b  = w1c + 211200;                // 200*224
  u16* wc1  = c2b + 44800;                 // 300*1056
  u16* wc2  = wc1 + 316800;                // 300*320
  float* ball  = (float*)(wc2 + 96000);    // 800
  float* stats = ball + 832;               // 600
  float* scsh  = stats + 600;              // 600
  float* acc2  = scsh + 600;               // 2 (+pad)
  int* deg_et = (int*)(acc2 + 8);
  int* off_et = deg_et + 4 * (size_t)N;
  int* cursor = off_et + 4 * (size_t)N;
  int* esrc   = cursor + 4 * (size_t)N;
  int* bsum   = esrc + E;
  const int L4 = 4 * N;
  const int NB = (L4 + 1023) / 1024;
  u8* h8 = (u8*)(((uintptr_t)(bsum + NB) + 255) & ~(uintptr_t)255);
  size_t need = (size_t)((h8 + (size_t)N * 224) - (u8*)base);

  if (ws_size < need) {
    fail_k<<<1, 64, 0, stream>>>((float*)d_out, -(float)(ws_size >> 20));
    return;
  }

  // ---- CSR build + packs ----
  hipMemsetAsync(deg_et, 0, sizeof(int) * 4 * (size_t)N, stream);
  init_ah_k<<<4096, 256, 0, stream>>>(feat, ah, N);
  init_h8_k<<<2048, 256, 0, stream>>>(feat, h8, N);
  count_deg_k<<<2048, 256, 0, stream>>>(dst, etyp, deg_et, N, E);
  bsum_k<<<NB, 1024, 0, stream>>>(deg_et, bsum, L4);
  scanb_k<<<1, 1024, 0, stream>>>(bsum, NB);
  scan_fin_k<<<NB, 1024, 0, stream>>>(deg_et, bsum, off_et, L4);
  copy_int_k<<<512, 256, 0, stream>>>(off_et, cursor, L4);
  fill_src_k<<<2048, 256, 0, stream>>>(src, dst, etyp, cursor, esrc, N, E);
  pack_wcat8_k<<<651, 256, 0, stream>>>(ggnnW, ggnnB, Wcat8);
  pack_wall_i_k<<<1400, 256, 0, stream>>>(Wih, Whh, Wall);
  ball_i_k<<<4, 256, 0, stream>>>(bih, bhh, ball);
  pack_w1c_k<<<825, 256, 0, stream>>>(conv1w, w1c);
  pack_lin_b<<<175, 256, 0, stream>>>(conv2w, c2b, 200, 200, 224);
  pack_wc1_b<<<1238, 256, 0, stream>>>(convc1w, wc1);
  pack_lin_b<<<375, 256, 0, stream>>>(convc2w, wc2, 300, 300, 320);

  // ---- GGNN 8 steps (full-N, 4 dispatches/step) ----
  u8*  scat8 = (u8*)R1;          // N x 832 fp8
  u16* hnewb = (u16*)R1;         // N x 224 bf16 (phase B scratch; scat8 dead)

  const int gy = (N + 255) / 256;
  const int gyp = ((gy + 7) / 8) * 8;

  for (int step = 0; step < 8; ++step) {
    agg8_k<<<4096, 256, 0, stream>>>(off_et, deg_et, esrc, h8, scat8, N);
    gemm_a8<<<dim3(2, gyp), 512, 0, stream>>>(scat8, 832, Wcat8, 832,
                                              ah, 448, 224, N, 200, 832, gy);
    gemm_gru<<<dim3(7, gyp), 512, 0, stream>>>(ah, 448, Wall, 448, N, 448, ball,
                                               hnewb, h8, gy);
    hcopy_k<<<4096, 256, 0, stream>>>(hnewb, ah, N);
  }

  // ---- conv paths ----
  const int L1 = N - 2;
  const int L2 = (L1 - 3) / 2 + 1;
  const int L3 = (L2 - 2) / 2 + 1;

  u16* cmat = (u16*)R1;                                              // N*352
  u16* out1 = (u16*)base;                                            // L1*200
  size_t y1_off = (((size_t)L1 * 400) + 255) & ~(size_t)255;
  u16* y1 = (u16*)(base + y1_off);                                   // L2*224
  size_t o2_off = y1_off + ((((size_t)L2 * 448) + 255) & ~(size_t)255);
  u16* out2 = (u16*)(base + o2_off);                                 // L2*200
  float* Y2f = (float*)base;                                         // L3*200 f32
  size_t oc1_off = (((size_t)L3 * 800) + 255) & ~(size_t)255;
  u16* outc1 = (u16*)(base + oc1_off);                               // L1*300
  u16* z1 = (u16*)R1;                                                // L2*320
  size_t oc2_off = (((size_t)L2 * 640) + 255) & ~(size_t)255;
  u16* outc2 = (u16*)(R1 + oc2_off);                                 // L2*300
  float* Z2f = (float*)(base + oc1_off);                             // L3*300 f32

  cmat_k<<<4096, 256, 0, stream>>>(ah, feat, cmat, N);

  // Y path
  gemmL(stream, cmat, 352, w1c, 1056, out1, 200, 200, L1, 200, 1056, nullptr);
  hipMemsetAsync(stats, 0, sizeof(float) * 400, stream);
  bn_stats2_k<<<512, 1024, 0, stream>>>(out1, L1, 200, stats);
  bn_fin_k<<<2, 256, 0, stream>>>(stats, bnyg, bnyb, 200, 1.f / (float)L1, scsh);
  pool_bf_k<<<2048, 256, 0, stream>>>(out1, 200, scsh, 3, 2, y1, 224, L2);

  gemmL(stream, y1, 224, c2b, 224, out2, 200, 200, L2, 200, 224, nullptr);
  hipMemsetAsync(stats, 0, sizeof(float) * 400, stream);
  bn_stats2_k<<<512, 1024, 0, stream>>>(out2, L2, 200, stats);
  bn_fin_k<<<2, 256, 0, stream>>>(stats, bnyg, bnyb, 200, 1.f / (float)L2, scsh);
  pool_f32_k<<<2048, 256, 0, stream>>>(out2, 200, scsh, 2, 2, Y2f, L3);

  // Z path
  gemmL(stream, cmat, 352, wc1, 1056, outc1, 300, 300, L1, 300, 1056, nullptr);
  hipMemsetAsync(stats, 0, sizeof(float) * 600, stream);
  bn_stats2_k<<<512, 1024, 0, stream>>>(outc1, L1, 300, stats);
  bn_fin_k<<<2, 256, 0, stream>>>(stats, bncg, bncb, 300, 1.f / (float)L1, scsh);
  pool_bf_k<<<2048, 256, 0, stream>>>(outc1, 300, scsh, 3, 2, z1, 320, L2);

  gemmL(stream, z1, 320, wc2, 320, outc2, 300, 300, L2, 300, 320, nullptr);
  hipMemsetAsync(stats, 0, sizeof(float) * 600, stream);
  bn_stats2_k<<<512, 1024, 0, stream>>>(outc2, L2, 300, stats);
  bn_fin_k<<<2, 256, 0, stream>>>(stats, bncg, bncb, 300, 1.f / (float)L2, scsh);
  pool_f32_k<<<2048, 256, 0, stream>>>(outc2, 300, scsh, 2, 2, Z2f, L3);

  // ---- final MLP product + mean + sigmoid ----
  hipMemsetAsync(acc2, 0, sizeof(float) * 2, stream);
  final_dot_k<<<256, 256, 0, stream>>>(Y2f, Z2f, mlpyw, mlpyb, mlpzw, mlpzb, acc2, L3);
  final_out_k<<<1, 64, 0, stream>>>(acc2, 1.f / (float)L3, (float*)d_out);
}

// Round 14
// 3591.196 us; speedup vs baseline: 1.5023x; 1.0409x over previous
//
#include <hip/hip_runtime.h>
#include <cstddef>
#include <cstdint>

// ============================================================================
// DevignModel round 14: agg8 VALU diet.
//  - HW packed fp8 encode (v_cvt_pk_fp8_f32) replaces software __hip_cvt
//  - f32x2 packed accumulation (v_pk_add_f32) in the decode loop
//  - everything else unchanged from r13
// ============================================================================

typedef unsigned short u16;
typedef unsigned char u8;
typedef unsigned long long u64;
typedef __attribute__((ext_vector_type(8))) short bf16x8;
typedef __attribute__((ext_vector_type(4))) float f32x4;
typedef __attribute__((ext_vector_type(2))) float f32x2;
typedef __attribute__((ext_vector_type(4))) unsigned short u16x4;
typedef __attribute__((ext_vector_type(8))) unsigned short u16x8;

static __device__ __forceinline__ float bf2f(u16 u) {
  union { unsigned int i; float f; } v; v.i = ((unsigned int)u) << 16; return v.f;
}
static __device__ __forceinline__ u16 f2bf(float f) {
  union { float f; unsigned int i; } v; v.f = f;
  unsigned int r = v.i + 0x7FFFu + ((v.i >> 16) & 1u);
  return (u16)(r >> 16);
}
static __device__ __forceinline__ float sigm(float x) { return 1.f / (1.f + __expf(-x)); }
// HW fp8 e4m3 (OCP on gfx950) encode
static __device__ __forceinline__ u8 f2fp8(float x) {
  return (u8)(__builtin_amdgcn_cvt_pk_fp8_f32(x, 0.f, 0, false) & 0xff);
}

static __device__ __forceinline__ void gload16(const void* gp, void* lp) {
  __builtin_amdgcn_global_load_lds(
      (const __attribute__((address_space(1))) void*)gp,
      (__attribute__((address_space(3))) void*)lp, 16, 0, 0);
}

__global__ void fail_k(float* out, float code) { out[0] = code; out[1] = code; }

// ah[n][448]: [a(200)+pad24 | h(200)+pad24]; h0 = [feat | 0]
__global__ void init_ah_k(const float* __restrict__ feat, u16* __restrict__ ah, int N) {
  int total = N * 448;
  for (int i = blockIdx.x * blockDim.x + threadIdx.x; i < total; i += blockDim.x * gridDim.x) {
    int n = i / 448, j = i - n * 448;
    u16 v = 0;
    if (j >= 224 && j < 324) v = f2bf(feat[(size_t)n * 100 + (j - 224)]);
    ah[i] = v;
  }
}

// h8[n][224] fp8: [h(200) | 0(24)]
__global__ void init_h8_k(const float* __restrict__ feat, u8* __restrict__ h8, int N) {
  int total = N * 224;
  for (int i = blockIdx.x * blockDim.x + threadIdx.x; i < total; i += blockDim.x * gridDim.x) {
    int n = i / 224, c = i - n * 224;
    h8[i] = (c < 100) ? f2fp8(feat[(size_t)n * 100 + c]) : (u8)0;
  }
}

__global__ void count_deg_k(const int* __restrict__ dst, const int* __restrict__ et,
                            int* __restrict__ deg_et, int N, int E) {
  for (int e = blockIdx.x * blockDim.x + threadIdx.x; e < E; e += blockDim.x * gridDim.x)
    atomicAdd(&deg_et[et[e] * N + dst[e]], 1);
}

// ---- parallel exclusive scan (3 kernels) ----
__global__ __launch_bounds__(1024) void bsum_k(const int* __restrict__ cnt,
                                               int* __restrict__ bsum, int L) {
  __shared__ int buf[1024];
  int i = blockIdx.x * 1024 + threadIdx.x;
  buf[threadIdx.x] = (i < L) ? cnt[i] : 0;
  __syncthreads();
  for (int o = 512; o > 0; o >>= 1) {
    if (threadIdx.x < o) buf[threadIdx.x] += buf[threadIdx.x + o];
    __syncthreads();
  }
  if (threadIdx.x == 0) bsum[blockIdx.x] = buf[0];
}

__global__ __launch_bounds__(1024) void scanb_k(int* __restrict__ bsum, int nb) {
  __shared__ int buf[1024];
  int v = (threadIdx.x < nb) ? bsum[threadIdx.x] : 0;
  buf[threadIdx.x] = v;
  __syncthreads();
  for (int o = 1; o < 1024; o <<= 1) {
    int t = (threadIdx.x >= o) ? buf[threadIdx.x - o] : 0;
    __syncthreads();
    buf[threadIdx.x] += t;
    __syncthreads();
  }
  if (threadIdx.x < nb) bsum[threadIdx.x] = buf[threadIdx.x] - v;
}

__global__ __launch_bounds__(1024) void scan_fin_k(const int* __restrict__ cnt,
                                                   const int* __restrict__ bsum,
                                                   int* __restrict__ off, int L) {
  __shared__ int buf[1024];
  int i = blockIdx.x * 1024 + threadIdx.x;
  int v = (i < L) ? cnt[i] : 0;
  buf[threadIdx.x] = v;
  __syncthreads();
  for (int o = 1; o < 1024; o <<= 1) {
    int t = (threadIdx.x >= o) ? buf[threadIdx.x - o] : 0;
    __syncthreads();
    buf[threadIdx.x] += t;
    __syncthreads();
  }
  if (i < L) off[i] = buf[threadIdx.x] - v + bsum[blockIdx.x];
}

__global__ void copy_int_k(const int* __restrict__ a, int* __restrict__ b, int n) {
  for (int i = blockIdx.x * blockDim.x + threadIdx.x; i < n; i += blockDim.x * gridDim.x) b[i] = a[i];
}

__global__ void fill_src_k(const int* __restrict__ src, const int* __restrict__ dst,
                           const int* __restrict__ et, int* __restrict__ cursor,
                           int* __restrict__ esrc, int N, int E) {
  for (int e = blockIdx.x * blockDim.x + threadIdx.x; e < E; e += blockDim.x * gridDim.x) {
    int p = atomicAdd(&cursor[et[e] * N + dst[e]], 1);
    esrc[p] = src[e];
  }
}

// ---- weight packs ----

__global__ void pack_wcat8_k(const float* __restrict__ W, const float* __restrict__ gb,
                             u8* __restrict__ dst) {
  int total = 200 * 832;
  for (int i = blockIdx.x * blockDim.x + threadIdx.x; i < total; i += blockDim.x * gridDim.x) {
    int o = i / 832, kp = i - o * 832;
    float v = 0.f;
    if (kp < 800) { int k = kp / 200, kk = kp - k * 200; v = W[((size_t)k * 200 + o) * 200 + kk]; }
    else if (kp < 804) v = gb[(kp - 800) * 200 + o];
    dst[i] = f2fp8(v);
  }
}

// Wall_i[800][448] gate-interleaved (row 4o+g)
__global__ void pack_wall_i_k(const float* __restrict__ Wih, const float* __restrict__ Whh,
                              u16* __restrict__ dst) {
  int total = 800 * 448;
  for (int i = blockIdx.x * blockDim.x + threadIdx.x; i < total; i += blockDim.x * gridDim.x) {
    int jp = i / 448, kp = i - jp * 448;
    int o = jp >> 2, g = jp & 3;
    float v = 0.f;
    if (g == 0) {
      if (kp < 200) v = Wih[(size_t)o * 200 + kp];
      else if (kp >= 224 && kp < 424) v = Whh[(size_t)o * 200 + (kp - 224)];
    } else if (g == 1) {
      if (kp < 200) v = Wih[(size_t)(200 + o) * 200 + kp];
      else if (kp >= 224 && kp < 424) v = Whh[(size_t)(200 + o) * 200 + (kp - 224)];
    } else if (g == 2) {
      if (kp < 200) v = Wih[(size_t)(400 + o) * 200 + kp];
    } else {
      if (kp >= 224 && kp < 424) v = Whh[(size_t)(400 + o) * 200 + (kp - 224)];
    }
    dst[i] = f2bf(v);
  }
}

__global__ void ball_i_k(const float* __restrict__ bih, const float* __restrict__ bhh,
                         float* __restrict__ ball) {
  int j = blockIdx.x * blockDim.x + threadIdx.x;
  if (j < 800) {
    int o = j >> 2, g = j & 3;
    float v;
    if (g == 0) v = bih[o] + bhh[o];
    else if (g == 1) v = bih[200 + o] + bhh[200 + o];
    else if (g == 2) v = bih[400 + o];
    else v = bhh[400 + o];
    ball[j] = v;
  }
}

__global__ void pack_lin_b(const float* __restrict__ src, u16* __restrict__ dst,
                           int Nn, int K, int Kp) {
  int total = Nn * Kp;
  for (int i = blockIdx.x * blockDim.x + threadIdx.x; i < total; i += blockDim.x * gridDim.x) {
    int o = i / Kp, kp = i - o * Kp;
    dst[i] = (kp < K) ? f2bf(src[(size_t)o * K + kp]) : (u16)0;
  }
}

__global__ void pack_w1c_k(const float* __restrict__ src, u16* __restrict__ dst) {
  int total = 200 * 1056;
  for (int i = blockIdx.x * blockDim.x + threadIdx.x; i < total; i += blockDim.x * gridDim.x) {
    int o = i / 1056, r = i - o * 1056;
    int t = r / 352, kp = r - t * 352;
    dst[i] = (kp < 200) ? f2bf(src[((size_t)o * 200 + kp) * 3 + t]) : (u16)0;
  }
}

__global__ void pack_wc1_b(const float* __restrict__ src, u16* __restrict__ dst) {
  int total = 300 * 1056;
  for (int i = blockIdx.x * blockDim.x + threadIdx.x; i < total; i += blockDim.x * gridDim.x) {
    int o = i / 1056, r = i - o * 1056;
    int t = r / 352, kp = r - t * 352;
    int ci = (kp < 224) ? (kp < 200 ? kp : -1) : ((kp - 224) < 100 ? 200 + (kp - 224) : -1);
    dst[i] = (ci >= 0) ? f2bf(src[((size_t)o * 300 + ci) * 3 + t]) : (u16)0;
  }
}

// aggregation from fp8 table -> fp8 scat: wave per (node,etype); 4 edges in
// flight via 16-lane sub-groups; f32x2 packed accumulate; HW fp8 encode.
__global__ void agg8_k(const int* __restrict__ off_et, const int* __restrict__ deg_et,
                       const int* __restrict__ esrc, const u8* __restrict__ h8,
                       u8* __restrict__ scat8, int N) {
  int gtid = blockIdx.x * blockDim.x + threadIdx.x;
  int wid = gtid >> 6, lane = threadIdx.x & 63;
  int nw = (blockDim.x * gridDim.x) >> 6;
  int sub = lane >> 4, l = lane & 15;
  int total = N * 4;
  for (int u = wid; u < total; u += nw) {
    int n = u >> 2, k = u & 3;
    u8* srow = scat8 + (size_t)n * 832;
    int rs = off_et[(size_t)k * N + n], d = deg_et[(size_t)k * N + n];
    f32x2 a2[8];
#pragma unroll
    for (int j = 0; j < 8; ++j) a2[j] = (f32x2)0.f;
    if (l < 13) {
      for (int i = sub; i < d; i += 4) {
        const u8* hr = h8 + (size_t)esrc[rs + i] * 224 + l * 16;
        uint4 v = *reinterpret_cast<const uint4*>(hr);
        a2[0] += __builtin_amdgcn_cvt_pk_f32_fp8(v.x, 0);
        a2[1] += __builtin_amdgcn_cvt_pk_f32_fp8(v.x, 1);
        a2[2] += __builtin_amdgcn_cvt_pk_f32_fp8(v.y, 0);
        a2[3] += __builtin_amdgcn_cvt_pk_f32_fp8(v.y, 1);
        a2[4] += __builtin_amdgcn_cvt_pk_f32_fp8(v.z, 0);
        a2[5] += __builtin_amdgcn_cvt_pk_f32_fp8(v.z, 1);
        a2[6] += __builtin_amdgcn_cvt_pk_f32_fp8(v.w, 0);
        a2[7] += __builtin_amdgcn_cvt_pk_f32_fp8(v.w, 1);
      }
    }
#pragma unroll
    for (int j = 0; j < 8; ++j) {
      a2[j][0] += __shfl_xor(a2[j][0], 16);
      a2[j][1] += __shfl_xor(a2[j][1], 16);
      a2[j][0] += __shfl_xor(a2[j][0], 32);
      a2[j][1] += __shfl_xor(a2[j][1], 32);
    }
    if (sub == 0 && l < 13) {
      int d0, d1, d2, d3;
      d0 = __builtin_amdgcn_cvt_pk_fp8_f32(a2[0][0], a2[0][1], 0, false);
      d0 = __builtin_amdgcn_cvt_pk_fp8_f32(a2[1][0], a2[1][1], d0, true);
      d1 = __builtin_amdgcn_cvt_pk_fp8_f32(a2[2][0], a2[2][1], 0, false);
      d1 = __builtin_amdgcn_cvt_pk_fp8_f32(a2[3][0], a2[3][1], d1, true);
      *reinterpret_cast<uint2*>(srow + k * 200 + l * 16) = make_uint2(d0, d1);
      if (l < 12) {
        d2 = __builtin_amdgcn_cvt_pk_fp8_f32(a2[4][0], a2[4][1], 0, false);
        d2 = __builtin_amdgcn_cvt_pk_fp8_f32(a2[5][0], a2[5][1], d2, true);
        d3 = __builtin_amdgcn_cvt_pk_fp8_f32(a2[6][0], a2[6][1], 0, false);
        d3 = __builtin_amdgcn_cvt_pk_fp8_f32(a2[7][0], a2[7][1], d3, true);
        *reinterpret_cast<uint2*>(srow + k * 200 + l * 16 + 8) = make_uint2(d2, d3);
      }
    }
    if (k == 0 && lane == 13) {
      float g0 = (float)deg_et[(size_t)0 * N + n];
      float g1 = (float)deg_et[(size_t)1 * N + n];
      float g2 = (float)deg_et[(size_t)2 * N + n];
      float g3 = (float)deg_et[(size_t)3 * N + n];
      int rr = __builtin_amdgcn_cvt_pk_fp8_f32(g0, g1, 0, false);
      rr = __builtin_amdgcn_cvt_pk_fp8_f32(g2, g3, rr, true);
      *reinterpret_cast<unsigned*>(srow + 800) = (unsigned)rr;
    }
    if (k == 3 && lane >= 32 && lane < 39)
      *reinterpret_cast<unsigned*>(srow + 804 + (lane - 32) * 4) = 0;
  }
}

// ------- fp8 MFMA GEMM (phase A): 256x128 tile, 3-deep counted-vmcnt pipeline ----
__global__ __launch_bounds__(512, 4) void gemm_a8(
    const u8* __restrict__ A, int lda,
    const u8* __restrict__ B, int ldb,
    u16* __restrict__ Cb, int ldcb, int npad,
    int M, int Nn, int K, int gyr) {
  const int gx = gridDim.x;
  int lin = blockIdx.y * gx + blockIdx.x;
  int k8 = lin & 7, j = lin >> 3;
  int band = gridDim.y >> 3;
  int yy = j / gx, xx = j - yy * gx;
  int by = k8 * band + yy;
  if (by >= gyr) return;
  const int m0 = by * 256, n0 = xx * 128;

  __shared__ __align__(16) u8 As[3 * 8192];
  __shared__ __align__(16) u8 Bs[3 * 4096];
  const int tid = threadIdx.x;
  const int lane = tid & 63;
  const int w = tid >> 6;
  const int wr = w >> 1, wc = w & 1;
  const int fr = lane & 15;
  const int g = lane >> 4;

  const int rowA = tid >> 1;
  const int cA = (tid & 1) ^ (rowA & 1);
  int gaA = m0 + rowA; if (gaA >= M) gaA = M - 1;
  const u8* pa = A + (size_t)gaA * lda + cA * 16;
  u8* lA = &As[(size_t)(w * 64) * 16];
  const int sB = w * 32 + (lane & 31);
  const int rowB = sB >> 1;
  const int cB = (sB & 1) ^ (rowB & 1);
  int gbB = n0 + rowB; if (gbB >= Nn) gbB = Nn - 1;
  const u8* pb = B + (size_t)gbB * ldb + cB * 16;
  u8* lB = &Bs[(size_t)(w * 32) * 16];
  const bool doB = (lane < 32);

  const int rdoff = (((g >> 1) ^ (fr & 1)) << 4) + ((g & 1) << 3);

  f32x4 acc[4][4] = {};
  const int nt = K >> 5;
  const int ABUF = 8192, BBUF = 4096;

  gload16(pa, lA);
  if (doB) gload16(pb, lB);
  pa += 32; pb += 32;
  if (nt > 1) {
    gload16(pa, lA + ABUF);
    if (doB) gload16(pb, lB + BBUF);
    pa += 32; pb += 32;
  }

  for (int t = 0; t < nt; ++t) {
    if (t + 1 < nt) asm volatile("s_waitcnt vmcnt(2)" ::: "memory");
    else            asm volatile("s_waitcnt vmcnt(0)" ::: "memory");
    __builtin_amdgcn_s_barrier();
    if (t + 2 < nt) {
      int bi = (t + 2) % 3;
      gload16(pa, lA + bi * ABUF);
      if (doB) gload16(pb, lB + bi * BBUF);
      pa += 32; pb += 32;
    }
    int ca = (t % 3) * ABUF, cbb = (t % 3) * BBUF;
    long af[4], bfv[4];
#pragma unroll
    for (int i = 0; i < 4; ++i) {
      int row = wr * 64 + i * 16 + fr;
      af[i] = *reinterpret_cast<const long*>(&As[ca + row * 32 + rdoff]);
    }
#pragma unroll
    for (int jj = 0; jj < 4; ++jj) {
      int row = wc * 64 + jj * 16 + fr;
      bfv[jj] = *reinterpret_cast<const long*>(&Bs[cbb + row * 32 + rdoff]);
    }
    __builtin_amdgcn_s_setprio(1);
#pragma unroll
    for (int i = 0; i < 4; ++i)
#pragma unroll
      for (int jj = 0; jj < 4; ++jj)
        acc[i][jj] = __builtin_amdgcn_mfma_f32_16x16x32_fp8_fp8(af[i], bfv[jj], acc[i][jj], 0, 0, 0);
    __builtin_amdgcn_s_setprio(0);
  }

  const int er = (lane >> 4) * 4;
  const int ec = lane & 15;
#pragma unroll
  for (int i = 0; i < 4; ++i) {
#pragma unroll
    for (int jj = 0; jj < 4; ++jj) {
      int n = n0 + wc * 64 + jj * 16 + ec;
#pragma unroll
      for (int r = 0; r < 4; ++r) {
        int m = m0 + wr * 64 + i * 16 + er + r;
        if (m >= M) continue;
        if (n < Nn) Cb[(size_t)m * ldcb + n] = f2bf(acc[i][jj][r]);
        else if (n < npad) Cb[(size_t)m * ldcb + n] = (u16)0;
      }
    }
  }
}

// ------- generic bf16 MFMA GEMM, 256x128 tile (conv paths) ------
__global__ __launch_bounds__(512, 4) void gemm_mfma(
    const u16* __restrict__ A, int lda,
    const u16* __restrict__ B, int ldb,
    u16* __restrict__ Cb, int ldcb, int npad,
    int M, int Nn, int K, const float* __restrict__ bias, int gyr) {
  const int gx = gridDim.x;
  int lin = blockIdx.y * gx + blockIdx.x;
  int k8 = lin & 7, j = lin >> 3;
  int band = gridDim.y >> 3;
  int yy = j / gx, xx = j - yy * gx;
  int by = k8 * band + yy;
  if (by >= gyr) return;
  const int m0 = by * 256, n0 = xx * 128;

  __shared__ __align__(16) u16 As[3 * 8192];
  __shared__ __align__(16) u16 Bs[3 * 4096];
  const int tid = threadIdx.x;
  const int lane = tid & 63;
  const int w = tid >> 6;
  const int wr = w >> 1, wc = w & 1;
  const int fr = lane & 15;
  const int g = lane >> 4;

  const int sA0 = w * 64 + lane, sA1 = sA0 + 512, sB = sA0;
  int rA0 = sA0 >> 2, cA0 = (sA0 & 3) ^ ((rA0 >> 1) & 3);
  int rA1 = sA1 >> 2, cA1 = (sA1 & 3) ^ ((rA1 >> 1) & 3);
  int rB  = sB  >> 2, cB  = (sB & 3) ^ ((rB >> 1) & 3);
  int ga0 = m0 + rA0; if (ga0 >= M) ga0 = M - 1;
  int ga1 = m0 + rA1; if (ga1 >= M) ga1 = M - 1;
  int gb  = n0 + rB;  if (gb >= Nn) gb = Nn - 1;
  const u16* pa0 = A + (size_t)ga0 * lda + cA0 * 8;
  const u16* pa1 = A + (size_t)ga1 * lda + cA1 * 8;
  const u16* pb  = B + (size_t)gb  * ldb + cB * 8;
  u16* lA0 = &As[(w * 64) * 8];
  u16* lA1 = &As[(512 + w * 64) * 8];
  u16* lB  = &Bs[(w * 64) * 8];

  const int gxr = g ^ ((fr >> 1) & 3);

  f32x4 acc[4][4] = {};
  const int nt = K >> 5;
  const int ABUF = 8192, BBUF = 4096;

  gload16(pa0, lA0); gload16(pa1, lA1); gload16(pb, lB);
  pa0 += 32; pa1 += 32; pb += 32;
  if (nt > 1) {
    gload16(pa0, lA0 + ABUF); gload16(pa1, lA1 + ABUF); gload16(pb, lB + BBUF);
    pa0 += 32; pa1 += 32; pb += 32;
  }

  for (int t = 0; t < nt; ++t) {
    if (t + 1 < nt) asm volatile("s_waitcnt vmcnt(3)" ::: "memory");
    else            asm volatile("s_waitcnt vmcnt(0)" ::: "memory");
    __builtin_amdgcn_s_barrier();
    if (t + 2 < nt) {
      int bi = (t + 2) % 3;
      gload16(pa0, lA0 + bi * ABUF); gload16(pa1, lA1 + bi * ABUF); gload16(pb, lB + bi * BBUF);
      pa0 += 32; pa1 += 32; pb += 32;
    }
    int ca = (t % 3) * ABUF, cbb = (t % 3) * BBUF;
    bf16x8 af[4], bfv[4];
#pragma unroll
    for (int i = 0; i < 4; ++i) {
      int row = wr * 64 + i * 16 + fr;
      af[i] = *reinterpret_cast<const bf16x8*>(&As[ca + (row * 4 + gxr) * 8]);
    }
#pragma unroll
    for (int jj = 0; jj < 4; ++jj) {
      int row = wc * 64 + jj * 16 + fr;
      bfv[jj] = *reinterpret_cast<const bf16x8*>(&Bs[cbb + (row * 4 + gxr) * 8]);
    }
    __builtin_amdgcn_s_setprio(1);
#pragma unroll
    for (int i = 0; i < 4; ++i)
#pragma unroll
      for (int jj = 0; jj < 4; ++jj)
        acc[i][jj] = __builtin_amdgcn_mfma_f32_16x16x32_bf16(af[i], bfv[jj], acc[i][jj], 0, 0, 0);
    __builtin_amdgcn_s_setprio(0);
  }

  const int er = (lane >> 4) * 4;
  const int ec = lane & 15;
#pragma unroll
  for (int i = 0; i < 4; ++i) {
#pragma unroll
    for (int jj = 0; jj < 4; ++jj) {
      int n = n0 + wc * 64 + jj * 16 + ec;
#pragma unroll
      for (int r = 0; r < 4; ++r) {
        int m = m0 + wr * 64 + i * 16 + er + r;
        if (m >= M) continue;
        if (n < Nn) {
          float v = acc[i][jj][r];
          if (bias) v += bias[n];
          Cb[(size_t)m * ldcb + n] = f2bf(v);
        } else if (n < npad) {
          Cb[(size_t)m * ldcb + n] = (u16)0;
        }
      }
    }
  }
}

// ------- gates GEMM with fused GRU epilogue (Nn=800 interleaved, gx=7) ------
__global__ __launch_bounds__(512, 4) void gemm_gru(
    const u16* __restrict__ A, int lda,
    const u16* __restrict__ B, int ldb,
    int M, int K, const float* __restrict__ bias,
    u16* __restrict__ hnew, u8* __restrict__ h8c, int gyr) {
  const int gx = gridDim.x;
  int lin = blockIdx.y * gx + blockIdx.x;
  int k8 = lin & 7, j = lin >> 3;
  int band = gridDim.y >> 3;
  int yy = j / gx, xx = j - yy * gx;
  int by = k8 * band + yy;
  if (by >= gyr) return;
  const int m0 = by * 256, n0 = xx * 128;
  const int Nn = 800;

  __shared__ __align__(16) u16 SM[3 * 8192 + 3 * 4096];
  u16* As = SM;
  u16* Bs = SM + 3 * 8192;
  const int tid = threadIdx.x;
  const int lane = tid & 63;
  const int w = tid >> 6;
  const int wr = w >> 1, wc = w & 1;
  const int fr = lane & 15;
  const int g = lane >> 4;

  const int sA0 = w * 64 + lane, sA1 = sA0 + 512, sB = sA0;
  int rA0 = sA0 >> 2, cA0 = (sA0 & 3) ^ ((rA0 >> 1) & 3);
  int rA1 = sA1 >> 2, cA1 = (sA1 & 3) ^ ((rA1 >> 1) & 3);
  int rB  = sB  >> 2, cB  = (sB & 3) ^ ((rB >> 1) & 3);
  int ga0 = m0 + rA0; if (ga0 >= M) ga0 = M - 1;
  int ga1 = m0 + rA1; if (ga1 >= M) ga1 = M - 1;
  int gb  = n0 + rB;  if (gb >= Nn) gb = Nn - 1;
  const u16* pa0 = A + (size_t)ga0 * lda + cA0 * 8;
  const u16* pa1 = A + (size_t)ga1 * lda + cA1 * 8;
  const u16* pb  = B + (size_t)gb  * ldb + cB * 8;
  u16* lA0 = &As[(w * 64) * 8];
  u16* lA1 = &As[(512 + w * 64) * 8];
  u16* lB  = &Bs[(w * 64) * 8];

  const int gxr = g ^ ((fr >> 1) & 3);

  f32x4 acc[4][4] = {};
  const int nt = K >> 5;
  const int ABUF = 8192, BBUF = 4096;

  gload16(pa0, lA0); gload16(pa1, lA1); gload16(pb, lB);
  pa0 += 32; pa1 += 32; pb += 32;
  if (nt > 1) {
    gload16(pa0, lA0 + ABUF); gload16(pa1, lA1 + ABUF); gload16(pb, lB + BBUF);
    pa0 += 32; pa1 += 32; pb += 32;
  }

  for (int t = 0; t < nt; ++t) {
    if (t + 1 < nt) asm volatile("s_waitcnt vmcnt(3)" ::: "memory");
    else            asm volatile("s_waitcnt vmcnt(0)" ::: "memory");
    __builtin_amdgcn_s_barrier();
    if (t + 2 < nt) {
      int bi = (t + 2) % 3;
      gload16(pa0, lA0 + bi * ABUF); gload16(pa1, lA1 + bi * ABUF); gload16(pb, lB + bi * BBUF);
      pa0 += 32; pa1 += 32; pb += 32;
    }
    int ca = (t % 3) * ABUF, cbb = (t % 3) * BBUF;
    bf16x8 af[4], bfv[4];
#pragma unroll
    for (int i = 0; i < 4; ++i) {
      int row = wr * 64 + i * 16 + fr;
      af[i] = *reinterpret_cast<const bf16x8*>(&As[ca + (row * 4 + gxr) * 8]);
    }
#pragma unroll
    for (int jj = 0; jj < 4; ++jj) {
      int row = wc * 64 + jj * 16 + fr;
      bfv[jj] = *reinterpret_cast<const bf16x8*>(&Bs[cbb + (row * 4 + gxr) * 8]);
    }
    __builtin_amdgcn_s_setprio(1);
#pragma unroll
    for (int i = 0; i < 4; ++i)
#pragma unroll
      for (int jj = 0; jj < 4; ++jj)
        acc[i][jj] = __builtin_amdgcn_mfma_f32_16x16x32_bf16(af[i], bfv[jj], acc[i][jj], 0, 0, 0);
    __builtin_amdgcn_s_setprio(0);
  }

  // ---- fused GRU epilogue ----
  const int er = (lane >> 4) * 4;
  const int ec = lane & 15;
  __syncthreads();
  float* ep = (float*)SM + (size_t)w * 2048;   // per-wave [64][32] f32

  for (int hh = 0; hh < 2; ++hh) {
#pragma unroll
    for (int jj2 = 0; jj2 < 2; ++jj2) {
      int jj = hh * 2 + jj2;
      int n = n0 + wc * 64 + jj * 16 + ec;
      float bv = (n < 800) ? bias[n] : 0.f;
#pragma unroll
      for (int i = 0; i < 4; ++i)
#pragma unroll
        for (int r = 0; r < 4; ++r) {
          int row_loc = i * 16 + er + r;
          ep[row_loc * 32 + jj2 * 16 + ec] = acc[i][jj][r] + bv;
        }
    }
    __syncthreads();
#pragma unroll
    for (int p = 0; p < 8; ++p) {
      int idx = p * 64 + lane;
      int row = idx >> 3, og = idx & 7;
      int n_base = n0 + wc * 64 + hh * 32 + og * 4;
      int m = m0 + wr * 64 + row;
      if (n_base < 800 && m < M) {
        f32x4 gv = *reinterpret_cast<f32x4*>(&ep[row * 32 + og * 4]);
        float rg = sigm(gv[0]);
        float zg = sigm(gv[1]);
        float x = gv[2] + rg * gv[3];
        float e2 = __expf(2.f * x);
        float nn = (e2 - 1.f) / (e2 + 1.f);
        int o = n_base >> 2;
        float hold = bf2f(A[(size_t)m * 448 + 224 + o]);
        float hv = (1.f - zg) * nn + zg * hold;
        hnew[(size_t)m * 224 + o] = f2bf(hv);
        h8c[(size_t)m * 224 + o] = f2fp8(hv);
      }
    }
    __syncthreads();
  }
}

// merge hnew (bf16, stride 224) into ah h-slice
__global__ void hcopy_k(const u16* __restrict__ hn_, u16* __restrict__ ahc, int Nc) {
  int total = Nc * 200;
  for (int i = blockIdx.x * blockDim.x + threadIdx.x; i < total; i += blockDim.x * gridDim.x) {
    int n = i / 200, o = i - n * 200;
    ahc[(size_t)n * 448 + 224 + o] = hn_[(size_t)n * 224 + o];
  }
}

// cmat[n][352] = [h(224) | feat(100) | 0(28)]
__global__ void cmat_k(const u16* __restrict__ ah, const float* __restrict__ feat,
                       u16* __restrict__ c, int N) {
  int total = N * 352;
  for (int i = blockIdx.x * blockDim.x + threadIdx.x; i < total; i += blockDim.x * gridDim.x) {
    int n = i / 352, j = i - n * 352;
    u16 v;
    if (j < 224) v = ah[(size_t)n * 448 + 224 + j];
    else { int f = j - 224; v = (f < 100) ? f2bf(feat[(size_t)n * 100 + f]) : (u16)0; }
    c[i] = v;
  }
}

__global__ __launch_bounds__(1024) void bn_stats2_k(const u16* __restrict__ X, int L, int C,
                                                    float* __restrict__ stats) {
  const int Q = 1024 / C;
  const int T = Q * C;
  const int tid = threadIdx.x;
  float s = 0.f, q = 0.f;
  int c = 0;
  if (tid < T) {
    int qi = tid / C; c = tid - qi * C;
    for (size_t r = (size_t)blockIdx.x * Q + qi; r < (size_t)L; r += (size_t)gridDim.x * Q) {
      float v = bf2f(X[r * C + c]);
      s += v; q += v * v;
    }
  }
  __shared__ float sb[304], qb[304];
  for (int cc = tid; cc < C; cc += 1024) { sb[cc] = 0.f; qb[cc] = 0.f; }
  __syncthreads();
  if (tid < T) { atomicAdd(&sb[c], s); atomicAdd(&qb[c], q); }
  __syncthreads();
  for (int cc = tid; cc < C; cc += 1024) {
    atomicAdd(&stats[cc], sb[cc]);
    atomicAdd(&stats[C + cc], qb[cc]);
  }
}

__global__ void bn_fin_k(const float* __restrict__ stats, const float* __restrict__ g,
                         const float* __restrict__ b, int C, float Linv,
                         float* __restrict__ scsh) {
  int c = blockIdx.x * blockDim.x + threadIdx.x;
  if (c < C) {
    float mean = stats[c] * Linv;
    float var = stats[C + c] * Linv - mean * mean;
    float sc = g[c] * rsqrtf(var + 1e-5f);
    scsh[c] = sc;
    scsh[C + c] = b[c] - mean * sc;
  }
}

__global__ void pool_bf_k(const u16* __restrict__ X, int C, const float* __restrict__ scsh,
                          int kw, int stride, u16* __restrict__ Y, int Cpad, int Lout) {
  int total = Lout * Cpad;
  for (int i = blockIdx.x * blockDim.x + threadIdx.x; i < total; i += blockDim.x * gridDim.x) {
    int lp = i / Cpad, c = i - lp * Cpad;
    if (c >= C) { Y[i] = (u16)0; continue; }
    float sc = scsh[c], sh = scsh[C + c];
    int l0 = lp * stride;
    float m = 0.f;
    for (int wq = 0; wq < kw; ++wq)
      m = fmaxf(m, fmaf(bf2f(X[(size_t)(l0 + wq) * C + c]), sc, sh));
    Y[i] = f2bf(m);
  }
}

__global__ void pool_f32_k(const u16* __restrict__ X, int C, const float* __restrict__ scsh,
                           int kw, int stride, float* __restrict__ Y, int Lout) {
  int total = Lout * C;
  for (int i = blockIdx.x * blockDim.x + threadIdx.x; i < total; i += blockDim.x * gridDim.x) {
    int lp = i / C, c = i - lp * C;
    float sc = scsh[c], sh = scsh[C + c];
    int l0 = lp * stride;
    float m = 0.f;
    for (int wq = 0; wq < kw; ++wq)
      m = fmaxf(m, fmaf(bf2f(X[(size_t)(l0 + wq) * C + c]), sc, sh));
    Y[i] = m;
  }
}

__global__ __launch_bounds__(256) void final_dot_k(
    const float* __restrict__ Y2, const float* __restrict__ Z2,
    const float* __restrict__ wy, const float* __restrict__ by,
    const float* __restrict__ wz, const float* __restrict__ bz,
    float* __restrict__ acc, int L) {
  float s0 = 0.f, s1 = 0.f;
  for (int lp = blockIdx.x * blockDim.x + threadIdx.x; lp < L; lp += blockDim.x * gridDim.x) {
    const float* y = Y2 + (size_t)lp * 200;
    const float* z = Z2 + (size_t)lp * 300;
    float d0 = 0.f, d1 = 0.f;
    for (int k = 0; k < 200; ++k) { float v = y[k]; d0 += v * wy[k]; d1 += v * wy[200 + k]; }
    float e0 = 0.f, e1 = 0.f;
    for (int k = 0; k < 300; ++k) { float v = z[k]; e0 += v * wz[k]; e1 += v * wz[300 + k]; }
    s0 += (d0 + by[0]) * (e0 + bz[0]);
    s1 += (d1 + by[1]) * (e1 + bz[1]);
  }
  __shared__ float r0[256], r1[256];
  r0[threadIdx.x] = s0; r1[threadIdx.x] = s1;
  __syncthreads();
  for (int off = 128; off > 0; off >>= 1) {
    if (threadIdx.x < off) { r0[threadIdx.x] += r0[threadIdx.x + off]; r1[threadIdx.x] += r1[threadIdx.x + off]; }
    __syncthreads();
  }
  if (threadIdx.x == 0) { atomicAdd(&acc[0], r0[0]); atomicAdd(&acc[1], r1[0]); }
}

__global__ void final_out_k(const float* __restrict__ acc, float invL, float* __restrict__ out) {
  int j = threadIdx.x;
  if (j < 2) out[j] = 1.f / (1.f + expf(-acc[j] * invL));
}

// ---------------- host ----------------

static inline void gemmL(hipStream_t st, const u16* A, int lda, const u16* B, int ldb,
                         u16* Cb, int ldcb, int npad, int M, int Nn, int K, const float* bias) {
  int ncols = (npad > Nn) ? npad : Nn;
  int gx = (ncols + 127) / 128;
  int gy = (M + 255) / 256;
  int gyp = ((gy + 7) / 8) * 8;
  dim3 g(gx, gyp);
  gemm_mfma<<<g, 512, 0, st>>>(A, lda, B, ldb, Cb, ldcb, npad, M, Nn, K, bias, gy);
}

extern "C" void kernel_launch(void* const* d_in, const int* in_sizes, int n_in,
                              void* d_out, int out_size, void* d_ws, size_t ws_size,
                              hipStream_t stream) {
  (void)n_in; (void)out_size;
  const float* feat    = (const float*)d_in[0];
  const int*   eix     = (const int*)d_in[1];
  const int*   etyp    = (const int*)d_in[2];
  const float* ggnnW   = (const float*)d_in[3];
  const float* ggnnB   = (const float*)d_in[4];
  const float* Wih     = (const float*)d_in[5];
  const float* Whh     = (const float*)d_in[6];
  const float* bih     = (const float*)d_in[7];
  const float* bhh     = (const float*)d_in[8];
  const float* conv1w  = (const float*)d_in[9];
  const float* conv2w  = (const float*)d_in[11];
  const float* convc1w = (const float*)d_in[13];
  const float* convc2w = (const float*)d_in[15];
  const float* bnyg    = (const float*)d_in[17];
  const float* bnyb    = (const float*)d_in[18];
  const float* bncg    = (const float*)d_in[19];
  const float* bncb    = (const float*)d_in[20];
  const float* mlpyw   = (const float*)d_in[21];
  const float* mlpyb   = (const float*)d_in[22];
  const float* mlpzw   = (const float*)d_in[23];
  const float* mlpzb   = (const float*)d_in[24];

  const int N = in_sizes[0] / 100;
  const int E = in_sizes[2];
  const int* src = eix;
  const int* dst = eix + E;

  char* base = (char*)d_ws;
  const size_t AH_B = (size_t)N * 448 * 2;
  const int CH = (N + 1) / 2;
  const size_t SCR_B = (size_t)CH * 1664;

  u16* ah = (u16*)base;
  char* R1 = base + AH_B;
  char* WREG = R1 + SCR_B;

  u8*  Wcat8 = (u8*)WREG;                  // 200*832 fp8
  u16* Wall = (u16*)(WREG + 166400);       // 800*448 (interleaved)
  u16* w1c  = Wall + 358400;               // 200*1056
  u16* c2b  = w1c + 211200;                // 200*224
  u16* wc1  = c2b + 44800;                 // 300*1056
  u16* wc2  = wc1 + 316800;                // 300*320
  float* ball  = (float*)(wc2 + 96000);
  float* stats = ball + 832;
  float* scsh  = stats + 600;
  float* acc2  = scsh + 600;
  int* deg_et = (int*)(acc2 + 8);
  int* off_et = deg_et + 4 * (size_t)N;
  int* cursor = off_et + 4 * (size_t)N;
  int* esrc   = cursor + 4 * (size_t)N;
  int* bsum   = esrc + E;
  const int L4 = 4 * N;
  const int NB = (L4 + 1023) / 1024;
  u8* h8 = (u8*)(((uintptr_t)(bsum + NB) + 255) & ~(uintptr_t)255);
  size_t need = (size_t)((h8 + (size_t)N * 224) - (u8*)base);

  if (ws_size < need) {
    fail_k<<<1, 64, 0, stream>>>((float*)d_out, -(float)(ws_size >> 20));
    return;
  }

  // ---- CSR build + packs ----
  hipMemsetAsync(deg_et, 0, sizeof(int) * 4 * (size_t)N, stream);
  init_ah_k<<<4096, 256, 0, stream>>>(feat, ah, N);
  init_h8_k<<<2048, 256, 0, stream>>>(feat, h8, N);
  count_deg_k<<<2048, 256, 0, stream>>>(dst, etyp, deg_et, N, E);
  bsum_k<<<NB, 1024, 0, stream>>>(deg_et, bsum, L4);
  scanb_k<<<1, 1024, 0, stream>>>(bsum, NB);
  scan_fin_k<<<NB, 1024, 0, stream>>>(deg_et, bsum, off_et, L4);
  copy_int_k<<<512, 256, 0, stream>>>(off_et, cursor, L4);
  fill_src_k<<<2048, 256, 0, stream>>>(src, dst, etyp, cursor, esrc, N, E);
  pack_wcat8_k<<<651, 256, 0, stream>>>(ggnnW, ggnnB, Wcat8);
  pack_wall_i_k<<<1400, 256, 0, stream>>>(Wih, Whh, Wall);
  ball_i_k<<<4, 256, 0, stream>>>(bih, bhh, ball);
  pack_w1c_k<<<825, 256, 0, stream>>>(conv1w, w1c);
  pack_lin_b<<<175, 256, 0, stream>>>(conv2w, c2b, 200, 200, 224);
  pack_wc1_b<<<1238, 256, 0, stream>>>(convc1w, wc1);
  pack_lin_b<<<375, 256, 0, stream>>>(convc2w, wc2, 300, 300, 320);

  // ---- GGNN 8 steps (full-N, 4 dispatches/step) ----
  u8*  scat8 = (u8*)R1;
  u16* hnewb = (u16*)R1;

  const int gy = (N + 255) / 256;
  const int gyp = ((gy + 7) / 8) * 8;

  for (int step = 0; step < 8; ++step) {
    agg8_k<<<4096, 256, 0, stream>>>(off_et, deg_et, esrc, h8, scat8, N);
    gemm_a8<<<dim3(2, gyp), 512, 0, stream>>>(scat8, 832, Wcat8, 832,
                                              ah, 448, 224, N, 200, 832, gy);
    gemm_gru<<<dim3(7, gyp), 512, 0, stream>>>(ah, 448, Wall, 448, N, 448, ball,
                                               hnewb, h8, gy);
    hcopy_k<<<4096, 256, 0, stream>>>(hnewb, ah, N);
  }

  // ---- conv paths ----
  const int L1 = N - 2;
  const int L2 = (L1 - 3) / 2 + 1;
  const int L3 = (L2 - 2) / 2 + 1;

  u16* cmat = (u16*)R1;
  u16* out1 = (u16*)base;
  size_t y1_off = (((size_t)L1 * 400) + 255) & ~(size_t)255;
  u16* y1 = (u16*)(base + y1_off);
  size_t o2_off = y1_off + ((((size_t)L2 * 448) + 255) & ~(size_t)255);
  u16* out2 = (u16*)(base + o2_off);
  float* Y2f = (float*)base;
  size_t oc1_off = (((size_t)L3 * 800) + 255) & ~(size_t)255;
  u16* outc1 = (u16*)(base + oc1_off);
  u16* z1 = (u16*)R1;
  size_t oc2_off = (((size_t)L2 * 640) + 255) & ~(size_t)255;
  u16* outc2 = (u16*)(R1 + oc2_off);
  float* Z2f = (float*)(base + oc1_off);

  cmat_k<<<4096, 256, 0, stream>>>(ah, feat, cmat, N);

  // Y path
  gemmL(stream, cmat, 352, w1c, 1056, out1, 200, 200, L1, 200, 1056, nullptr);
  hipMemsetAsync(stats, 0, sizeof(float) * 400, stream);
  bn_stats2_k<<<512, 1024, 0, stream>>>(out1, L1, 200, stats);
  bn_fin_k<<<2, 256, 0, stream>>>(stats, bnyg, bnyb, 200, 1.f / (float)L1, scsh);
  pool_bf_k<<<2048, 256, 0, stream>>>(out1, 200, scsh, 3, 2, y1, 224, L2);

  gemmL(stream, y1, 224, c2b, 224, out2, 200, 200, L2, 200, 224, nullptr);
  hipMemsetAsync(stats, 0, sizeof(float) * 400, stream);
  bn_stats2_k<<<512, 1024, 0, stream>>>(out2, L2, 200, stats);
  bn_fin_k<<<2, 256, 0, stream>>>(stats, bnyg, bnyb, 200, 1.f / (float)L2, scsh);
  pool_f32_k<<<2048, 256, 0, stream>>>(out2, 200, scsh, 2, 2, Y2f, L3);

  // Z path
  gemmL(stream, cmat, 352, wc1, 1056, outc1, 300, 300, L1, 300, 1056, nullptr);
  hipMemsetAsync(stats, 0, sizeof(float) * 600, stream);
  bn_stats2_k<<<512, 1024, 0, stream>>>(outc1, L1, 300, stats);
  bn_fin_k<<<2, 256, 0, stream>>>(stats, bncg, bncb, 300, 1.f / (float)L1, scsh);
  pool_bf_k<<<2048, 256, 0, stream>>>(outc1, 300, scsh, 3, 2, z1, 320, L2);

  gemmL(stream, z1, 320, wc2, 320, outc2, 300, 300, L2, 300, 320, nullptr);
  hipMemsetAsync(stats, 0, sizeof(float) * 600, stream);
  bn_stats2_k<<<512, 1024, 0, stream>>>(outc2, L2, 300, stats);
  bn_fin_k<<<2, 256, 0, stream>>>(stats, bncg, bncb, 300, 1.f / (float)L2, scsh);
  pool_f32_k<<<2048, 256, 0, stream>>>(outc2, 300, scsh, 2, 2, Z2f, L3);

  // ---- final MLP product + mean + sigmoid ----
  hipMemsetAsync(acc2, 0, sizeof(float) * 2, stream);
  final_dot_k<<<256, 256, 0, stream>>>(Y2f, Z2f, mlpyw, mlpyb, mlpzw, mlpzb, acc2, L3);
  final_out_k<<<1, 64, 0, stream>>>(acc2, 1.f / (float)L3, (float*)d_out);
}

// Round 15
// 3503.673 us; speedup vs baseline: 1.5398x; 1.0250x over previous
//
#include <hip/hip_runtime.h>
#include <cstddef>
#include <cstdint>

// ============================================================================
// DevignModel round 15: fp8 GGNN state pipeline.
//  - ahq[N][448] fp8 [a|h]; hb[N][224] bf16 (GRU-hold + cmat only)
//  - gemm_a8 writes fp8 a-slice; gemm_gru8 = K=448 fp8 GEMM + fused GRU
//  - hcopy8 fp8 (22 MB vs 45 MB)
// ============================================================================

typedef unsigned short u16;
typedef unsigned char u8;
typedef __attribute__((ext_vector_type(8))) short bf16x8;
typedef __attribute__((ext_vector_type(4))) float f32x4;
typedef __attribute__((ext_vector_type(2))) float f32x2;

static __device__ __forceinline__ float bf2f(u16 u) {
  union { unsigned int i; float f; } v; v.i = ((unsigned int)u) << 16; return v.f;
}
static __device__ __forceinline__ u16 f2bf(float f) {
  union { float f; unsigned int i; } v; v.f = f;
  unsigned int r = v.i + 0x7FFFu + ((v.i >> 16) & 1u);
  return (u16)(r >> 16);
}
static __device__ __forceinline__ float sigm(float x) { return 1.f / (1.f + __expf(-x)); }
static __device__ __forceinline__ u8 f2fp8(float x) {
  return (u8)(__builtin_amdgcn_cvt_pk_fp8_f32(x, 0.f, 0, false) & 0xff);
}

static __device__ __forceinline__ void gload16(const void* gp, void* lp) {
  __builtin_amdgcn_global_load_lds(
      (const __attribute__((address_space(1))) void*)gp,
      (__attribute__((address_space(3))) void*)lp, 16, 0, 0);
}

__global__ void fail_k(float* out, float code) { out[0] = code; out[1] = code; }

// hb[n][224] bf16 = [feat | 0]
__global__ void init_hb_k(const float* __restrict__ feat, u16* __restrict__ hb, int N) {
  int total = N * 224;
  for (int i = blockIdx.x * blockDim.x + threadIdx.x; i < total; i += blockDim.x * gridDim.x) {
    int n = i / 224, c = i - n * 224;
    hb[i] = (c < 100) ? f2bf(feat[(size_t)n * 100 + c]) : (u16)0;
  }
}

// ahq h-slice fp8 = [feat | 0] (incl pad zeros)
__global__ void init_hq_k(const float* __restrict__ feat, u8* __restrict__ ahq, int N) {
  int total = N * 224;
  for (int i = blockIdx.x * blockDim.x + threadIdx.x; i < total; i += blockDim.x * gridDim.x) {
    int n = i / 224, c = i - n * 224;
    ahq[(size_t)n * 448 + 224 + c] = (c < 100) ? f2fp8(feat[(size_t)n * 100 + c]) : (u8)0;
  }
}

__global__ void count_deg_k(const int* __restrict__ dst, const int* __restrict__ et,
                            int* __restrict__ deg_et, int N, int E) {
  for (int e = blockIdx.x * blockDim.x + threadIdx.x; e < E; e += blockDim.x * gridDim.x)
    atomicAdd(&deg_et[et[e] * N + dst[e]], 1);
}

// ---- parallel exclusive scan (3 kernels) ----
__global__ __launch_bounds__(1024) void bsum_k(const int* __restrict__ cnt,
                                               int* __restrict__ bsum, int L) {
  __shared__ int buf[1024];
  int i = blockIdx.x * 1024 + threadIdx.x;
  buf[threadIdx.x] = (i < L) ? cnt[i] : 0;
  __syncthreads();
  for (int o = 512; o > 0; o >>= 1) {
    if (threadIdx.x < o) buf[threadIdx.x] += buf[threadIdx.x + o];
    __syncthreads();
  }
  if (threadIdx.x == 0) bsum[blockIdx.x] = buf[0];
}

__global__ __launch_bounds__(1024) void scanb_k(int* __restrict__ bsum, int nb) {
  __shared__ int buf[1024];
  int v = (threadIdx.x < nb) ? bsum[threadIdx.x] : 0;
  buf[threadIdx.x] = v;
  __syncthreads();
  for (int o = 1; o < 1024; o <<= 1) {
    int t = (threadIdx.x >= o) ? buf[threadIdx.x - o] : 0;
    __syncthreads();
    buf[threadIdx.x] += t;
    __syncthreads();
  }
  if (threadIdx.x < nb) bsum[threadIdx.x] = buf[threadIdx.x] - v;
}

__global__ __launch_bounds__(1024) void scan_fin_k(const int* __restrict__ cnt,
                                                   const int* __restrict__ bsum,
                                                   int* __restrict__ off, int L) {
  __shared__ int buf[1024];
  int i = blockIdx.x * 1024 + threadIdx.x;
  int v = (i < L) ? cnt[i] : 0;
  buf[threadIdx.x] = v;
  __syncthreads();
  for (int o = 1; o < 1024; o <<= 1) {
    int t = (threadIdx.x >= o) ? buf[threadIdx.x - o] : 0;
    __syncthreads();
    buf[threadIdx.x] += t;
    __syncthreads();
  }
  if (i < L) off[i] = buf[threadIdx.x] - v + bsum[blockIdx.x];
}

__global__ void copy_int_k(const int* __restrict__ a, int* __restrict__ b, int n) {
  for (int i = blockIdx.x * blockDim.x + threadIdx.x; i < n; i += blockDim.x * gridDim.x) b[i] = a[i];
}

__global__ void fill_src_k(const int* __restrict__ src, const int* __restrict__ dst,
                           const int* __restrict__ et, int* __restrict__ cursor,
                           int* __restrict__ esrc, int N, int E) {
  for (int e = blockIdx.x * blockDim.x + threadIdx.x; e < E; e += blockDim.x * gridDim.x) {
    int p = atomicAdd(&cursor[et[e] * N + dst[e]], 1);
    esrc[p] = src[e];
  }
}

// ---- weight packs ----

__global__ void pack_wcat8_k(const float* __restrict__ W, const float* __restrict__ gb,
                             u8* __restrict__ dst) {
  int total = 200 * 832;
  for (int i = blockIdx.x * blockDim.x + threadIdx.x; i < total; i += blockDim.x * gridDim.x) {
    int o = i / 832, kp = i - o * 832;
    float v = 0.f;
    if (kp < 800) { int k = kp / 200, kk = kp - k * 200; v = W[((size_t)k * 200 + o) * 200 + kk]; }
    else if (kp < 804) v = gb[(kp - 800) * 200 + o];
    dst[i] = f2fp8(v);
  }
}

// Wall8[800][448] fp8, gate-interleaved (row 4o+g): [Wih | 0 | Whh | 0]
__global__ void pack_wall8_k(const float* __restrict__ Wih, const float* __restrict__ Whh,
                             u8* __restrict__ dst) {
  int total = 800 * 448;
  for (int i = blockIdx.x * blockDim.x + threadIdx.x; i < total; i += blockDim.x * gridDim.x) {
    int jp = i / 448, kp = i - jp * 448;
    int o = jp >> 2, g = jp & 3;
    float v = 0.f;
    if (g == 0) {
      if (kp < 200) v = Wih[(size_t)o * 200 + kp];
      else if (kp >= 224 && kp < 424) v = Whh[(size_t)o * 200 + (kp - 224)];
    } else if (g == 1) {
      if (kp < 200) v = Wih[(size_t)(200 + o) * 200 + kp];
      else if (kp >= 224 && kp < 424) v = Whh[(size_t)(200 + o) * 200 + (kp - 224)];
    } else if (g == 2) {
      if (kp < 200) v = Wih[(size_t)(400 + o) * 200 + kp];
    } else {
      if (kp >= 224 && kp < 424) v = Whh[(size_t)(400 + o) * 200 + (kp - 224)];
    }
    dst[i] = f2fp8(v);
  }
}

__global__ void ball_i_k(const float* __restrict__ bih, const float* __restrict__ bhh,
                         float* __restrict__ ball) {
  int j = blockIdx.x * blockDim.x + threadIdx.x;
  if (j < 800) {
    int o = j >> 2, g = j & 3;
    float v;
    if (g == 0) v = bih[o] + bhh[o];
    else if (g == 1) v = bih[200 + o] + bhh[200 + o];
    else if (g == 2) v = bih[400 + o];
    else v = bhh[400 + o];
    ball[j] = v;
  }
}

__global__ void pack_lin_b(const float* __restrict__ src, u16* __restrict__ dst,
                           int Nn, int K, int Kp) {
  int total = Nn * Kp;
  for (int i = blockIdx.x * blockDim.x + threadIdx.x; i < total; i += blockDim.x * gridDim.x) {
    int o = i / Kp, kp = i - o * Kp;
    dst[i] = (kp < K) ? f2bf(src[(size_t)o * K + kp]) : (u16)0;
  }
}

__global__ void pack_w1c_k(const float* __restrict__ src, u16* __restrict__ dst) {
  int total = 200 * 1056;
  for (int i = blockIdx.x * blockDim.x + threadIdx.x; i < total; i += blockDim.x * gridDim.x) {
    int o = i / 1056, r = i - o * 1056;
    int t = r / 352, kp = r - t * 352;
    dst[i] = (kp < 200) ? f2bf(src[((size_t)o * 200 + kp) * 3 + t]) : (u16)0;
  }
}

__global__ void pack_wc1_b(const float* __restrict__ src, u16* __restrict__ dst) {
  int total = 300 * 1056;
  for (int i = blockIdx.x * blockDim.x + threadIdx.x; i < total; i += blockDim.x * gridDim.x) {
    int o = i / 1056, r = i - o * 1056;
    int t = r / 352, kp = r - t * 352;
    int ci = (kp < 224) ? (kp < 200 ? kp : -1) : ((kp - 224) < 100 ? 200 + (kp - 224) : -1);
    dst[i] = (ci >= 0) ? f2bf(src[((size_t)o * 300 + ci) * 3 + t]) : (u16)0;
  }
}

// aggregation from ahq h-slice (fp8, stride 448) -> fp8 scat
__global__ void agg8_k(const int* __restrict__ off_et, const int* __restrict__ deg_et,
                       const int* __restrict__ esrc, const u8* __restrict__ ahq,
                       u8* __restrict__ scat8, int N) {
  int gtid = blockIdx.x * blockDim.x + threadIdx.x;
  int wid = gtid >> 6, lane = threadIdx.x & 63;
  int nw = (blockDim.x * gridDim.x) >> 6;
  int sub = lane >> 4, l = lane & 15;
  int total = N * 4;
  for (int u = wid; u < total; u += nw) {
    int n = u >> 2, k = u & 3;
    u8* srow = scat8 + (size_t)n * 832;
    int rs = off_et[(size_t)k * N + n], d = deg_et[(size_t)k * N + n];
    f32x2 a2[8];
#pragma unroll
    for (int j = 0; j < 8; ++j) a2[j] = (f32x2)0.f;
    if (l < 13) {
      for (int i = sub; i < d; i += 4) {
        const u8* hr = ahq + (size_t)esrc[rs + i] * 448 + 224 + l * 16;
        uint4 v = *reinterpret_cast<const uint4*>(hr);
        a2[0] += __builtin_amdgcn_cvt_pk_f32_fp8(v.x, 0);
        a2[1] += __builtin_amdgcn_cvt_pk_f32_fp8(v.x, 1);
        a2[2] += __builtin_amdgcn_cvt_pk_f32_fp8(v.y, 0);
        a2[3] += __builtin_amdgcn_cvt_pk_f32_fp8(v.y, 1);
        a2[4] += __builtin_amdgcn_cvt_pk_f32_fp8(v.z, 0);
        a2[5] += __builtin_amdgcn_cvt_pk_f32_fp8(v.z, 1);
        a2[6] += __builtin_amdgcn_cvt_pk_f32_fp8(v.w, 0);
        a2[7] += __builtin_amdgcn_cvt_pk_f32_fp8(v.w, 1);
      }
    }
#pragma unroll
    for (int j = 0; j < 8; ++j) {
      a2[j][0] += __shfl_xor(a2[j][0], 16);
      a2[j][1] += __shfl_xor(a2[j][1], 16);
      a2[j][0] += __shfl_xor(a2[j][0], 32);
      a2[j][1] += __shfl_xor(a2[j][1], 32);
    }
    if (sub == 0 && l < 13) {
      int d0, d1, d2, d3;
      d0 = __builtin_amdgcn_cvt_pk_fp8_f32(a2[0][0], a2[0][1], 0, false);
      d0 = __builtin_amdgcn_cvt_pk_fp8_f32(a2[1][0], a2[1][1], d0, true);
      d1 = __builtin_amdgcn_cvt_pk_fp8_f32(a2[2][0], a2[2][1], 0, false);
      d1 = __builtin_amdgcn_cvt_pk_fp8_f32(a2[3][0], a2[3][1], d1, true);
      *reinterpret_cast<uint2*>(srow + k * 200 + l * 16) = make_uint2(d0, d1);
      if (l < 12) {
        d2 = __builtin_amdgcn_cvt_pk_fp8_f32(a2[4][0], a2[4][1], 0, false);
        d2 = __builtin_amdgcn_cvt_pk_fp8_f32(a2[5][0], a2[5][1], d2, true);
        d3 = __builtin_amdgcn_cvt_pk_fp8_f32(a2[6][0], a2[6][1], 0, false);
        d3 = __builtin_amdgcn_cvt_pk_fp8_f32(a2[7][0], a2[7][1], d3, true);
        *reinterpret_cast<uint2*>(srow + k * 200 + l * 16 + 8) = make_uint2(d2, d3);
      }
    }
    if (k == 0 && lane == 13) {
      float g0 = (float)deg_et[(size_t)0 * N + n];
      float g1 = (float)deg_et[(size_t)1 * N + n];
      float g2 = (float)deg_et[(size_t)2 * N + n];
      float g3 = (float)deg_et[(size_t)3 * N + n];
      int rr = __builtin_amdgcn_cvt_pk_fp8_f32(g0, g1, 0, false);
      rr = __builtin_amdgcn_cvt_pk_fp8_f32(g2, g3, rr, true);
      *reinterpret_cast<unsigned*>(srow + 800) = (unsigned)rr;
    }
    if (k == 3 && lane >= 32 && lane < 39)
      *reinterpret_cast<unsigned*>(srow + 804 + (lane - 32) * 4) = 0;
  }
}

// ------- fp8 MFMA GEMM (phase A): writes fp8 a-slice into ahq ----
__global__ __launch_bounds__(512, 4) void gemm_a8(
    const u8* __restrict__ A, int lda,
    const u8* __restrict__ B, int ldb,
    u8* __restrict__ Cq, int ldcb, int npad,
    int M, int Nn, int K, int gyr) {
  const int gx = gridDim.x;
  int lin = blockIdx.y * gx + blockIdx.x;
  int k8 = lin & 7, j = lin >> 3;
  int band = gridDim.y >> 3;
  int yy = j / gx, xx = j - yy * gx;
  int by = k8 * band + yy;
  if (by >= gyr) return;
  const int m0 = by * 256, n0 = xx * 128;

  __shared__ __align__(16) u8 As[3 * 8192];
  __shared__ __align__(16) u8 Bs[3 * 4096];
  const int tid = threadIdx.x;
  const int lane = tid & 63;
  const int w = tid >> 6;
  const int wr = w >> 1, wc = w & 1;
  const int fr = lane & 15;
  const int g = lane >> 4;

  const int rowA = tid >> 1;
  const int cA = (tid & 1) ^ (rowA & 1);
  int gaA = m0 + rowA; if (gaA >= M) gaA = M - 1;
  const u8* pa = A + (size_t)gaA * lda + cA * 16;
  u8* lA = &As[(size_t)(w * 64) * 16];
  const int sB = w * 32 + (lane & 31);
  const int rowB = sB >> 1;
  const int cB = (sB & 1) ^ (rowB & 1);
  int gbB = n0 + rowB; if (gbB >= Nn) gbB = Nn - 1;
  const u8* pb = B + (size_t)gbB * ldb + cB * 16;
  u8* lB = &Bs[(size_t)(w * 32) * 16];
  const bool doB = (lane < 32);

  const int rdoff = (((g >> 1) ^ (fr & 1)) << 4) + ((g & 1) << 3);

  f32x4 acc[4][4] = {};
  const int nt = K >> 5;
  const int ABUF = 8192, BBUF = 4096;

  gload16(pa, lA);
  if (doB) gload16(pb, lB);
  pa += 32; pb += 32;
  if (nt > 1) {
    gload16(pa, lA + ABUF);
    if (doB) gload16(pb, lB + BBUF);
    pa += 32; pb += 32;
  }

  for (int t = 0; t < nt; ++t) {
    if (t + 1 < nt) asm volatile("s_waitcnt vmcnt(2)" ::: "memory");
    else            asm volatile("s_waitcnt vmcnt(0)" ::: "memory");
    __builtin_amdgcn_s_barrier();
    if (t + 2 < nt) {
      int bi = (t + 2) % 3;
      gload16(pa, lA + bi * ABUF);
      if (doB) gload16(pb, lB + bi * BBUF);
      pa += 32; pb += 32;
    }
    int ca = (t % 3) * ABUF, cbb = (t % 3) * BBUF;
    long af[4], bfv[4];
#pragma unroll
    for (int i = 0; i < 4; ++i) {
      int row = wr * 64 + i * 16 + fr;
      af[i] = *reinterpret_cast<const long*>(&As[ca + row * 32 + rdoff]);
    }
#pragma unroll
    for (int jj = 0; jj < 4; ++jj) {
      int row = wc * 64 + jj * 16 + fr;
      bfv[jj] = *reinterpret_cast<const long*>(&Bs[cbb + row * 32 + rdoff]);
    }
    __builtin_amdgcn_s_setprio(1);
#pragma unroll
    for (int i = 0; i < 4; ++i)
#pragma unroll
      for (int jj = 0; jj < 4; ++jj)
        acc[i][jj] = __builtin_amdgcn_mfma_f32_16x16x32_fp8_fp8(af[i], bfv[jj], acc[i][jj], 0, 0, 0);
    __builtin_amdgcn_s_setprio(0);
  }

  const int er = (lane >> 4) * 4;
  const int ec = lane & 15;
#pragma unroll
  for (int i = 0; i < 4; ++i) {
#pragma unroll
    for (int jj = 0; jj < 4; ++jj) {
      int n = n0 + wc * 64 + jj * 16 + ec;
#pragma unroll
      for (int r = 0; r < 4; ++r) {
        int m = m0 + wr * 64 + i * 16 + er + r;
        if (m >= M) continue;
        if (n < Nn) Cq[(size_t)m * ldcb + n] = f2fp8(acc[i][jj][r]);
        else if (n < npad) Cq[(size_t)m * ldcb + n] = (u8)0;
      }
    }
  }
}

// ------- fp8 gates GEMM + fused GRU (A=ahq K=448 fp8, B=Wall8, gx=7) ------
__global__ __launch_bounds__(512, 4) void gemm_gru8(
    const u8* __restrict__ A, int lda,
    const u8* __restrict__ B, int ldb,
    int M, int K, const float* __restrict__ bias,
    u16* __restrict__ hb, u8* __restrict__ hq, int gyr) {
  const int gx = gridDim.x;
  int lin = blockIdx.y * gx + blockIdx.x;
  int k8 = lin & 7, j = lin >> 3;
  int band = gridDim.y >> 3;
  int yy = j / gx, xx = j - yy * gx;
  int by = k8 * band + yy;
  if (by >= gyr) return;
  const int m0 = by * 256, n0 = xx * 128;
  const int Nn = 800;

  __shared__ __align__(16) u8 SM8[65536];   // K-loop: 36864 B; epilogue: 8x8192 B
  u8* As = SM8;
  u8* Bs = SM8 + 24576;
  const int tid = threadIdx.x;
  const int lane = tid & 63;
  const int w = tid >> 6;
  const int wr = w >> 1, wc = w & 1;
  const int fr = lane & 15;
  const int g = lane >> 4;

  const int rowA = tid >> 1;
  const int cA = (tid & 1) ^ (rowA & 1);
  int gaA = m0 + rowA; if (gaA >= M) gaA = M - 1;
  const u8* pa = A + (size_t)gaA * lda + cA * 16;
  u8* lA = &As[(size_t)(w * 64) * 16];
  const int sB = w * 32 + (lane & 31);
  const int rowB = sB >> 1;
  const int cB = (sB & 1) ^ (rowB & 1);
  int gbB = n0 + rowB; if (gbB >= Nn) gbB = Nn - 1;
  const u8* pb = B + (size_t)gbB * ldb + cB * 16;
  u8* lB = &Bs[(size_t)(w * 32) * 16];
  const bool doB = (lane < 32);

  const int rdoff = (((g >> 1) ^ (fr & 1)) << 4) + ((g & 1) << 3);

  f32x4 acc[4][4] = {};
  const int nt = K >> 5;
  const int ABUF = 8192, BBUF = 4096;

  gload16(pa, lA);
  if (doB) gload16(pb, lB);
  pa += 32; pb += 32;
  if (nt > 1) {
    gload16(pa, lA + ABUF);
    if (doB) gload16(pb, lB + BBUF);
    pa += 32; pb += 32;
  }

  for (int t = 0; t < nt; ++t) {
    if (t + 1 < nt) asm volatile("s_waitcnt vmcnt(2)" ::: "memory");
    else            asm volatile("s_waitcnt vmcnt(0)" ::: "memory");
    __builtin_amdgcn_s_barrier();
    if (t + 2 < nt) {
      int bi = (t + 2) % 3;
      gload16(pa, lA + bi * ABUF);
      if (doB) gload16(pb, lB + bi * BBUF);
      pa += 32; pb += 32;
    }
    int ca = (t % 3) * ABUF, cbb = (t % 3) * BBUF;
    long af[4], bfv[4];
#pragma unroll
    for (int i = 0; i < 4; ++i) {
      int row = wr * 64 + i * 16 + fr;
      af[i] = *reinterpret_cast<const long*>(&As[ca + row * 32 + rdoff]);
    }
#pragma unroll
    for (int jj = 0; jj < 4; ++jj) {
      int row = wc * 64 + jj * 16 + fr;
      bfv[jj] = *reinterpret_cast<const long*>(&Bs[cbb + row * 32 + rdoff]);
    }
    __builtin_amdgcn_s_setprio(1);
#pragma unroll
    for (int i = 0; i < 4; ++i)
#pragma unroll
      for (int jj = 0; jj < 4; ++jj)
        acc[i][jj] = __builtin_amdgcn_mfma_f32_16x16x32_fp8_fp8(af[i], bfv[jj], acc[i][jj], 0, 0, 0);
    __builtin_amdgcn_s_setprio(0);
  }

  // ---- fused GRU epilogue (LDS transpose; gates = 4 consecutive cols) ----
  const int er = (lane >> 4) * 4;
  const int ec = lane & 15;
  __syncthreads();
  float* ep = (float*)(SM8) + (size_t)w * 2048;   // per-wave [64][32] f32

  for (int hh = 0; hh < 2; ++hh) {
#pragma unroll
    for (int jj2 = 0; jj2 < 2; ++jj2) {
      int jj = hh * 2 + jj2;
      int n = n0 + wc * 64 + jj * 16 + ec;
      float bv = (n < 800) ? bias[n] : 0.f;
#pragma unroll
      for (int i = 0; i < 4; ++i)
#pragma unroll
        for (int r = 0; r < 4; ++r) {
          int row_loc = i * 16 + er + r;
          ep[row_loc * 32 + jj2 * 16 + ec] = acc[i][jj][r] + bv;
        }
    }
    __syncthreads();
#pragma unroll
    for (int p = 0; p < 8; ++p) {
      int idx = p * 64 + lane;
      int row = idx >> 3, og = idx & 7;
      int n_base = n0 + wc * 64 + hh * 32 + og * 4;
      int m = m0 + wr * 64 + row;
      if (n_base < 800 && m < M) {
        f32x4 gv = *reinterpret_cast<f32x4*>(&ep[row * 32 + og * 4]);
        float rg = sigm(gv[0]);
        float zg = sigm(gv[1]);
        float x = gv[2] + rg * gv[3];
        float e2 = __expf(2.f * x);
        float nn = (e2 - 1.f) / (e2 + 1.f);
        int o = n_base >> 2;
        float hold = bf2f(hb[(size_t)m * 224 + o]);
        float hv = (1.f - zg) * nn + zg * hold;
        hb[(size_t)m * 224 + o] = f2bf(hv);
        hq[(size_t)m * 224 + o] = f2fp8(hv);
      }
    }
    __syncthreads();
  }
}

// merge hq_next (fp8, stride 224) into ahq h-slice (stride 448)
__global__ void hcopy8_k(const u8* __restrict__ hq, u8* __restrict__ ahq, int N) {
  int total = N * 50;
  for (int i = blockIdx.x * blockDim.x + threadIdx.x; i < total; i += blockDim.x * gridDim.x) {
    int n = i / 50, o4 = (i - n * 50) * 4;
    *reinterpret_cast<unsigned*>(ahq + (size_t)n * 448 + 224 + o4) =
        *reinterpret_cast<const unsigned*>(hq + (size_t)n * 224 + o4);
  }
}

// ------- generic bf16 MFMA GEMM, 256x128 tile (conv paths) ------
__global__ __launch_bounds__(512, 4) void gemm_mfma(
    const u16* __restrict__ A, int lda,
    const u16* __restrict__ B, int ldb,
    u16* __restrict__ Cb, int ldcb, int npad,
    int M, int Nn, int K, const float* __restrict__ bias, int gyr) {
  const int gx = gridDim.x;
  int lin = blockIdx.y * gx + blockIdx.x;
  int k8 = lin & 7, j = lin >> 3;
  int band = gridDim.y >> 3;
  int yy = j / gx, xx = j - yy * gx;
  int by = k8 * band + yy;
  if (by >= gyr) return;
  const int m0 = by * 256, n0 = xx * 128;

  __shared__ __align__(16) u16 As[3 * 8192];
  __shared__ __align__(16) u16 Bs[3 * 4096];
  const int tid = threadIdx.x;
  const int lane = tid & 63;
  const int w = tid >> 6;
  const int wr = w >> 1, wc = w & 1;
  const int fr = lane & 15;
  const int g = lane >> 4;

  const int sA0 = w * 64 + lane, sA1 = sA0 + 512, sB = sA0;
  int rA0 = sA0 >> 2, cA0 = (sA0 & 3) ^ ((rA0 >> 1) & 3);
  int rA1 = sA1 >> 2, cA1 = (sA1 & 3) ^ ((rA1 >> 1) & 3);
  int rB  = sB  >> 2, cB  = (sB & 3) ^ ((rB >> 1) & 3);
  int ga0 = m0 + rA0; if (ga0 >= M) ga0 = M - 1;
  int ga1 = m0 + rA1; if (ga1 >= M) ga1 = M - 1;
  int gb  = n0 + rB;  if (gb >= Nn) gb = Nn - 1;
  const u16* pa0 = A + (size_t)ga0 * lda + cA0 * 8;
  const u16* pa1 = A + (size_t)ga1 * lda + cA1 * 8;
  const u16* pb  = B + (size_t)gb  * ldb + cB * 8;
  u16* lA0 = &As[(w * 64) * 8];
  u16* lA1 = &As[(512 + w * 64) * 8];
  u16* lB  = &Bs[(w * 64) * 8];

  const int gxr = g ^ ((fr >> 1) & 3);

  f32x4 acc[4][4] = {};
  const int nt = K >> 5;
  const int ABUF = 8192, BBUF = 4096;

  gload16(pa0, lA0); gload16(pa1, lA1); gload16(pb, lB);
  pa0 += 32; pa1 += 32; pb += 32;
  if (nt > 1) {
    gload16(pa0, lA0 + ABUF); gload16(pa1, lA1 + ABUF); gload16(pb, lB + BBUF);
    pa0 += 32; pa1 += 32; pb += 32;
  }

  for (int t = 0; t < nt; ++t) {
    if (t + 1 < nt) asm volatile("s_waitcnt vmcnt(3)" ::: "memory");
    else            asm volatile("s_waitcnt vmcnt(0)" ::: "memory");
    __builtin_amdgcn_s_barrier();
    if (t + 2 < nt) {
      int bi = (t + 2) % 3;
      gload16(pa0, lA0 + bi * ABUF); gload16(pa1, lA1 + bi * ABUF); gload16(pb, lB + bi * BBUF);
      pa0 += 32; pa1 += 32; pb += 32;
    }
    int ca = (t % 3) * ABUF, cbb = (t % 3) * BBUF;
    bf16x8 af[4], bfv[4];
#pragma unroll
    for (int i = 0; i < 4; ++i) {
      int row = wr * 64 + i * 16 + fr;
      af[i] = *reinterpret_cast<const bf16x8*>(&As[ca + (row * 4 + gxr) * 8]);
    }
#pragma unroll
    for (int jj = 0; jj < 4; ++jj) {
      int row = wc * 64 + jj * 16 + fr;
      bfv[jj] = *reinterpret_cast<const bf16x8*>(&Bs[cbb + (row * 4 + gxr) * 8]);
    }
    __builtin_amdgcn_s_setprio(1);
#pragma unroll
    for (int i = 0; i < 4; ++i)
#pragma unroll
      for (int jj = 0; jj < 4; ++jj)
        acc[i][jj] = __builtin_amdgcn_mfma_f32_16x16x32_bf16(af[i], bfv[jj], acc[i][jj], 0, 0, 0);
    __builtin_amdgcn_s_setprio(0);
  }

  const int er = (lane >> 4) * 4;
  const int ec = lane & 15;
#pragma unroll
  for (int i = 0; i < 4; ++i) {
#pragma unroll
    for (int jj = 0; jj < 4; ++jj) {
      int n = n0 + wc * 64 + jj * 16 + ec;
#pragma unroll
      for (int r = 0; r < 4; ++r) {
        int m = m0 + wr * 64 + i * 16 + er + r;
        if (m >= M) continue;
        if (n < Nn) {
          float v = acc[i][jj][r];
          if (bias) v += bias[n];
          Cb[(size_t)m * ldcb + n] = f2bf(v);
        } else if (n < npad) {
          Cb[(size_t)m * ldcb + n] = (u16)0;
        }
      }
    }
  }
}

// cmat[n][352] = [hb(224 incl zero pads) | feat(100) | 0(28)]
__global__ void cmat_k(const u16* __restrict__ hb, const float* __restrict__ feat,
                       u16* __restrict__ c, int N) {
  int total = N * 352;
  for (int i = blockIdx.x * blockDim.x + threadIdx.x; i < total; i += blockDim.x * gridDim.x) {
    int n = i / 352, j = i - n * 352;
    u16 v;
    if (j < 224) v = hb[(size_t)n * 224 + j];
    else { int f = j - 224; v = (f < 100) ? f2bf(feat[(size_t)n * 100 + f]) : (u16)0; }
    c[i] = v;
  }
}

__global__ __launch_bounds__(1024) void bn_stats2_k(const u16* __restrict__ X, int L, int C,
                                                    float* __restrict__ stats) {
  const int Q = 1024 / C;
  const int T = Q * C;
  const int tid = threadIdx.x;
  float s = 0.f, q = 0.f;
  int c = 0;
  if (tid < T) {
    int qi = tid / C; c = tid - qi * C;
    for (size_t r = (size_t)blockIdx.x * Q + qi; r < (size_t)L; r += (size_t)gridDim.x * Q) {
      float v = bf2f(X[r * C + c]);
      s += v; q += v * v;
    }
  }
  __shared__ float sb[304], qb[304];
  for (int cc = tid; cc < C; cc += 1024) { sb[cc] = 0.f; qb[cc] = 0.f; }
  __syncthreads();
  if (tid < T) { atomicAdd(&sb[c], s); atomicAdd(&qb[c], q); }
  __syncthreads();
  for (int cc = tid; cc < C; cc += 1024) {
    atomicAdd(&stats[cc], sb[cc]);
    atomicAdd(&stats[C + cc], qb[cc]);
  }
}

__global__ void bn_fin_k(const float* __restrict__ stats, const float* __restrict__ g,
                         const float* __restrict__ b, int C, float Linv,
                         float* __restrict__ scsh) {
  int c = blockIdx.x * blockDim.x + threadIdx.x;
  if (c < C) {
    float mean = stats[c] * Linv;
    float var = stats[C + c] * Linv - mean * mean;
    float sc = g[c] * rsqrtf(var + 1e-5f);
    scsh[c] = sc;
    scsh[C + c] = b[c] - mean * sc;
  }
}

__global__ void pool_bf_k(const u16* __restrict__ X, int C, const float* __restrict__ scsh,
                          int kw, int stride, u16* __restrict__ Y, int Cpad, int Lout) {
  int total = Lout * Cpad;
  for (int i = blockIdx.x * blockDim.x + threadIdx.x; i < total; i += blockDim.x * gridDim.x) {
    int lp = i / Cpad, c = i - lp * Cpad;
    if (c >= C) { Y[i] = (u16)0; continue; }
    float sc = scsh[c], sh = scsh[C + c];
    int l0 = lp * stride;
    float m = 0.f;
    for (int wq = 0; wq < kw; ++wq)
      m = fmaxf(m, fmaf(bf2f(X[(size_t)(l0 + wq) * C + c]), sc, sh));
    Y[i] = f2bf(m);
  }
}

__global__ void pool_f32_k(const u16* __restrict__ X, int C, const float* __restrict__ scsh,
                           int kw, int stride, float* __restrict__ Y, int Lout) {
  int total = Lout * C;
  for (int i = blockIdx.x * blockDim.x + threadIdx.x; i < total; i += blockDim.x * gridDim.x) {
    int lp = i / C, c = i - lp * C;
    float sc = scsh[c], sh = scsh[C + c];
    int l0 = lp * stride;
    float m = 0.f;
    for (int wq = 0; wq < kw; ++wq)
      m = fmaxf(m, fmaf(bf2f(X[(size_t)(l0 + wq) * C + c]), sc, sh));
    Y[i] = m;
  }
}

__global__ __launch_bounds__(256) void final_dot_k(
    const float* __restrict__ Y2, const float* __restrict__ Z2,
    const float* __restrict__ wy, const float* __restrict__ by,
    const float* __restrict__ wz, const float* __restrict__ bz,
    float* __restrict__ acc, int L) {
  float s0 = 0.f, s1 = 0.f;
  for (int lp = blockIdx.x * blockDim.x + threadIdx.x; lp < L; lp += blockDim.x * gridDim.x) {
    const float* y = Y2 + (size_t)lp * 200;
    const float* z = Z2 + (size_t)lp * 300;
    float d0 = 0.f, d1 = 0.f;
    for (int k = 0; k < 200; ++k) { float v = y[k]; d0 += v * wy[k]; d1 += v * wy[200 + k]; }
    float e0 = 0.f, e1 = 0.f;
    for (int k = 0; k < 300; ++k) { float v = z[k]; e0 += v * wz[k]; e1 += v * wz[300 + k]; }
    s0 += (d0 + by[0]) * (e0 + bz[0]);
    s1 += (d1 + by[1]) * (e1 + bz[1]);
  }
  __shared__ float r0[256], r1[256];
  r0[threadIdx.x] = s0; r1[threadIdx.x] = s1;
  __syncthreads();
  for (int off = 128; off > 0; off >>= 1) {
    if (threadIdx.x < off) { r0[threadIdx.x] += r0[threadIdx.x + off]; r1[threadIdx.x] += r1[threadIdx.x + off]; }
    __syncthreads();
  }
  if (threadIdx.x == 0) { atomicAdd(&acc[0], r0[0]); atomicAdd(&acc[1], r1[0]); }
}

__global__ void final_out_k(const float* __restrict__ acc, float invL, float* __restrict__ out) {
  int j = threadIdx.x;
  if (j < 2) out[j] = 1.f / (1.f + expf(-acc[j] * invL));
}

// ---------------- host ----------------

static inline void gemmL(hipStream_t st, const u16* A, int lda, const u16* B, int ldb,
                         u16* Cb, int ldcb, int npad, int M, int Nn, int K, const float* bias) {
  int ncols = (npad > Nn) ? npad : Nn;
  int gx = (ncols + 127) / 128;
  int gy = (M + 255) / 256;
  int gyp = ((gy + 7) / 8) * 8;
  dim3 g(gx, gyp);
  gemm_mfma<<<g, 512, 0, st>>>(A, lda, B, ldb, Cb, ldcb, npad, M, Nn, K, bias, gy);
}

extern "C" void kernel_launch(void* const* d_in, const int* in_sizes, int n_in,
                              void* d_out, int out_size, void* d_ws, size_t ws_size,
                              hipStream_t stream) {
  (void)n_in; (void)out_size;
  const float* feat    = (const float*)d_in[0];
  const int*   eix     = (const int*)d_in[1];
  const int*   etyp    = (const int*)d_in[2];
  const float* ggnnW   = (const float*)d_in[3];
  const float* ggnnB   = (const float*)d_in[4];
  const float* Wih     = (const float*)d_in[5];
  const float* Whh     = (const float*)d_in[6];
  const float* bih     = (const float*)d_in[7];
  const float* bhh     = (const float*)d_in[8];
  const float* conv1w  = (const float*)d_in[9];
  const float* conv2w  = (const float*)d_in[11];
  const float* convc1w = (const float*)d_in[13];
  const float* convc2w = (const float*)d_in[15];
  const float* bnyg    = (const float*)d_in[17];
  const float* bnyb    = (const float*)d_in[18];
  const float* bncg    = (const float*)d_in[19];
  const float* bncb    = (const float*)d_in[20];
  const float* mlpyw   = (const float*)d_in[21];
  const float* mlpyb   = (const float*)d_in[22];
  const float* mlpzw   = (const float*)d_in[23];
  const float* mlpzb   = (const float*)d_in[24];

  const int N = in_sizes[0] / 100;
  const int E = in_sizes[2];
  const int* src = eix;
  const int* dst = eix + E;

  char* base = (char*)d_ws;
  const size_t AHQ_B = (size_t)N * 448;        // fp8 [a|h]
  const size_t HB_B  = (size_t)N * 224 * 2;    // bf16 h
  const int CH = (N + 1) / 2;
  const size_t SCR_B = (size_t)CH * 1664;      // >= N*832 (scat8), N*352*2 (cmat)

  u8*  ahq = (u8*)base;
  u16* hb  = (u16*)(base + AHQ_B);
  char* R1 = base + AHQ_B + HB_B;
  char* WREG = R1 + SCR_B;

  u8*  Wcat8 = (u8*)WREG;                  // 200*832 fp8
  u8*  Wall8 = Wcat8 + 166400;             // 800*448 fp8
  u16* w1c   = (u16*)(Wall8 + 358400);     // 200*1056
  u16* c2b   = w1c + 211200;               // 200*224
  u16* wc1   = c2b + 44800;                // 300*1056
  u16* wc2   = wc1 + 316800;               // 300*320
  float* ball  = (float*)(wc2 + 96000);
  float* stats = ball + 832;
  float* scsh  = stats + 600;
  float* acc2  = scsh + 600;
  int* deg_et = (int*)(acc2 + 8);
  int* off_et = deg_et + 4 * (size_t)N;
  int* cursor = off_et + 4 * (size_t)N;
  int* esrc   = cursor + 4 * (size_t)N;
  int* bsum   = esrc + E;
  const int L4 = 4 * N;
  const int NB = (L4 + 1023) / 1024;
  size_t need = (size_t)((char*)(bsum + NB) - base);

  if (ws_size < need) {
    fail_k<<<1, 64, 0, stream>>>((float*)d_out, -(float)(ws_size >> 20));
    return;
  }

  // ---- CSR build + packs ----
  hipMemsetAsync(deg_et, 0, sizeof(int) * 4 * (size_t)N, stream);
  init_hb_k<<<2048, 256, 0, stream>>>(feat, hb, N);
  init_hq_k<<<2048, 256, 0, stream>>>(feat, ahq, N);
  count_deg_k<<<2048, 256, 0, stream>>>(dst, etyp, deg_et, N, E);
  bsum_k<<<NB, 1024, 0, stream>>>(deg_et, bsum, L4);
  scanb_k<<<1, 1024, 0, stream>>>(bsum, NB);
  scan_fin_k<<<NB, 1024, 0, stream>>>(deg_et, bsum, off_et, L4);
  copy_int_k<<<512, 256, 0, stream>>>(off_et, cursor, L4);
  fill_src_k<<<2048, 256, 0, stream>>>(src, dst, etyp, cursor, esrc, N, E);
  pack_wcat8_k<<<651, 256, 0, stream>>>(ggnnW, ggnnB, Wcat8);
  pack_wall8_k<<<1400, 256, 0, stream>>>(Wih, Whh, Wall8);
  ball_i_k<<<4, 256, 0, stream>>>(bih, bhh, ball);
  pack_w1c_k<<<825, 256, 0, stream>>>(conv1w, w1c);
  pack_lin_b<<<175, 256, 0, stream>>>(conv2w, c2b, 200, 200, 224);
  pack_wc1_b<<<1238, 256, 0, stream>>>(convc1w, wc1);
  pack_lin_b<<<375, 256, 0, stream>>>(convc2w, wc2, 300, 300, 320);

  // ---- GGNN 8 steps ----
  u8* scat8   = (u8*)R1;   // N x 832 (phase A)
  u8* hq_next = (u8*)R1;   // N x 224 (phase B; scat8 dead)

  const int gy = (N + 255) / 256;
  const int gyp = ((gy + 7) / 8) * 8;

  for (int step = 0; step < 8; ++step) {
    agg8_k<<<4096, 256, 0, stream>>>(off_et, deg_et, esrc, ahq, scat8, N);
    gemm_a8<<<dim3(2, gyp), 512, 0, stream>>>(scat8, 832, Wcat8, 832,
                                              ahq, 448, 224, N, 200, 832, gy);
    gemm_gru8<<<dim3(7, gyp), 512, 0, stream>>>(ahq, 448, Wall8, 448, N, 448, ball,
                                                hb, hq_next, gy);
    hcopy8_k<<<2048, 256, 0, stream>>>(hq_next, ahq, N);
  }

  // ---- conv paths ----
  const int L1 = N - 2;
  const int L2 = (L1 - 3) / 2 + 1;
  const int L3 = (L2 - 2) / 2 + 1;

  u16* cmat = (u16*)R1;
  u16* out1 = (u16*)base;
  size_t y1_off = (((size_t)L1 * 400) + 255) & ~(size_t)255;
  u16* y1 = (u16*)(base + y1_off);
  size_t o2_off = y1_off + ((((size_t)L2 * 448) + 255) & ~(size_t)255);
  u16* out2 = (u16*)(base + o2_off);
  float* Y2f = (float*)base;
  size_t oc1_off = (((size_t)L3 * 800) + 255) & ~(size_t)255;
  u16* outc1 = (u16*)(base + oc1_off);
  u16* z1 = (u16*)R1;
  size_t oc2_off = (((size_t)L2 * 640) + 255) & ~(size_t)255;
  u16* outc2 = (u16*)(R1 + oc2_off);
  float* Z2f = (float*)(base + oc1_off);

  cmat_k<<<4096, 256, 0, stream>>>(hb, feat, cmat, N);

  // Y path
  gemmL(stream, cmat, 352, w1c, 1056, out1, 200, 200, L1, 200, 1056, nullptr);
  hipMemsetAsync(stats, 0, sizeof(float) * 400, stream);
  bn_stats2_k<<<512, 1024, 0, stream>>>(out1, L1, 200, stats);
  bn_fin_k<<<2, 256, 0, stream>>>(stats, bnyg, bnyb, 200, 1.f / (float)L1, scsh);
  pool_bf_k<<<2048, 256, 0, stream>>>(out1, 200, scsh, 3, 2, y1, 224, L2);

  gemmL(stream, y1, 224, c2b, 224, out2, 200, 200, L2, 200, 224, nullptr);
  hipMemsetAsync(stats, 0, sizeof(float) * 400, stream);
  bn_stats2_k<<<512, 1024, 0, stream>>>(out2, L2, 200, stats);
  bn_fin_k<<<2, 256, 0, stream>>>(stats, bnyg, bnyb, 200, 1.f / (float)L2, scsh);
  pool_f32_k<<<2048, 256, 0, stream>>>(out2, 200, scsh, 2, 2, Y2f, L3);

  // Z path
  gemmL(stream, cmat, 352, wc1, 1056, outc1, 300, 300, L1, 300, 1056, nullptr);
  hipMemsetAsync(stats, 0, sizeof(float) * 600, stream);
  bn_stats2_k<<<512, 1024, 0, stream>>>(outc1, L1, 300, stats);
  bn_fin_k<<<2, 256, 0, stream>>>(stats, bncg, bncb, 300, 1.f / (float)L1, scsh);
  pool_bf_k<<<2048, 256, 0, stream>>>(outc1, 300, scsh, 3, 2, z1, 320, L2);

  gemmL(stream, z1, 320, wc2, 320, outc2, 300, 300, L2, 300, 320, nullptr);
  hipMemsetAsync(stats, 0, sizeof(float) * 600, stream);
  bn_stats2_k<<<512, 1024, 0, stream>>>(outc2, L2, 300, stats);
  bn_fin_k<<<2, 256, 0, stream>>>(stats, bncg, bncb, 300, 1.f / (float)L2, scsh);
  pool_f32_k<<<2048, 256, 0, stream>>>(outc2, 300, scsh, 2, 2, Z2f, L3);

  // ---- final MLP product + mean + sigmoid ----
  hipMemsetAsync(acc2, 0, sizeof(float) * 2, stream);
  final_dot_k<<<256, 256, 0, stream>>>(Y2f, Z2f, mlpyw, mlpyb, mlpzw, mlpzb, acc2, L3);
  final_out_k<<<1, 64, 0, stream>>>(acc2, 1.f / (float)L3, (float*)d_out);
}

// Round 16
// 3043.223 us; speedup vs baseline: 1.7728x; 1.1513x over previous
//
#include <hip/hip_runtime.h>
#include <cstddef>
#include <cstdint>

// ============================================================================
// DevignModel round 16: agg8 restructure.
//  - wave per NODE; 16-lane group per etype; serial edge loop, NO shfl reduce
//  - gather from dense hqd[N][224] fp8 (22.4 MB) written by gemm_gru8
//  - everything else unchanged from r15
// ============================================================================

typedef unsigned short u16;
typedef unsigned char u8;
typedef __attribute__((ext_vector_type(8))) short bf16x8;
typedef __attribute__((ext_vector_type(4))) float f32x4;
typedef __attribute__((ext_vector_type(2))) float f32x2;

static __device__ __forceinline__ float bf2f(u16 u) {
  union { unsigned int i; float f; } v; v.i = ((unsigned int)u) << 16; return v.f;
}
static __device__ __forceinline__ u16 f2bf(float f) {
  union { float f; unsigned int i; } v; v.f = f;
  unsigned int r = v.i + 0x7FFFu + ((v.i >> 16) & 1u);
  return (u16)(r >> 16);
}
static __device__ __forceinline__ float sigm(float x) { return 1.f / (1.f + __expf(-x)); }
static __device__ __forceinline__ u8 f2fp8(float x) {
  return (u8)(__builtin_amdgcn_cvt_pk_fp8_f32(x, 0.f, 0, false) & 0xff);
}

static __device__ __forceinline__ void gload16(const void* gp, void* lp) {
  __builtin_amdgcn_global_load_lds(
      (const __attribute__((address_space(1))) void*)gp,
      (__attribute__((address_space(3))) void*)lp, 16, 0, 0);
}

__global__ void fail_k(float* out, float code) { out[0] = code; out[1] = code; }

// hb[n][224] bf16 = [feat | 0]
__global__ void init_hb_k(const float* __restrict__ feat, u16* __restrict__ hb, int N) {
  int total = N * 224;
  for (int i = blockIdx.x * blockDim.x + threadIdx.x; i < total; i += blockDim.x * gridDim.x) {
    int n = i / 224, c = i - n * 224;
    hb[i] = (c < 100) ? f2bf(feat[(size_t)n * 100 + c]) : (u16)0;
  }
}

// dense hqd[n][224] fp8 AND ahq h-slice = [feat | 0]
__global__ void init_hq_k(const float* __restrict__ feat, u8* __restrict__ hqd,
                          u8* __restrict__ ahq, int N) {
  int total = N * 224;
  for (int i = blockIdx.x * blockDim.x + threadIdx.x; i < total; i += blockDim.x * gridDim.x) {
    int n = i / 224, c = i - n * 224;
    u8 v = (c < 100) ? f2fp8(feat[(size_t)n * 100 + c]) : (u8)0;
    hqd[i] = v;
    ahq[(size_t)n * 448 + 224 + c] = v;
  }
}

__global__ void count_deg_k(const int* __restrict__ dst, const int* __restrict__ et,
                            int* __restrict__ deg_et, int N, int E) {
  for (int e = blockIdx.x * blockDim.x + threadIdx.x; e < E; e += blockDim.x * gridDim.x)
    atomicAdd(&deg_et[et[e] * N + dst[e]], 1);
}

// ---- parallel exclusive scan (3 kernels) ----
__global__ __launch_bounds__(1024) void bsum_k(const int* __restrict__ cnt,
                                               int* __restrict__ bsum, int L) {
  __shared__ int buf[1024];
  int i = blockIdx.x * 1024 + threadIdx.x;
  buf[threadIdx.x] = (i < L) ? cnt[i] : 0;
  __syncthreads();
  for (int o = 512; o > 0; o >>= 1) {
    if (threadIdx.x < o) buf[threadIdx.x] += buf[threadIdx.x + o];
    __syncthreads();
  }
  if (threadIdx.x == 0) bsum[blockIdx.x] = buf[0];
}

__global__ __launch_bounds__(1024) void scanb_k(int* __restrict__ bsum, int nb) {
  __shared__ int buf[1024];
  int v = (threadIdx.x < nb) ? bsum[threadIdx.x] : 0;
  buf[threadIdx.x] = v;
  __syncthreads();
  for (int o = 1; o < 1024; o <<= 1) {
    int t = (threadIdx.x >= o) ? buf[threadIdx.x - o] : 0;
    __syncthreads();
    buf[threadIdx.x] += t;
    __syncthreads();
  }
  if (threadIdx.x < nb) bsum[threadIdx.x] = buf[threadIdx.x] - v;
}

__global__ __launch_bounds__(1024) void scan_fin_k(const int* __restrict__ cnt,
                                                   const int* __restrict__ bsum,
                                                   int* __restrict__ off, int L) {
  __shared__ int buf[1024];
  int i = blockIdx.x * 1024 + threadIdx.x;
  int v = (i < L) ? cnt[i] : 0;
  buf[threadIdx.x] = v;
  __syncthreads();
  for (int o = 1; o < 1024; o <<= 1) {
    int t = (threadIdx.x >= o) ? buf[threadIdx.x - o] : 0;
    __syncthreads();
    buf[threadIdx.x] += t;
    __syncthreads();
  }
  if (i < L) off[i] = buf[threadIdx.x] - v + bsum[blockIdx.x];
}

__global__ void copy_int_k(const int* __restrict__ a, int* __restrict__ b, int n) {
  for (int i = blockIdx.x * blockDim.x + threadIdx.x; i < n; i += blockDim.x * gridDim.x) b[i] = a[i];
}

__global__ void fill_src_k(const int* __restrict__ src, const int* __restrict__ dst,
                           const int* __restrict__ et, int* __restrict__ cursor,
                           int* __restrict__ esrc, int N, int E) {
  for (int e = blockIdx.x * blockDim.x + threadIdx.x; e < E; e += blockDim.x * gridDim.x) {
    int p = atomicAdd(&cursor[et[e] * N + dst[e]], 1);
    esrc[p] = src[e];
  }
}

// ---- weight packs ----

__global__ void pack_wcat8_k(const float* __restrict__ W, const float* __restrict__ gb,
                             u8* __restrict__ dst) {
  int total = 200 * 832;
  for (int i = blockIdx.x * blockDim.x + threadIdx.x; i < total; i += blockDim.x * gridDim.x) {
    int o = i / 832, kp = i - o * 832;
    float v = 0.f;
    if (kp < 800) { int k = kp / 200, kk = kp - k * 200; v = W[((size_t)k * 200 + o) * 200 + kk]; }
    else if (kp < 804) v = gb[(kp - 800) * 200 + o];
    dst[i] = f2fp8(v);
  }
}

// Wall8[800][448] fp8, gate-interleaved (row 4o+g)
__global__ void pack_wall8_k(const float* __restrict__ Wih, const float* __restrict__ Whh,
                             u8* __restrict__ dst) {
  int total = 800 * 448;
  for (int i = blockIdx.x * blockDim.x + threadIdx.x; i < total; i += blockDim.x * gridDim.x) {
    int jp = i / 448, kp = i - jp * 448;
    int o = jp >> 2, g = jp & 3;
    float v = 0.f;
    if (g == 0) {
      if (kp < 200) v = Wih[(size_t)o * 200 + kp];
      else if (kp >= 224 && kp < 424) v = Whh[(size_t)o * 200 + (kp - 224)];
    } else if (g == 1) {
      if (kp < 200) v = Wih[(size_t)(200 + o) * 200 + kp];
      else if (kp >= 224 && kp < 424) v = Whh[(size_t)(200 + o) * 200 + (kp - 224)];
    } else if (g == 2) {
      if (kp < 200) v = Wih[(size_t)(400 + o) * 200 + kp];
    } else {
      if (kp >= 224 && kp < 424) v = Whh[(size_t)(400 + o) * 200 + (kp - 224)];
    }
    dst[i] = f2fp8(v);
  }
}

__global__ void ball_i_k(const float* __restrict__ bih, const float* __restrict__ bhh,
                         float* __restrict__ ball) {
  int j = blockIdx.x * blockDim.x + threadIdx.x;
  if (j < 800) {
    int o = j >> 2, g = j & 3;
    float v;
    if (g == 0) v = bih[o] + bhh[o];
    else if (g == 1) v = bih[200 + o] + bhh[200 + o];
    else if (g == 2) v = bih[400 + o];
    else v = bhh[400 + o];
    ball[j] = v;
  }
}

__global__ void pack_lin_b(const float* __restrict__ src, u16* __restrict__ dst,
                           int Nn, int K, int Kp) {
  int total = Nn * Kp;
  for (int i = blockIdx.x * blockDim.x + threadIdx.x; i < total; i += blockDim.x * gridDim.x) {
    int o = i / Kp, kp = i - o * Kp;
    dst[i] = (kp < K) ? f2bf(src[(size_t)o * K + kp]) : (u16)0;
  }
}

__global__ void pack_w1c_k(const float* __restrict__ src, u16* __restrict__ dst) {
  int total = 200 * 1056;
  for (int i = blockIdx.x * blockDim.x + threadIdx.x; i < total; i += blockDim.x * gridDim.x) {
    int o = i / 1056, r = i - o * 1056;
    int t = r / 352, kp = r - t * 352;
    dst[i] = (kp < 200) ? f2bf(src[((size_t)o * 200 + kp) * 3 + t]) : (u16)0;
  }
}

__global__ void pack_wc1_b(const float* __restrict__ src, u16* __restrict__ dst) {
  int total = 300 * 1056;
  for (int i = blockIdx.x * blockDim.x + threadIdx.x; i < total; i += blockDim.x * gridDim.x) {
    int o = i / 1056, r = i - o * 1056;
    int t = r / 352, kp = r - t * 352;
    int ci = (kp < 224) ? (kp < 200 ? kp : -1) : ((kp - 224) < 100 ? 200 + (kp - 224) : -1);
    dst[i] = (ci >= 0) ? f2bf(src[((size_t)o * 300 + ci) * 3 + t]) : (u16)0;
  }
}

// aggregation: wave per NODE; 16-lane group per etype; serial edges, no reduce
__global__ void agg8_k(const int* __restrict__ off_et, const int* __restrict__ deg_et,
                       const int* __restrict__ esrc, const u8* __restrict__ hqd,
                       u8* __restrict__ scat8, int N) {
  int gtid = blockIdx.x * blockDim.x + threadIdx.x;
  int wid = gtid >> 6, lane = threadIdx.x & 63;
  int nw = (blockDim.x * gridDim.x) >> 6;
  int sub = lane >> 4, l = lane & 15;
  for (int n = wid; n < N; n += nw) {
    u8* srow = scat8 + (size_t)n * 832;
    int rs = off_et[(size_t)sub * N + n];
    int d  = deg_et[(size_t)sub * N + n];
    f32x2 a2[8];
#pragma unroll
    for (int j = 0; j < 8; ++j) a2[j] = (f32x2)0.f;
    for (int i = 0; i < d; ++i) {
      if (l < 13) {
        const u8* hr = hqd + (size_t)esrc[rs + i] * 224 + l * 16;
        uint4 v = *reinterpret_cast<const uint4*>(hr);
        a2[0] += __builtin_amdgcn_cvt_pk_f32_fp8(v.x, 0);
        a2[1] += __builtin_amdgcn_cvt_pk_f32_fp8(v.x, 1);
        a2[2] += __builtin_amdgcn_cvt_pk_f32_fp8(v.y, 0);
        a2[3] += __builtin_amdgcn_cvt_pk_f32_fp8(v.y, 1);
        a2[4] += __builtin_amdgcn_cvt_pk_f32_fp8(v.z, 0);
        a2[5] += __builtin_amdgcn_cvt_pk_f32_fp8(v.z, 1);
        a2[6] += __builtin_amdgcn_cvt_pk_f32_fp8(v.w, 0);
        a2[7] += __builtin_amdgcn_cvt_pk_f32_fp8(v.w, 1);
      }
    }
    if (l < 13) {
      int d0, d1;
      d0 = __builtin_amdgcn_cvt_pk_fp8_f32(a2[0][0], a2[0][1], 0, false);
      d0 = __builtin_amdgcn_cvt_pk_fp8_f32(a2[1][0], a2[1][1], d0, true);
      d1 = __builtin_amdgcn_cvt_pk_fp8_f32(a2[2][0], a2[2][1], 0, false);
      d1 = __builtin_amdgcn_cvt_pk_fp8_f32(a2[3][0], a2[3][1], d1, true);
      *reinterpret_cast<uint2*>(srow + sub * 200 + l * 16) = make_uint2(d0, d1);
      if (l < 12) {
        int d2, d3;
        d2 = __builtin_amdgcn_cvt_pk_fp8_f32(a2[4][0], a2[4][1], 0, false);
        d2 = __builtin_amdgcn_cvt_pk_fp8_f32(a2[5][0], a2[5][1], d2, true);
        d3 = __builtin_amdgcn_cvt_pk_fp8_f32(a2[6][0], a2[6][1], 0, false);
        d3 = __builtin_amdgcn_cvt_pk_fp8_f32(a2[7][0], a2[7][1], d3, true);
        *reinterpret_cast<uint2*>(srow + sub * 200 + l * 16 + 8) = make_uint2(d2, d3);
      }
    }
    if (sub == 0 && l == 13) {
      float g0 = (float)deg_et[(size_t)0 * N + n];
      float g1 = (float)deg_et[(size_t)1 * N + n];
      float g2 = (float)deg_et[(size_t)2 * N + n];
      float g3 = (float)deg_et[(size_t)3 * N + n];
      int rr = __builtin_amdgcn_cvt_pk_fp8_f32(g0, g1, 0, false);
      rr = __builtin_amdgcn_cvt_pk_fp8_f32(g2, g3, rr, true);
      *reinterpret_cast<unsigned*>(srow + 800) = (unsigned)rr;
    }
    if (sub == 3 && l >= 1 && l <= 7)
      *reinterpret_cast<unsigned*>(srow + 804 + (l - 1) * 4) = 0;
  }
}

// ------- fp8 MFMA GEMM (phase A): writes fp8 a-slice into ahq ----
__global__ __launch_bounds__(512, 4) void gemm_a8(
    const u8* __restrict__ A, int lda,
    const u8* __restrict__ B, int ldb,
    u8* __restrict__ Cq, int ldcb, int npad,
    int M, int Nn, int K, int gyr) {
  const int gx = gridDim.x;
  int lin = blockIdx.y * gx + blockIdx.x;
  int k8 = lin & 7, j = lin >> 3;
  int band = gridDim.y >> 3;
  int yy = j / gx, xx = j - yy * gx;
  int by = k8 * band + yy;
  if (by >= gyr) return;
  const int m0 = by * 256, n0 = xx * 128;

  __shared__ __align__(16) u8 As[3 * 8192];
  __shared__ __align__(16) u8 Bs[3 * 4096];
  const int tid = threadIdx.x;
  const int lane = tid & 63;
  const int w = tid >> 6;
  const int wr = w >> 1, wc = w & 1;
  const int fr = lane & 15;
  const int g = lane >> 4;

  const int rowA = tid >> 1;
  const int cA = (tid & 1) ^ (rowA & 1);
  int gaA = m0 + rowA; if (gaA >= M) gaA = M - 1;
  const u8* pa = A + (size_t)gaA * lda + cA * 16;
  u8* lA = &As[(size_t)(w * 64) * 16];
  const int sB = w * 32 + (lane & 31);
  const int rowB = sB >> 1;
  const int cB = (sB & 1) ^ (rowB & 1);
  int gbB = n0 + rowB; if (gbB >= Nn) gbB = Nn - 1;
  const u8* pb = B + (size_t)gbB * ldb + cB * 16;
  u8* lB = &Bs[(size_t)(w * 32) * 16];
  const bool doB = (lane < 32);

  const int rdoff = (((g >> 1) ^ (fr & 1)) << 4) + ((g & 1) << 3);

  f32x4 acc[4][4] = {};
  const int nt = K >> 5;
  const int ABUF = 8192, BBUF = 4096;

  gload16(pa, lA);
  if (doB) gload16(pb, lB);
  pa += 32; pb += 32;
  if (nt > 1) {
    gload16(pa, lA + ABUF);
    if (doB) gload16(pb, lB + BBUF);
    pa += 32; pb += 32;
  }

  for (int t = 0; t < nt; ++t) {
    if (t + 1 < nt) asm volatile("s_waitcnt vmcnt(2)" ::: "memory");
    else            asm volatile("s_waitcnt vmcnt(0)" ::: "memory");
    __builtin_amdgcn_s_barrier();
    if (t + 2 < nt) {
      int bi = (t + 2) % 3;
      gload16(pa, lA + bi * ABUF);
      if (doB) gload16(pb, lB + bi * BBUF);
      pa += 32; pb += 32;
    }
    int ca = (t % 3) * ABUF, cbb = (t % 3) * BBUF;
    long af[4], bfv[4];
#pragma unroll
    for (int i = 0; i < 4; ++i) {
      int row = wr * 64 + i * 16 + fr;
      af[i] = *reinterpret_cast<const long*>(&As[ca + row * 32 + rdoff]);
    }
#pragma unroll
    for (int jj = 0; jj < 4; ++jj) {
      int row = wc * 64 + jj * 16 + fr;
      bfv[jj] = *reinterpret_cast<const long*>(&Bs[cbb + row * 32 + rdoff]);
    }
    __builtin_amdgcn_s_setprio(1);
#pragma unroll
    for (int i = 0; i < 4; ++i)
#pragma unroll
      for (int jj = 0; jj < 4; ++jj)
        acc[i][jj] = __builtin_amdgcn_mfma_f32_16x16x32_fp8_fp8(af[i], bfv[jj], acc[i][jj], 0, 0, 0);
    __builtin_amdgcn_s_setprio(0);
  }

  const int er = (lane >> 4) * 4;
  const int ec = lane & 15;
#pragma unroll
  for (int i = 0; i < 4; ++i) {
#pragma unroll
    for (int jj = 0; jj < 4; ++jj) {
      int n = n0 + wc * 64 + jj * 16 + ec;
#pragma unroll
      for (int r = 0; r < 4; ++r) {
        int m = m0 + wr * 64 + i * 16 + er + r;
        if (m >= M) continue;
        if (n < Nn) Cq[(size_t)m * ldcb + n] = f2fp8(acc[i][jj][r]);
        else if (n < npad) Cq[(size_t)m * ldcb + n] = (u8)0;
      }
    }
  }
}

// ------- fp8 gates GEMM + fused GRU (A=ahq K=448, B=Wall8, gx=7) ------
__global__ __launch_bounds__(512, 4) void gemm_gru8(
    const u8* __restrict__ A, int lda,
    const u8* __restrict__ B, int ldb,
    int M, int K, const float* __restrict__ bias,
    u16* __restrict__ hb, u8* __restrict__ hq, int gyr) {
  const int gx = gridDim.x;
  int lin = blockIdx.y * gx + blockIdx.x;
  int k8 = lin & 7, j = lin >> 3;
  int band = gridDim.y >> 3;
  int yy = j / gx, xx = j - yy * gx;
  int by = k8 * band + yy;
  if (by >= gyr) return;
  const int m0 = by * 256, n0 = xx * 128;
  const int Nn = 800;

  __shared__ __align__(16) u8 SM8[65536];
  u8* As = SM8;
  u8* Bs = SM8 + 24576;
  const int tid = threadIdx.x;
  const int lane = tid & 63;
  const int w = tid >> 6;
  const int wr = w >> 1, wc = w & 1;
  const int fr = lane & 15;
  const int g = lane >> 4;

  const int rowA = tid >> 1;
  const int cA = (tid & 1) ^ (rowA & 1);
  int gaA = m0 + rowA; if (gaA >= M) gaA = M - 1;
  const u8* pa = A + (size_t)gaA * lda + cA * 16;
  u8* lA = &As[(size_t)(w * 64) * 16];
  const int sB = w * 32 + (lane & 31);
  const int rowB = sB >> 1;
  const int cB = (sB & 1) ^ (rowB & 1);
  int gbB = n0 + rowB; if (gbB >= Nn) gbB = Nn - 1;
  const u8* pb = B + (size_t)gbB * ldb + cB * 16;
  u8* lB = &Bs[(size_t)(w * 32) * 16];
  const bool doB = (lane < 32);

  const int rdoff = (((g >> 1) ^ (fr & 1)) << 4) + ((g & 1) << 3);

  f32x4 acc[4][4] = {};
  const int nt = K >> 5;
  const int ABUF = 8192, BBUF = 4096;

  gload16(pa, lA);
  if (doB) gload16(pb, lB);
  pa += 32; pb += 32;
  if (nt > 1) {
    gload16(pa, lA + ABUF);
    if (doB) gload16(pb, lB + BBUF);
    pa += 32; pb += 32;
  }

  for (int t = 0; t < nt; ++t) {
    if (t + 1 < nt) asm volatile("s_waitcnt vmcnt(2)" ::: "memory");
    else            asm volatile("s_waitcnt vmcnt(0)" ::: "memory");
    __builtin_amdgcn_s_barrier();
    if (t + 2 < nt) {
      int bi = (t + 2) % 3;
      gload16(pa, lA + bi * ABUF);
      if (doB) gload16(pb, lB + bi * BBUF);
      pa += 32; pb += 32;
    }
    int ca = (t % 3) * ABUF, cbb = (t % 3) * BBUF;
    long af[4], bfv[4];
#pragma unroll
    for (int i = 0; i < 4; ++i) {
      int row = wr * 64 + i * 16 + fr;
      af[i] = *reinterpret_cast<const long*>(&As[ca + row * 32 + rdoff]);
    }
#pragma unroll
    for (int jj = 0; jj < 4; ++jj) {
      int row = wc * 64 + jj * 16 + fr;
      bfv[jj] = *reinterpret_cast<const long*>(&Bs[cbb + row * 32 + rdoff]);
    }
    __builtin_amdgcn_s_setprio(1);
#pragma unroll
    for (int i = 0; i < 4; ++i)
#pragma unroll
      for (int jj = 0; jj < 4; ++jj)
        acc[i][jj] = __builtin_amdgcn_mfma_f32_16x16x32_fp8_fp8(af[i], bfv[jj], acc[i][jj], 0, 0, 0);
    __builtin_amdgcn_s_setprio(0);
  }

  // ---- fused GRU epilogue ----
  const int er = (lane >> 4) * 4;
  const int ec = lane & 15;
  __syncthreads();
  float* ep = (float*)(SM8) + (size_t)w * 2048;

  for (int hh = 0; hh < 2; ++hh) {
#pragma unroll
    for (int jj2 = 0; jj2 < 2; ++jj2) {
      int jj = hh * 2 + jj2;
      int n = n0 + wc * 64 + jj * 16 + ec;
      float bv = (n < 800) ? bias[n] : 0.f;
#pragma unroll
      for (int i = 0; i < 4; ++i)
#pragma unroll
        for (int r = 0; r < 4; ++r) {
          int row_loc = i * 16 + er + r;
          ep[row_loc * 32 + jj2 * 16 + ec] = acc[i][jj][r] + bv;
        }
    }
    __syncthreads();
#pragma unroll
    for (int p = 0; p < 8; ++p) {
      int idx = p * 64 + lane;
      int row = idx >> 3, og = idx & 7;
      int n_base = n0 + wc * 64 + hh * 32 + og * 4;
      int m = m0 + wr * 64 + row;
      if (n_base < 800 && m < M) {
        f32x4 gv = *reinterpret_cast<f32x4*>(&ep[row * 32 + og * 4]);
        float rg = sigm(gv[0]);
        float zg = sigm(gv[1]);
        float x = gv[2] + rg * gv[3];
        float e2 = __expf(2.f * x);
        float nn = (e2 - 1.f) / (e2 + 1.f);
        int o = n_base >> 2;
        float hold = bf2f(hb[(size_t)m * 224 + o]);
        float hv = (1.f - zg) * nn + zg * hold;
        hb[(size_t)m * 224 + o] = f2bf(hv);
        hq[(size_t)m * 224 + o] = f2fp8(hv);
      }
    }
    __syncthreads();
  }
}

// merge hqd (fp8, stride 224) into ahq h-slice (stride 448)
__global__ void hcopy8_k(const u8* __restrict__ hq, u8* __restrict__ ahq, int N) {
  int total = N * 50;
  for (int i = blockIdx.x * blockDim.x + threadIdx.x; i < total; i += blockDim.x * gridDim.x) {
    int n = i / 50, o4 = (i - n * 50) * 4;
    *reinterpret_cast<unsigned*>(ahq + (size_t)n * 448 + 224 + o4) =
        *reinterpret_cast<const unsigned*>(hq + (size_t)n * 224 + o4);
  }
}

// ------- generic bf16 MFMA GEMM, 256x128 tile (conv paths) ------
__global__ __launch_bounds__(512, 4) void gemm_mfma(
    const u16* __restrict__ A, int lda,
    const u16* __restrict__ B, int ldb,
    u16* __restrict__ Cb, int ldcb, int npad,
    int M, int Nn, int K, const float* __restrict__ bias, int gyr) {
  const int gx = gridDim.x;
  int lin = blockIdx.y * gx + blockIdx.x;
  int k8 = lin & 7, j = lin >> 3;
  int band = gridDim.y >> 3;
  int yy = j / gx, xx = j - yy * gx;
  int by = k8 * band + yy;
  if (by >= gyr) return;
  const int m0 = by * 256, n0 = xx * 128;

  __shared__ __align__(16) u16 As[3 * 8192];
  __shared__ __align__(16) u16 Bs[3 * 4096];
  const int tid = threadIdx.x;
  const int lane = tid & 63;
  const int w = tid >> 6;
  const int wr = w >> 1, wc = w & 1;
  const int fr = lane & 15;
  const int g = lane >> 4;

  const int sA0 = w * 64 + lane, sA1 = sA0 + 512, sB = sA0;
  int rA0 = sA0 >> 2, cA0 = (sA0 & 3) ^ ((rA0 >> 1) & 3);
  int rA1 = sA1 >> 2, cA1 = (sA1 & 3) ^ ((rA1 >> 1) & 3);
  int rB  = sB  >> 2, cB  = (sB & 3) ^ ((rB >> 1) & 3);
  int ga0 = m0 + rA0; if (ga0 >= M) ga0 = M - 1;
  int ga1 = m0 + rA1; if (ga1 >= M) ga1 = M - 1;
  int gb  = n0 + rB;  if (gb >= Nn) gb = Nn - 1;
  const u16* pa0 = A + (size_t)ga0 * lda + cA0 * 8;
  const u16* pa1 = A + (size_t)ga1 * lda + cA1 * 8;
  const u16* pb  = B + (size_t)gb  * ldb + cB * 8;
  u16* lA0 = &As[(w * 64) * 8];
  u16* lA1 = &As[(512 + w * 64) * 8];
  u16* lB  = &Bs[(w * 64) * 8];

  const int gxr = g ^ ((fr >> 1) & 3);

  f32x4 acc[4][4] = {};
  const int nt = K >> 5;
  const int ABUF = 8192, BBUF = 4096;

  gload16(pa0, lA0); gload16(pa1, lA1); gload16(pb, lB);
  pa0 += 32; pa1 += 32; pb += 32;
  if (nt > 1) {
    gload16(pa0, lA0 + ABUF); gload16(pa1, lA1 + ABUF); gload16(pb, lB + BBUF);
    pa0 += 32; pa1 += 32; pb += 32;
  }

  for (int t = 0; t < nt; ++t) {
    if (t + 1 < nt) asm volatile("s_waitcnt vmcnt(3)" ::: "memory");
    else            asm volatile("s_waitcnt vmcnt(0)" ::: "memory");
    __builtin_amdgcn_s_barrier();
    if (t + 2 < nt) {
      int bi = (t + 2) % 3;
      gload16(pa0, lA0 + bi * ABUF); gload16(pa1, lA1 + bi * ABUF); gload16(pb, lB + bi * BBUF);
      pa0 += 32; pa1 += 32; pb += 32;
    }
    int ca = (t % 3) * ABUF, cbb = (t % 3) * BBUF;
    bf16x8 af[4], bfv[4];
#pragma unroll
    for (int i = 0; i < 4; ++i) {
      int row = wr * 64 + i * 16 + fr;
      af[i] = *reinterpret_cast<const bf16x8*>(&As[ca + (row * 4 + gxr) * 8]);
    }
#pragma unroll
    for (int jj = 0; jj < 4; ++jj) {
      int row = wc * 64 + jj * 16 + fr;
      bfv[jj] = *reinterpret_cast<const bf16x8*>(&Bs[cbb + (row * 4 + gxr) * 8]);
    }
    __builtin_amdgcn_s_setprio(1);
#pragma unroll
    for (int i = 0; i < 4; ++i)
#pragma unroll
      for (int jj = 0; jj < 4; ++jj)
        acc[i][jj] = __builtin_amdgcn_mfma_f32_16x16x32_bf16(af[i], bfv[jj], acc[i][jj], 0, 0, 0);
    __builtin_amdgcn_s_setprio(0);
  }

  const int er = (lane >> 4) * 4;
  const int ec = lane & 15;
#pragma unroll
  for (int i = 0; i < 4; ++i) {
#pragma unroll
    for (int jj = 0; jj < 4; ++jj) {
      int n = n0 + wc * 64 + jj * 16 + ec;
#pragma unroll
      for (int r = 0; r < 4; ++r) {
        int m = m0 + wr * 64 + i * 16 + er + r;
        if (m >= M) continue;
        if (n < Nn) {
          float v = acc[i][jj][r];
          if (bias) v += bias[n];
          Cb[(size_t)m * ldcb + n] = f2bf(v);
        } else if (n < npad) {
          Cb[(size_t)m * ldcb + n] = (u16)0;
        }
      }
    }
  }
}

// cmat[n][352] = [hb(224 incl zero pads) | feat(100) | 0(28)]
__global__ void cmat_k(const u16* __restrict__ hb, const float* __restrict__ feat,
                       u16* __restrict__ c, int N) {
  int total = N * 352;
  for (int i = blockIdx.x * blockDim.x + threadIdx.x; i < total; i += blockDim.x * gridDim.x) {
    int n = i / 352, j = i - n * 352;
    u16 v;
    if (j < 224) v = hb[(size_t)n * 224 + j];
    else { int f = j - 224; v = (f < 100) ? f2bf(feat[(size_t)n * 100 + f]) : (u16)0; }
    c[i] = v;
  }
}

__global__ __launch_bounds__(1024) void bn_stats2_k(const u16* __restrict__ X, int L, int C,
                                                    float* __restrict__ stats) {
  const int Q = 1024 / C;
  const int T = Q * C;
  const int tid = threadIdx.x;
  float s = 0.f, q = 0.f;
  int c = 0;
  if (tid < T) {
    int qi = tid / C; c = tid - qi * C;
    for (size_t r = (size_t)blockIdx.x * Q + qi; r < (size_t)L; r += (size_t)gridDim.x * Q) {
      float v = bf2f(X[r * C + c]);
      s += v; q += v * v;
    }
  }
  __shared__ float sb[304], qb[304];
  for (int cc = tid; cc < C; cc += 1024) { sb[cc] = 0.f; qb[cc] = 0.f; }
  __syncthreads();
  if (tid < T) { atomicAdd(&sb[c], s); atomicAdd(&qb[c], q); }
  __syncthreads();
  for (int cc = tid; cc < C; cc += 1024) {
    atomicAdd(&stats[cc], sb[cc]);
    atomicAdd(&stats[C + cc], qb[cc]);
  }
}

__global__ void bn_fin_k(const float* __restrict__ stats, const float* __restrict__ g,
                         const float* __restrict__ b, int C, float Linv,
                         float* __restrict__ scsh) {
  int c = blockIdx.x * blockDim.x + threadIdx.x;
  if (c < C) {
    float mean = stats[c] * Linv;
    float var = stats[C + c] * Linv - mean * mean;
    float sc = g[c] * rsqrtf(var + 1e-5f);
    scsh[c] = sc;
    scsh[C + c] = b[c] - mean * sc;
  }
}

__global__ void pool_bf_k(const u16* __restrict__ X, int C, const float* __restrict__ scsh,
                          int kw, int stride, u16* __restrict__ Y, int Cpad, int Lout) {
  int total = Lout * Cpad;
  for (int i = blockIdx.x * blockDim.x + threadIdx.x; i < total; i += blockDim.x * gridDim.x) {
    int lp = i / Cpad, c = i - lp * Cpad;
    if (c >= C) { Y[i] = (u16)0; continue; }
    float sc = scsh[c], sh = scsh[C + c];
    int l0 = lp * stride;
    float m = 0.f;
    for (int wq = 0; wq < kw; ++wq)
      m = fmaxf(m, fmaf(bf2f(X[(size_t)(l0 + wq) * C + c]), sc, sh));
    Y[i] = f2bf(m);
  }
}

__global__ void pool_f32_k(const u16* __restrict__ X, int C, const float* __restrict__ scsh,
                           int kw, int stride, float* __restrict__ Y, int Lout) {
  int total = Lout * C;
  for (int i = blockIdx.x * blockDim.x + threadIdx.x; i < total; i += blockDim.x * gridDim.x) {
    int lp = i / C, c = i - lp * C;
    float sc = scsh[c], sh = scsh[C + c];
    int l0 = lp * stride;
    float m = 0.f;
    for (int wq = 0; wq < kw; ++wq)
      m = fmaxf(m, fmaf(bf2f(X[(size_t)(l0 + wq) * C + c]), sc, sh));
    Y[i] = m;
  }
}

__global__ __launch_bounds__(256) void final_dot_k(
    const float* __restrict__ Y2, const float* __restrict__ Z2,
    const float* __restrict__ wy, const float* __restrict__ by,
    const float* __restrict__ wz, const float* __restrict__ bz,
    float* __restrict__ acc, int L) {
  float s0 = 0.f, s1 = 0.f;
  for (int lp = blockIdx.x * blockDim.x + threadIdx.x; lp < L; lp += blockDim.x * gridDim.x) {
    const float* y = Y2 + (size_t)lp * 200;
    const float* z = Z2 + (size_t)lp * 300;
    float d0 = 0.f, d1 = 0.f;
    for (int k = 0; k < 200; ++k) { float v = y[k]; d0 += v * wy[k]; d1 += v * wy[200 + k]; }
    float e0 = 0.f, e1 = 0.f;
    for (int k = 0; k < 300; ++k) { float v = z[k]; e0 += v * wz[k]; e1 += v * wz[300 + k]; }
    s0 += (d0 + by[0]) * (e0 + bz[0]);
    s1 += (d1 + by[1]) * (e1 + bz[1]);
  }
  __shared__ float r0[256], r1[256];
  r0[threadIdx.x] = s0; r1[threadIdx.x] = s1;
  __syncthreads();
  for (int off = 128; off > 0; off >>= 1) {
    if (threadIdx.x < off) { r0[threadIdx.x] += r0[threadIdx.x + off]; r1[threadIdx.x] += r1[threadIdx.x + off]; }
    __syncthreads();
  }
  if (threadIdx.x == 0) { atomicAdd(&acc[0], r0[0]); atomicAdd(&acc[1], r1[0]); }
}

__global__ void final_out_k(const float* __restrict__ acc, float invL, float* __restrict__ out) {
  int j = threadIdx.x;
  if (j < 2) out[j] = 1.f / (1.f + expf(-acc[j] * invL));
}

// ---------------- host ----------------

static inline void gemmL(hipStream_t st, const u16* A, int lda, const u16* B, int ldb,
                         u16* Cb, int ldcb, int npad, int M, int Nn, int K, const float* bias) {
  int ncols = (npad > Nn) ? npad : Nn;
  int gx = (ncols + 127) / 128;
  int gy = (M + 255) / 256;
  int gyp = ((gy + 7) / 8) * 8;
  dim3 g(gx, gyp);
  gemm_mfma<<<g, 512, 0, st>>>(A, lda, B, ldb, Cb, ldcb, npad, M, Nn, K, bias, gy);
}

extern "C" void kernel_launch(void* const* d_in, const int* in_sizes, int n_in,
                              void* d_out, int out_size, void* d_ws, size_t ws_size,
                              hipStream_t stream) {
  (void)n_in; (void)out_size;
  const float* feat    = (const float*)d_in[0];
  const int*   eix     = (const int*)d_in[1];
  const int*   etyp    = (const int*)d_in[2];
  const float* ggnnW   = (const float*)d_in[3];
  const float* ggnnB   = (const float*)d_in[4];
  const float* Wih     = (const float*)d_in[5];
  const float* Whh     = (const float*)d_in[6];
  const float* bih     = (const float*)d_in[7];
  const float* bhh     = (const float*)d_in[8];
  const float* conv1w  = (const float*)d_in[9];
  const float* conv2w  = (const float*)d_in[11];
  const float* convc1w = (const float*)d_in[13];
  const float* convc2w = (const float*)d_in[15];
  const float* bnyg    = (const float*)d_in[17];
  const float* bnyb    = (const float*)d_in[18];
  const float* bncg    = (const float*)d_in[19];
  const float* bncb    = (const float*)d_in[20];
  const float* mlpyw   = (const float*)d_in[21];
  const float* mlpyb   = (const float*)d_in[22];
  const float* mlpzw   = (const float*)d_in[23];
  const float* mlpzb   = (const float*)d_in[24];

  const int N = in_sizes[0] / 100;
  const int E = in_sizes[2];
  const int* src = eix;
  const int* dst = eix + E;

  char* base = (char*)d_ws;
  const size_t AHQ_B = (size_t)N * 448;        // fp8 [a|h]
  const size_t HB_B  = (size_t)N * 224 * 2;    // bf16 h
  const size_t HQD_B = (size_t)N * 224;        // dense fp8 h (gather table)
  const int CH = (N + 1) / 2;
  const size_t SCR_B = (size_t)CH * 1664;

  u8*  ahq = (u8*)base;
  u16* hb  = (u16*)(base + AHQ_B);
  u8*  hqd = (u8*)(base + AHQ_B + HB_B);
  char* R1 = base + AHQ_B + HB_B + HQD_B;
  char* WREG = R1 + SCR_B;

  u8*  Wcat8 = (u8*)WREG;
  u8*  Wall8 = Wcat8 + 166400;
  u16* w1c   = (u16*)(Wall8 + 358400);
  u16* c2b   = w1c + 211200;
  u16* wc1   = c2b + 44800;
  u16* wc2   = wc1 + 316800;
  float* ball  = (float*)(wc2 + 96000);
  float* stats = ball + 832;
  float* scsh  = stats + 600;
  float* acc2  = scsh + 600;
  int* deg_et = (int*)(acc2 + 8);
  int* off_et = deg_et + 4 * (size_t)N;
  int* cursor = off_et + 4 * (size_t)N;
  int* esrc   = cursor + 4 * (size_t)N;
  int* bsum   = esrc + E;
  const int L4 = 4 * N;
  const int NB = (L4 + 1023) / 1024;
  size_t need = (size_t)((char*)(bsum + NB) - base);

  if (ws_size < need) {
    fail_k<<<1, 64, 0, stream>>>((float*)d_out, -(float)(ws_size >> 20));
    return;
  }

  // ---- CSR build + packs ----
  hipMemsetAsync(deg_et, 0, sizeof(int) * 4 * (size_t)N, stream);
  init_hb_k<<<2048, 256, 0, stream>>>(feat, hb, N);
  init_hq_k<<<2048, 256, 0, stream>>>(feat, hqd, ahq, N);
  count_deg_k<<<2048, 256, 0, stream>>>(dst, etyp, deg_et, N, E);
  bsum_k<<<NB, 1024, 0, stream>>>(deg_et, bsum, L4);
  scanb_k<<<1, 1024, 0, stream>>>(bsum, NB);
  scan_fin_k<<<NB, 1024, 0, stream>>>(deg_et, bsum, off_et, L4);
  copy_int_k<<<512, 256, 0, stream>>>(off_et, cursor, L4);
  fill_src_k<<<2048, 256, 0, stream>>>(src, dst, etyp, cursor, esrc, N, E);
  pack_wcat8_k<<<651, 256, 0, stream>>>(ggnnW, ggnnB, Wcat8);
  pack_wall8_k<<<1400, 256, 0, stream>>>(Wih, Whh, Wall8);
  ball_i_k<<<4, 256, 0, stream>>>(bih, bhh, ball);
  pack_w1c_k<<<825, 256, 0, stream>>>(conv1w, w1c);
  pack_lin_b<<<175, 256, 0, stream>>>(conv2w, c2b, 200, 200, 224);
  pack_wc1_b<<<1238, 256, 0, stream>>>(convc1w, wc1);
  pack_lin_b<<<375, 256, 0, stream>>>(convc2w, wc2, 300, 300, 320);

  // ---- GGNN 8 steps ----
  u8* scat8 = (u8*)R1;   // N x 832

  const int gy = (N + 255) / 256;
  const int gyp = ((gy + 7) / 8) * 8;

  for (int step = 0; step < 8; ++step) {
    agg8_k<<<4096, 256, 0, stream>>>(off_et, deg_et, esrc, hqd, scat8, N);
    gemm_a8<<<dim3(2, gyp), 512, 0, stream>>>(scat8, 832, Wcat8, 832,
                                              ahq, 448, 224, N, 200, 832, gy);
    gemm_gru8<<<dim3(7, gyp), 512, 0, stream>>>(ahq, 448, Wall8, 448, N, 448, ball,
                                                hb, hqd, gy);
    hcopy8_k<<<2048, 256, 0, stream>>>(hqd, ahq, N);
  }

  // ---- conv paths ----
  const int L1 = N - 2;
  const int L2 = (L1 - 3) / 2 + 1;
  const int L3 = (L2 - 2) / 2 + 1;

  u16* cmat = (u16*)R1;
  u16* out1 = (u16*)base;
  size_t y1_off = (((size_t)L1 * 400) + 255) & ~(size_t)255;
  u16* y1 = (u16*)(base + y1_off);
  size_t o2_off = y1_off + ((((size_t)L2 * 448) + 255) & ~(size_t)255);
  u16* out2 = (u16*)(base + o2_off);
  float* Y2f = (float*)base;
  size_t oc1_off = (((size_t)L3 * 800) + 255) & ~(size_t)255;
  u16* outc1 = (u16*)(base + oc1_off);
  u16* z1 = (u16*)R1;
  size_t oc2_off = (((size_t)L2 * 640) + 255) & ~(size_t)255;
  u16* outc2 = (u16*)(R1 + oc2_off);
  float* Z2f = (float*)(base + oc1_off);

  cmat_k<<<4096, 256, 0, stream>>>(hb, feat, cmat, N);

  // Y path
  gemmL(stream, cmat, 352, w1c, 1056, out1, 200, 200, L1, 200, 1056, nullptr);
  hipMemsetAsync(stats, 0, sizeof(float) * 400, stream);
  bn_stats2_k<<<512, 1024, 0, stream>>>(out1, L1, 200, stats);
  bn_fin_k<<<2, 256, 0, stream>>>(stats, bnyg, bnyb, 200, 1.f / (float)L1, scsh);
  pool_bf_k<<<2048, 256, 0, stream>>>(out1, 200, scsh, 3, 2, y1, 224, L2);

  gemmL(stream, y1, 224, c2b, 224, out2, 200, 200, L2, 200, 224, nullptr);
  hipMemsetAsync(stats, 0, sizeof(float) * 400, stream);
  bn_stats2_k<<<512, 1024, 0, stream>>>(out2, L2, 200, stats);
  bn_fin_k<<<2, 256, 0, stream>>>(stats, bnyg, bnyb, 200, 1.f / (float)L2, scsh);
  pool_f32_k<<<2048, 256, 0, stream>>>(out2, 200, scsh, 2, 2, Y2f, L3);

  // Z path
  gemmL(stream, cmat, 352, wc1, 1056, outc1, 300, 300, L1, 300, 1056, nullptr);
  hipMemsetAsync(stats, 0, sizeof(float) * 600, stream);
  bn_stats2_k<<<512, 1024, 0, stream>>>(outc1, L1, 300, stats);
  bn_fin_k<<<2, 256, 0, stream>>>(stats, bncg, bncb, 300, 1.f / (float)L1, scsh);
  pool_bf_k<<<2048, 256, 0, stream>>>(outc1, 300, scsh, 3, 2, z1, 320, L2);

  gemmL(stream, z1, 320, wc2, 320, outc2, 300, 300, L2, 300, 320, nullptr);
  hipMemsetAsync(stats, 0, sizeof(float) * 600, stream);
  bn_stats2_k<<<512, 1024, 0, stream>>>(outc2, L2, 300, stats);
  bn_fin_k<<<2, 256, 0, stream>>>(stats, bncg, bncb, 300, 1.f / (float)L2, scsh);
  pool_f32_k<<<2048, 256, 0, stream>>>(outc2, 300, scsh, 2, 2, Z2f, L3);

  // ---- final MLP product + mean + sigmoid ----
  hipMemsetAsync(acc2, 0, sizeof(float) * 2, stream);
  final_dot_k<<<256, 256, 0, stream>>>(Y2f, Z2f, mlpyw, mlpyb, mlpzw, mlpzb, acc2, L3);
  final_out_k<<<1, 64, 0, stream>>>(acc2, 1.f / (float)L3, (float*)d_out);
}

// Round 17
// 2985.101 us; speedup vs baseline: 1.8073x; 1.0195x over previous
//
#include <hip/hip_runtime.h>
#include <cstddef>
#include <cstdint>

// ============================================================================
// DevignModel round 17: fp8 GEMM LDS swizzle fix.
//  - swizzle bit row&1 -> (row>>2)&1 in gemm_a8 + gemm_gru8 (both sides):
//    16-lane fragment group now tiles all 8 slot-groups (2-way = free)
//    instead of 4 (4-way = 1.58x). Everything else unchanged from r16.
// ============================================================================

typedef unsigned short u16;
typedef unsigned char u8;
typedef __attribute__((ext_vector_type(8))) short bf16x8;
typedef __attribute__((ext_vector_type(4))) float f32x4;
typedef __attribute__((ext_vector_type(2))) float f32x2;

static __device__ __forceinline__ float bf2f(u16 u) {
  union { unsigned int i; float f; } v; v.i = ((unsigned int)u) << 16; return v.f;
}
static __device__ __forceinline__ u16 f2bf(float f) {
  union { float f; unsigned int i; } v; v.f = f;
  unsigned int r = v.i + 0x7FFFu + ((v.i >> 16) & 1u);
  return (u16)(r >> 16);
}
static __device__ __forceinline__ float sigm(float x) { return 1.f / (1.f + __expf(-x)); }
static __device__ __forceinline__ u8 f2fp8(float x) {
  return (u8)(__builtin_amdgcn_cvt_pk_fp8_f32(x, 0.f, 0, false) & 0xff);
}

static __device__ __forceinline__ void gload16(const void* gp, void* lp) {
  __builtin_amdgcn_global_load_lds(
      (const __attribute__((address_space(1))) void*)gp,
      (__attribute__((address_space(3))) void*)lp, 16, 0, 0);
}

__global__ void fail_k(float* out, float code) { out[0] = code; out[1] = code; }

// hb[n][224] bf16 = [feat | 0]
__global__ void init_hb_k(const float* __restrict__ feat, u16* __restrict__ hb, int N) {
  int total = N * 224;
  for (int i = blockIdx.x * blockDim.x + threadIdx.x; i < total; i += blockDim.x * gridDim.x) {
    int n = i / 224, c = i - n * 224;
    hb[i] = (c < 100) ? f2bf(feat[(size_t)n * 100 + c]) : (u16)0;
  }
}

// dense hqd[n][224] fp8 AND ahq h-slice = [feat | 0]
__global__ void init_hq_k(const float* __restrict__ feat, u8* __restrict__ hqd,
                          u8* __restrict__ ahq, int N) {
  int total = N * 224;
  for (int i = blockIdx.x * blockDim.x + threadIdx.x; i < total; i += blockDim.x * gridDim.x) {
    int n = i / 224, c = i - n * 224;
    u8 v = (c < 100) ? f2fp8(feat[(size_t)n * 100 + c]) : (u8)0;
    hqd[i] = v;
    ahq[(size_t)n * 448 + 224 + c] = v;
  }
}

__global__ void count_deg_k(const int* __restrict__ dst, const int* __restrict__ et,
                            int* __restrict__ deg_et, int N, int E) {
  for (int e = blockIdx.x * blockDim.x + threadIdx.x; e < E; e += blockDim.x * gridDim.x)
    atomicAdd(&deg_et[et[e] * N + dst[e]], 1);
}

// ---- parallel exclusive scan (3 kernels) ----
__global__ __launch_bounds__(1024) void bsum_k(const int* __restrict__ cnt,
                                               int* __restrict__ bsum, int L) {
  __shared__ int buf[1024];
  int i = blockIdx.x * 1024 + threadIdx.x;
  buf[threadIdx.x] = (i < L) ? cnt[i] : 0;
  __syncthreads();
  for (int o = 512; o > 0; o >>= 1) {
    if (threadIdx.x < o) buf[threadIdx.x] += buf[threadIdx.x + o];
    __syncthreads();
  }
  if (threadIdx.x == 0) bsum[blockIdx.x] = buf[0];
}

__global__ __launch_bounds__(1024) void scanb_k(int* __restrict__ bsum, int nb) {
  __shared__ int buf[1024];
  int v = (threadIdx.x < nb) ? bsum[threadIdx.x] : 0;
  buf[threadIdx.x] = v;
  __syncthreads();
  for (int o = 1; o < 1024; o <<= 1) {
    int t = (threadIdx.x >= o) ? buf[threadIdx.x - o] : 0;
    __syncthreads();
    buf[threadIdx.x] += t;
    __syncthreads();
  }
  if (threadIdx.x < nb) bsum[threadIdx.x] = buf[threadIdx.x] - v;
}

__global__ __launch_bounds__(1024) void scan_fin_k(const int* __restrict__ cnt,
                                                   const int* __restrict__ bsum,
                                                   int* __restrict__ off, int L) {
  __shared__ int buf[1024];
  int i = blockIdx.x * 1024 + threadIdx.x;
  int v = (i < L) ? cnt[i] : 0;
  buf[threadIdx.x] = v;
  __syncthreads();
  for (int o = 1; o < 1024; o <<= 1) {
    int t = (threadIdx.x >= o) ? buf[threadIdx.x - o] : 0;
    __syncthreads();
    buf[threadIdx.x] += t;
    __syncthreads();
  }
  if (i < L) off[i] = buf[threadIdx.x] - v + bsum[blockIdx.x];
}

__global__ void copy_int_k(const int* __restrict__ a, int* __restrict__ b, int n) {
  for (int i = blockIdx.x * blockDim.x + threadIdx.x; i < n; i += blockDim.x * gridDim.x) b[i] = a[i];
}

__global__ void fill_src_k(const int* __restrict__ src, const int* __restrict__ dst,
                           const int* __restrict__ et, int* __restrict__ cursor,
                           int* __restrict__ esrc, int N, int E) {
  for (int e = blockIdx.x * blockDim.x + threadIdx.x; e < E; e += blockDim.x * gridDim.x) {
    int p = atomicAdd(&cursor[et[e] * N + dst[e]], 1);
    esrc[p] = src[e];
  }
}

// ---- weight packs ----

__global__ void pack_wcat8_k(const float* __restrict__ W, const float* __restrict__ gb,
                             u8* __restrict__ dst) {
  int total = 200 * 832;
  for (int i = blockIdx.x * blockDim.x + threadIdx.x; i < total; i += blockDim.x * gridDim.x) {
    int o = i / 832, kp = i - o * 832;
    float v = 0.f;
    if (kp < 800) { int k = kp / 200, kk = kp - k * 200; v = W[((size_t)k * 200 + o) * 200 + kk]; }
    else if (kp < 804) v = gb[(kp - 800) * 200 + o];
    dst[i] = f2fp8(v);
  }
}

// Wall8[800][448] fp8, gate-interleaved (row 4o+g)
__global__ void pack_wall8_k(const float* __restrict__ Wih, const float* __restrict__ Whh,
                             u8* __restrict__ dst) {
  int total = 800 * 448;
  for (int i = blockIdx.x * blockDim.x + threadIdx.x; i < total; i += blockDim.x * gridDim.x) {
    int jp = i / 448, kp = i - jp * 448;
    int o = jp >> 2, g = jp & 3;
    float v = 0.f;
    if (g == 0) {
      if (kp < 200) v = Wih[(size_t)o * 200 + kp];
      else if (kp >= 224 && kp < 424) v = Whh[(size_t)o * 200 + (kp - 224)];
    } else if (g == 1) {
      if (kp < 200) v = Wih[(size_t)(200 + o) * 200 + kp];
      else if (kp >= 224 && kp < 424) v = Whh[(size_t)(200 + o) * 200 + (kp - 224)];
    } else if (g == 2) {
      if (kp < 200) v = Wih[(size_t)(400 + o) * 200 + kp];
    } else {
      if (kp >= 224 && kp < 424) v = Whh[(size_t)(400 + o) * 200 + (kp - 224)];
    }
    dst[i] = f2fp8(v);
  }
}

__global__ void ball_i_k(const float* __restrict__ bih, const float* __restrict__ bhh,
                         float* __restrict__ ball) {
  int j = blockIdx.x * blockDim.x + threadIdx.x;
  if (j < 800) {
    int o = j >> 2, g = j & 3;
    float v;
    if (g == 0) v = bih[o] + bhh[o];
    else if (g == 1) v = bih[200 + o] + bhh[200 + o];
    else if (g == 2) v = bih[400 + o];
    else v = bhh[400 + o];
    ball[j] = v;
  }
}

__global__ void pack_lin_b(const float* __restrict__ src, u16* __restrict__ dst,
                           int Nn, int K, int Kp) {
  int total = Nn * Kp;
  for (int i = blockIdx.x * blockDim.x + threadIdx.x; i < total; i += blockDim.x * gridDim.x) {
    int o = i / Kp, kp = i - o * Kp;
    dst[i] = (kp < K) ? f2bf(src[(size_t)o * K + kp]) : (u16)0;
  }
}

__global__ void pack_w1c_k(const float* __restrict__ src, u16* __restrict__ dst) {
  int total = 200 * 1056;
  for (int i = blockIdx.x * blockDim.x + threadIdx.x; i < total; i += blockDim.x * gridDim.x) {
    int o = i / 1056, r = i - o * 1056;
    int t = r / 352, kp = r - t * 352;
    dst[i] = (kp < 200) ? f2bf(src[((size_t)o * 200 + kp) * 3 + t]) : (u16)0;
  }
}

__global__ void pack_wc1_b(const float* __restrict__ src, u16* __restrict__ dst) {
  int total = 300 * 1056;
  for (int i = blockIdx.x * blockDim.x + threadIdx.x; i < total; i += blockDim.x * gridDim.x) {
    int o = i / 1056, r = i - o * 1056;
    int t = r / 352, kp = r - t * 352;
    int ci = (kp < 224) ? (kp < 200 ? kp : -1) : ((kp - 224) < 100 ? 200 + (kp - 224) : -1);
    dst[i] = (ci >= 0) ? f2bf(src[((size_t)o * 300 + ci) * 3 + t]) : (u16)0;
  }
}

// aggregation: wave per NODE; 16-lane group per etype; serial edges, no reduce
__global__ void agg8_k(const int* __restrict__ off_et, const int* __restrict__ deg_et,
                       const int* __restrict__ esrc, const u8* __restrict__ hqd,
                       u8* __restrict__ scat8, int N) {
  int gtid = blockIdx.x * blockDim.x + threadIdx.x;
  int wid = gtid >> 6, lane = threadIdx.x & 63;
  int nw = (blockDim.x * gridDim.x) >> 6;
  int sub = lane >> 4, l = lane & 15;
  for (int n = wid; n < N; n += nw) {
    u8* srow = scat8 + (size_t)n * 832;
    int rs = off_et[(size_t)sub * N + n];
    int d  = deg_et[(size_t)sub * N + n];
    f32x2 a2[8];
#pragma unroll
    for (int j = 0; j < 8; ++j) a2[j] = (f32x2)0.f;
    for (int i = 0; i < d; ++i) {
      if (l < 13) {
        const u8* hr = hqd + (size_t)esrc[rs + i] * 224 + l * 16;
        uint4 v = *reinterpret_cast<const uint4*>(hr);
        a2[0] += __builtin_amdgcn_cvt_pk_f32_fp8(v.x, 0);
        a2[1] += __builtin_amdgcn_cvt_pk_f32_fp8(v.x, 1);
        a2[2] += __builtin_amdgcn_cvt_pk_f32_fp8(v.y, 0);
        a2[3] += __builtin_amdgcn_cvt_pk_f32_fp8(v.y, 1);
        a2[4] += __builtin_amdgcn_cvt_pk_f32_fp8(v.z, 0);
        a2[5] += __builtin_amdgcn_cvt_pk_f32_fp8(v.z, 1);
        a2[6] += __builtin_amdgcn_cvt_pk_f32_fp8(v.w, 0);
        a2[7] += __builtin_amdgcn_cvt_pk_f32_fp8(v.w, 1);
      }
    }
    if (l < 13) {
      int d0, d1;
      d0 = __builtin_amdgcn_cvt_pk_fp8_f32(a2[0][0], a2[0][1], 0, false);
      d0 = __builtin_amdgcn_cvt_pk_fp8_f32(a2[1][0], a2[1][1], d0, true);
      d1 = __builtin_amdgcn_cvt_pk_fp8_f32(a2[2][0], a2[2][1], 0, false);
      d1 = __builtin_amdgcn_cvt_pk_fp8_f32(a2[3][0], a2[3][1], d1, true);
      *reinterpret_cast<uint2*>(srow + sub * 200 + l * 16) = make_uint2(d0, d1);
      if (l < 12) {
        int d2, d3;
        d2 = __builtin_amdgcn_cvt_pk_fp8_f32(a2[4][0], a2[4][1], 0, false);
        d2 = __builtin_amdgcn_cvt_pk_fp8_f32(a2[5][0], a2[5][1], d2, true);
        d3 = __builtin_amdgcn_cvt_pk_fp8_f32(a2[6][0], a2[6][1], 0, false);
        d3 = __builtin_amdgcn_cvt_pk_fp8_f32(a2[7][0], a2[7][1], d3, true);
        *reinterpret_cast<uint2*>(srow + sub * 200 + l * 16 + 8) = make_uint2(d2, d3);
      }
    }
    if (sub == 0 && l == 13) {
      float g0 = (float)deg_et[(size_t)0 * N + n];
      float g1 = (float)deg_et[(size_t)1 * N + n];
      float g2 = (float)deg_et[(size_t)2 * N + n];
      float g3 = (float)deg_et[(size_t)3 * N + n];
      int rr = __builtin_amdgcn_cvt_pk_fp8_f32(g0, g1, 0, false);
      rr = __builtin_amdgcn_cvt_pk_fp8_f32(g2, g3, rr, true);
      *reinterpret_cast<unsigned*>(srow + 800) = (unsigned)rr;
    }
    if (sub == 3 && l >= 1 && l <= 7)
      *reinterpret_cast<unsigned*>(srow + 804 + (l - 1) * 4) = 0;
  }
}

// ------- fp8 MFMA GEMM (phase A): writes fp8 a-slice into ahq ----
// LDS slot s = 2*row + (chunk ^ ((row>>2)&1)) -> 2-way (free) bank pattern.
__global__ __launch_bounds__(512, 4) void gemm_a8(
    const u8* __restrict__ A, int lda,
    const u8* __restrict__ B, int ldb,
    u8* __restrict__ Cq, int ldcb, int npad,
    int M, int Nn, int K, int gyr) {
  const int gx = gridDim.x;
  int lin = blockIdx.y * gx + blockIdx.x;
  int k8 = lin & 7, j = lin >> 3;
  int band = gridDim.y >> 3;
  int yy = j / gx, xx = j - yy * gx;
  int by = k8 * band + yy;
  if (by >= gyr) return;
  const int m0 = by * 256, n0 = xx * 128;

  __shared__ __align__(16) u8 As[3 * 8192];
  __shared__ __align__(16) u8 Bs[3 * 4096];
  const int tid = threadIdx.x;
  const int lane = tid & 63;
  const int w = tid >> 6;
  const int wr = w >> 1, wc = w & 1;
  const int fr = lane & 15;
  const int g = lane >> 4;

  const int rowA = tid >> 1;
  const int cA = (tid & 1) ^ ((rowA >> 2) & 1);
  int gaA = m0 + rowA; if (gaA >= M) gaA = M - 1;
  const u8* pa = A + (size_t)gaA * lda + cA * 16;
  u8* lA = &As[(size_t)(w * 64) * 16];
  const int sB = w * 32 + (lane & 31);
  const int rowB = sB >> 1;
  const int cB = (sB & 1) ^ ((rowB >> 2) & 1);
  int gbB = n0 + rowB; if (gbB >= Nn) gbB = Nn - 1;
  const u8* pb = B + (size_t)gbB * ldb + cB * 16;
  u8* lB = &Bs[(size_t)(w * 32) * 16];
  const bool doB = (lane < 32);

  const int rdoff = (((g >> 1) ^ ((fr >> 2) & 1)) << 4) + ((g & 1) << 3);

  f32x4 acc[4][4] = {};
  const int nt = K >> 5;
  const int ABUF = 8192, BBUF = 4096;

  gload16(pa, lA);
  if (doB) gload16(pb, lB);
  pa += 32; pb += 32;
  if (nt > 1) {
    gload16(pa, lA + ABUF);
    if (doB) gload16(pb, lB + BBUF);
    pa += 32; pb += 32;
  }

  for (int t = 0; t < nt; ++t) {
    if (t + 1 < nt) asm volatile("s_waitcnt vmcnt(2)" ::: "memory");
    else            asm volatile("s_waitcnt vmcnt(0)" ::: "memory");
    __builtin_amdgcn_s_barrier();
    if (t + 2 < nt) {
      int bi = (t + 2) % 3;
      gload16(pa, lA + bi * ABUF);
      if (doB) gload16(pb, lB + bi * BBUF);
      pa += 32; pb += 32;
    }
    int ca = (t % 3) * ABUF, cbb = (t % 3) * BBUF;
    long af[4], bfv[4];
#pragma unroll
    for (int i = 0; i < 4; ++i) {
      int row = wr * 64 + i * 16 + fr;
      af[i] = *reinterpret_cast<const long*>(&As[ca + row * 32 + rdoff]);
    }
#pragma unroll
    for (int jj = 0; jj < 4; ++jj) {
      int row = wc * 64 + jj * 16 + fr;
      bfv[jj] = *reinterpret_cast<const long*>(&Bs[cbb + row * 32 + rdoff]);
    }
    __builtin_amdgcn_s_setprio(1);
#pragma unroll
    for (int i = 0; i < 4; ++i)
#pragma unroll
      for (int jj = 0; jj < 4; ++jj)
        acc[i][jj] = __builtin_amdgcn_mfma_f32_16x16x32_fp8_fp8(af[i], bfv[jj], acc[i][jj], 0, 0, 0);
    __builtin_amdgcn_s_setprio(0);
  }

  const int er = (lane >> 4) * 4;
  const int ec = lane & 15;
#pragma unroll
  for (int i = 0; i < 4; ++i) {
#pragma unroll
    for (int jj = 0; jj < 4; ++jj) {
      int n = n0 + wc * 64 + jj * 16 + ec;
#pragma unroll
      for (int r = 0; r < 4; ++r) {
        int m = m0 + wr * 64 + i * 16 + er + r;
        if (m >= M) continue;
        if (n < Nn) Cq[(size_t)m * ldcb + n] = f2fp8(acc[i][jj][r]);
        else if (n < npad) Cq[(size_t)m * ldcb + n] = (u8)0;
      }
    }
  }
}

// ------- fp8 gates GEMM + fused GRU (A=ahq K=448, B=Wall8, gx=7) ------
__global__ __launch_bounds__(512, 4) void gemm_gru8(
    const u8* __restrict__ A, int lda,
    const u8* __restrict__ B, int ldb,
    int M, int K, const float* __restrict__ bias,
    u16* __restrict__ hb, u8* __restrict__ hq, int gyr) {
  const int gx = gridDim.x;
  int lin = blockIdx.y * gx + blockIdx.x;
  int k8 = lin & 7, j = lin >> 3;
  int band = gridDim.y >> 3;
  int yy = j / gx, xx = j - yy * gx;
  int by = k8 * band + yy;
  if (by >= gyr) return;
  const int m0 = by * 256, n0 = xx * 128;
  const int Nn = 800;

  __shared__ __align__(16) u8 SM8[65536];
  u8* As = SM8;
  u8* Bs = SM8 + 24576;
  const int tid = threadIdx.x;
  const int lane = tid & 63;
  const int w = tid >> 6;
  const int wr = w >> 1, wc = w & 1;
  const int fr = lane & 15;
  const int g = lane >> 4;

  const int rowA = tid >> 1;
  const int cA = (tid & 1) ^ ((rowA >> 2) & 1);
  int gaA = m0 + rowA; if (gaA >= M) gaA = M - 1;
  const u8* pa = A + (size_t)gaA * lda + cA * 16;
  u8* lA = &As[(size_t)(w * 64) * 16];
  const int sB = w * 32 + (lane & 31);
  const int rowB = sB >> 1;
  const int cB = (sB & 1) ^ ((rowB >> 2) & 1);
  int gbB = n0 + rowB; if (gbB >= Nn) gbB = Nn - 1;
  const u8* pb = B + (size_t)gbB * ldb + cB * 16;
  u8* lB = &Bs[(size_t)(w * 32) * 16];
  const bool doB = (lane < 32);

  const int rdoff = (((g >> 1) ^ ((fr >> 2) & 1)) << 4) + ((g & 1) << 3);

  f32x4 acc[4][4] = {};
  const int nt = K >> 5;
  const int ABUF = 8192, BBUF = 4096;

  gload16(pa, lA);
  if (doB) gload16(pb, lB);
  pa += 32; pb += 32;
  if (nt > 1) {
    gload16(pa, lA + ABUF);
    if (doB) gload16(pb, lB + BBUF);
    pa += 32; pb += 32;
  }

  for (int t = 0; t < nt; ++t) {
    if (t + 1 < nt) asm volatile("s_waitcnt vmcnt(2)" ::: "memory");
    else            asm volatile("s_waitcnt vmcnt(0)" ::: "memory");
    __builtin_amdgcn_s_barrier();
    if (t + 2 < nt) {
      int bi = (t + 2) % 3;
      gload16(pa, lA + bi * ABUF);
      if (doB) gload16(pb, lB + bi * BBUF);
      pa += 32; pb += 32;
    }
    int ca = (t % 3) * ABUF, cbb = (t % 3) * BBUF;
    long af[4], bfv[4];
#pragma unroll
    for (int i = 0; i < 4; ++i) {
      int row = wr * 64 + i * 16 + fr;
      af[i] = *reinterpret_cast<const long*>(&As[ca + row * 32 + rdoff]);
    }
#pragma unroll
    for (int jj = 0; jj < 4; ++jj) {
      int row = wc * 64 + jj * 16 + fr;
      bfv[jj] = *reinterpret_cast<const long*>(&Bs[cbb + row * 32 + rdoff]);
    }
    __builtin_amdgcn_s_setprio(1);
#pragma unroll
    for (int i = 0; i < 4; ++i)
#pragma unroll
      for (int jj = 0; jj < 4; ++jj)
        acc[i][jj] = __builtin_amdgcn_mfma_f32_16x16x32_fp8_fp8(af[i], bfv[jj], acc[i][jj], 0, 0, 0);
    __builtin_amdgcn_s_setprio(0);
  }

  // ---- fused GRU epilogue ----
  const int er = (lane >> 4) * 4;
  const int ec = lane & 15;
  __syncthreads();
  float* ep = (float*)(SM8) + (size_t)w * 2048;

  for (int hh = 0; hh < 2; ++hh) {
#pragma unroll
    for (int jj2 = 0; jj2 < 2; ++jj2) {
      int jj = hh * 2 + jj2;
      int n = n0 + wc * 64 + jj * 16 + ec;
      float bv = (n < 800) ? bias[n] : 0.f;
#pragma unroll
      for (int i = 0; i < 4; ++i)
#pragma unroll
        for (int r = 0; r < 4; ++r) {
          int row_loc = i * 16 + er + r;
          ep[row_loc * 32 + jj2 * 16 + ec] = acc[i][jj][r] + bv;
        }
    }
    __syncthreads();
#pragma unroll
    for (int p = 0; p < 8; ++p) {
      int idx = p * 64 + lane;
      int row = idx >> 3, og = idx & 7;
      int n_base = n0 + wc * 64 + hh * 32 + og * 4;
      int m = m0 + wr * 64 + row;
      if (n_base < 800 && m < M) {
        f32x4 gv = *reinterpret_cast<f32x4*>(&ep[row * 32 + og * 4]);
        float rg = sigm(gv[0]);
        float zg = sigm(gv[1]);
        float x = gv[2] + rg * gv[3];
        float e2 = __expf(2.f * x);
        float nn = (e2 - 1.f) / (e2 + 1.f);
        int o = n_base >> 2;
        float hold = bf2f(hb[(size_t)m * 224 + o]);
        float hv = (1.f - zg) * nn + zg * hold;
        hb[(size_t)m * 224 + o] = f2bf(hv);
        hq[(size_t)m * 224 + o] = f2fp8(hv);
      }
    }
    __syncthreads();
  }
}

// merge hqd (fp8, stride 224) into ahq h-slice (stride 448)
__global__ void hcopy8_k(const u8* __restrict__ hq, u8* __restrict__ ahq, int N) {
  int total = N * 50;
  for (int i = blockIdx.x * blockDim.x + threadIdx.x; i < total; i += blockDim.x * gridDim.x) {
    int n = i / 50, o4 = (i - n * 50) * 4;
    *reinterpret_cast<unsigned*>(ahq + (size_t)n * 448 + 224 + o4) =
        *reinterpret_cast<const unsigned*>(hq + (size_t)n * 224 + o4);
  }
}

// ------- generic bf16 MFMA GEMM, 256x128 tile (conv paths) ------
__global__ __launch_bounds__(512, 4) void gemm_mfma(
    const u16* __restrict__ A, int lda,
    const u16* __restrict__ B, int ldb,
    u16* __restrict__ Cb, int ldcb, int npad,
    int M, int Nn, int K, const float* __restrict__ bias, int gyr) {
  const int gx = gridDim.x;
  int lin = blockIdx.y * gx + blockIdx.x;
  int k8 = lin & 7, j = lin >> 3;
  int band = gridDim.y >> 3;
  int yy = j / gx, xx = j - yy * gx;
  int by = k8 * band + yy;
  if (by >= gyr) return;
  const int m0 = by * 256, n0 = xx * 128;

  __shared__ __align__(16) u16 As[3 * 8192];
  __shared__ __align__(16) u16 Bs[3 * 4096];
  const int tid = threadIdx.x;
  const int lane = tid & 63;
  const int w = tid >> 6;
  const int wr = w >> 1, wc = w & 1;
  const int fr = lane & 15;
  const int g = lane >> 4;

  const int sA0 = w * 64 + lane, sA1 = sA0 + 512, sB = sA0;
  int rA0 = sA0 >> 2, cA0 = (sA0 & 3) ^ ((rA0 >> 1) & 3);
  int rA1 = sA1 >> 2, cA1 = (sA1 & 3) ^ ((rA1 >> 1) & 3);
  int rB  = sB  >> 2, cB  = (sB & 3) ^ ((rB >> 1) & 3);
  int ga0 = m0 + rA0; if (ga0 >= M) ga0 = M - 1;
  int ga1 = m0 + rA1; if (ga1 >= M) ga1 = M - 1;
  int gb  = n0 + rB;  if (gb >= Nn) gb = Nn - 1;
  const u16* pa0 = A + (size_t)ga0 * lda + cA0 * 8;
  const u16* pa1 = A + (size_t)ga1 * lda + cA1 * 8;
  const u16* pb  = B + (size_t)gb  * ldb + cB * 8;
  u16* lA0 = &As[(w * 64) * 8];
  u16* lA1 = &As[(512 + w * 64) * 8];
  u16* lB  = &Bs[(w * 64) * 8];

  const int gxr = g ^ ((fr >> 1) & 3);

  f32x4 acc[4][4] = {};
  const int nt = K >> 5;
  const int ABUF = 8192, BBUF = 4096;

  gload16(pa0, lA0); gload16(pa1, lA1); gload16(pb, lB);
  pa0 += 32; pa1 += 32; pb += 32;
  if (nt > 1) {
    gload16(pa0, lA0 + ABUF); gload16(pa1, lA1 + ABUF); gload16(pb, lB + BBUF);
    pa0 += 32; pa1 += 32; pb += 32;
  }

  for (int t = 0; t < nt; ++t) {
    if (t + 1 < nt) asm volatile("s_waitcnt vmcnt(3)" ::: "memory");
    else            asm volatile("s_waitcnt vmcnt(0)" ::: "memory");
    __builtin_amdgcn_s_barrier();
    if (t + 2 < nt) {
      int bi = (t + 2) % 3;
      gload16(pa0, lA0 + bi * ABUF); gload16(pa1, lA1 + bi * ABUF); gload16(pb, lB + bi * BBUF);
      pa0 += 32; pa1 += 32; pb += 32;
    }
    int ca = (t % 3) * ABUF, cbb = (t % 3) * BBUF;
    bf16x8 af[4], bfv[4];
#pragma unroll
    for (int i = 0; i < 4; ++i) {
      int row = wr * 64 + i * 16 + fr;
      af[i] = *reinterpret_cast<const bf16x8*>(&As[ca + (row * 4 + gxr) * 8]);
    }
#pragma unroll
    for (int jj = 0; jj < 4; ++jj) {
      int row = wc * 64 + jj * 16 + fr;
      bfv[jj] = *reinterpret_cast<const bf16x8*>(&Bs[cbb + (row * 4 + gxr) * 8]);
    }
    __builtin_amdgcn_s_setprio(1);
#pragma unroll
    for (int i = 0; i < 4; ++i)
#pragma unroll
      for (int jj = 0; jj < 4; ++jj)
        acc[i][jj] = __builtin_amdgcn_mfma_f32_16x16x32_bf16(af[i], bfv[jj], acc[i][jj], 0, 0, 0);
    __builtin_amdgcn_s_setprio(0);
  }

  const int er = (lane >> 4) * 4;
  const int ec = lane & 15;
#pragma unroll
  for (int i = 0; i < 4; ++i) {
#pragma unroll
    for (int jj = 0; jj < 4; ++jj) {
      int n = n0 + wc * 64 + jj * 16 + ec;
#pragma unroll
      for (int r = 0; r < 4; ++r) {
        int m = m0 + wr * 64 + i * 16 + er + r;
        if (m >= M) continue;
        if (n < Nn) {
          float v = acc[i][jj][r];
          if (bias) v += bias[n];
          Cb[(size_t)m * ldcb + n] = f2bf(v);
        } else if (n < npad) {
          Cb[(size_t)m * ldcb + n] = (u16)0;
        }
      }
    }
  }
}

// cmat[n][352] = [hb(224 incl zero pads) | feat(100) | 0(28)]
__global__ void cmat_k(const u16* __restrict__ hb, const float* __restrict__ feat,
                       u16* __restrict__ c, int N) {
  int total = N * 352;
  for (int i = blockIdx.x * blockDim.x + threadIdx.x; i < total; i += blockDim.x * gridDim.x) {
    int n = i / 352, j = i - n * 352;
    u16 v;
    if (j < 224) v = hb[(size_t)n * 224 + j];
    else { int f = j - 224; v = (f < 100) ? f2bf(feat[(size_t)n * 100 + f]) : (u16)0; }
    c[i] = v;
  }
}

__global__ __launch_bounds__(1024) void bn_stats2_k(const u16* __restrict__ X, int L, int C,
                                                    float* __restrict__ stats) {
  const int Q = 1024 / C;
  const int T = Q * C;
  const int tid = threadIdx.x;
  float s = 0.f, q = 0.f;
  int c = 0;
  if (tid < T) {
    int qi = tid / C; c = tid - qi * C;
    for (size_t r = (size_t)blockIdx.x * Q + qi; r < (size_t)L; r += (size_t)gridDim.x * Q) {
      float v = bf2f(X[r * C + c]);
      s += v; q += v * v;
    }
  }
  __shared__ float sb[304], qb[304];
  for (int cc = tid; cc < C; cc += 1024) { sb[cc] = 0.f; qb[cc] = 0.f; }
  __syncthreads();
  if (tid < T) { atomicAdd(&sb[c], s); atomicAdd(&qb[c], q); }
  __syncthreads();
  for (int cc = tid; cc < C; cc += 1024) {
    atomicAdd(&stats[cc], sb[cc]);
    atomicAdd(&stats[C + cc], qb[cc]);
  }
}

__global__ void bn_fin_k(const float* __restrict__ stats, const float* __restrict__ g,
                         const float* __restrict__ b, int C, float Linv,
                         float* __restrict__ scsh) {
  int c = blockIdx.x * blockDim.x + threadIdx.x;
  if (c < C) {
    float mean = stats[c] * Linv;
    float var = stats[C + c] * Linv - mean * mean;
    float sc = g[c] * rsqrtf(var + 1e-5f);
    scsh[c] = sc;
    scsh[C + c] = b[c] - mean * sc;
  }
}

__global__ void pool_bf_k(const u16* __restrict__ X, int C, const float* __restrict__ scsh,
                          int kw, int stride, u16* __restrict__ Y, int Cpad, int Lout) {
  int total = Lout * Cpad;
  for (int i = blockIdx.x * blockDim.x + threadIdx.x; i < total; i += blockDim.x * gridDim.x) {
    int lp = i / Cpad, c = i - lp * Cpad;
    if (c >= C) { Y[i] = (u16)0; continue; }
    float sc = scsh[c], sh = scsh[C + c];
    int l0 = lp * stride;
    float m = 0.f;
    for (int wq = 0; wq < kw; ++wq)
      m = fmaxf(m, fmaf(bf2f(X[(size_t)(l0 + wq) * C + c]), sc, sh));
    Y[i] = f2bf(m);
  }
}

__global__ void pool_f32_k(const u16* __restrict__ X, int C, const float* __restrict__ scsh,
                           int kw, int stride, float* __restrict__ Y, int Lout) {
  int total = Lout * C;
  for (int i = blockIdx.x * blockDim.x + threadIdx.x; i < total; i += blockDim.x * gridDim.x) {
    int lp = i / C, c = i - lp * C;
    float sc = scsh[c], sh = scsh[C + c];
    int l0 = lp * stride;
    float m = 0.f;
    for (int wq = 0; wq < kw; ++wq)
      m = fmaxf(m, fmaf(bf2f(X[(size_t)(l0 + wq) * C + c]), sc, sh));
    Y[i] = m;
  }
}

__global__ __launch_bounds__(256) void final_dot_k(
    const float* __restrict__ Y2, const float* __restrict__ Z2,
    const float* __restrict__ wy, const float* __restrict__ by,
    const float* __restrict__ wz, const float* __restrict__ bz,
    float* __restrict__ acc, int L) {
  float s0 = 0.f, s1 = 0.f;
  for (int lp = blockIdx.x * blockDim.x + threadIdx.x; lp < L; lp += blockDim.x * gridDim.x) {
    const float* y = Y2 + (size_t)lp * 200;
    const float* z = Z2 + (size_t)lp * 300;
    float d0 = 0.f, d1 = 0.f;
    for (int k = 0; k < 200; ++k) { float v = y[k]; d0 += v * wy[k]; d1 += v * wy[200 + k]; }
    float e0 = 0.f, e1 = 0.f;
    for (int k = 0; k < 300; ++k) { float v = z[k]; e0 += v * wz[k]; e1 += v * wz[300 + k]; }
    s0 += (d0 + by[0]) * (e0 + bz[0]);
    s1 += (d1 + by[1]) * (e1 + bz[1]);
  }
  __shared__ float r0[256], r1[256];
  r0[threadIdx.x] = s0; r1[threadIdx.x] = s1;
  __syncthreads();
  for (int off = 128; off > 0; off >>= 1) {
    if (threadIdx.x < off) { r0[threadIdx.x] += r0[threadIdx.x + off]; r1[threadIdx.x] += r1[threadIdx.x + off]; }
    __syncthreads();
  }
  if (threadIdx.x == 0) { atomicAdd(&acc[0], r0[0]); atomicAdd(&acc[1], r1[0]); }
}

__global__ void final_out_k(const float* __restrict__ acc, float invL, float* __restrict__ out) {
  int j = threadIdx.x;
  if (j < 2) out[j] = 1.f / (1.f + expf(-acc[j] * invL));
}

// ---------------- host ----------------

static inline void gemmL(hipStream_t st, const u16* A, int lda, const u16* B, int ldb,
                         u16* Cb, int ldcb, int npad, int M, int Nn, int K, const float* bias) {
  int ncols = (npad > Nn) ? npad : Nn;
  int gx = (ncols + 127) / 128;
  int gy = (M + 255) / 256;
  int gyp = ((gy + 7) / 8) * 8;
  dim3 g(gx, gyp);
  gemm_mfma<<<g, 512, 0, st>>>(A, lda, B, ldb, Cb, ldcb, npad, M, Nn, K, bias, gy);
}

extern "C" void kernel_launch(void* const* d_in, const int* in_sizes, int n_in,
                              void* d_out, int out_size, void* d_ws, size_t ws_size,
                              hipStream_t stream) {
  (void)n_in; (void)out_size;
  const float* feat    = (const float*)d_in[0];
  const int*   eix     = (const int*)d_in[1];
  const int*   etyp    = (const int*)d_in[2];
  const float* ggnnW   = (const float*)d_in[3];
  const float* ggnnB   = (const float*)d_in[4];
  const float* Wih     = (const float*)d_in[5];
  const float* Whh     = (const float*)d_in[6];
  const float* bih     = (const float*)d_in[7];
  const float* bhh     = (const float*)d_in[8];
  const float* conv1w  = (const float*)d_in[9];
  const float* conv2w  = (const float*)d_in[11];
  const float* convc1w = (const float*)d_in[13];
  const float* convc2w = (const float*)d_in[15];
  const float* bnyg    = (const float*)d_in[17];
  const float* bnyb    = (const float*)d_in[18];
  const float* bncg    = (const float*)d_in[19];
  const float* bncb    = (const float*)d_in[20];
  const float* mlpyw   = (const float*)d_in[21];
  const float* mlpyb   = (const float*)d_in[22];
  const float* mlpzw   = (const float*)d_in[23];
  const float* mlpzb   = (const float*)d_in[24];

  const int N = in_sizes[0] / 100;
  const int E = in_sizes[2];
  const int* src = eix;
  const int* dst = eix + E;

  char* base = (char*)d_ws;
  const size_t AHQ_B = (size_t)N * 448;
  const size_t HB_B  = (size_t)N * 224 * 2;
  const size_t HQD_B = (size_t)N * 224;
  const int CH = (N + 1) / 2;
  const size_t SCR_B = (size_t)CH * 1664;

  u8*  ahq = (u8*)base;
  u16* hb  = (u16*)(base + AHQ_B);
  u8*  hqd = (u8*)(base + AHQ_B + HB_B);
  char* R1 = base + AHQ_B + HB_B + HQD_B;
  char* WREG = R1 + SCR_B;

  u8*  Wcat8 = (u8*)WREG;
  u8*  Wall8 = Wcat8 + 166400;
  u16* w1c   = (u16*)(Wall8 + 358400);
  u16* c2b   = w1c + 211200;
  u16* wc1   = c2b + 44800;
  u16* wc2   = wc1 + 316800;
  float* ball  = (float*)(wc2 + 96000);
  float* stats = ball + 832;
  float* scsh  = stats + 600;
  float* acc2  = scsh + 600;
  int* deg_et = (int*)(acc2 + 8);
  int* off_et = deg_et + 4 * (size_t)N;
  int* cursor = off_et + 4 * (size_t)N;
  int* esrc   = cursor + 4 * (size_t)N;
  int* bsum   = esrc + E;
  const int L4 = 4 * N;
  const int NB = (L4 + 1023) / 1024;
  size_t need = (size_t)((char*)(bsum + NB) - base);

  if (ws_size < need) {
    fail_k<<<1, 64, 0, stream>>>((float*)d_out, -(float)(ws_size >> 20));
    return;
  }

  // ---- CSR build + packs ----
  hipMemsetAsync(deg_et, 0, sizeof(int) * 4 * (size_t)N, stream);
  init_hb_k<<<2048, 256, 0, stream>>>(feat, hb, N);
  init_hq_k<<<2048, 256, 0, stream>>>(feat, hqd, ahq, N);
  count_deg_k<<<2048, 256, 0, stream>>>(dst, etyp, deg_et, N, E);
  bsum_k<<<NB, 1024, 0, stream>>>(deg_et, bsum, L4);
  scanb_k<<<1, 1024, 0, stream>>>(bsum, NB);
  scan_fin_k<<<NB, 1024, 0, stream>>>(deg_et, bsum, off_et, L4);
  copy_int_k<<<512, 256, 0, stream>>>(off_et, cursor, L4);
  fill_src_k<<<2048, 256, 0, stream>>>(src, dst, etyp, cursor, esrc, N, E);
  pack_wcat8_k<<<651, 256, 0, stream>>>(ggnnW, ggnnB, Wcat8);
  pack_wall8_k<<<1400, 256, 0, stream>>>(Wih, Whh, Wall8);
  ball_i_k<<<4, 256, 0, stream>>>(bih, bhh, ball);
  pack_w1c_k<<<825, 256, 0, stream>>>(conv1w, w1c);
  pack_lin_b<<<175, 256, 0, stream>>>(conv2w, c2b, 200, 200, 224);
  pack_wc1_b<<<1238, 256, 0, stream>>>(convc1w, wc1);
  pack_lin_b<<<375, 256, 0, stream>>>(convc2w, wc2, 300, 300, 320);

  // ---- GGNN 8 steps ----
  u8* scat8 = (u8*)R1;

  const int gy = (N + 255) / 256;
  const int gyp = ((gy + 7) / 8) * 8;

  for (int step = 0; step < 8; ++step) {
    agg8_k<<<4096, 256, 0, stream>>>(off_et, deg_et, esrc, hqd, scat8, N);
    gemm_a8<<<dim3(2, gyp), 512, 0, stream>>>(scat8, 832, Wcat8, 832,
                                              ahq, 448, 224, N, 200, 832, gy);
    gemm_gru8<<<dim3(7, gyp), 512, 0, stream>>>(ahq, 448, Wall8, 448, N, 448, ball,
                                                hb, hqd, gy);
    hcopy8_k<<<2048, 256, 0, stream>>>(hqd, ahq, N);
  }

  // ---- conv paths ----
  const int L1 = N - 2;
  const int L2 = (L1 - 3) / 2 + 1;
  const int L3 = (L2 - 2) / 2 + 1;

  u16* cmat = (u16*)R1;
  u16* out1 = (u16*)base;
  size_t y1_off = (((size_t)L1 * 400) + 255) & ~(size_t)255;
  u16* y1 = (u16*)(base + y1_off);
  size_t o2_off = y1_off + ((((size_t)L2 * 448) + 255) & ~(size_t)255);
  u16* out2 = (u16*)(base + o2_off);
  float* Y2f = (float*)base;
  size_t oc1_off = (((size_t)L3 * 800) + 255) & ~(size_t)255;
  u16* outc1 = (u16*)(base + oc1_off);
  u16* z1 = (u16*)R1;
  size_t oc2_off = (((size_t)L2 * 640) + 255) & ~(size_t)255;
  u16* outc2 = (u16*)(R1 + oc2_off);
  float* Z2f = (float*)(base + oc1_off);

  cmat_k<<<4096, 256, 0, stream>>>(hb, feat, cmat, N);

  // Y path
  gemmL(stream, cmat, 352, w1c, 1056, out1, 200, 200, L1, 200, 1056, nullptr);
  hipMemsetAsync(stats, 0, sizeof(float) * 400, stream);
  bn_stats2_k<<<512, 1024, 0, stream>>>(out1, L1, 200, stats);
  bn_fin_k<<<2, 256, 0, stream>>>(stats, bnyg, bnyb, 200, 1.f / (float)L1, scsh);
  pool_bf_k<<<2048, 256, 0, stream>>>(out1, 200, scsh, 3, 2, y1, 224, L2);

  gemmL(stream, y1, 224, c2b, 224, out2, 200, 200, L2, 200, 224, nullptr);
  hipMemsetAsync(stats, 0, sizeof(float) * 400, stream);
  bn_stats2_k<<<512, 1024, 0, stream>>>(out2, L2, 200, stats);
  bn_fin_k<<<2, 256, 0, stream>>>(stats, bnyg, bnyb, 200, 1.f / (float)L2, scsh);
  pool_f32_k<<<2048, 256, 0, stream>>>(out2, 200, scsh, 2, 2, Y2f, L3);

  // Z path
  gemmL(stream, cmat, 352, wc1, 1056, outc1, 300, 300, L1, 300, 1056, nullptr);
  hipMemsetAsync(stats, 0, sizeof(float) * 600, stream);
  bn_stats2_k<<<512, 1024, 0, stream>>>(outc1, L1, 300, stats);
  bn_fin_k<<<2, 256, 0, stream>>>(stats, bncg, bncb, 300, 1.f / (float)L1, scsh);
  pool_bf_k<<<2048, 256, 0, stream>>>(outc1, 300, scsh, 3, 2, z1, 320, L2);

  gemmL(stream, z1, 320, wc2, 320, outc2, 300, 300, L2, 300, 320, nullptr);
  hipMemsetAsync(stats, 0, sizeof(float) * 600, stream);
  bn_stats2_k<<<512, 1024, 0, stream>>>(outc2, L2, 300, stats);
  bn_fin_k<<<2, 256, 0, stream>>>(stats, bncg, bncb, 300, 1.f / (float)L2, scsh);
  pool_f32_k<<<2048, 256, 0, stream>>>(outc2, 300, scsh, 2, 2, Z2f, L3);

  // ---- final MLP product + mean + sigmoid ----
  hipMemsetAsync(acc2, 0, sizeof(float) * 2, stream);
  final_dot_k<<<256, 256, 0, stream>>>(Y2f, Z2f, mlpyw, mlpyb, mlpzw, mlpzb, acc2, L3);
  final_out_k<<<1, 64, 0, stream>>>(acc2, 1.f / (float)L3, (float*)d_out);
}

// Round 18
// 2858.941 us; speedup vs baseline: 1.8871x; 1.0441x over previous
//
#include <hip/hip_runtime.h>
#include <cstddef>
#include <cstdint>

// ============================================================================
// DevignModel round 18:
//  - dense aq[N][224]; gemm_gru8 K-loop reads aq (tiles 0-6) + h-table (7-13)
//    -> no ahq, no hcopy; h-table ping-pongs (hq0/hq1) for write safety
//  - GRU epilogue LDS stride 32 -> 36 f32 (2-way banks, aligned)
//  - agg8: 2-deep software-pipelined edge loop
// ============================================================================

typedef unsigned short u16;
typedef unsigned char u8;
typedef __attribute__((ext_vector_type(8))) short bf16x8;
typedef __attribute__((ext_vector_type(4))) float f32x4;
typedef __attribute__((ext_vector_type(2))) float f32x2;

static __device__ __forceinline__ float bf2f(u16 u) {
  union { unsigned int i; float f; } v; v.i = ((unsigned int)u) << 16; return v.f;
}
static __device__ __forceinline__ u16 f2bf(float f) {
  union { float f; unsigned int i; } v; v.f = f;
  unsigned int r = v.i + 0x7FFFu + ((v.i >> 16) & 1u);
  return (u16)(r >> 16);
}
static __device__ __forceinline__ float sigm(float x) { return 1.f / (1.f + __expf(-x)); }
static __device__ __forceinline__ u8 f2fp8(float x) {
  return (u8)(__builtin_amdgcn_cvt_pk_fp8_f32(x, 0.f, 0, false) & 0xff);
}

static __device__ __forceinline__ void gload16(const void* gp, void* lp) {
  __builtin_amdgcn_global_load_lds(
      (const __attribute__((address_space(1))) void*)gp,
      (__attribute__((address_space(3))) void*)lp, 16, 0, 0);
}

__global__ void fail_k(float* out, float code) { out[0] = code; out[1] = code; }

// hb[n][224] bf16 = [feat | 0]
__global__ void init_hb_k(const float* __restrict__ feat, u16* __restrict__ hb, int N) {
  int total = N * 224;
  for (int i = blockIdx.x * blockDim.x + threadIdx.x; i < total; i += blockDim.x * gridDim.x) {
    int n = i / 224, c = i - n * 224;
    hb[i] = (c < 100) ? f2bf(feat[(size_t)n * 100 + c]) : (u16)0;
  }
}

// dense hq0[n][224] fp8 = [feat | 0]
__global__ void init_hq_k(const float* __restrict__ feat, u8* __restrict__ hq0, int N) {
  int total = N * 224;
  for (int i = blockIdx.x * blockDim.x + threadIdx.x; i < total; i += blockDim.x * gridDim.x) {
    int n = i / 224, c = i - n * 224;
    hq0[i] = (c < 100) ? f2fp8(feat[(size_t)n * 100 + c]) : (u8)0;
  }
}

__global__ void count_deg_k(const int* __restrict__ dst, const int* __restrict__ et,
                            int* __restrict__ deg_et, int N, int E) {
  for (int e = blockIdx.x * blockDim.x + threadIdx.x; e < E; e += blockDim.x * gridDim.x)
    atomicAdd(&deg_et[et[e] * N + dst[e]], 1);
}

// ---- parallel exclusive scan (3 kernels) ----
__global__ __launch_bounds__(1024) void bsum_k(const int* __restrict__ cnt,
                                               int* __restrict__ bsum, int L) {
  __shared__ int buf[1024];
  int i = blockIdx.x * 1024 + threadIdx.x;
  buf[threadIdx.x] = (i < L) ? cnt[i] : 0;
  __syncthreads();
  for (int o = 512; o > 0; o >>= 1) {
    if (threadIdx.x < o) buf[threadIdx.x] += buf[threadIdx.x + o];
    __syncthreads();
  }
  if (threadIdx.x == 0) bsum[blockIdx.x] = buf[0];
}

__global__ __launch_bounds__(1024) void scanb_k(int* __restrict__ bsum, int nb) {
  __shared__ int buf[1024];
  int v = (threadIdx.x < nb) ? bsum[threadIdx.x] : 0;
  buf[threadIdx.x] = v;
  __syncthreads();
  for (int o = 1; o < 1024; o <<= 1) {
    int t = (threadIdx.x >= o) ? buf[threadIdx.x - o] : 0;
    __syncthreads();
    buf[threadIdx.x] += t;
    __syncthreads();
  }
  if (threadIdx.x < nb) bsum[threadIdx.x] = buf[threadIdx.x] - v;
}

__global__ __launch_bounds__(1024) void scan_fin_k(const int* __restrict__ cnt,
                                                   const int* __restrict__ bsum,
                                                   int* __restrict__ off, int L) {
  __shared__ int buf[1024];
  int i = blockIdx.x * 1024 + threadIdx.x;
  int v = (i < L) ? cnt[i] : 0;
  buf[threadIdx.x] = v;
  __syncthreads();
  for (int o = 1; o < 1024; o <<= 1) {
    int t = (threadIdx.x >= o) ? buf[threadIdx.x - o] : 0;
    __syncthreads();
    buf[threadIdx.x] += t;
    __syncthreads();
  }
  if (i < L) off[i] = buf[threadIdx.x] - v + bsum[blockIdx.x];
}

__global__ void copy_int_k(const int* __restrict__ a, int* __restrict__ b, int n) {
  for (int i = blockIdx.x * blockDim.x + threadIdx.x; i < n; i += blockDim.x * gridDim.x) b[i] = a[i];
}

__global__ void fill_src_k(const int* __restrict__ src, const int* __restrict__ dst,
                           const int* __restrict__ et, int* __restrict__ cursor,
                           int* __restrict__ esrc, int N, int E) {
  for (int e = blockIdx.x * blockDim.x + threadIdx.x; e < E; e += blockDim.x * gridDim.x) {
    int p = atomicAdd(&cursor[et[e] * N + dst[e]], 1);
    esrc[p] = src[e];
  }
}

// ---- weight packs ----

__global__ void pack_wcat8_k(const float* __restrict__ W, const float* __restrict__ gb,
                             u8* __restrict__ dst) {
  int total = 200 * 832;
  for (int i = blockIdx.x * blockDim.x + threadIdx.x; i < total; i += blockDim.x * gridDim.x) {
    int o = i / 832, kp = i - o * 832;
    float v = 0.f;
    if (kp < 800) { int k = kp / 200, kk = kp - k * 200; v = W[((size_t)k * 200 + o) * 200 + kk]; }
    else if (kp < 804) v = gb[(kp - 800) * 200 + o];
    dst[i] = f2fp8(v);
  }
}

// Wall8[800][448] fp8, gate-interleaved (row 4o+g)
__global__ void pack_wall8_k(const float* __restrict__ Wih, const float* __restrict__ Whh,
                             u8* __restrict__ dst) {
  int total = 800 * 448;
  for (int i = blockIdx.x * blockDim.x + threadIdx.x; i < total; i += blockDim.x * gridDim.x) {
    int jp = i / 448, kp = i - jp * 448;
    int o = jp >> 2, g = jp & 3;
    float v = 0.f;
    if (g == 0) {
      if (kp < 200) v = Wih[(size_t)o * 200 + kp];
      else if (kp >= 224 && kp < 424) v = Whh[(size_t)o * 200 + (kp - 224)];
    } else if (g == 1) {
      if (kp < 200) v = Wih[(size_t)(200 + o) * 200 + kp];
      else if (kp >= 224 && kp < 424) v = Whh[(size_t)(200 + o) * 200 + (kp - 224)];
    } else if (g == 2) {
      if (kp < 200) v = Wih[(size_t)(400 + o) * 200 + kp];
    } else {
      if (kp >= 224 && kp < 424) v = Whh[(size_t)(400 + o) * 200 + (kp - 224)];
    }
    dst[i] = f2fp8(v);
  }
}

__global__ void ball_i_k(const float* __restrict__ bih, const float* __restrict__ bhh,
                         float* __restrict__ ball) {
  int j = blockIdx.x * blockDim.x + threadIdx.x;
  if (j < 800) {
    int o = j >> 2, g = j & 3;
    float v;
    if (g == 0) v = bih[o] + bhh[o];
    else if (g == 1) v = bih[200 + o] + bhh[200 + o];
    else if (g == 2) v = bih[400 + o];
    else v = bhh[400 + o];
    ball[j] = v;
  }
}

__global__ void pack_lin_b(const float* __restrict__ src, u16* __restrict__ dst,
                           int Nn, int K, int Kp) {
  int total = Nn * Kp;
  for (int i = blockIdx.x * blockDim.x + threadIdx.x; i < total; i += blockDim.x * gridDim.x) {
    int o = i / Kp, kp = i - o * Kp;
    dst[i] = (kp < K) ? f2bf(src[(size_t)o * K + kp]) : (u16)0;
  }
}

__global__ void pack_w1c_k(const float* __restrict__ src, u16* __restrict__ dst) {
  int total = 200 * 1056;
  for (int i = blockIdx.x * blockDim.x + threadIdx.x; i < total; i += blockDim.x * gridDim.x) {
    int o = i / 1056, r = i - o * 1056;
    int t = r / 352, kp = r - t * 352;
    dst[i] = (kp < 200) ? f2bf(src[((size_t)o * 200 + kp) * 3 + t]) : (u16)0;
  }
}

__global__ void pack_wc1_b(const float* __restrict__ src, u16* __restrict__ dst) {
  int total = 300 * 1056;
  for (int i = blockIdx.x * blockDim.x + threadIdx.x; i < total; i += blockDim.x * gridDim.x) {
    int o = i / 1056, r = i - o * 1056;
    int t = r / 352, kp = r - t * 352;
    int ci = (kp < 224) ? (kp < 200 ? kp : -1) : ((kp - 224) < 100 ? 200 + (kp - 224) : -1);
    dst[i] = (ci >= 0) ? f2bf(src[((size_t)o * 300 + ci) * 3 + t]) : (u16)0;
  }
}

// aggregation: wave per NODE; 16-lane group per etype; 2-deep pipelined edges
__global__ void agg8_k(const int* __restrict__ off_et, const int* __restrict__ deg_et,
                       const int* __restrict__ esrc, const u8* __restrict__ hqd,
                       u8* __restrict__ scat8, int N) {
  int gtid = blockIdx.x * blockDim.x + threadIdx.x;
  int wid = gtid >> 6, lane = threadIdx.x & 63;
  int nw = (blockDim.x * gridDim.x) >> 6;
  int sub = lane >> 4, l = lane & 15;
  for (int n = wid; n < N; n += nw) {
    u8* srow = scat8 + (size_t)n * 832;
    int rs = off_et[(size_t)sub * N + n];
    int d  = deg_et[(size_t)sub * N + n];
    f32x2 a2[8];
#pragma unroll
    for (int j = 0; j < 8; ++j) a2[j] = (f32x2)0.f;
    if (l < 13 && d > 0) {
      const size_t lo = (size_t)l * 16;
      uint4 v = *reinterpret_cast<const uint4*>(hqd + (size_t)esrc[rs] * 224 + lo);
      for (int i = 1; i < d; ++i) {
        uint4 vn = *reinterpret_cast<const uint4*>(hqd + (size_t)esrc[rs + i] * 224 + lo);
        a2[0] += __builtin_amdgcn_cvt_pk_f32_fp8(v.x, 0);
        a2[1] += __builtin_amdgcn_cvt_pk_f32_fp8(v.x, 1);
        a2[2] += __builtin_amdgcn_cvt_pk_f32_fp8(v.y, 0);
        a2[3] += __builtin_amdgcn_cvt_pk_f32_fp8(v.y, 1);
        a2[4] += __builtin_amdgcn_cvt_pk_f32_fp8(v.z, 0);
        a2[5] += __builtin_amdgcn_cvt_pk_f32_fp8(v.z, 1);
        a2[6] += __builtin_amdgcn_cvt_pk_f32_fp8(v.w, 0);
        a2[7] += __builtin_amdgcn_cvt_pk_f32_fp8(v.w, 1);
        v = vn;
      }
      a2[0] += __builtin_amdgcn_cvt_pk_f32_fp8(v.x, 0);
      a2[1] += __builtin_amdgcn_cvt_pk_f32_fp8(v.x, 1);
      a2[2] += __builtin_amdgcn_cvt_pk_f32_fp8(v.y, 0);
      a2[3] += __builtin_amdgcn_cvt_pk_f32_fp8(v.y, 1);
      a2[4] += __builtin_amdgcn_cvt_pk_f32_fp8(v.z, 0);
      a2[5] += __builtin_amdgcn_cvt_pk_f32_fp8(v.z, 1);
      a2[6] += __builtin_amdgcn_cvt_pk_f32_fp8(v.w, 0);
      a2[7] += __builtin_amdgcn_cvt_pk_f32_fp8(v.w, 1);
    }
    if (l < 13) {
      int d0, d1;
      d0 = __builtin_amdgcn_cvt_pk_fp8_f32(a2[0][0], a2[0][1], 0, false);
      d0 = __builtin_amdgcn_cvt_pk_fp8_f32(a2[1][0], a2[1][1], d0, true);
      d1 = __builtin_amdgcn_cvt_pk_fp8_f32(a2[2][0], a2[2][1], 0, false);
      d1 = __builtin_amdgcn_cvt_pk_fp8_f32(a2[3][0], a2[3][1], d1, true);
      *reinterpret_cast<uint2*>(srow + sub * 200 + l * 16) = make_uint2(d0, d1);
      if (l < 12) {
        int d2, d3;
        d2 = __builtin_amdgcn_cvt_pk_fp8_f32(a2[4][0], a2[4][1], 0, false);
        d2 = __builtin_amdgcn_cvt_pk_fp8_f32(a2[5][0], a2[5][1], d2, true);
        d3 = __builtin_amdgcn_cvt_pk_fp8_f32(a2[6][0], a2[6][1], 0, false);
        d3 = __builtin_amdgcn_cvt_pk_fp8_f32(a2[7][0], a2[7][1], d3, true);
        *reinterpret_cast<uint2*>(srow + sub * 200 + l * 16 + 8) = make_uint2(d2, d3);
      }
    }
    if (sub == 0 && l == 13) {
      float g0 = (float)deg_et[(size_t)0 * N + n];
      float g1 = (float)deg_et[(size_t)1 * N + n];
      float g2 = (float)deg_et[(size_t)2 * N + n];
      float g3 = (float)deg_et[(size_t)3 * N + n];
      int rr = __builtin_amdgcn_cvt_pk_fp8_f32(g0, g1, 0, false);
      rr = __builtin_amdgcn_cvt_pk_fp8_f32(g2, g3, rr, true);
      *reinterpret_cast<unsigned*>(srow + 800) = (unsigned)rr;
    }
    if (sub == 3 && l >= 1 && l <= 7)
      *reinterpret_cast<unsigned*>(srow + 804 + (l - 1) * 4) = 0;
  }
}

// ------- fp8 MFMA GEMM (phase A): writes dense fp8 aq[N][224] ----
__global__ __launch_bounds__(512, 4) void gemm_a8(
    const u8* __restrict__ A, int lda,
    const u8* __restrict__ B, int ldb,
    u8* __restrict__ Cq, int ldcb, int npad,
    int M, int Nn, int K, int gyr) {
  const int gx = gridDim.x;
  int lin = blockIdx.y * gx + blockIdx.x;
  int k8 = lin & 7, j = lin >> 3;
  int band = gridDim.y >> 3;
  int yy = j / gx, xx = j - yy * gx;
  int by = k8 * band + yy;
  if (by >= gyr) return;
  const int m0 = by * 256, n0 = xx * 128;

  __shared__ __align__(16) u8 As[3 * 8192];
  __shared__ __align__(16) u8 Bs[3 * 4096];
  const int tid = threadIdx.x;
  const int lane = tid & 63;
  const int w = tid >> 6;
  const int wr = w >> 1, wc = w & 1;
  const int fr = lane & 15;
  const int g = lane >> 4;

  const int rowA = tid >> 1;
  const int cA = (tid & 1) ^ ((rowA >> 2) & 1);
  int gaA = m0 + rowA; if (gaA >= M) gaA = M - 1;
  const u8* pa = A + (size_t)gaA * lda + cA * 16;
  u8* lA = &As[(size_t)(w * 64) * 16];
  const int sB = w * 32 + (lane & 31);
  const int rowB = sB >> 1;
  const int cB = (sB & 1) ^ ((rowB >> 2) & 1);
  int gbB = n0 + rowB; if (gbB >= Nn) gbB = Nn - 1;
  const u8* pb = B + (size_t)gbB * ldb + cB * 16;
  u8* lB = &Bs[(size_t)(w * 32) * 16];
  const bool doB = (lane < 32);

  const int rdoff = (((g >> 1) ^ ((fr >> 2) & 1)) << 4) + ((g & 1) << 3);

  f32x4 acc[4][4] = {};
  const int nt = K >> 5;
  const int ABUF = 8192, BBUF = 4096;

  gload16(pa, lA);
  if (doB) gload16(pb, lB);
  pa += 32; pb += 32;
  if (nt > 1) {
    gload16(pa, lA + ABUF);
    if (doB) gload16(pb, lB + BBUF);
    pa += 32; pb += 32;
  }

  for (int t = 0; t < nt; ++t) {
    if (t + 1 < nt) asm volatile("s_waitcnt vmcnt(2)" ::: "memory");
    else            asm volatile("s_waitcnt vmcnt(0)" ::: "memory");
    __builtin_amdgcn_s_barrier();
    if (t + 2 < nt) {
      int bi = (t + 2) % 3;
      gload16(pa, lA + bi * ABUF);
      if (doB) gload16(pb, lB + bi * BBUF);
      pa += 32; pb += 32;
    }
    int ca = (t % 3) * ABUF, cbb = (t % 3) * BBUF;
    long af[4], bfv[4];
#pragma unroll
    for (int i = 0; i < 4; ++i) {
      int row = wr * 64 + i * 16 + fr;
      af[i] = *reinterpret_cast<const long*>(&As[ca + row * 32 + rdoff]);
    }
#pragma unroll
    for (int jj = 0; jj < 4; ++jj) {
      int row = wc * 64 + jj * 16 + fr;
      bfv[jj] = *reinterpret_cast<const long*>(&Bs[cbb + row * 32 + rdoff]);
    }
    __builtin_amdgcn_s_setprio(1);
#pragma unroll
    for (int i = 0; i < 4; ++i)
#pragma unroll
      for (int jj = 0; jj < 4; ++jj)
        acc[i][jj] = __builtin_amdgcn_mfma_f32_16x16x32_fp8_fp8(af[i], bfv[jj], acc[i][jj], 0, 0, 0);
    __builtin_amdgcn_s_setprio(0);
  }

  const int er = (lane >> 4) * 4;
  const int ec = lane & 15;
#pragma unroll
  for (int i = 0; i < 4; ++i) {
#pragma unroll
    for (int jj = 0; jj < 4; ++jj) {
      int n = n0 + wc * 64 + jj * 16 + ec;
#pragma unroll
      for (int r = 0; r < 4; ++r) {
        int m = m0 + wr * 64 + i * 16 + er + r;
        if (m >= M) continue;
        if (n < Nn) Cq[(size_t)m * ldcb + n] = f2fp8(acc[i][jj][r]);
        else if (n < npad) Cq[(size_t)m * ldcb + n] = (u8)0;
      }
    }
  }
}

// ------- fp8 gates GEMM + fused GRU; A = [aq | hq] two-source, K=448 ------
__global__ __launch_bounds__(512, 4) void gemm_gru8(
    const u8* __restrict__ Aa, const u8* __restrict__ Ah,
    const u8* __restrict__ B, int ldb,
    int M, const float* __restrict__ bias,
    u16* __restrict__ hb, u8* __restrict__ hqout, int gyr) {
  const int gx = gridDim.x;
  int lin = blockIdx.y * gx + blockIdx.x;
  int k8 = lin & 7, j = lin >> 3;
  int band = gridDim.y >> 3;
  int yy = j / gx, xx = j - yy * gx;
  int by = k8 * band + yy;
  if (by >= gyr) return;
  const int m0 = by * 256, n0 = xx * 128;
  const int Nn = 800;

  __shared__ __align__(16) u8 SM8[73728];  // K-loop 36864 B; epilogue 8x9216 B
  u8* As = SM8;
  u8* Bs = SM8 + 24576;
  const int tid = threadIdx.x;
  const int lane = tid & 63;
  const int w = tid >> 6;
  const int wr = w >> 1, wc = w & 1;
  const int fr = lane & 15;
  const int g = lane >> 4;

  const int rowA = tid >> 1;
  const int cA = (tid & 1) ^ ((rowA >> 2) & 1);
  int gaA = m0 + rowA; if (gaA >= M) gaA = M - 1;
  const u8* paA = Aa + (size_t)gaA * 224 + cA * 16;
  const u8* paH = Ah + (size_t)gaA * 224 + cA * 16;
  u8* lA = &As[(size_t)(w * 64) * 16];
  const int sB = w * 32 + (lane & 31);
  const int rowB = sB >> 1;
  const int cB = (sB & 1) ^ ((rowB >> 2) & 1);
  int gbB = n0 + rowB; if (gbB >= Nn) gbB = Nn - 1;
  const u8* pb = B + (size_t)gbB * ldb + cB * 16;
  u8* lB = &Bs[(size_t)(w * 32) * 16];
  const bool doB = (lane < 32);

  const int rdoff = (((g >> 1) ^ ((fr >> 2) & 1)) << 4) + ((g & 1) << 3);

  f32x4 acc[4][4] = {};
  const int nt = 14, kh = 7;   // K=448: tiles 0-6 from aq, 7-13 from hq
  const int ABUF = 8192, BBUF = 4096;

  gload16(paA, lA);
  if (doB) gload16(pb, lB);
  pb += 32;
  gload16(paA + 32, lA + ABUF);
  if (doB) gload16(pb, lB + BBUF);
  pb += 32;

  for (int t = 0; t < nt; ++t) {
    if (t + 1 < nt) asm volatile("s_waitcnt vmcnt(2)" ::: "memory");
    else            asm volatile("s_waitcnt vmcnt(0)" ::: "memory");
    __builtin_amdgcn_s_barrier();
    int tt = t + 2;
    if (tt < nt) {
      int bi = tt % 3;
      const u8* srcA = (tt < kh) ? (paA + tt * 32) : (paH + (tt - kh) * 32);
      gload16(srcA, lA + bi * ABUF);
      if (doB) gload16(pb, lB + bi * BBUF);
      pb += 32;
    }
    int ca = (t % 3) * ABUF, cbb = (t % 3) * BBUF;
    long af[4], bfv[4];
#pragma unroll
    for (int i = 0; i < 4; ++i) {
      int row = wr * 64 + i * 16 + fr;
      af[i] = *reinterpret_cast<const long*>(&As[ca + row * 32 + rdoff]);
    }
#pragma unroll
    for (int jj = 0; jj < 4; ++jj) {
      int row = wc * 64 + jj * 16 + fr;
      bfv[jj] = *reinterpret_cast<const long*>(&Bs[cbb + row * 32 + rdoff]);
    }
    __builtin_amdgcn_s_setprio(1);
#pragma unroll
    for (int i = 0; i < 4; ++i)
#pragma unroll
      for (int jj = 0; jj < 4; ++jj)
        acc[i][jj] = __builtin_amdgcn_mfma_f32_16x16x32_fp8_fp8(af[i], bfv[jj], acc[i][jj], 0, 0, 0);
    __builtin_amdgcn_s_setprio(0);
  }

  // ---- fused GRU epilogue (LDS stride 36 f32: 2-way banks, aligned) ----
  const int er = (lane >> 4) * 4;
  const int ec = lane & 15;
  __syncthreads();
  float* ep = (float*)(SM8) + (size_t)w * 2304;   // per-wave [64][36] f32

  for (int hh = 0; hh < 2; ++hh) {
#pragma unroll
    for (int jj2 = 0; jj2 < 2; ++jj2) {
      int jj = hh * 2 + jj2;
      int n = n0 + wc * 64 + jj * 16 + ec;
      float bv = (n < 800) ? bias[n] : 0.f;
#pragma unroll
      for (int i = 0; i < 4; ++i)
#pragma unroll
        for (int r = 0; r < 4; ++r) {
          int row_loc = i * 16 + er + r;
          ep[row_loc * 36 + jj2 * 16 + ec] = acc[i][jj][r] + bv;
        }
    }
    __syncthreads();
#pragma unroll
    for (int p = 0; p < 8; ++p) {
      int idx = p * 64 + lane;
      int row = idx >> 3, og = idx & 7;
      int n_base = n0 + wc * 64 + hh * 32 + og * 4;
      int m = m0 + wr * 64 + row;
      if (n_base < 800 && m < M) {
        f32x4 gv = *reinterpret_cast<f32x4*>(&ep[row * 36 + og * 4]);
        float rg = sigm(gv[0]);
        float zg = sigm(gv[1]);
        float x = gv[2] + rg * gv[3];
        float e2 = __expf(2.f * x);
        float nn = (e2 - 1.f) / (e2 + 1.f);
        int o = n_base >> 2;
        float hold = bf2f(hb[(size_t)m * 224 + o]);
        float hv = (1.f - zg) * nn + zg * hold;
        hb[(size_t)m * 224 + o] = f2bf(hv);
        hqout[(size_t)m * 224 + o] = f2fp8(hv);
      }
    }
    __syncthreads();
  }
}

// ------- generic bf16 MFMA GEMM, 256x128 tile (conv paths) ------
__global__ __launch_bounds__(512, 4) void gemm_mfma(
    const u16* __restrict__ A, int lda,
    const u16* __restrict__ B, int ldb,
    u16* __restrict__ Cb, int ldcb, int npad,
    int M, int Nn, int K, const float* __restrict__ bias, int gyr) {
  const int gx = gridDim.x;
  int lin = blockIdx.y * gx + blockIdx.x;
  int k8 = lin & 7, j = lin >> 3;
  int band = gridDim.y >> 3;
  int yy = j / gx, xx = j - yy * gx;
  int by = k8 * band + yy;
  if (by >= gyr) return;
  const int m0 = by * 256, n0 = xx * 128;

  __shared__ __align__(16) u16 As[3 * 8192];
  __shared__ __align__(16) u16 Bs[3 * 4096];
  const int tid = threadIdx.x;
  const int lane = tid & 63;
  const int w = tid >> 6;
  const int wr = w >> 1, wc = w & 1;
  const int fr = lane & 15;
  const int g = lane >> 4;

  const int sA0 = w * 64 + lane, sA1 = sA0 + 512, sB = sA0;
  int rA0 = sA0 >> 2, cA0 = (sA0 & 3) ^ ((rA0 >> 1) & 3);
  int rA1 = sA1 >> 2, cA1 = (sA1 & 3) ^ ((rA1 >> 1) & 3);
  int rB  = sB  >> 2, cB  = (sB & 3) ^ ((rB >> 1) & 3);
  int ga0 = m0 + rA0; if (ga0 >= M) ga0 = M - 1;
  int ga1 = m0 + rA1; if (ga1 >= M) ga1 = M - 1;
  int gb  = n0 + rB;  if (gb >= Nn) gb = Nn - 1;
  const u16* pa0 = A + (size_t)ga0 * lda + cA0 * 8;
  const u16* pa1 = A + (size_t)ga1 * lda + cA1 * 8;
  const u16* pb  = B + (size_t)gb  * ldb + cB * 8;
  u16* lA0 = &As[(w * 64) * 8];
  u16* lA1 = &As[(512 + w * 64) * 8];
  u16* lB  = &Bs[(w * 64) * 8];

  const int gxr = g ^ ((fr >> 1) & 3);

  f32x4 acc[4][4] = {};
  const int nt = K >> 5;
  const int ABUF = 8192, BBUF = 4096;

  gload16(pa0, lA0); gload16(pa1, lA1); gload16(pb, lB);
  pa0 += 32; pa1 += 32; pb += 32;
  if (nt > 1) {
    gload16(pa0, lA0 + ABUF); gload16(pa1, lA1 + ABUF); gload16(pb, lB + BBUF);
    pa0 += 32; pa1 += 32; pb += 32;
  }

  for (int t = 0; t < nt; ++t) {
    if (t + 1 < nt) asm volatile("s_waitcnt vmcnt(3)" ::: "memory");
    else            asm volatile("s_waitcnt vmcnt(0)" ::: "memory");
    __builtin_amdgcn_s_barrier();
    if (t + 2 < nt) {
      int bi = (t + 2) % 3;
      gload16(pa0, lA0 + bi * ABUF); gload16(pa1, lA1 + bi * ABUF); gload16(pb, lB + bi * BBUF);
      pa0 += 32; pa1 += 32; pb += 32;
    }
    int ca = (t % 3) * ABUF, cbb = (t % 3) * BBUF;
    bf16x8 af[4], bfv[4];
#pragma unroll
    for (int i = 0; i < 4; ++i) {
      int row = wr * 64 + i * 16 + fr;
      af[i] = *reinterpret_cast<const bf16x8*>(&As[ca + (row * 4 + gxr) * 8]);
    }
#pragma unroll
    for (int jj = 0; jj < 4; ++jj) {
      int row = wc * 64 + jj * 16 + fr;
      bfv[jj] = *reinterpret_cast<const bf16x8*>(&Bs[cbb + (row * 4 + gxr) * 8]);
    }
    __builtin_amdgcn_s_setprio(1);
#pragma unroll
    for (int i = 0; i < 4; ++i)
#pragma unroll
      for (int jj = 0; jj < 4; ++jj)
        acc[i][jj] = __builtin_amdgcn_mfma_f32_16x16x32_bf16(af[i], bfv[jj], acc[i][jj], 0, 0, 0);
    __builtin_amdgcn_s_setprio(0);
  }

  const int er = (lane >> 4) * 4;
  const int ec = lane & 15;
#pragma unroll
  for (int i = 0; i < 4; ++i) {
#pragma unroll
    for (int jj = 0; jj < 4; ++jj) {
      int n = n0 + wc * 64 + jj * 16 + ec;
#pragma unroll
      for (int r = 0; r < 4; ++r) {
        int m = m0 + wr * 64 + i * 16 + er + r;
        if (m >= M) continue;
        if (n < Nn) {
          float v = acc[i][jj][r];
          if (bias) v += bias[n];
          Cb[(size_t)m * ldcb + n] = f2bf(v);
        } else if (n < npad) {
          Cb[(size_t)m * ldcb + n] = (u16)0;
        }
      }
    }
  }
}

// cmat[n][352] = [hb(224 incl zero pads) | feat(100) | 0(28)]
__global__ void cmat_k(const u16* __restrict__ hb, const float* __restrict__ feat,
                       u16* __restrict__ c, int N) {
  int total = N * 352;
  for (int i = blockIdx.x * blockDim.x + threadIdx.x; i < total; i += blockDim.x * gridDim.x) {
    int n = i / 352, j = i - n * 352;
    u16 v;
    if (j < 224) v = hb[(size_t)n * 224 + j];
    else { int f = j - 224; v = (f < 100) ? f2bf(feat[(size_t)n * 100 + f]) : (u16)0; }
    c[i] = v;
  }
}

__global__ __launch_bounds__(1024) void bn_stats2_k(const u16* __restrict__ X, int L, int C,
                                                    float* __restrict__ stats) {
  const int Q = 1024 / C;
  const int T = Q * C;
  const int tid = threadIdx.x;
  float s = 0.f, q = 0.f;
  int c = 0;
  if (tid < T) {
    int qi = tid / C; c = tid - qi * C;
    for (size_t r = (size_t)blockIdx.x * Q + qi; r < (size_t)L; r += (size_t)gridDim.x * Q) {
      float v = bf2f(X[r * C + c]);
      s += v; q += v * v;
    }
  }
  __shared__ float sb[304], qb[304];
  for (int cc = tid; cc < C; cc += 1024) { sb[cc] = 0.f; qb[cc] = 0.f; }
  __syncthreads();
  if (tid < T) { atomicAdd(&sb[c], s); atomicAdd(&qb[c], q); }
  __syncthreads();
  for (int cc = tid; cc < C; cc += 1024) {
    atomicAdd(&stats[cc], sb[cc]);
    atomicAdd(&stats[C + cc], qb[cc]);
  }
}

__global__ void bn_fin_k(const float* __restrict__ stats, const float* __restrict__ g,
                         const float* __restrict__ b, int C, float Linv,
                         float* __restrict__ scsh) {
  int c = blockIdx.x * blockDim.x + threadIdx.x;
  if (c < C) {
    float mean = stats[c] * Linv;
    float var = stats[C + c] * Linv - mean * mean;
    float sc = g[c] * rsqrtf(var + 1e-5f);
    scsh[c] = sc;
    scsh[C + c] = b[c] - mean * sc;
  }
}

__global__ void pool_bf_k(const u16* __restrict__ X, int C, const float* __restrict__ scsh,
                          int kw, int stride, u16* __restrict__ Y, int Cpad, int Lout) {
  int total = Lout * Cpad;
  for (int i = blockIdx.x * blockDim.x + threadIdx.x; i < total; i += blockDim.x * gridDim.x) {
    int lp = i / Cpad, c = i - lp * Cpad;
    if (c >= C) { Y[i] = (u16)0; continue; }
    float sc = scsh[c], sh = scsh[C + c];
    int l0 = lp * stride;
    float m = 0.f;
    for (int wq = 0; wq < kw; ++wq)
      m = fmaxf(m, fmaf(bf2f(X[(size_t)(l0 + wq) * C + c]), sc, sh));
    Y[i] = f2bf(m);
  }
}

__global__ void pool_f32_k(const u16* __restrict__ X, int C, const float* __restrict__ scsh,
                           int kw, int stride, float* __restrict__ Y, int Lout) {
  int total = Lout * C;
  for (int i = blockIdx.x * blockDim.x + threadIdx.x; i < total; i += blockDim.x * gridDim.x) {
    int lp = i / C, c = i - lp * C;
    float sc = scsh[c], sh = scsh[C + c];
    int l0 = lp * stride;
    float m = 0.f;
    for (int wq = 0; wq < kw; ++wq)
      m = fmaxf(m, fmaf(bf2f(X[(size_t)(l0 + wq) * C + c]), sc, sh));
    Y[i] = m;
  }
}

__global__ __launch_bounds__(256) void final_dot_k(
    const float* __restrict__ Y2, const float* __restrict__ Z2,
    const float* __restrict__ wy, const float* __restrict__ by,
    const float* __restrict__ wz, const float* __restrict__ bz,
    float* __restrict__ acc, int L) {
  float s0 = 0.f, s1 = 0.f;
  for (int lp = blockIdx.x * blockDim.x + threadIdx.x; lp < L; lp += blockDim.x * gridDim.x) {
    const float* y = Y2 + (size_t)lp * 200;
    const float* z = Z2 + (size_t)lp * 300;
    float d0 = 0.f, d1 = 0.f;
    for (int k = 0; k < 200; ++k) { float v = y[k]; d0 += v * wy[k]; d1 += v * wy[200 + k]; }
    float e0 = 0.f, e1 = 0.f;
    for (int k = 0; k < 300; ++k) { float v = z[k]; e0 += v * wz[k]; e1 += v * wz[300 + k]; }
    s0 += (d0 + by[0]) * (e0 + bz[0]);
    s1 += (d1 + by[1]) * (e1 + bz[1]);
  }
  __shared__ float r0[256], r1[256];
  r0[threadIdx.x] = s0; r1[threadIdx.x] = s1;
  __syncthreads();
  for (int off = 128; off > 0; off >>= 1) {
    if (threadIdx.x < off) { r0[threadIdx.x] += r0[threadIdx.x + off]; r1[threadIdx.x] += r1[threadIdx.x + off]; }
    __syncthreads();
  }
  if (threadIdx.x == 0) { atomicAdd(&acc[0], r0[0]); atomicAdd(&acc[1], r1[0]); }
}

__global__ void final_out_k(const float* __restrict__ acc, float invL, float* __restrict__ out) {
  int j = threadIdx.x;
  if (j < 2) out[j] = 1.f / (1.f + expf(-acc[j] * invL));
}

// ---------------- host ----------------

static inline void gemmL(hipStream_t st, const u16* A, int lda, const u16* B, int ldb,
                         u16* Cb, int ldcb, int npad, int M, int Nn, int K, const float* bias) {
  int ncols = (npad > Nn) ? npad : Nn;
  int gx = (ncols + 127) / 128;
  int gy = (M + 255) / 256;
  int gyp = ((gy + 7) / 8) * 8;
  dim3 g(gx, gyp);
  gemm_mfma<<<g, 512, 0, st>>>(A, lda, B, ldb, Cb, ldcb, npad, M, Nn, K, bias, gy);
}

extern "C" void kernel_launch(void* const* d_in, const int* in_sizes, int n_in,
                              void* d_out, int out_size, void* d_ws, size_t ws_size,
                              hipStream_t stream) {
  (void)n_in; (void)out_size;
  const float* feat    = (const float*)d_in[0];
  const int*   eix     = (const int*)d_in[1];
  const int*   etyp    = (const int*)d_in[2];
  const float* ggnnW   = (const float*)d_in[3];
  const float* ggnnB   = (const float*)d_in[4];
  const float* Wih     = (const float*)d_in[5];
  const float* Whh     = (const float*)d_in[6];
  const float* bih     = (const float*)d_in[7];
  const float* bhh     = (const float*)d_in[8];
  const float* conv1w  = (const float*)d_in[9];
  const float* conv2w  = (const float*)d_in[11];
  const float* convc1w = (const float*)d_in[13];
  const float* convc2w = (const float*)d_in[15];
  const float* bnyg    = (const float*)d_in[17];
  const float* bnyb    = (const float*)d_in[18];
  const float* bncg    = (const float*)d_in[19];
  const float* bncb    = (const float*)d_in[20];
  const float* mlpyw   = (const float*)d_in[21];
  const float* mlpyb   = (const float*)d_in[22];
  const float* mlpzw   = (const float*)d_in[23];
  const float* mlpzb   = (const float*)d_in[24];

  const int N = in_sizes[0] / 100;
  const int E = in_sizes[2];
  const int* src = eix;
  const int* dst = eix + E;

  char* base = (char*)d_ws;
  const size_t HB_B  = (size_t)N * 224 * 2;    // bf16 h
  const size_t Q_B   = (size_t)N * 224;        // one fp8 table
  const int CH = (N + 1) / 2;
  const size_t SCR_B = (size_t)CH * 1664;

  u16* hb  = (u16*)base;
  u8*  aq  = (u8*)(base + HB_B);
  u8*  hq0 = aq + Q_B;
  u8*  hq1 = hq0 + Q_B;
  char* R1 = (char*)(hq1 + Q_B);
  char* WREG = R1 + SCR_B;

  u8*  Wcat8 = (u8*)WREG;
  u8*  Wall8 = Wcat8 + 166400;
  u16* w1c   = (u16*)(Wall8 + 358400);
  u16* c2b   = w1c + 211200;
  u16* wc1   = c2b + 44800;
  u16* wc2   = wc1 + 316800;
  float* ball  = (float*)(wc2 + 96000);
  float* stats = ball + 832;
  float* scsh  = stats + 600;
  float* acc2  = scsh + 600;
  int* deg_et = (int*)(acc2 + 8);
  int* off_et = deg_et + 4 * (size_t)N;
  int* cursor = off_et + 4 * (size_t)N;
  int* esrc   = cursor + 4 * (size_t)N;
  int* bsum   = esrc + E;
  const int L4 = 4 * N;
  const int NB = (L4 + 1023) / 1024;
  size_t need = (size_t)((char*)(bsum + NB) - base);

  if (ws_size < need) {
    fail_k<<<1, 64, 0, stream>>>((float*)d_out, -(float)(ws_size >> 20));
    return;
  }

  // ---- CSR build + packs ----
  hipMemsetAsync(deg_et, 0, sizeof(int) * 4 * (size_t)N, stream);
  init_hb_k<<<2048, 256, 0, stream>>>(feat, hb, N);
  init_hq_k<<<2048, 256, 0, stream>>>(feat, hq0, N);
  count_deg_k<<<2048, 256, 0, stream>>>(dst, etyp, deg_et, N, E);
  bsum_k<<<NB, 1024, 0, stream>>>(deg_et, bsum, L4);
  scanb_k<<<1, 1024, 0, stream>>>(bsum, NB);
  scan_fin_k<<<NB, 1024, 0, stream>>>(deg_et, bsum, off_et, L4);
  copy_int_k<<<512, 256, 0, stream>>>(off_et, cursor, L4);
  fill_src_k<<<2048, 256, 0, stream>>>(src, dst, etyp, cursor, esrc, N, E);
  pack_wcat8_k<<<651, 256, 0, stream>>>(ggnnW, ggnnB, Wcat8);
  pack_wall8_k<<<1400, 256, 0, stream>>>(Wih, Whh, Wall8);
  ball_i_k<<<4, 256, 0, stream>>>(bih, bhh, ball);
  pack_w1c_k<<<825, 256, 0, stream>>>(conv1w, w1c);
  pack_lin_b<<<175, 256, 0, stream>>>(conv2w, c2b, 200, 200, 224);
  pack_wc1_b<<<1238, 256, 0, stream>>>(convc1w, wc1);
  pack_lin_b<<<375, 256, 0, stream>>>(convc2w, wc2, 300, 300, 320);

  // ---- GGNN 8 steps (ping-pong h tables) ----
  u8* scat8 = (u8*)R1;

  const int gy = (N + 255) / 256;
  const int gyp = ((gy + 7) / 8) * 8;

  u8* hqA = hq0;
  u8* hqB = hq1;
  for (int step = 0; step < 8; ++step) {
    agg8_k<<<4096, 256, 0, stream>>>(off_et, deg_et, esrc, hqA, scat8, N);
    gemm_a8<<<dim3(2, gyp), 512, 0, stream>>>(scat8, 832, Wcat8, 832,
                                              aq, 224, 224, N, 200, 832, gy);
    gemm_gru8<<<dim3(7, gyp), 512, 0, stream>>>(aq, hqA, Wall8, 448, N, ball,
                                                hb, hqB, gy);
    u8* t = hqA; hqA = hqB; hqB = t;
  }

  // ---- conv paths ----
  const int L1 = N - 2;
  const int L2 = (L1 - 3) / 2 + 1;
  const int L3 = (L2 - 2) / 2 + 1;

  u16* cmat = (u16*)R1;
  u16* out1 = (u16*)base;
  size_t y1_off = (((size_t)L1 * 400) + 255) & ~(size_t)255;
  u16* y1 = (u16*)(base + y1_off);
  size_t o2_off = y1_off + ((((size_t)L2 * 448) + 255) & ~(size_t)255);
  u16* out2 = (u16*)(base + o2_off);
  float* Y2f = (float*)base;
  size_t oc1_off = (((size_t)L3 * 800) + 255) & ~(size_t)255;
  u16* outc1 = (u16*)(base + oc1_off);
  u16* z1 = (u16*)R1;
  size_t oc2_off = (((size_t)L2 * 640) + 255) & ~(size_t)255;
  u16* outc2 = (u16*)(R1 + oc2_off);
  float* Z2f = (float*)(base + oc1_off);

  cmat_k<<<4096, 256, 0, stream>>>(hb, feat, cmat, N);

  // Y path
  gemmL(stream, cmat, 352, w1c, 1056, out1, 200, 200, L1, 200, 1056, nullptr);
  hipMemsetAsync(stats, 0, sizeof(float) * 400, stream);
  bn_stats2_k<<<512, 1024, 0, stream>>>(out1, L1, 200, stats);
  bn_fin_k<<<2, 256, 0, stream>>>(stats, bnyg, bnyb, 200, 1.f / (float)L1, scsh);
  pool_bf_k<<<2048, 256, 0, stream>>>(out1, 200, scsh, 3, 2, y1, 224, L2);

  gemmL(stream, y1, 224, c2b, 224, out2, 200, 200, L2, 200, 224, nullptr);
  hipMemsetAsync(stats, 0, sizeof(float) * 400, stream);
  bn_stats2_k<<<512, 1024, 0, stream>>>(out2, L2, 200, stats);
  bn_fin_k<<<2, 256, 0, stream>>>(stats, bnyg, bnyb, 200, 1.f / (float)L2, scsh);
  pool_f32_k<<<2048, 256, 0, stream>>>(out2, 200, scsh, 2, 2, Y2f, L3);

  // Z path
  gemmL(stream, cmat, 352, wc1, 1056, outc1, 300, 300, L1, 300, 1056, nullptr);
  hipMemsetAsync(stats, 0, sizeof(float) * 600, stream);
  bn_stats2_k<<<512, 1024, 0, stream>>>(outc1, L1, 300, stats);
  bn_fin_k<<<2, 256, 0, stream>>>(stats, bncg, bncb, 300, 1.f / (float)L1, scsh);
  pool_bf_k<<<2048, 256, 0, stream>>>(outc1, 300, scsh, 3, 2, z1, 320, L2);

  gemmL(stream, z1, 320, wc2, 320, outc2, 300, 300, L2, 300, 320, nullptr);
  hipMemsetAsync(stats, 0, sizeof(float) * 600, stream);
  bn_stats2_k<<<512, 1024, 0, stream>>>(outc2, L2, 300, stats);
  bn_fin_k<<<2, 256, 0, stream>>>(stats, bncg, bncb, 300, 1.f / (float)L2, scsh);
  pool_f32_k<<<2048, 256, 0, stream>>>(outc2, 300, scsh, 2, 2, Z2f, L3);

  // ---- final MLP product + mean + sigmoid ----
  hipMemsetAsync(acc2, 0, sizeof(float) * 2, stream);
  final_dot_k<<<256, 256, 0, stream>>>(Y2f, Z2f, mlpyw, mlpyb, mlpzw, mlpzb, acc2, L3);
  final_out_k<<<1, 64, 0, stream>>>(acc2, 1.f / (float)L3, (float*)d_out);
}

// Round 19
// 2803.300 us; speedup vs baseline: 1.9246x; 1.0198x over previous
//
#include <hip/hip_runtime.h>
#include <cstddef>
#include <cstdint>

// ============================================================================
// DevignModel round 19: fp8 conv path (reuses gemm_a8 for ALL fp8 GEMMs).
//  - cmat8[N][352] fp8 built from hq table; conv weights/activations fp8
//  - bn_stats8/pool read fp8; stats/f32 math unchanged
//  - GGNN loop identical to r18
// ============================================================================

typedef unsigned short u16;
typedef unsigned char u8;
typedef __attribute__((ext_vector_type(8))) short bf16x8;
typedef __attribute__((ext_vector_type(4))) float f32x4;
typedef __attribute__((ext_vector_type(2))) float f32x2;

static __device__ __forceinline__ float bf2f(u16 u) {
  union { unsigned int i; float f; } v; v.i = ((unsigned int)u) << 16; return v.f;
}
static __device__ __forceinline__ u16 f2bf(float f) {
  union { float f; unsigned int i; } v; v.f = f;
  unsigned int r = v.i + 0x7FFFu + ((v.i >> 16) & 1u);
  return (u16)(r >> 16);
}
static __device__ __forceinline__ float sigm(float x) { return 1.f / (1.f + __expf(-x)); }
static __device__ __forceinline__ u8 f2fp8(float x) {
  return (u8)(__builtin_amdgcn_cvt_pk_fp8_f32(x, 0.f, 0, false) & 0xff);
}
static __device__ __forceinline__ float fp82f(u8 b) {
  f32x2 p = __builtin_amdgcn_cvt_pk_f32_fp8((unsigned)b, false);
  return p[0];
}

static __device__ __forceinline__ void gload16(const void* gp, void* lp) {
  __builtin_amdgcn_global_load_lds(
      (const __attribute__((address_space(1))) void*)gp,
      (__attribute__((address_space(3))) void*)lp, 16, 0, 0);
}

__global__ void fail_k(float* out, float code) { out[0] = code; out[1] = code; }

// hb[n][224] bf16 = [feat | 0]  (GRU hold state only)
__global__ void init_hb_k(const float* __restrict__ feat, u16* __restrict__ hb, int N) {
  int total = N * 224;
  for (int i = blockIdx.x * blockDim.x + threadIdx.x; i < total; i += blockDim.x * gridDim.x) {
    int n = i / 224, c = i - n * 224;
    hb[i] = (c < 100) ? f2bf(feat[(size_t)n * 100 + c]) : (u16)0;
  }
}

// dense hq0[n][224] fp8 = [feat | 0]
__global__ void init_hq_k(const float* __restrict__ feat, u8* __restrict__ hq0, int N) {
  int total = N * 224;
  for (int i = blockIdx.x * blockDim.x + threadIdx.x; i < total; i += blockDim.x * gridDim.x) {
    int n = i / 224, c = i - n * 224;
    hq0[i] = (c < 100) ? f2fp8(feat[(size_t)n * 100 + c]) : (u8)0;
  }
}

__global__ void count_deg_k(const int* __restrict__ dst, const int* __restrict__ et,
                            int* __restrict__ deg_et, int N, int E) {
  for (int e = blockIdx.x * blockDim.x + threadIdx.x; e < E; e += blockDim.x * gridDim.x)
    atomicAdd(&deg_et[et[e] * N + dst[e]], 1);
}

// ---- parallel exclusive scan (3 kernels) ----
__global__ __launch_bounds__(1024) void bsum_k(const int* __restrict__ cnt,
                                               int* __restrict__ bsum, int L) {
  __shared__ int buf[1024];
  int i = blockIdx.x * 1024 + threadIdx.x;
  buf[threadIdx.x] = (i < L) ? cnt[i] : 0;
  __syncthreads();
  for (int o = 512; o > 0; o >>= 1) {
    if (threadIdx.x < o) buf[threadIdx.x] += buf[threadIdx.x + o];
    __syncthreads();
  }
  if (threadIdx.x == 0) bsum[blockIdx.x] = buf[0];
}

__global__ __launch_bounds__(1024) void scanb_k(int* __restrict__ bsum, int nb) {
  __shared__ int buf[1024];
  int v = (threadIdx.x < nb) ? bsum[threadIdx.x] : 0;
  buf[threadIdx.x] = v;
  __syncthreads();
  for (int o = 1; o < 1024; o <<= 1) {
    int t = (threadIdx.x >= o) ? buf[threadIdx.x - o] : 0;
    __syncthreads();
    buf[threadIdx.x] += t;
    __syncthreads();
  }
  if (threadIdx.x < nb) bsum[threadIdx.x] = buf[threadIdx.x] - v;
}

__global__ __launch_bounds__(1024) void scan_fin_k(const int* __restrict__ cnt,
                                                   const int* __restrict__ bsum,
                                                   int* __restrict__ off, int L) {
  __shared__ int buf[1024];
  int i = blockIdx.x * 1024 + threadIdx.x;
  int v = (i < L) ? cnt[i] : 0;
  buf[threadIdx.x] = v;
  __syncthreads();
  for (int o = 1; o < 1024; o <<= 1) {
    int t = (threadIdx.x >= o) ? buf[threadIdx.x - o] : 0;
    __syncthreads();
    buf[threadIdx.x] += t;
    __syncthreads();
  }
  if (i < L) off[i] = buf[threadIdx.x] - v + bsum[blockIdx.x];
}

__global__ void copy_int_k(const int* __restrict__ a, int* __restrict__ b, int n) {
  for (int i = blockIdx.x * blockDim.x + threadIdx.x; i < n; i += blockDim.x * gridDim.x) b[i] = a[i];
}

__global__ void fill_src_k(const int* __restrict__ src, const int* __restrict__ dst,
                           const int* __restrict__ et, int* __restrict__ cursor,
                           int* __restrict__ esrc, int N, int E) {
  for (int e = blockIdx.x * blockDim.x + threadIdx.x; e < E; e += blockDim.x * gridDim.x) {
    int p = atomicAdd(&cursor[et[e] * N + dst[e]], 1);
    esrc[p] = src[e];
  }
}

// ---- weight packs (all fp8) ----

__global__ void pack_wcat8_k(const float* __restrict__ W, const float* __restrict__ gb,
                             u8* __restrict__ dst) {
  int total = 200 * 832;
  for (int i = blockIdx.x * blockDim.x + threadIdx.x; i < total; i += blockDim.x * gridDim.x) {
    int o = i / 832, kp = i - o * 832;
    float v = 0.f;
    if (kp < 800) { int k = kp / 200, kk = kp - k * 200; v = W[((size_t)k * 200 + o) * 200 + kk]; }
    else if (kp < 804) v = gb[(kp - 800) * 200 + o];
    dst[i] = f2fp8(v);
  }
}

// Wall8[800][448] fp8, gate-interleaved (row 4o+g)
__global__ void pack_wall8_k(const float* __restrict__ Wih, const float* __restrict__ Whh,
                             u8* __restrict__ dst) {
  int total = 800 * 448;
  for (int i = blockIdx.x * blockDim.x + threadIdx.x; i < total; i += blockDim.x * gridDim.x) {
    int jp = i / 448, kp = i - jp * 448;
    int o = jp >> 2, g = jp & 3;
    float v = 0.f;
    if (g == 0) {
      if (kp < 200) v = Wih[(size_t)o * 200 + kp];
      else if (kp >= 224 && kp < 424) v = Whh[(size_t)o * 200 + (kp - 224)];
    } else if (g == 1) {
      if (kp < 200) v = Wih[(size_t)(200 + o) * 200 + kp];
      else if (kp >= 224 && kp < 424) v = Whh[(size_t)(200 + o) * 200 + (kp - 224)];
    } else if (g == 2) {
      if (kp < 200) v = Wih[(size_t)(400 + o) * 200 + kp];
    } else {
      if (kp >= 224 && kp < 424) v = Whh[(size_t)(400 + o) * 200 + (kp - 224)];
    }
    dst[i] = f2fp8(v);
  }
}

__global__ void ball_i_k(const float* __restrict__ bih, const float* __restrict__ bhh,
                         float* __restrict__ ball) {
  int j = blockIdx.x * blockDim.x + threadIdx.x;
  if (j < 800) {
    int o = j >> 2, g = j & 3;
    float v;
    if (g == 0) v = bih[o] + bhh[o];
    else if (g == 1) v = bih[200 + o] + bhh[200 + o];
    else if (g == 2) v = bih[400 + o];
    else v = bhh[400 + o];
    ball[j] = v;
  }
}

// generic fp8 linear pack: src [Nn][K] -> dst [Nn][Kp]
__global__ void pack_lin8_k(const float* __restrict__ src, u8* __restrict__ dst,
                            int Nn, int K, int Kp) {
  int total = Nn * Kp;
  for (int i = blockIdx.x * blockDim.x + threadIdx.x; i < total; i += blockDim.x * gridDim.x) {
    int o = i / Kp, kp = i - o * Kp;
    dst[i] = (kp < K) ? f2fp8(src[(size_t)o * K + kp]) : (u8)0;
  }
}

// conv1 over cmat8 layout: [200][1056], [o][t*352+kp] = w[o][kp][t] (kp<200)
__global__ void pack_w1c8_k(const float* __restrict__ src, u8* __restrict__ dst) {
  int total = 200 * 1056;
  for (int i = blockIdx.x * blockDim.x + threadIdx.x; i < total; i += blockDim.x * gridDim.x) {
    int o = i / 1056, r = i - o * 1056;
    int t = r / 352, kp = r - t * 352;
    dst[i] = (kp < 200) ? f2fp8(src[((size_t)o * 200 + kp) * 3 + t]) : (u8)0;
  }
}

// convc1 [300][300][3] -> [300][1056] matching cmat8 layout [h(224)|feat(128)]
__global__ void pack_wc18_k(const float* __restrict__ src, u8* __restrict__ dst) {
  int total = 300 * 1056;
  for (int i = blockIdx.x * blockDim.x + threadIdx.x; i < total; i += blockDim.x * gridDim.x) {
    int o = i / 1056, r = i - o * 1056;
    int t = r / 352, kp = r - t * 352;
    int ci = (kp < 224) ? (kp < 200 ? kp : -1) : ((kp - 224) < 100 ? 200 + (kp - 224) : -1);
    dst[i] = (ci >= 0) ? f2fp8(src[((size_t)o * 300 + ci) * 3 + t]) : (u8)0;
  }
}

// aggregation: wave per NODE; 16-lane group per etype; 2-deep pipelined edges
__global__ void agg8_k(const int* __restrict__ off_et, const int* __restrict__ deg_et,
                       const int* __restrict__ esrc, const u8* __restrict__ hqd,
                       u8* __restrict__ scat8, int N) {
  int gtid = blockIdx.x * blockDim.x + threadIdx.x;
  int wid = gtid >> 6, lane = threadIdx.x & 63;
  int nw = (blockDim.x * gridDim.x) >> 6;
  int sub = lane >> 4, l = lane & 15;
  for (int n = wid; n < N; n += nw) {
    u8* srow = scat8 + (size_t)n * 832;
    int rs = off_et[(size_t)sub * N + n];
    int d  = deg_et[(size_t)sub * N + n];
    f32x2 a2[8];
#pragma unroll
    for (int j = 0; j < 8; ++j) a2[j] = (f32x2)0.f;
    if (l < 13 && d > 0) {
      const size_t lo = (size_t)l * 16;
      uint4 v = *reinterpret_cast<const uint4*>(hqd + (size_t)esrc[rs] * 224 + lo);
      for (int i = 1; i < d; ++i) {
        uint4 vn = *reinterpret_cast<const uint4*>(hqd + (size_t)esrc[rs + i] * 224 + lo);
        a2[0] += __builtin_amdgcn_cvt_pk_f32_fp8(v.x, 0);
        a2[1] += __builtin_amdgcn_cvt_pk_f32_fp8(v.x, 1);
        a2[2] += __builtin_amdgcn_cvt_pk_f32_fp8(v.y, 0);
        a2[3] += __builtin_amdgcn_cvt_pk_f32_fp8(v.y, 1);
        a2[4] += __builtin_amdgcn_cvt_pk_f32_fp8(v.z, 0);
        a2[5] += __builtin_amdgcn_cvt_pk_f32_fp8(v.z, 1);
        a2[6] += __builtin_amdgcn_cvt_pk_f32_fp8(v.w, 0);
        a2[7] += __builtin_amdgcn_cvt_pk_f32_fp8(v.w, 1);
        v = vn;
      }
      a2[0] += __builtin_amdgcn_cvt_pk_f32_fp8(v.x, 0);
      a2[1] += __builtin_amdgcn_cvt_pk_f32_fp8(v.x, 1);
      a2[2] += __builtin_amdgcn_cvt_pk_f32_fp8(v.y, 0);
      a2[3] += __builtin_amdgcn_cvt_pk_f32_fp8(v.y, 1);
      a2[4] += __builtin_amdgcn_cvt_pk_f32_fp8(v.z, 0);
      a2[5] += __builtin_amdgcn_cvt_pk_f32_fp8(v.z, 1);
      a2[6] += __builtin_amdgcn_cvt_pk_f32_fp8(v.w, 0);
      a2[7] += __builtin_amdgcn_cvt_pk_f32_fp8(v.w, 1);
    }
    if (l < 13) {
      int d0, d1;
      d0 = __builtin_amdgcn_cvt_pk_fp8_f32(a2[0][0], a2[0][1], 0, false);
      d0 = __builtin_amdgcn_cvt_pk_fp8_f32(a2[1][0], a2[1][1], d0, true);
      d1 = __builtin_amdgcn_cvt_pk_fp8_f32(a2[2][0], a2[2][1], 0, false);
      d1 = __builtin_amdgcn_cvt_pk_fp8_f32(a2[3][0], a2[3][1], d1, true);
      *reinterpret_cast<uint2*>(srow + sub * 200 + l * 16) = make_uint2(d0, d1);
      if (l < 12) {
        int d2, d3;
        d2 = __builtin_amdgcn_cvt_pk_fp8_f32(a2[4][0], a2[4][1], 0, false);
        d2 = __builtin_amdgcn_cvt_pk_fp8_f32(a2[5][0], a2[5][1], d2, true);
        d3 = __builtin_amdgcn_cvt_pk_fp8_f32(a2[6][0], a2[6][1], 0, false);
        d3 = __builtin_amdgcn_cvt_pk_fp8_f32(a2[7][0], a2[7][1], d3, true);
        *reinterpret_cast<uint2*>(srow + sub * 200 + l * 16 + 8) = make_uint2(d2, d3);
      }
    }
    if (sub == 0 && l == 13) {
      float g0 = (float)deg_et[(size_t)0 * N + n];
      float g1 = (float)deg_et[(size_t)1 * N + n];
      float g2 = (float)deg_et[(size_t)2 * N + n];
      float g3 = (float)deg_et[(size_t)3 * N + n];
      int rr = __builtin_amdgcn_cvt_pk_fp8_f32(g0, g1, 0, false);
      rr = __builtin_amdgcn_cvt_pk_fp8_f32(g2, g3, rr, true);
      *reinterpret_cast<unsigned*>(srow + 800) = (unsigned)rr;
    }
    if (sub == 3 && l >= 1 && l <= 7)
      *reinterpret_cast<unsigned*>(srow + 804 + (l - 1) * 4) = 0;
  }
}

// ------- generic fp8 MFMA GEMM: Cq[M,0:Nn] = A@B^T, fp8 out, 256x128 tile ----
__global__ __launch_bounds__(512, 4) void gemm_a8(
    const u8* __restrict__ A, int lda,
    const u8* __restrict__ B, int ldb,
    u8* __restrict__ Cq, int ldcb, int npad,
    int M, int Nn, int K, int gyr) {
  const int gx = gridDim.x;
  int lin = blockIdx.y * gx + blockIdx.x;
  int k8 = lin & 7, j = lin >> 3;
  int band = gridDim.y >> 3;
  int yy = j / gx, xx = j - yy * gx;
  int by = k8 * band + yy;
  if (by >= gyr) return;
  const int m0 = by * 256, n0 = xx * 128;

  __shared__ __align__(16) u8 As[3 * 8192];
  __shared__ __align__(16) u8 Bs[3 * 4096];
  const int tid = threadIdx.x;
  const int lane = tid & 63;
  const int w = tid >> 6;
  const int wr = w >> 1, wc = w & 1;
  const int fr = lane & 15;
  const int g = lane >> 4;

  const int rowA = tid >> 1;
  const int cA = (tid & 1) ^ ((rowA >> 2) & 1);
  int gaA = m0 + rowA; if (gaA >= M) gaA = M - 1;
  const u8* pa = A + (size_t)gaA * lda + cA * 16;
  u8* lA = &As[(size_t)(w * 64) * 16];
  const int sB = w * 32 + (lane & 31);
  const int rowB = sB >> 1;
  const int cB = (sB & 1) ^ ((rowB >> 2) & 1);
  int gbB = n0 + rowB; if (gbB >= Nn) gbB = Nn - 1;
  const u8* pb = B + (size_t)gbB * ldb + cB * 16;
  u8* lB = &Bs[(size_t)(w * 32) * 16];
  const bool doB = (lane < 32);

  const int rdoff = (((g >> 1) ^ ((fr >> 2) & 1)) << 4) + ((g & 1) << 3);

  f32x4 acc[4][4] = {};
  const int nt = K >> 5;
  const int ABUF = 8192, BBUF = 4096;

  gload16(pa, lA);
  if (doB) gload16(pb, lB);
  pa += 32; pb += 32;
  if (nt > 1) {
    gload16(pa, lA + ABUF);
    if (doB) gload16(pb, lB + BBUF);
    pa += 32; pb += 32;
  }

  for (int t = 0; t < nt; ++t) {
    if (t + 1 < nt) asm volatile("s_waitcnt vmcnt(2)" ::: "memory");
    else            asm volatile("s_waitcnt vmcnt(0)" ::: "memory");
    __builtin_amdgcn_s_barrier();
    if (t + 2 < nt) {
      int bi = (t + 2) % 3;
      gload16(pa, lA + bi * ABUF);
      if (doB) gload16(pb, lB + bi * BBUF);
      pa += 32; pb += 32;
    }
    int ca = (t % 3) * ABUF, cbb = (t % 3) * BBUF;
    long af[4], bfv[4];
#pragma unroll
    for (int i = 0; i < 4; ++i) {
      int row = wr * 64 + i * 16 + fr;
      af[i] = *reinterpret_cast<const long*>(&As[ca + row * 32 + rdoff]);
    }
#pragma unroll
    for (int jj = 0; jj < 4; ++jj) {
      int row = wc * 64 + jj * 16 + fr;
      bfv[jj] = *reinterpret_cast<const long*>(&Bs[cbb + row * 32 + rdoff]);
    }
    __builtin_amdgcn_s_setprio(1);
#pragma unroll
    for (int i = 0; i < 4; ++i)
#pragma unroll
      for (int jj = 0; jj < 4; ++jj)
        acc[i][jj] = __builtin_amdgcn_mfma_f32_16x16x32_fp8_fp8(af[i], bfv[jj], acc[i][jj], 0, 0, 0);
    __builtin_amdgcn_s_setprio(0);
  }

  const int er = (lane >> 4) * 4;
  const int ec = lane & 15;
#pragma unroll
  for (int i = 0; i < 4; ++i) {
#pragma unroll
    for (int jj = 0; jj < 4; ++jj) {
      int n = n0 + wc * 64 + jj * 16 + ec;
#pragma unroll
      for (int r = 0; r < 4; ++r) {
        int m = m0 + wr * 64 + i * 16 + er + r;
        if (m >= M) continue;
        if (n < Nn) Cq[(size_t)m * ldcb + n] = f2fp8(acc[i][jj][r]);
        else if (n < npad) Cq[(size_t)m * ldcb + n] = (u8)0;
      }
    }
  }
}

// ------- fp8 gates GEMM + fused GRU; A = [aq | hq] two-source, K=448 ------
__global__ __launch_bounds__(512, 4) void gemm_gru8(
    const u8* __restrict__ Aa, const u8* __restrict__ Ah,
    const u8* __restrict__ B, int ldb,
    int M, const float* __restrict__ bias,
    u16* __restrict__ hb, u8* __restrict__ hqout, int gyr) {
  const int gx = gridDim.x;
  int lin = blockIdx.y * gx + blockIdx.x;
  int k8 = lin & 7, j = lin >> 3;
  int band = gridDim.y >> 3;
  int yy = j / gx, xx = j - yy * gx;
  int by = k8 * band + yy;
  if (by >= gyr) return;
  const int m0 = by * 256, n0 = xx * 128;
  const int Nn = 800;

  __shared__ __align__(16) u8 SM8[73728];
  u8* As = SM8;
  u8* Bs = SM8 + 24576;
  const int tid = threadIdx.x;
  const int lane = tid & 63;
  const int w = tid >> 6;
  const int wr = w >> 1, wc = w & 1;
  const int fr = lane & 15;
  const int g = lane >> 4;

  const int rowA = tid >> 1;
  const int cA = (tid & 1) ^ ((rowA >> 2) & 1);
  int gaA = m0 + rowA; if (gaA >= M) gaA = M - 1;
  const u8* paA = Aa + (size_t)gaA * 224 + cA * 16;
  const u8* paH = Ah + (size_t)gaA * 224 + cA * 16;
  u8* lA = &As[(size_t)(w * 64) * 16];
  const int sB = w * 32 + (lane & 31);
  const int rowB = sB >> 1;
  const int cB = (sB & 1) ^ ((rowB >> 2) & 1);
  int gbB = n0 + rowB; if (gbB >= Nn) gbB = Nn - 1;
  const u8* pb = B + (size_t)gbB * ldb + cB * 16;
  u8* lB = &Bs[(size_t)(w * 32) * 16];
  const bool doB = (lane < 32);

  const int rdoff = (((g >> 1) ^ ((fr >> 2) & 1)) << 4) + ((g & 1) << 3);

  f32x4 acc[4][4] = {};
  const int nt = 14, kh = 7;
  const int ABUF = 8192, BBUF = 4096;

  gload16(paA, lA);
  if (doB) gload16(pb, lB);
  pb += 32;
  gload16(paA + 32, lA + ABUF);
  if (doB) gload16(pb, lB + BBUF);
  pb += 32;

  for (int t = 0; t < nt; ++t) {
    if (t + 1 < nt) asm volatile("s_waitcnt vmcnt(2)" ::: "memory");
    else            asm volatile("s_waitcnt vmcnt(0)" ::: "memory");
    __builtin_amdgcn_s_barrier();
    int tt = t + 2;
    if (tt < nt) {
      int bi = tt % 3;
      const u8* srcA = (tt < kh) ? (paA + tt * 32) : (paH + (tt - kh) * 32);
      gload16(srcA, lA + bi * ABUF);
      if (doB) gload16(pb, lB + bi * BBUF);
      pb += 32;
    }
    int ca = (t % 3) * ABUF, cbb = (t % 3) * BBUF;
    long af[4], bfv[4];
#pragma unroll
    for (int i = 0; i < 4; ++i) {
      int row = wr * 64 + i * 16 + fr;
      af[i] = *reinterpret_cast<const long*>(&As[ca + row * 32 + rdoff]);
    }
#pragma unroll
    for (int jj = 0; jj < 4; ++jj) {
      int row = wc * 64 + jj * 16 + fr;
      bfv[jj] = *reinterpret_cast<const long*>(&Bs[cbb + row * 32 + rdoff]);
    }
    __builtin_amdgcn_s_setprio(1);
#pragma unroll
    for (int i = 0; i < 4; ++i)
#pragma unroll
      for (int jj = 0; jj < 4; ++jj)
        acc[i][jj] = __builtin_amdgcn_mfma_f32_16x16x32_fp8_fp8(af[i], bfv[jj], acc[i][jj], 0, 0, 0);
    __builtin_amdgcn_s_setprio(0);
  }

  // ---- fused GRU epilogue (LDS stride 36 f32) ----
  const int er = (lane >> 4) * 4;
  const int ec = lane & 15;
  __syncthreads();
  float* ep = (float*)(SM8) + (size_t)w * 2304;

  for (int hh = 0; hh < 2; ++hh) {
#pragma unroll
    for (int jj2 = 0; jj2 < 2; ++jj2) {
      int jj = hh * 2 + jj2;
      int n = n0 + wc * 64 + jj * 16 + ec;
      float bv = (n < 800) ? bias[n] : 0.f;
#pragma unroll
      for (int i = 0; i < 4; ++i)
#pragma unroll
        for (int r = 0; r < 4; ++r) {
          int row_loc = i * 16 + er + r;
          ep[row_loc * 36 + jj2 * 16 + ec] = acc[i][jj][r] + bv;
        }
    }
    __syncthreads();
#pragma unroll
    for (int p = 0; p < 8; ++p) {
      int idx = p * 64 + lane;
      int row = idx >> 3, og = idx & 7;
      int n_base = n0 + wc * 64 + hh * 32 + og * 4;
      int m = m0 + wr * 64 + row;
      if (n_base < 800 && m < M) {
        f32x4 gv = *reinterpret_cast<f32x4*>(&ep[row * 36 + og * 4]);
        float rg = sigm(gv[0]);
        float zg = sigm(gv[1]);
        float x = gv[2] + rg * gv[3];
        float e2 = __expf(2.f * x);
        float nn = (e2 - 1.f) / (e2 + 1.f);
        int o = n_base >> 2;
        float hold = bf2f(hb[(size_t)m * 224 + o]);
        float hv = (1.f - zg) * nn + zg * hold;
        hb[(size_t)m * 224 + o] = f2bf(hv);
        hqout[(size_t)m * 224 + o] = f2fp8(hv);
      }
    }
    __syncthreads();
  }
}

// cmat8[n][352] fp8 = [hq(224) | feat(100) | 0(28)]
__global__ void cmat8_k(const u8* __restrict__ hq, const float* __restrict__ feat,
                        u8* __restrict__ c, int N) {
  int total = N * 352;
  for (int i = blockIdx.x * blockDim.x + threadIdx.x; i < total; i += blockDim.x * gridDim.x) {
    int n = i / 352, j = i - n * 352;
    u8 v;
    if (j < 224) v = hq[(size_t)n * 224 + j];
    else { int f = j - 224; v = (f < 100) ? f2fp8(feat[(size_t)n * 100 + f]) : (u8)0; }
    c[i] = v;
  }
}

// per-channel stats over fp8 X [L,C]
__global__ __launch_bounds__(1024) void bn_stats8_k(const u8* __restrict__ X, int L, int C,
                                                    float* __restrict__ stats) {
  const int Q = 1024 / C;
  const int T = Q * C;
  const int tid = threadIdx.x;
  float s = 0.f, q = 0.f;
  int c = 0;
  if (tid < T) {
    int qi = tid / C; c = tid - qi * C;
    for (size_t r = (size_t)blockIdx.x * Q + qi; r < (size_t)L; r += (size_t)gridDim.x * Q) {
      float v = fp82f(X[r * C + c]);
      s += v; q += v * v;
    }
  }
  __shared__ float sb[304], qb[304];
  for (int cc = tid; cc < C; cc += 1024) { sb[cc] = 0.f; qb[cc] = 0.f; }
  __syncthreads();
  if (tid < T) { atomicAdd(&sb[c], s); atomicAdd(&qb[c], q); }
  __syncthreads();
  for (int cc = tid; cc < C; cc += 1024) {
    atomicAdd(&stats[cc], sb[cc]);
    atomicAdd(&stats[C + cc], qb[cc]);
  }
}

__global__ void bn_fin_k(const float* __restrict__ stats, const float* __restrict__ g,
                         const float* __restrict__ b, int C, float Linv,
                         float* __restrict__ scsh) {
  int c = blockIdx.x * blockDim.x + threadIdx.x;
  if (c < C) {
    float mean = stats[c] * Linv;
    float var = stats[C + c] * Linv - mean * mean;
    float sc = g[c] * rsqrtf(var + 1e-5f);
    scsh[c] = sc;
    scsh[C + c] = b[c] - mean * sc;
  }
}

// fused bn+relu+maxpool: fp8 in -> fp8 out (padded to Cpad)
__global__ void pool_q8_k(const u8* __restrict__ X, int C, const float* __restrict__ scsh,
                          int kw, int stride, u8* __restrict__ Y, int Cpad, int Lout) {
  int total = Lout * Cpad;
  for (int i = blockIdx.x * blockDim.x + threadIdx.x; i < total; i += blockDim.x * gridDim.x) {
    int lp = i / Cpad, c = i - lp * Cpad;
    if (c >= C) { Y[i] = (u8)0; continue; }
    float sc = scsh[c], sh = scsh[C + c];
    int l0 = lp * stride;
    float m = 0.f;
    for (int wq = 0; wq < kw; ++wq)
      m = fmaxf(m, fmaf(fp82f(X[(size_t)(l0 + wq) * C + c]), sc, sh));
    Y[i] = f2fp8(m);
  }
}

// fused bn+relu+maxpool: fp8 in -> f32 out
__global__ void pool_f328_k(const u8* __restrict__ X, int C, const float* __restrict__ scsh,
                            int kw, int stride, float* __restrict__ Y, int Lout) {
  int total = Lout * C;
  for (int i = blockIdx.x * blockDim.x + threadIdx.x; i < total; i += blockDim.x * gridDim.x) {
    int lp = i / C, c = i - lp * C;
    float sc = scsh[c], sh = scsh[C + c];
    int l0 = lp * stride;
    float m = 0.f;
    for (int wq = 0; wq < kw; ++wq)
      m = fmaxf(m, fmaf(fp82f(X[(size_t)(l0 + wq) * C + c]), sc, sh));
    Y[i] = m;
  }
}

__global__ __launch_bounds__(256) void final_dot_k(
    const float* __restrict__ Y2, const float* __restrict__ Z2,
    const float* __restrict__ wy, const float* __restrict__ by,
    const float* __restrict__ wz, const float* __restrict__ bz,
    float* __restrict__ acc, int L) {
  float s0 = 0.f, s1 = 0.f;
  for (int lp = blockIdx.x * blockDim.x + threadIdx.x; lp < L; lp += blockDim.x * gridDim.x) {
    const float* y = Y2 + (size_t)lp * 200;
    const float* z = Z2 + (size_t)lp * 300;
    float d0 = 0.f, d1 = 0.f;
    for (int k = 0; k < 200; ++k) { float v = y[k]; d0 += v * wy[k]; d1 += v * wy[200 + k]; }
    float e0 = 0.f, e1 = 0.f;
    for (int k = 0; k < 300; ++k) { float v = z[k]; e0 += v * wz[k]; e1 += v * wz[300 + k]; }
    s0 += (d0 + by[0]) * (e0 + bz[0]);
    s1 += (d1 + by[1]) * (e1 + bz[1]);
  }
  __shared__ float r0[256], r1[256];
  r0[threadIdx.x] = s0; r1[threadIdx.x] = s1;
  __syncthreads();
  for (int off = 128; off > 0; off >>= 1) {
    if (threadIdx.x < off) { r0[threadIdx.x] += r0[threadIdx.x + off]; r1[threadIdx.x] += r1[threadIdx.x + off]; }
    __syncthreads();
  }
  if (threadIdx.x == 0) { atomicAdd(&acc[0], r0[0]); atomicAdd(&acc[1], r1[0]); }
}

__global__ void final_out_k(const float* __restrict__ acc, float invL, float* __restrict__ out) {
  int j = threadIdx.x;
  if (j < 2) out[j] = 1.f / (1.f + expf(-acc[j] * invL));
}

// ---------------- host ----------------

static inline void gemm8(hipStream_t st, const u8* A, int lda, const u8* B, int ldb,
                         u8* Cq, int ldcb, int npad, int M, int Nn, int K) {
  int ncols = (npad > Nn) ? npad : Nn;
  int gx = (ncols + 127) / 128;
  int gy = (M + 255) / 256;
  int gyp = ((gy + 7) / 8) * 8;
  dim3 g(gx, gyp);
  gemm_a8<<<g, 512, 0, st>>>(A, lda, B, ldb, Cq, ldcb, npad, M, Nn, K, gy);
}

extern "C" void kernel_launch(void* const* d_in, const int* in_sizes, int n_in,
                              void* d_out, int out_size, void* d_ws, size_t ws_size,
                              hipStream_t stream) {
  (void)n_in; (void)out_size;
  const float* feat    = (const float*)d_in[0];
  const int*   eix     = (const int*)d_in[1];
  const int*   etyp    = (const int*)d_in[2];
  const float* ggnnW   = (const float*)d_in[3];
  const float* ggnnB   = (const float*)d_in[4];
  const float* Wih     = (const float*)d_in[5];
  const float* Whh     = (const float*)d_in[6];
  const float* bih     = (const float*)d_in[7];
  const float* bhh     = (const float*)d_in[8];
  const float* conv1w  = (const float*)d_in[9];
  const float* conv2w  = (const float*)d_in[11];
  const float* convc1w = (const float*)d_in[13];
  const float* convc2w = (const float*)d_in[15];
  const float* bnyg    = (const float*)d_in[17];
  const float* bnyb    = (const float*)d_in[18];
  const float* bncg    = (const float*)d_in[19];
  const float* bncb    = (const float*)d_in[20];
  const float* mlpyw   = (const float*)d_in[21];
  const float* mlpyb   = (const float*)d_in[22];
  const float* mlpzw   = (const float*)d_in[23];
  const float* mlpzb   = (const float*)d_in[24];

  const int N = in_sizes[0] / 100;
  const int E = in_sizes[2];
  const int* src = eix;
  const int* dst = eix + E;

  char* base = (char*)d_ws;
  const size_t HB_B  = (size_t)N * 224 * 2;
  const size_t Q_B   = (size_t)N * 224;
  const int CH = (N + 1) / 2;
  const size_t SCR_B = (size_t)CH * 1664;

  u16* hb  = (u16*)base;
  u8*  aq  = (u8*)(base + HB_B);
  u8*  hq0 = aq + Q_B;
  u8*  hq1 = hq0 + Q_B;
  char* R1 = (char*)(hq1 + Q_B);
  char* WREG = R1 + SCR_B;

  u8*  Wcat8 = (u8*)WREG;                    // 166400
  u8*  Wall8 = Wcat8 + 166400;               // 358400
  u8*  w1c8  = Wall8 + 358400;               // 211200
  u8*  c2b8  = w1c8 + 211200;                // 44800
  u8*  wc18  = c2b8 + 44800;                 // 316800
  u8*  wc28  = wc18 + 316800;                // 96000
  float* ball  = (float*)(((uintptr_t)(wc28 + 96000) + 255) & ~(uintptr_t)255);
  float* stats = ball + 832;
  float* scsh  = stats + 600;
  float* acc2  = scsh + 600;
  int* deg_et = (int*)(acc2 + 8);
  int* off_et = deg_et + 4 * (size_t)N;
  int* cursor = off_et + 4 * (size_t)N;
  int* esrc   = cursor + 4 * (size_t)N;
  int* bsum   = esrc + E;
  const int L4 = 4 * N;
  const int NB = (L4 + 1023) / 1024;
  size_t need = (size_t)((char*)(bsum + NB) - base);

  if (ws_size < need) {
    fail_k<<<1, 64, 0, stream>>>((float*)d_out, -(float)(ws_size >> 20));
    return;
  }

  // ---- CSR build + packs ----
  hipMemsetAsync(deg_et, 0, sizeof(int) * 4 * (size_t)N, stream);
  init_hb_k<<<2048, 256, 0, stream>>>(feat, hb, N);
  init_hq_k<<<2048, 256, 0, stream>>>(feat, hq0, N);
  count_deg_k<<<2048, 256, 0, stream>>>(dst, etyp, deg_et, N, E);
  bsum_k<<<NB, 1024, 0, stream>>>(deg_et, bsum, L4);
  scanb_k<<<1, 1024, 0, stream>>>(bsum, NB);
  scan_fin_k<<<NB, 1024, 0, stream>>>(deg_et, bsum, off_et, L4);
  copy_int_k<<<512, 256, 0, stream>>>(off_et, cursor, L4);
  fill_src_k<<<2048, 256, 0, stream>>>(src, dst, etyp, cursor, esrc, N, E);
  pack_wcat8_k<<<651, 256, 0, stream>>>(ggnnW, ggnnB, Wcat8);
  pack_wall8_k<<<1400, 256, 0, stream>>>(Wih, Whh, Wall8);
  ball_i_k<<<4, 256, 0, stream>>>(bih, bhh, ball);
  pack_w1c8_k<<<825, 256, 0, stream>>>(conv1w, w1c8);
  pack_lin8_k<<<175, 256, 0, stream>>>(conv2w, c2b8, 200, 200, 224);
  pack_wc18_k<<<1238, 256, 0, stream>>>(convc1w, wc18);
  pack_lin8_k<<<375, 256, 0, stream>>>(convc2w, wc28, 300, 300, 320);

  // ---- GGNN 8 steps (ping-pong h tables) ----
  u8* scat8 = (u8*)R1;

  const int gy = (N + 255) / 256;
  const int gyp = ((gy + 7) / 8) * 8;

  u8* hqA = hq0;
  u8* hqB = hq1;
  for (int step = 0; step < 8; ++step) {
    agg8_k<<<4096, 256, 0, stream>>>(off_et, deg_et, esrc, hqA, scat8, N);
    gemm_a8<<<dim3(2, gyp), 512, 0, stream>>>(scat8, 832, Wcat8, 832,
                                              aq, 224, 224, N, 200, 832, gy);
    gemm_gru8<<<dim3(7, gyp), 512, 0, stream>>>(aq, hqA, Wall8, 448, N, ball,
                                                hb, hqB, gy);
    u8* t = hqA; hqA = hqB; hqB = t;
  }

  // ---- conv paths (all fp8 via gemm_a8) ----
  const int L1 = N - 2;
  const int L2 = (L1 - 3) / 2 + 1;
  const int L3 = (L2 - 2) / 2 + 1;

  u8* cmat8 = (u8*)R1;                                      // N*352 (35 MB, R1=83MB)
  u8* out1q = (u8*)base;                                    // L1*200 (20 MB; hb dead)
  u8* y1q   = (u8*)base + 20500000;                         // L2*224 (11.2 MB)
  u8* out2q = (u8*)base + 32000000;                         // L2*200 (10 MB)
  float* Y2f = (float*)aq;                                  // L3*200*4 = 20 MB (aq dead)
  u8* outc1q = hq0;                                         // L1*300 (30 MB; hq dead after cmat8)
  u8* z1q    = (u8*)R1 + 37000000;                          // L2*320 (16 MB; after cmat8)
  u8* outc2q = (u8*)R1 + 54000000;                          // L2*300 (15 MB)
  float* Z2f = (float*)base;                                // L3*300*4 = 30 MB (Y bufs dead)

  cmat8_k<<<4096, 256, 0, stream>>>(hqA, feat, cmat8, N);

  // Y path
  gemm8(stream, cmat8, 352, w1c8, 1056, out1q, 200, 200, L1, 200, 1056);
  hipMemsetAsync(stats, 0, sizeof(float) * 400, stream);
  bn_stats8_k<<<512, 1024, 0, stream>>>(out1q, L1, 200, stats);
  bn_fin_k<<<2, 256, 0, stream>>>(stats, bnyg, bnyb, 200, 1.f / (float)L1, scsh);
  pool_q8_k<<<2048, 256, 0, stream>>>(out1q, 200, scsh, 3, 2, y1q, 224, L2);

  gemm8(stream, y1q, 224, c2b8, 224, out2q, 200, 200, L2, 200, 224);
  hipMemsetAsync(stats, 0, sizeof(float) * 400, stream);
  bn_stats8_k<<<512, 1024, 0, stream>>>(out2q, L2, 200, stats);
  bn_fin_k<<<2, 256, 0, stream>>>(stats, bnyg, bnyb, 200, 1.f / (float)L2, scsh);
  pool_f328_k<<<2048, 256, 0, stream>>>(out2q, 200, scsh, 2, 2, Y2f, L3);

  // Z path
  gemm8(stream, cmat8, 352, wc18, 1056, outc1q, 300, 300, L1, 300, 1056);
  hipMemsetAsync(stats, 0, sizeof(float) * 600, stream);
  bn_stats8_k<<<512, 1024, 0, stream>>>(outc1q, L1, 300, stats);
  bn_fin_k<<<2, 256, 0, stream>>>(stats, bncg, bncb, 300, 1.f / (float)L1, scsh);
  pool_q8_k<<<2048, 256, 0, stream>>>(outc1q, 300, scsh, 3, 2, z1q, 320, L2);

  gemm8(stream, z1q, 320, wc28, 320, outc2q, 300, 300, L2, 300, 320);
  hipMemsetAsync(stats, 0, sizeof(float) * 600, stream);
  bn_stats8_k<<<512, 1024, 0, stream>>>(outc2q, L2, 300, stats);
  bn_fin_k<<<2, 256, 0, stream>>>(stats, bncg, bncb, 300, 1.f / (float)L2, scsh);
  pool_f328_k<<<2048, 256, 0, stream>>>(outc2q, 300, scsh, 2, 2, Z2f, L3);

  // ---- final MLP product + mean + sigmoid ----
  hipMemsetAsync(acc2, 0, sizeof(float) * 2, stream);
  final_dot_k<<<256, 256, 0, stream>>>(Y2f, Z2f, mlpyw, mlpyb, mlpzw, mlpzb, acc2, L3);
  final_out_k<<<1, 64, 0, stream>>>(acc2, 1.f / (float)L3, (float*)d_out);
}